// Round 1
// baseline (3753.920 us; speedup 1.0000x reference)
//
#include <hip/hip_runtime.h>
#include <hip/hip_bf16.h>
#include <math.h>

// ---- model constants ----
constexpr int Bb = 4, Ls = 1024, DM = 512, DI = 1024, NH = 16, HD = 64, DS = 64;
constexpr int CDIM = DI + 2 * DS;         // 1152
constexpr int DIP  = 2 * DI + 2 * DS + NH; // 2192
constexpr float EPSf = 1e-5f;
constexpr int TOK = Bb * Ls;              // 4096

#define DEVI __device__ __forceinline__

DEVI float wsum(float v) {
#pragma unroll
  for (int o = 32; o > 0; o >>= 1) v += __shfl_xor(v, o);
  return v;
}
DEVI float sigmoidf_(float x) { return 1.f / (1.f + __expf(-x)); }

DEVI void ld8(const float* __restrict__ p, int lane, float (&x)[8]) {
  float4 a = *(const float4*)(p + lane * 4);
  float4 b = *(const float4*)(p + 256 + lane * 4);
  x[0] = a.x; x[1] = a.y; x[2] = a.z; x[3] = a.w;
  x[4] = b.x; x[5] = b.y; x[6] = b.z; x[7] = b.w;
}
DEVI void st8(float* __restrict__ p, int lane, const float (&x)[8]) {
  float4 a = make_float4(x[0], x[1], x[2], x[3]);
  float4 b = make_float4(x[4], x[5], x[6], x[7]);
  *(float4*)(p + lane * 4) = a;
  *(float4*)(p + 256 + lane * 4) = b;
}
// wave-level LN over 512 (8 elems/lane), in-place on regs
DEVI void norm8(float (&x)[8]) {
  float s = 0;
#pragma unroll
  for (int j = 0; j < 8; ++j) s += x[j];
  float mean = wsum(s) * (1.f / 512.f);
#pragma unroll
  for (int j = 0; j < 8; ++j) x[j] -= mean;
  float q = 0;
#pragma unroll
  for (int j = 0; j < 8; ++j) q += x[j] * x[j];
  float var = wsum(q) * (1.f / 512.f);
  float inv = rsqrtf(var + EPSf);
#pragma unroll
  for (int j = 0; j < 8; ++j) x[j] *= inv;
}

// ---- embedding + value-encoder stage 1 ----
__global__ __launch_bounds__(256) void k_embed(const int* __restrict__ src, const float* __restrict__ values,
    const float* __restrict__ embed, const float* __restrict__ gg, const float* __restrict__ gb,
    const float* __restrict__ vw1, const float* __restrict__ vb1,
    float* __restrict__ hbuf, float* __restrict__ v1buf) {
  int gw = (blockIdx.x * 256 + threadIdx.x) >> 6;
  int lane = threadIdx.x & 63;
  if (gw >= TOK) return;
  const float* er = embed + (size_t)src[gw] * DM;
  float x[8];
  ld8(er, lane, x);
  norm8(x);
  float g[8], bv[8];
  ld8(gg, lane, g); ld8(gb, lane, bv);
#pragma unroll
  for (int j = 0; j < 8; ++j) x[j] = x[j] * g[j] + bv[j];
  st8(hbuf + (size_t)gw * DM, lane, x);
  float val = fminf(values[gw], 512.f);
  float w1[8], b1[8];
  ld8(vw1, lane, w1); ld8(vb1, lane, b1);
  float v[8];
#pragma unroll
  for (int j = 0; j < 8; ++j) v[j] = fmaxf(val * w1[j] + b1[j], 0.f);
  st8(v1buf + (size_t)gw * DM, lane, v);
}

// h = (h + LN(t2)*g+b) * (mask?0:1)
__global__ __launch_bounds__(256) void k_haddv(const float* __restrict__ t2, const float* __restrict__ g,
    const float* __restrict__ bb, const unsigned char* __restrict__ mask, float* __restrict__ hbuf) {
  int gw = (blockIdx.x * 256 + threadIdx.x) >> 6;
  int lane = threadIdx.x & 63;
  if (gw >= TOK) return;
  float x[8];
  ld8(t2 + (size_t)gw * DM, lane, x);
  norm8(x);
  float gv[8], bv[8], h[8];
  ld8(g, lane, gv); ld8(bb, lane, bv);
  ld8(hbuf + (size_t)gw * DM, lane, h);
  float mf = mask[gw] ? 0.f : 1.f;
#pragma unroll
  for (int j = 0; j < 8; ++j) h[j] = (h[j] + x[j] * gv[j] + bv[j]) * mf;
  st8(hbuf + (size_t)gw * DM, lane, h);
}

// dst = LN(src), no affine
__global__ __launch_bounds__(256) void k_ln512(const float* __restrict__ src, float* __restrict__ dst) {
  int gw = (blockIdx.x * 256 + threadIdx.x) >> 6;
  int lane = threadIdx.x & 63;
  if (gw >= TOK) return;
  float x[8];
  ld8(src + (size_t)gw * DM, lane, x);
  norm8(x);
  st8(dst + (size_t)gw * DM, lane, x);
}

// h = LN((f+r)/2), no affine
__global__ __launch_bounds__(256) void k_comb(const float* __restrict__ f, const float* __restrict__ r,
                                              float* __restrict__ dst) {
  int gw = (blockIdx.x * 256 + threadIdx.x) >> 6;
  int lane = threadIdx.x & 63;
  if (gw >= TOK) return;
  float x[8], y[8];
  ld8(f + (size_t)gw * DM, lane, x);
  ld8(r + (size_t)gw * DM, lane, y);
#pragma unroll
  for (int j = 0; j < 8; ++j) x[j] = 0.5f * (x[j] + y[j]);
  norm8(x);
  st8(dst + (size_t)gw * DM, lane, x);
}

// ---- generic fp32 GEMM: C[M,N] = A[M,K] @ W[N,K]^T (+bias, act) ----
// ACT: 0 none, 1 relu, 2 leaky(0.01)
template <int ACT>
__global__ __launch_bounds__(256) void gemm_nt(const float* __restrict__ A, const float* __restrict__ W,
    const float* __restrict__ bias, float* __restrict__ C, int M, int N, int K) {
  constexpr int BM = 128, BN = 128, BK = 32;
  __shared__ float As[BK][BM + 4];
  __shared__ float Ws[BK][BN + 4];
  int tid = threadIdx.x;
  int bm = blockIdx.y * BM, bn = blockIdx.x * BN;
  int ty = tid >> 4, tx = tid & 15;
  float acc[8][8] = {};
  int lr = tid >> 3;
  int lk = (tid & 7) * 4;
  for (int k0 = 0; k0 < K; k0 += BK) {
#pragma unroll
    for (int q = 0; q < 4; ++q) {
      int row = lr + q * 32;
      float4 a = make_float4(0, 0, 0, 0);
      int gm = bm + row;
      if (gm < M) a = *(const float4*)(A + (size_t)gm * K + k0 + lk);
      As[lk + 0][row] = a.x; As[lk + 1][row] = a.y; As[lk + 2][row] = a.z; As[lk + 3][row] = a.w;
      float4 w = make_float4(0, 0, 0, 0);
      int gn = bn + row;
      if (gn < N) w = *(const float4*)(W + (size_t)gn * K + k0 + lk);
      Ws[lk + 0][row] = w.x; Ws[lk + 1][row] = w.y; Ws[lk + 2][row] = w.z; Ws[lk + 3][row] = w.w;
    }
    __syncthreads();
#pragma unroll 8
    for (int k = 0; k < BK; ++k) {
      float4 a0 = *(const float4*)&As[k][ty * 8];
      float4 a1 = *(const float4*)&As[k][ty * 8 + 4];
      float4 w0 = *(const float4*)&Ws[k][tx * 8];
      float4 w1 = *(const float4*)&Ws[k][tx * 8 + 4];
      float av[8] = {a0.x, a0.y, a0.z, a0.w, a1.x, a1.y, a1.z, a1.w};
      float wv[8] = {w0.x, w0.y, w0.z, w0.w, w1.x, w1.y, w1.z, w1.w};
#pragma unroll
      for (int i = 0; i < 8; ++i)
#pragma unroll
        for (int j = 0; j < 8; ++j) acc[i][j] = fmaf(av[i], wv[j], acc[i][j]);
    }
    __syncthreads();
  }
#pragma unroll
  for (int i = 0; i < 8; ++i) {
    int m = bm + ty * 8 + i;
    if (m >= M) continue;
#pragma unroll
    for (int j = 0; j < 8; ++j) {
      int n = bn + tx * 8 + j;
      if (n >= N) continue;
      float v = acc[i][j];
      if (bias) v += bias[n];
      if (ACT == 1) v = fmaxf(v, 0.f);
      if (ACT == 2) v = v > 0.f ? v : 0.01f * v;
      C[(size_t)m * N + n] = v;
    }
  }
}

// ---- depthwise causal conv (k=4) + silu on xBC slice of zx ----
__global__ __launch_bounds__(256) void k_conv(const float* __restrict__ zx, const float* __restrict__ cw,
                                              const float* __restrict__ cb, float* __restrict__ xbca) {
  int idx = blockIdx.x * 256 + threadIdx.x;
  if (idx >= TOK * CDIM) return;
  int c = idx % CDIM;
  int bt = idx / CDIM;
  int t = bt & (Ls - 1);
  int b = bt >> 10;
  const float* col = zx + (size_t)(b * Ls) * DIP + DI + c;
  float4 w = *(const float4*)(cw + c * 4);
  float s = cb[c];
  if (t >= 3) {
    s += w.x * col[(size_t)(t - 3) * DIP] + w.y * col[(size_t)(t - 2) * DIP] +
         w.z * col[(size_t)(t - 1) * DIP] + w.w * col[(size_t)t * DIP];
  } else {
    float wk[4] = {w.x, w.y, w.z, w.w};
#pragma unroll
    for (int k = 0; k < 4; ++k) {
      int tt = t - 3 + k;
      if (tt >= 0) s += wk[k] * col[(size_t)tt * DIP];
    }
  }
  xbca[idx] = s * sigmoidf_(s);
}

// ---- dt = softplus(raw + bias), dA = exp(-exp(Alog)*dt) ----
__global__ __launch_bounds__(256) void k_dtda(const float* __restrict__ zx, const float* __restrict__ dtbias,
    const float* __restrict__ Alog, float* __restrict__ dt, float* __restrict__ dA) {
  int i = blockIdx.x * 256 + threadIdx.x;
  if (i >= TOK * NH) return;
  int hh = i & 15;
  int bt = i >> 4;
  float raw = zx[(size_t)bt * DIP + 2 * DI + 2 * DS + hh] + dtbias[hh];
  float d = raw > 20.f ? raw : log1pf(__expf(raw));
  dt[i] = d;
  dA[i] = __expf(-__expf(Alog[hh]) * d);
}

// ---- sequential SSM scan. block = 1 wave; grid = B*NH*4 (p-groups of 16) ----
__global__ __launch_bounds__(64) void k_scan(const float* __restrict__ xbca, const float* __restrict__ dtb,
    const float* __restrict__ dAb, const float* __restrict__ Dk, float* __restrict__ y) {
  int blk = blockIdx.x;
  int pg = blk & 3;
  int bh = blk >> 2;
  int hh = bh & (NH - 1);
  int b = bh >> 4;
  int tid = threadIdx.x;
  int lp = tid >> 2;
  int nc = tid & 3;
  int p = pg * 16 + lp;
  int n0 = nc * 16;
  const float* base = xbca + (size_t)b * Ls * CDIM;
  const float* xp = base + hh * HD + p;
  const float* Bp = base + DI + n0;
  const float* Cp = base + DI + DS + n0;
  const float* dtp = dtb + (size_t)b * Ls * NH + hh;
  const float* dAp = dAb + (size_t)b * Ls * NH + hh;
  float Dh = Dk[hh];
  float* yp = y + (size_t)b * Ls * DI + hh * HD + p;

  float s[16];
#pragma unroll
  for (int j = 0; j < 16; ++j) s[j] = 0.f;

  float4 Bv[4], Cv[4];
  float xv, dtv, dAv;
#pragma unroll
  for (int q = 0; q < 4; ++q) {
    Bv[q] = *(const float4*)(Bp + q * 4);
    Cv[q] = *(const float4*)(Cp + q * 4);
  }
  xv = *xp; dtv = *dtp; dAv = *dAp;

  for (int t = 0; t < Ls; ++t) {
    float4 Bc[4], Cc[4];
    float xc = xv, dtc = dtv, dAc = dAv;
#pragma unroll
    for (int q = 0; q < 4; ++q) { Bc[q] = Bv[q]; Cc[q] = Cv[q]; }
    if (t + 1 < Ls) {
      const float* rB = Bp + (size_t)(t + 1) * CDIM;
      const float* rC = Cp + (size_t)(t + 1) * CDIM;
#pragma unroll
      for (int q = 0; q < 4; ++q) {
        Bv[q] = *(const float4*)(rB + q * 4);
        Cv[q] = *(const float4*)(rC + q * 4);
      }
      xv = xp[(size_t)(t + 1) * CDIM];
      dtv = dtp[(size_t)(t + 1) * NH];
      dAv = dAp[(size_t)(t + 1) * NH];
    }
    float w = dtc * xc;
    float acc = 0.f;
#pragma unroll
    for (int q = 0; q < 4; ++q) {
      s[4 * q + 0] = fmaf(s[4 * q + 0], dAc, w * Bc[q].x); acc = fmaf(s[4 * q + 0], Cc[q].x, acc);
      s[4 * q + 1] = fmaf(s[4 * q + 1], dAc, w * Bc[q].y); acc = fmaf(s[4 * q + 1], Cc[q].y, acc);
      s[4 * q + 2] = fmaf(s[4 * q + 2], dAc, w * Bc[q].z); acc = fmaf(s[4 * q + 2], Cc[q].z, acc);
      s[4 * q + 3] = fmaf(s[4 * q + 3], dAc, w * Bc[q].w); acc = fmaf(s[4 * q + 3], Cc[q].w, acc);
    }
    acc += __shfl_xor(acc, 1);
    acc += __shfl_xor(acc, 2);
    if (nc == 0) yp[(size_t)t * DI] = fmaf(Dh, xc, acc);
  }
}

// ---- y = y*silu(z); y = y*rsqrt(mean(y^2)+eps)*nw ---- (row width 1024)
__global__ __launch_bounds__(256) void k_gaterms(float* __restrict__ y, const float* __restrict__ zx,
                                                 const float* __restrict__ nw) {
  int gw = (blockIdx.x * 256 + threadIdx.x) >> 6;
  int lane = threadIdx.x & 63;
  if (gw >= TOK) return;
  float* yr = y + (size_t)gw * DI;
  const float* zr = zx + (size_t)gw * DIP;
  float g[16];
  float ss = 0.f;
#pragma unroll
  for (int q = 0; q < 4; ++q) {
    float4 yv = *(const float4*)(yr + lane * 4 + q * 256);
    float4 zv = *(const float4*)(zr + lane * 4 + q * 256);
    g[4 * q + 0] = yv.x * zv.x * sigmoidf_(zv.x);
    g[4 * q + 1] = yv.y * zv.y * sigmoidf_(zv.y);
    g[4 * q + 2] = yv.z * zv.z * sigmoidf_(zv.z);
    g[4 * q + 3] = yv.w * zv.w * sigmoidf_(zv.w);
#pragma unroll
    for (int j = 0; j < 4; ++j) ss += g[4 * q + j] * g[4 * q + j];
  }
  ss = wsum(ss);
  float sc = rsqrtf(ss * (1.f / (float)DI) + EPSf);
#pragma unroll
  for (int q = 0; q < 4; ++q) {
    float4 nv = *(const float4*)(nw + lane * 4 + q * 256);
    float4 o;
    o.x = g[4 * q + 0] * sc * nv.x;
    o.y = g[4 * q + 1] * sc * nv.y;
    o.z = g[4 * q + 2] * sc * nv.z;
    o.w = g[4 * q + 3] * sc * nv.w;
    *(float4*)(yr + lane * 4 + q * 256) = o;
  }
}

// ---- lengths = sum(!mask) per batch ----
__global__ __launch_bounds__(256) void k_lengths(const unsigned char* __restrict__ mask, int* __restrict__ len) {
  int b = blockIdx.x;
  int tid = threadIdx.x;
  int cnt = 0;
  for (int t = tid; t < Ls; t += 256) cnt += mask[b * Ls + t] ? 0 : 1;
#pragma unroll
  for (int o = 32; o > 0; o >>= 1) cnt += __shfl_xor(cnt, o);
  __shared__ int red[4];
  if ((tid & 63) == 0) red[tid >> 6] = cnt;
  __syncthreads();
  if (tid == 0) len[b] = red[0] + red[1] + red[2] + red[3];
}

// ---- in-place smart flip (involution) of [B,Ls,Wd] ----
__global__ __launch_bounds__(256) void k_flip(float* __restrict__ buf, const int* __restrict__ len, int Wd) {
  int idx = blockIdx.x * 256 + threadIdx.x;
  int nc4 = Wd >> 2;
  int total = TOK * nc4;
  if (idx >= total) return;
  int c4 = idx % nc4;
  int bt = idx / nc4;
  int t = bt & (Ls - 1);
  int b = bt >> 10;
  int ln = len[b];
  int pos = (t < ln) ? (ln - 1 - t) : t;
  if (t < pos) {
    float4* p0 = (float4*)(buf + ((size_t)b * Ls + t) * Wd) + c4;
    float4* p1 = (float4*)(buf + ((size_t)b * Ls + pos) * Wd) + c4;
    float4 a = *p0, bv = *p1;
    *p0 = bv;
    *p1 = a;
  }
}

// ---- mlm head: dot(row, w3)+b3 ----
__global__ __launch_bounds__(256) void k_mlm(const float* __restrict__ e2, const float* __restrict__ w3,
                                             const float* __restrict__ b3, float* __restrict__ out) {
  int gw = (blockIdx.x * 256 + threadIdx.x) >> 6;
  int lane = threadIdx.x & 63;
  if (gw >= TOK) return;
  float x[8], w[8];
  ld8(e2 + (size_t)gw * DM, lane, x);
  ld8(w3, lane, w);
  float s = 0;
#pragma unroll
  for (int j = 0; j < 8; ++j) s += x[j] * w[j];
  s = wsum(s);
  if (lane == 0) out[gw] = s + b3[0];
}

__global__ __launch_bounds__(256) void k_cell(const float* __restrict__ h, float* __restrict__ out) {
  int i = blockIdx.x * 256 + threadIdx.x;
  if (i >= Bb * DM) return;
  int b = i >> 9, c = i & 511;
  out[i] = h[(size_t)b * Ls * DM + c];
}

// ---- classifier head: 2x (matvec+relu+LN affine) + final matvec; 1 block per batch ----
__global__ __launch_bounds__(256) void k_cls(const float* __restrict__ h,
    const float* __restrict__ w1, const float* __restrict__ b1, const float* __restrict__ g1, const float* __restrict__ bb1,
    const float* __restrict__ w2, const float* __restrict__ b2, const float* __restrict__ g2, const float* __restrict__ bb2,
    const float* __restrict__ wo, const float* __restrict__ bo, float* __restrict__ out) {
  __shared__ float xb[512];
  __shared__ float cc[512];
  __shared__ float red[4];
  int b = blockIdx.x, tid = threadIdx.x;
  const float* cell = h + (size_t)b * Ls * DM;
  xb[tid] = cell[tid];
  xb[tid + 256] = cell[tid + 256];
  __syncthreads();

  for (int pass = 0; pass < 2; ++pass) {
    const float* W = pass ? w2 : w1;
    const float* bias = pass ? b2 : b1;
    const float* g = pass ? g2 : g1;
    const float* bt = pass ? bb2 : bb1;
#pragma unroll 1
    for (int jj = 0; jj < 2; ++jj) {
      int j = tid + jj * 256;
      const float* wr = W + (size_t)j * DM;
      float sum = bias[j];
      for (int k = 0; k < DM; k += 4) {
        float4 wv = *(const float4*)(wr + k);
        sum += wv.x * xb[k] + wv.y * xb[k + 1] + wv.z * xb[k + 2] + wv.w * xb[k + 3];
      }
      cc[j] = fmaxf(sum, 0.f);
    }
    __syncthreads();
    float v0 = cc[tid], v1 = cc[tid + 256];
    float s = wsum(v0 + v1);
    if ((tid & 63) == 0) red[tid >> 6] = s;
    __syncthreads();
    float mean = (red[0] + red[1] + red[2] + red[3]) * (1.f / 512.f);
    __syncthreads();
    float d0 = v0 - mean, d1 = v1 - mean;
    float q = wsum(d0 * d0 + d1 * d1);
    if ((tid & 63) == 0) red[tid >> 6] = q;
    __syncthreads();
    float var = (red[0] + red[1] + red[2] + red[3]) * (1.f / 512.f);
    float inv = rsqrtf(var + EPSf);
    xb[tid] = d0 * inv * g[tid] + bt[tid];
    xb[tid + 256] = d1 * inv * g[tid + 256] + bt[tid + 256];
    __syncthreads();
  }
  if (tid < 164) {
    const float* wr = wo + (size_t)tid * DM;
    float sum = bo[tid];
    for (int k = 0; k < DM; k += 4) {
      float4 wv = *(const float4*)(wr + k);
      sum += wv.x * xb[k] + wv.y * xb[k + 1] + wv.z * xb[k + 2] + wv.w * xb[k + 3];
    }
    out[b * 164 + tid] = sum;
  }
}

// ---- workspace layout (floats) ----
constexpr size_t F_H  = 0;
constexpr size_t F_HN = F_H + (size_t)TOK * DM;
constexpr size_t F_ZX = F_HN + (size_t)TOK * DM;
constexpr size_t F_XB = F_ZX + (size_t)TOK * DIP;
constexpr size_t F_DT = F_XB + (size_t)TOK * CDIM;
constexpr size_t F_DA = F_DT + (size_t)TOK * NH;
constexpr size_t F_Y  = F_DA + (size_t)TOK * NH;
constexpr size_t F_OF = F_Y + (size_t)TOK * DI;
constexpr size_t F_OR = F_OF + (size_t)TOK * DM;
constexpr size_t F_LEN = F_OR + (size_t)TOK * DM;

extern "C" void kernel_launch(void* const* d_in, const int* in_sizes, int n_in,
                              void* d_out, int out_size, void* d_ws, size_t ws_size,
                              hipStream_t stream) {
  const int* src = (const int*)d_in[0];
  const float* values = (const float*)d_in[1];
  const unsigned char* mask = (const unsigned char*)d_in[2];
  const float* embed = (const float*)d_in[3];
  const float* ge_g = (const float*)d_in[4];
  const float* ge_b = (const float*)d_in[5];
  const float* ve_w1 = (const float*)d_in[6];
  const float* ve_b1 = (const float*)d_in[7];
  const float* ve_w2 = (const float*)d_in[8];
  const float* ve_b2 = (const float*)d_in[9];
  const float* ve_g = (const float*)d_in[10];
  const float* ve_bb = (const float*)d_in[11];
  const float* in_w = (const float*)d_in[12];
  const float* conv_w_f = (const float*)d_in[13];
  const float* conv_b_f = (const float*)d_in[14];
  const float* A_f = (const float*)d_in[15];
  const float* dtb_f = (const float*)d_in[16];
  const float* D_f = (const float*)d_in[17];
  const float* nw_f = (const float*)d_in[18];
  const float* conv_w_r = (const float*)d_in[19];
  const float* conv_b_r = (const float*)d_in[20];
  const float* A_r = (const float*)d_in[21];
  const float* dtb_r = (const float*)d_in[22];
  const float* D_r = (const float*)d_in[23];
  const float* nw_r = (const float*)d_in[24];
  const float* out_w = (const float*)d_in[25];
  const float* expr_w1 = (const float*)d_in[26];
  const float* expr_b1 = (const float*)d_in[27];
  const float* expr_w2 = (const float*)d_in[28];
  const float* expr_b2 = (const float*)d_in[29];
  const float* expr_w3 = (const float*)d_in[30];
  const float* expr_b3 = (const float*)d_in[31];
  const float* cls_w1 = (const float*)d_in[32];
  const float* cls_b1 = (const float*)d_in[33];
  const float* cls_g1 = (const float*)d_in[34];
  const float* cls_bb1 = (const float*)d_in[35];
  const float* cls_w2 = (const float*)d_in[36];
  const float* cls_b2 = (const float*)d_in[37];
  const float* cls_g2 = (const float*)d_in[38];
  const float* cls_bb2 = (const float*)d_in[39];
  const float* cls_wo = (const float*)d_in[40];
  const float* cls_bo = (const float*)d_in[41];

  float* ws = (float*)d_ws;
  float* h = ws + F_H;
  float* hn = ws + F_HN;
  float* zx = ws + F_ZX;
  float* xbca = ws + F_XB;
  float* dtb = ws + F_DT;
  float* dAb = ws + F_DA;
  float* ybuf = ws + F_Y;
  float* obf = ws + F_OF;
  float* obr = ws + F_OR;
  int* len = (int*)(ws + F_LEN);
  float* v1 = obf;   // reuse before layers
  float* t2 = obr;   // reuse before layers
  float* e1 = zx;    // reuse after layers
  float* e2 = xbca;  // reuse after layers
  float* out = (float*)d_out;

  // ---- embedding + value encoder ----
  k_embed<<<TOK / 4, 256, 0, stream>>>(src, values, embed, ge_g, ge_b, ve_w1, ve_b1, h, v1);
  gemm_nt<0><<<dim3(DM / 128, TOK / 128), 256, 0, stream>>>(v1, ve_w2, ve_b2, t2, TOK, DM, DM);
  k_haddv<<<TOK / 4, 256, 0, stream>>>(t2, ve_g, ve_bb, mask, h);
  k_lengths<<<Bb, 256, 0, stream>>>(mask, len);

  // ---- layers ----
  for (int i = 0; i < 2; ++i) {
    const float* inw = in_w + (size_t)i * DIP * DM;
    const float* outw = out_w + (size_t)i * DM * DI;
    k_ln512<<<TOK / 4, 256, 0, stream>>>(h, hn);
    for (int d = 0; d < 2; ++d) {
      const float* cw = (d ? conv_w_r : conv_w_f) + (size_t)i * CDIM * 4;
      const float* cb = (d ? conv_b_r : conv_b_f) + (size_t)i * CDIM;
      const float* Al = (d ? A_r : A_f) + (size_t)i * NH;
      const float* db = (d ? dtb_r : dtb_f) + (size_t)i * NH;
      const float* Dk = (d ? D_r : D_f) + (size_t)i * NH;
      const float* nw = (d ? nw_r : nw_f) + (size_t)i * DI;
      float* outbuf = d ? obr : obf;
      if (d == 1) k_flip<<<(TOK * (DM / 4) + 255) / 256, 256, 0, stream>>>(hn, len, DM);
      gemm_nt<0><<<dim3((DIP + 127) / 128, TOK / 128), 256, 0, stream>>>(hn, inw, nullptr, zx, TOK, DIP, DM);
      k_dtda<<<(TOK * NH + 255) / 256, 256, 0, stream>>>(zx, db, Al, dtb, dAb);
      k_conv<<<(TOK * CDIM + 255) / 256, 256, 0, stream>>>(zx, cw, cb, xbca);
      k_scan<<<Bb * NH * 4, 64, 0, stream>>>(xbca, dtb, dAb, Dk, ybuf);
      k_gaterms<<<TOK / 4, 256, 0, stream>>>(ybuf, zx, nw);
      gemm_nt<0><<<dim3(DM / 128, TOK / 128), 256, 0, stream>>>(ybuf, outw, nullptr, outbuf, TOK, DM, DI);
    }
    k_flip<<<(TOK * (DM / 4) + 255) / 256, 256, 0, stream>>>(obr, len, DM);
    k_comb<<<TOK / 4, 256, 0, stream>>>(obf, obr, h);
  }

  // ---- heads ----
  gemm_nt<2><<<dim3(DM / 128, TOK / 128), 256, 0, stream>>>(h, expr_w1, expr_b1, e1, TOK, DM, DM);
  gemm_nt<2><<<dim3(DM / 128, TOK / 128), 256, 0, stream>>>(e1, expr_w2, expr_b2, e2, TOK, DM, DM);
  k_mlm<<<TOK / 4, 256, 0, stream>>>(e2, expr_w3, expr_b3, out);
  k_cell<<<(Bb * DM + 255) / 256, 256, 0, stream>>>(h, out + TOK);
  k_cls<<<Bb, 256, 0, stream>>>(h, cls_w1, cls_b1, cls_g1, cls_bb1, cls_w2, cls_b2, cls_g2, cls_bb2,
                                cls_wo, cls_bo, out + TOK + Bb * DM);
}

// Round 2
// 2201.590 us; speedup vs baseline: 1.7051x; 1.7051x over previous
//
#include <hip/hip_runtime.h>
#include <hip/hip_bf16.h>
#include <math.h>

// ---- model constants ----
constexpr int Bb = 4, Ls = 1024, DM = 512, DI = 1024, NH = 16, HD = 64, DS = 64;
constexpr int CDIM = DI + 2 * DS;         // 1152
constexpr int DIP  = 2 * DI + 2 * DS + NH; // 2192
constexpr float EPSf = 1e-5f;
constexpr int TOK = Bb * Ls;              // 4096
constexpr int CH = 64, NCH = Ls / CH;     // chunked scan: 16 chunks of 64

#define DEVI __device__ __forceinline__

DEVI float wsum(float v) {
#pragma unroll
  for (int o = 32; o > 0; o >>= 1) v += __shfl_xor(v, o);
  return v;
}
DEVI float sigmoidf_(float x) { return 1.f / (1.f + __expf(-x)); }

DEVI void ld8(const float* __restrict__ p, int lane, float (&x)[8]) {
  float4 a = *(const float4*)(p + lane * 4);
  float4 b = *(const float4*)(p + 256 + lane * 4);
  x[0] = a.x; x[1] = a.y; x[2] = a.z; x[3] = a.w;
  x[4] = b.x; x[5] = b.y; x[6] = b.z; x[7] = b.w;
}
DEVI void st8(float* __restrict__ p, int lane, const float (&x)[8]) {
  float4 a = make_float4(x[0], x[1], x[2], x[3]);
  float4 b = make_float4(x[4], x[5], x[6], x[7]);
  *(float4*)(p + lane * 4) = a;
  *(float4*)(p + 256 + lane * 4) = b;
}
// wave-level LN over 512 (8 elems/lane), in-place on regs
DEVI void norm8(float (&x)[8]) {
  float s = 0;
#pragma unroll
  for (int j = 0; j < 8; ++j) s += x[j];
  float mean = wsum(s) * (1.f / 512.f);
#pragma unroll
  for (int j = 0; j < 8; ++j) x[j] -= mean;
  float q = 0;
#pragma unroll
  for (int j = 0; j < 8; ++j) q += x[j] * x[j];
  float var = wsum(q) * (1.f / 512.f);
  float inv = rsqrtf(var + EPSf);
#pragma unroll
  for (int j = 0; j < 8; ++j) x[j] *= inv;
}

// ---- embedding + value-encoder stage 1 ----
__global__ __launch_bounds__(256) void k_embed(const int* __restrict__ src, const float* __restrict__ values,
    const float* __restrict__ embed, const float* __restrict__ gg, const float* __restrict__ gb,
    const float* __restrict__ vw1, const float* __restrict__ vb1,
    float* __restrict__ hbuf, float* __restrict__ v1buf) {
  int gw = (blockIdx.x * 256 + threadIdx.x) >> 6;
  int lane = threadIdx.x & 63;
  if (gw >= TOK) return;
  const float* er = embed + (size_t)src[gw] * DM;
  float x[8];
  ld8(er, lane, x);
  norm8(x);
  float g[8], bv[8];
  ld8(gg, lane, g); ld8(gb, lane, bv);
#pragma unroll
  for (int j = 0; j < 8; ++j) x[j] = x[j] * g[j] + bv[j];
  st8(hbuf + (size_t)gw * DM, lane, x);
  float val = fminf(values[gw], 512.f);
  float w1[8], b1[8];
  ld8(vw1, lane, w1); ld8(vb1, lane, b1);
  float v[8];
#pragma unroll
  for (int j = 0; j < 8; ++j) v[j] = fmaxf(val * w1[j] + b1[j], 0.f);
  st8(v1buf + (size_t)gw * DM, lane, v);
}

// h = (h + LN(t2)*g+b) * (mask?0:1)
__global__ __launch_bounds__(256) void k_haddv(const float* __restrict__ t2, const float* __restrict__ g,
    const float* __restrict__ bb, const unsigned char* __restrict__ mask, float* __restrict__ hbuf) {
  int gw = (blockIdx.x * 256 + threadIdx.x) >> 6;
  int lane = threadIdx.x & 63;
  if (gw >= TOK) return;
  float x[8];
  ld8(t2 + (size_t)gw * DM, lane, x);
  norm8(x);
  float gv[8], bv[8], h[8];
  ld8(g, lane, gv); ld8(bb, lane, bv);
  ld8(hbuf + (size_t)gw * DM, lane, h);
  float mf = mask[gw] ? 0.f : 1.f;
#pragma unroll
  for (int j = 0; j < 8; ++j) h[j] = (h[j] + x[j] * gv[j] + bv[j]) * mf;
  st8(hbuf + (size_t)gw * DM, lane, h);
}

// dst = LN(src), no affine
__global__ __launch_bounds__(256) void k_ln512(const float* __restrict__ src, float* __restrict__ dst) {
  int gw = (blockIdx.x * 256 + threadIdx.x) >> 6;
  int lane = threadIdx.x & 63;
  if (gw >= TOK) return;
  float x[8];
  ld8(src + (size_t)gw * DM, lane, x);
  norm8(x);
  st8(dst + (size_t)gw * DM, lane, x);
}

// h = LN((f+r)/2), no affine
__global__ __launch_bounds__(256) void k_comb(const float* __restrict__ f, const float* __restrict__ r,
                                              float* __restrict__ dst) {
  int gw = (blockIdx.x * 256 + threadIdx.x) >> 6;
  int lane = threadIdx.x & 63;
  if (gw >= TOK) return;
  float x[8], y[8];
  ld8(f + (size_t)gw * DM, lane, x);
  ld8(r + (size_t)gw * DM, lane, y);
#pragma unroll
  for (int j = 0; j < 8; ++j) x[j] = 0.5f * (x[j] + y[j]);
  norm8(x);
  st8(dst + (size_t)gw * DM, lane, x);
}

// ---- generic fp32 GEMM: C[M,N] = A[M,K] @ W[N,K]^T (+bias, act) ----
// ACT: 0 none, 1 relu, 2 leaky(0.01)
template <int ACT>
__global__ __launch_bounds__(256) void gemm_nt(const float* __restrict__ A, const float* __restrict__ W,
    const float* __restrict__ bias, float* __restrict__ C, int M, int N, int K) {
  constexpr int BM = 128, BN = 128, BK = 32;
  __shared__ float As[BK][BM + 4];
  __shared__ float Ws[BK][BN + 4];
  int tid = threadIdx.x;
  int bm = blockIdx.y * BM, bn = blockIdx.x * BN;
  int ty = tid >> 4, tx = tid & 15;
  float acc[8][8] = {};
  int lr = tid >> 3;
  int lk = (tid & 7) * 4;
  for (int k0 = 0; k0 < K; k0 += BK) {
#pragma unroll
    for (int q = 0; q < 4; ++q) {
      int row = lr + q * 32;
      float4 a = make_float4(0, 0, 0, 0);
      int gm = bm + row;
      if (gm < M) a = *(const float4*)(A + (size_t)gm * K + k0 + lk);
      As[lk + 0][row] = a.x; As[lk + 1][row] = a.y; As[lk + 2][row] = a.z; As[lk + 3][row] = a.w;
      float4 w = make_float4(0, 0, 0, 0);
      int gn = bn + row;
      if (gn < N) w = *(const float4*)(W + (size_t)gn * K + k0 + lk);
      Ws[lk + 0][row] = w.x; Ws[lk + 1][row] = w.y; Ws[lk + 2][row] = w.z; Ws[lk + 3][row] = w.w;
    }
    __syncthreads();
#pragma unroll 8
    for (int k = 0; k < BK; ++k) {
      float4 a0 = *(const float4*)&As[k][ty * 8];
      float4 a1 = *(const float4*)&As[k][ty * 8 + 4];
      float4 w0 = *(const float4*)&Ws[k][tx * 8];
      float4 w1 = *(const float4*)&Ws[k][tx * 8 + 4];
      float av[8] = {a0.x, a0.y, a0.z, a0.w, a1.x, a1.y, a1.z, a1.w};
      float wv[8] = {w0.x, w0.y, w0.z, w0.w, w1.x, w1.y, w1.z, w1.w};
#pragma unroll
      for (int i = 0; i < 8; ++i)
#pragma unroll
        for (int j = 0; j < 8; ++j) acc[i][j] = fmaf(av[i], wv[j], acc[i][j]);
    }
    __syncthreads();
  }
#pragma unroll
  for (int i = 0; i < 8; ++i) {
    int m = bm + ty * 8 + i;
    if (m >= M) continue;
#pragma unroll
    for (int j = 0; j < 8; ++j) {
      int n = bn + tx * 8 + j;
      if (n >= N) continue;
      float v = acc[i][j];
      if (bias) v += bias[n];
      if (ACT == 1) v = fmaxf(v, 0.f);
      if (ACT == 2) v = v > 0.f ? v : 0.01f * v;
      C[(size_t)m * N + n] = v;
    }
  }
}

// ---- depthwise causal conv (k=4) + silu on xBC slice of zx ----
__global__ __launch_bounds__(256) void k_conv(const float* __restrict__ zx, const float* __restrict__ cw,
                                              const float* __restrict__ cb, float* __restrict__ xbca) {
  int idx = blockIdx.x * 256 + threadIdx.x;
  if (idx >= TOK * CDIM) return;
  int c = idx % CDIM;
  int bt = idx / CDIM;
  int t = bt & (Ls - 1);
  int b = bt >> 10;
  const float* col = zx + (size_t)(b * Ls) * DIP + DI + c;
  float4 w = *(const float4*)(cw + c * 4);
  float s = cb[c];
  if (t >= 3) {
    s += w.x * col[(size_t)(t - 3) * DIP] + w.y * col[(size_t)(t - 2) * DIP] +
         w.z * col[(size_t)(t - 1) * DIP] + w.w * col[(size_t)t * DIP];
  } else {
    float wk[4] = {w.x, w.y, w.z, w.w};
#pragma unroll
    for (int k = 0; k < 4; ++k) {
      int tt = t - 3 + k;
      if (tt >= 0) s += wk[k] * col[(size_t)tt * DIP];
    }
  }
  xbca[idx] = s * sigmoidf_(s);
}

// ---- dt = softplus(raw + bias); ldA = -exp(Alog)*dt  (LOG decay) ----
__global__ __launch_bounds__(256) void k_dtda(const float* __restrict__ zx, const float* __restrict__ dtbias,
    const float* __restrict__ Alog, float* __restrict__ dt, float* __restrict__ ldA) {
  int i = blockIdx.x * 256 + threadIdx.x;
  if (i >= TOK * NH) return;
  int hh = i & 15;
  int bt = i >> 4;
  float raw = zx[(size_t)bt * DIP + 2 * DI + 2 * DS + hh] + dtbias[hh];
  float d = raw > 20.f ? raw : log1pf(__expf(raw));
  dt[i] = d;
  ldA[i] = -__expf(Alog[hh]) * d;
}

// ======================= chunked SSD scan =======================
// Phase A: per (b,h,chunk): local Y (+ D*x), chunk state G[n][p], cum decay exp(L[t]).
// grid = Bb*NH*NCH, 256 threads.
__global__ __launch_bounds__(256) void k_chunk(const float* __restrict__ xbca, const float* __restrict__ dtb,
    const float* __restrict__ ldab, const float* __restrict__ Dk, float* __restrict__ y,
    float* __restrict__ gbuf, float* __restrict__ cumbuf) {
  __shared__ float xs[64][68];
  __shared__ float Bs[64][68];
  __shared__ float Cs[64][68];  // reused as W^T after matmul1
  __shared__ float ldsL[64], sdt[64];
  int blk = blockIdx.x;
  int c = blk & (NCH - 1);
  int bh = blk >> 4;
  int h = bh & (NH - 1);
  int b = bh >> 4;
  int tid = threadIdx.x;
  int t0 = (tid >> 4) * 4;  // ty*4
  int p0 = (tid & 15) * 4;  // tx*4 (also s0 / n0)
  int c0 = c * CH;

  // stage x, B, C (64x64 each)
  {
    int r = tid >> 2;
    int col0 = (tid & 3) * 16;
    const float* rowp = xbca + ((size_t)(b * Ls + c0 + r)) * CDIM;
#pragma unroll
    for (int u = 0; u < 4; ++u) {
      *(float4*)&xs[r][col0 + u * 4] = *(const float4*)(rowp + h * 64 + col0 + u * 4);
      *(float4*)&Bs[r][col0 + u * 4] = *(const float4*)(rowp + DI + col0 + u * 4);
      *(float4*)&Cs[r][col0 + u * 4] = *(const float4*)(rowp + DI + DS + col0 + u * 4);
    }
  }
  // stage dt, inclusive log-decay prefix L (wave 0)
  if (tid < 64) {
    size_t off = ((size_t)(b * Ls + c0 + tid)) * NH + h;
    sdt[tid] = dtb[off];
    float v = ldab[off];
#pragma unroll
    for (int o = 1; o < 64; o <<= 1) {
      float n = __shfl_up(v, o);
      if (tid >= o) v += n;
    }
    ldsL[tid] = v;
    cumbuf[(size_t)blk * 64 + tid] = __expf(v);
  }
  __syncthreads();

  // matmul1: S[t][s] = sum_n C[t][n]*B[s][n]
  float acc[4][4] = {};
  for (int k0 = 0; k0 < 64; k0 += 4) {
    float4 a4[4], b4[4];
#pragma unroll
    for (int i = 0; i < 4; ++i) a4[i] = *(const float4*)&Cs[t0 + i][k0];
#pragma unroll
    for (int j = 0; j < 4; ++j) b4[j] = *(const float4*)&Bs[p0 + j][k0];
#pragma unroll
    for (int i = 0; i < 4; ++i)
#pragma unroll
      for (int j = 0; j < 4; ++j) {
        float v = fmaf(a4[i].x, b4[j].x, acc[i][j]);
        v = fmaf(a4[i].y, b4[j].y, v);
        v = fmaf(a4[i].z, b4[j].z, v);
        acc[i][j] = fmaf(a4[i].w, b4[j].w, v);
      }
  }
  __syncthreads();  // everyone done reading Cs/Bs

  // decay+mask -> W^T into Cs; scale Bs rows by exp(Llast-L[s])*dt[s]
  {
    float Lt[4], Lsv[4], dts[4];
#pragma unroll
    for (int i = 0; i < 4; ++i) Lt[i] = ldsL[t0 + i];
#pragma unroll
    for (int j = 0; j < 4; ++j) { Lsv[j] = ldsL[p0 + j]; dts[j] = sdt[p0 + j]; }
#pragma unroll
    for (int i = 0; i < 4; ++i)
#pragma unroll
      for (int j = 0; j < 4; ++j) {
        float w = (p0 + j <= t0 + i) ? acc[i][j] * dts[j] * __expf(Lt[i] - Lsv[j]) : 0.f;
        Cs[p0 + j][t0 + i] = w;  // W^T[s][t]
      }
  }
  {
    int r = tid >> 2;
    int col0 = (tid & 3) * 16;
    float f = __expf(ldsL[63] - ldsL[r]) * sdt[r];
#pragma unroll
    for (int u = 0; u < 4; ++u) {
      float4 v = *(float4*)&Bs[r][col0 + u * 4];
      v.x *= f; v.y *= f; v.z *= f; v.w *= f;
      *(float4*)&Bs[r][col0 + u * 4] = v;
    }
  }
  __syncthreads();

  // matmul2: Y[t][p] = sum_s W[t][s]*x[s][p];  matmul3: G[n][p] = sum_s wB[s][n]*x[s][p]
  float accY[4][4] = {}, accG[4][4] = {};
  for (int k = 0; k < 64; ++k) {
    float4 wv = *(const float4*)&Cs[k][t0];
    float4 xv = *(const float4*)&xs[k][p0];
    float4 bv = *(const float4*)&Bs[k][t0];
    float wa[4] = {wv.x, wv.y, wv.z, wv.w};
    float ba[4] = {bv.x, bv.y, bv.z, bv.w};
    float xa[4] = {xv.x, xv.y, xv.z, xv.w};
#pragma unroll
    for (int i = 0; i < 4; ++i)
#pragma unroll
      for (int j = 0; j < 4; ++j) {
        accY[i][j] = fmaf(wa[i], xa[j], accY[i][j]);
        accG[i][j] = fmaf(ba[i], xa[j], accG[i][j]);
      }
  }

  float Dh = Dk[h];
#pragma unroll
  for (int i = 0; i < 4; ++i) {
    float4 xr = *(const float4*)&xs[t0 + i][p0];
    float4 o;
    o.x = fmaf(Dh, xr.x, accY[i][0]);
    o.y = fmaf(Dh, xr.y, accY[i][1]);
    o.z = fmaf(Dh, xr.z, accY[i][2]);
    o.w = fmaf(Dh, xr.w, accY[i][3]);
    *(float4*)(y + ((size_t)(b * Ls + c0 + t0 + i)) * DI + h * 64 + p0) = o;
    *(float4*)(gbuf + ((size_t)blk * 64 + t0 + i) * 64 + p0) =
        make_float4(accG[i][0], accG[i][1], accG[i][2], accG[i][3]);
  }
}

// Phase B: inter-chunk recurrence h <- exp(Llast)*h + G; store h_in per chunk.
// grid = Bb*NH, 256 threads; each thread 16 state elems (coalesced interleave).
__global__ __launch_bounds__(256) void k_chain(const float* __restrict__ gbuf, const float* __restrict__ cumbuf,
                                               float* __restrict__ hin) {
  int bh = blockIdx.x;
  int tid = threadIdx.x;
  float4 hv[4] = {};
  for (int c = 0; c < NCH; ++c) {
    size_t base = ((size_t)(bh * NCH + c)) * 4096;
    float Pc = cumbuf[(size_t)(bh * NCH + c) * 64 + 63];
#pragma unroll
    for (int k = 0; k < 4; ++k) {
      size_t e = base + (size_t)k * 1024 + tid * 4;
      *(float4*)(hin + e) = hv[k];
      float4 g = *(const float4*)(gbuf + e);
      hv[k].x = fmaf(Pc, hv[k].x, g.x);
      hv[k].y = fmaf(Pc, hv[k].y, g.y);
      hv[k].z = fmaf(Pc, hv[k].z, g.z);
      hv[k].w = fmaf(Pc, hv[k].w, g.w);
    }
  }
}

// Phase C: Y[t][p] += exp(L[t]) * sum_n C[t][n]*h_in[n][p].  grid = Bb*NH*NCH.
__global__ __launch_bounds__(256) void k_corr(const float* __restrict__ xbca, const float* __restrict__ hin,
                                              const float* __restrict__ cumbuf, float* __restrict__ y) {
  int blk = blockIdx.x;
  int c = blk & (NCH - 1);
  if (c == 0) return;  // h_in = 0
  __shared__ float Cs2[64][68];
  __shared__ float Hs[64][68];
  __shared__ float cdl[64];
  int bh = blk >> 4;
  int h = bh & (NH - 1);
  int b = bh >> 4;
  int tid = threadIdx.x;
  int t0 = (tid >> 4) * 4;
  int p0 = (tid & 15) * 4;
  int c0 = c * CH;
  {
    int r = tid >> 2;
    int col0 = (tid & 3) * 16;
    const float* rowp = xbca + ((size_t)(b * Ls + c0 + r)) * CDIM + DI + DS;
    const float* hrow = hin + ((size_t)blk) * 4096 + (size_t)r * 64;
#pragma unroll
    for (int u = 0; u < 4; ++u) {
      *(float4*)&Cs2[r][col0 + u * 4] = *(const float4*)(rowp + col0 + u * 4);
      *(float4*)&Hs[r][col0 + u * 4] = *(const float4*)(hrow + col0 + u * 4);
    }
  }
  if (tid < 64) cdl[tid] = cumbuf[(size_t)blk * 64 + tid];
  __syncthreads();

  float acc[4][4] = {};
  for (int k0 = 0; k0 < 64; k0 += 4) {
    float4 a4[4];
#pragma unroll
    for (int i = 0; i < 4; ++i) a4[i] = *(const float4*)&Cs2[t0 + i][k0];
    float a_[4][4];
#pragma unroll
    for (int i = 0; i < 4; ++i) { a_[i][0] = a4[i].x; a_[i][1] = a4[i].y; a_[i][2] = a4[i].z; a_[i][3] = a4[i].w; }
#pragma unroll
    for (int u = 0; u < 4; ++u) {
      float4 hv = *(const float4*)&Hs[k0 + u][p0];
      float ha[4] = {hv.x, hv.y, hv.z, hv.w};
#pragma unroll
      for (int i = 0; i < 4; ++i)
#pragma unroll
        for (int j = 0; j < 4; ++j) acc[i][j] = fmaf(a_[i][u], ha[j], acc[i][j]);
    }
  }
#pragma unroll
  for (int i = 0; i < 4; ++i) {
    float cd = cdl[t0 + i];
    float* yp = y + ((size_t)(b * Ls + c0 + t0 + i)) * DI + h * 64 + p0;
    float4 yv = *(float4*)yp;
    yv.x = fmaf(cd, acc[i][0], yv.x);
    yv.y = fmaf(cd, acc[i][1], yv.y);
    yv.z = fmaf(cd, acc[i][2], yv.z);
    yv.w = fmaf(cd, acc[i][3], yv.w);
    *(float4*)yp = yv;
  }
}
// ================================================================

// ---- y = y*silu(z); y = y*rsqrt(mean(y^2)+eps)*nw ---- (row width 1024)
__global__ __launch_bounds__(256) void k_gaterms(float* __restrict__ y, const float* __restrict__ zx,
                                                 const float* __restrict__ nw) {
  int gw = (blockIdx.x * 256 + threadIdx.x) >> 6;
  int lane = threadIdx.x & 63;
  if (gw >= TOK) return;
  float* yr = y + (size_t)gw * DI;
  const float* zr = zx + (size_t)gw * DIP;
  float g[16];
  float ss = 0.f;
#pragma unroll
  for (int q = 0; q < 4; ++q) {
    float4 yv = *(const float4*)(yr + lane * 4 + q * 256);
    float4 zv = *(const float4*)(zr + lane * 4 + q * 256);
    g[4 * q + 0] = yv.x * zv.x * sigmoidf_(zv.x);
    g[4 * q + 1] = yv.y * zv.y * sigmoidf_(zv.y);
    g[4 * q + 2] = yv.z * zv.z * sigmoidf_(zv.z);
    g[4 * q + 3] = yv.w * zv.w * sigmoidf_(zv.w);
#pragma unroll
    for (int j = 0; j < 4; ++j) ss += g[4 * q + j] * g[4 * q + j];
  }
  ss = wsum(ss);
  float sc = rsqrtf(ss * (1.f / (float)DI) + EPSf);
#pragma unroll
  for (int q = 0; q < 4; ++q) {
    float4 nv = *(const float4*)(nw + lane * 4 + q * 256);
    float4 o;
    o.x = g[4 * q + 0] * sc * nv.x;
    o.y = g[4 * q + 1] * sc * nv.y;
    o.z = g[4 * q + 2] * sc * nv.z;
    o.w = g[4 * q + 3] * sc * nv.w;
    *(float4*)(yr + lane * 4 + q * 256) = o;
  }
}

// ---- lengths = sum(!mask) per batch ----
__global__ __launch_bounds__(256) void k_lengths(const unsigned char* __restrict__ mask, int* __restrict__ len) {
  int b = blockIdx.x;
  int tid = threadIdx.x;
  int cnt = 0;
  for (int t = tid; t < Ls; t += 256) cnt += mask[b * Ls + t] ? 0 : 1;
#pragma unroll
  for (int o = 32; o > 0; o >>= 1) cnt += __shfl_xor(cnt, o);
  __shared__ int red[4];
  if ((tid & 63) == 0) red[tid >> 6] = cnt;
  __syncthreads();
  if (tid == 0) len[b] = red[0] + red[1] + red[2] + red[3];
}

// ---- in-place smart flip (involution) of [B,Ls,Wd] ----
__global__ __launch_bounds__(256) void k_flip(float* __restrict__ buf, const int* __restrict__ len, int Wd) {
  int idx = blockIdx.x * 256 + threadIdx.x;
  int nc4 = Wd >> 2;
  int total = TOK * nc4;
  if (idx >= total) return;
  int c4 = idx % nc4;
  int bt = idx / nc4;
  int t = bt & (Ls - 1);
  int b = bt >> 10;
  int ln = len[b];
  int pos = (t < ln) ? (ln - 1 - t) : t;
  if (t < pos) {
    float4* p0 = (float4*)(buf + ((size_t)b * Ls + t) * Wd) + c4;
    float4* p1 = (float4*)(buf + ((size_t)b * Ls + pos) * Wd) + c4;
    float4 a = *p0, bv = *p1;
    *p0 = bv;
    *p1 = a;
  }
}

// ---- mlm head: dot(row, w3)+b3 ----
__global__ __launch_bounds__(256) void k_mlm(const float* __restrict__ e2, const float* __restrict__ w3,
                                             const float* __restrict__ b3, float* __restrict__ out) {
  int gw = (blockIdx.x * 256 + threadIdx.x) >> 6;
  int lane = threadIdx.x & 63;
  if (gw >= TOK) return;
  float x[8], w[8];
  ld8(e2 + (size_t)gw * DM, lane, x);
  ld8(w3, lane, w);
  float s = 0;
#pragma unroll
  for (int j = 0; j < 8; ++j) s += x[j] * w[j];
  s = wsum(s);
  if (lane == 0) out[gw] = s + b3[0];
}

__global__ __launch_bounds__(256) void k_cell(const float* __restrict__ h, float* __restrict__ out) {
  int i = blockIdx.x * 256 + threadIdx.x;
  if (i >= Bb * DM) return;
  int b = i >> 9, c = i & 511;
  out[i] = h[(size_t)b * Ls * DM + c];
}

// ---- classifier head: 2x (matvec+relu+LN affine) + final matvec; 1 block per batch ----
__global__ __launch_bounds__(256) void k_cls(const float* __restrict__ h,
    const float* __restrict__ w1, const float* __restrict__ b1, const float* __restrict__ g1, const float* __restrict__ bb1,
    const float* __restrict__ w2, const float* __restrict__ b2, const float* __restrict__ g2, const float* __restrict__ bb2,
    const float* __restrict__ wo, const float* __restrict__ bo, float* __restrict__ out) {
  __shared__ float xb[512];
  __shared__ float cc[512];
  __shared__ float red[4];
  int b = blockIdx.x, tid = threadIdx.x;
  const float* cell = h + (size_t)b * Ls * DM;
  xb[tid] = cell[tid];
  xb[tid + 256] = cell[tid + 256];
  __syncthreads();

  for (int pass = 0; pass < 2; ++pass) {
    const float* W = pass ? w2 : w1;
    const float* bias = pass ? b2 : b1;
    const float* g = pass ? g2 : g1;
    const float* bt = pass ? bb2 : bb1;
#pragma unroll 1
    for (int jj = 0; jj < 2; ++jj) {
      int j = tid + jj * 256;
      const float* wr = W + (size_t)j * DM;
      float sum = bias[j];
      for (int k = 0; k < DM; k += 4) {
        float4 wv = *(const float4*)(wr + k);
        sum += wv.x * xb[k] + wv.y * xb[k + 1] + wv.z * xb[k + 2] + wv.w * xb[k + 3];
      }
      cc[j] = fmaxf(sum, 0.f);
    }
    __syncthreads();
    float v0 = cc[tid], v1 = cc[tid + 256];
    float s = wsum(v0 + v1);
    if ((tid & 63) == 0) red[tid >> 6] = s;
    __syncthreads();
    float mean = (red[0] + red[1] + red[2] + red[3]) * (1.f / 512.f);
    __syncthreads();
    float d0 = v0 - mean, d1 = v1 - mean;
    float q = wsum(d0 * d0 + d1 * d1);
    if ((tid & 63) == 0) red[tid >> 6] = q;
    __syncthreads();
    float var = (red[0] + red[1] + red[2] + red[3]) * (1.f / 512.f);
    float inv = rsqrtf(var + EPSf);
    xb[tid] = d0 * inv * g[tid] + bt[tid];
    xb[tid + 256] = d1 * inv * g[tid + 256] + bt[tid + 256];
    __syncthreads();
  }
  if (tid < 164) {
    const float* wr = wo + (size_t)tid * DM;
    float sum = bo[tid];
    for (int k = 0; k < DM; k += 4) {
      float4 wv = *(const float4*)(wr + k);
      sum += wv.x * xb[k] + wv.y * xb[k + 1] + wv.z * xb[k + 2] + wv.w * xb[k + 3];
    }
    out[b * 164 + tid] = sum;
  }
}

// ---- workspace layout (floats) ----
constexpr size_t F_H  = 0;
constexpr size_t F_HN = F_H + (size_t)TOK * DM;
constexpr size_t F_ZX = F_HN + (size_t)TOK * DM;
constexpr size_t F_XB = F_ZX + (size_t)TOK * DIP;
constexpr size_t F_DT = F_XB + (size_t)TOK * CDIM;
constexpr size_t F_DA = F_DT + (size_t)TOK * NH;
constexpr size_t F_Y  = F_DA + (size_t)TOK * NH;
constexpr size_t F_OF = F_Y + (size_t)TOK * DI;
constexpr size_t F_OR = F_OF + (size_t)TOK * DM;
constexpr size_t F_LEN = F_OR + (size_t)TOK * DM;
constexpr size_t F_G   = F_LEN + 16;
constexpr size_t F_HIN = F_G + (size_t)Bb * NH * NCH * HD * DS;
constexpr size_t F_CUM = F_HIN + (size_t)Bb * NH * NCH * HD * DS;

extern "C" void kernel_launch(void* const* d_in, const int* in_sizes, int n_in,
                              void* d_out, int out_size, void* d_ws, size_t ws_size,
                              hipStream_t stream) {
  const int* src = (const int*)d_in[0];
  const float* values = (const float*)d_in[1];
  const unsigned char* mask = (const unsigned char*)d_in[2];
  const float* embed = (const float*)d_in[3];
  const float* ge_g = (const float*)d_in[4];
  const float* ge_b = (const float*)d_in[5];
  const float* ve_w1 = (const float*)d_in[6];
  const float* ve_b1 = (const float*)d_in[7];
  const float* ve_w2 = (const float*)d_in[8];
  const float* ve_b2 = (const float*)d_in[9];
  const float* ve_g = (const float*)d_in[10];
  const float* ve_bb = (const float*)d_in[11];
  const float* in_w = (const float*)d_in[12];
  const float* conv_w_f = (const float*)d_in[13];
  const float* conv_b_f = (const float*)d_in[14];
  const float* A_f = (const float*)d_in[15];
  const float* dtb_f = (const float*)d_in[16];
  const float* D_f = (const float*)d_in[17];
  const float* nw_f = (const float*)d_in[18];
  const float* conv_w_r = (const float*)d_in[19];
  const float* conv_b_r = (const float*)d_in[20];
  const float* A_r = (const float*)d_in[21];
  const float* dtb_r = (const float*)d_in[22];
  const float* D_r = (const float*)d_in[23];
  const float* nw_r = (const float*)d_in[24];
  const float* out_w = (const float*)d_in[25];
  const float* expr_w1 = (const float*)d_in[26];
  const float* expr_b1 = (const float*)d_in[27];
  const float* expr_w2 = (const float*)d_in[28];
  const float* expr_b2 = (const float*)d_in[29];
  const float* expr_w3 = (const float*)d_in[30];
  const float* expr_b3 = (const float*)d_in[31];
  const float* cls_w1 = (const float*)d_in[32];
  const float* cls_b1 = (const float*)d_in[33];
  const float* cls_g1 = (const float*)d_in[34];
  const float* cls_bb1 = (const float*)d_in[35];
  const float* cls_w2 = (const float*)d_in[36];
  const float* cls_b2 = (const float*)d_in[37];
  const float* cls_g2 = (const float*)d_in[38];
  const float* cls_bb2 = (const float*)d_in[39];
  const float* cls_wo = (const float*)d_in[40];
  const float* cls_bo = (const float*)d_in[41];

  float* ws = (float*)d_ws;
  float* h = ws + F_H;
  float* hn = ws + F_HN;
  float* zx = ws + F_ZX;
  float* xbca = ws + F_XB;
  float* dtb = ws + F_DT;
  float* ldab = ws + F_DA;
  float* ybuf = ws + F_Y;
  float* obf = ws + F_OF;
  float* obr = ws + F_OR;
  int* len = (int*)(ws + F_LEN);
  float* gbuf = ws + F_G;
  float* hinb = ws + F_HIN;
  float* cumb = ws + F_CUM;
  float* v1 = obf;   // reuse before layers
  float* t2 = obr;   // reuse before layers
  float* e1 = zx;    // reuse after layers
  float* e2 = xbca;  // reuse after layers
  float* out = (float*)d_out;

  // ---- embedding + value encoder ----
  k_embed<<<TOK / 4, 256, 0, stream>>>(src, values, embed, ge_g, ge_b, ve_w1, ve_b1, h, v1);
  gemm_nt<0><<<dim3(DM / 128, TOK / 128), 256, 0, stream>>>(v1, ve_w2, ve_b2, t2, TOK, DM, DM);
  k_haddv<<<TOK / 4, 256, 0, stream>>>(t2, ve_g, ve_bb, mask, h);
  k_lengths<<<Bb, 256, 0, stream>>>(mask, len);

  // ---- layers ----
  for (int i = 0; i < 2; ++i) {
    const float* inw = in_w + (size_t)i * DIP * DM;
    const float* outw = out_w + (size_t)i * DM * DI;
    k_ln512<<<TOK / 4, 256, 0, stream>>>(h, hn);
    for (int d = 0; d < 2; ++d) {
      const float* cw = (d ? conv_w_r : conv_w_f) + (size_t)i * CDIM * 4;
      const float* cb = (d ? conv_b_r : conv_b_f) + (size_t)i * CDIM;
      const float* Al = (d ? A_r : A_f) + (size_t)i * NH;
      const float* db = (d ? dtb_r : dtb_f) + (size_t)i * NH;
      const float* Dk = (d ? D_r : D_f) + (size_t)i * NH;
      const float* nw = (d ? nw_r : nw_f) + (size_t)i * DI;
      float* outbuf = d ? obr : obf;
      if (d == 1) k_flip<<<(TOK * (DM / 4) + 255) / 256, 256, 0, stream>>>(hn, len, DM);
      gemm_nt<0><<<dim3((DIP + 127) / 128, TOK / 128), 256, 0, stream>>>(hn, inw, nullptr, zx, TOK, DIP, DM);
      k_dtda<<<(TOK * NH + 255) / 256, 256, 0, stream>>>(zx, db, Al, dtb, ldab);
      k_conv<<<(TOK * CDIM + 255) / 256, 256, 0, stream>>>(zx, cw, cb, xbca);
      k_chunk<<<Bb * NH * NCH, 256, 0, stream>>>(xbca, dtb, ldab, Dk, ybuf, gbuf, cumb);
      k_chain<<<Bb * NH, 256, 0, stream>>>(gbuf, cumb, hinb);
      k_corr<<<Bb * NH * NCH, 256, 0, stream>>>(xbca, hinb, cumb, ybuf);
      k_gaterms<<<TOK / 4, 256, 0, stream>>>(ybuf, zx, nw);
      gemm_nt<0><<<dim3(DM / 128, TOK / 128), 256, 0, stream>>>(ybuf, outw, nullptr, outbuf, TOK, DM, DI);
    }
    k_flip<<<(TOK * (DM / 4) + 255) / 256, 256, 0, stream>>>(obr, len, DM);
    k_comb<<<TOK / 4, 256, 0, stream>>>(obf, obr, h);
  }

  // ---- heads ----
  gemm_nt<2><<<dim3(DM / 128, TOK / 128), 256, 0, stream>>>(h, expr_w1, expr_b1, e1, TOK, DM, DM);
  gemm_nt<2><<<dim3(DM / 128, TOK / 128), 256, 0, stream>>>(e1, expr_w2, expr_b2, e2, TOK, DM, DM);
  k_mlm<<<TOK / 4, 256, 0, stream>>>(e2, expr_w3, expr_b3, out);
  k_cell<<<(Bb * DM + 255) / 256, 256, 0, stream>>>(h, out + TOK);
  k_cls<<<Bb, 256, 0, stream>>>(h, cls_w1, cls_b1, cls_g1, cls_bb1, cls_w2, cls_b2, cls_g2, cls_bb2,
                                cls_wo, cls_bo, out + TOK + Bb * DM);
}

// Round 3
// 832.490 us; speedup vs baseline: 4.5093x; 2.6446x over previous
//
#include <hip/hip_runtime.h>
#include <hip/hip_bf16.h>
#include <math.h>

// ---- model constants ----
constexpr int Bb = 4, Ls = 1024, DM = 512, DI = 1024, NH = 16, HD = 64, DS = 64;
constexpr int CDIM = DI + 2 * DS;         // 1152
constexpr int DIP  = 2 * DI + 2 * DS + NH; // 2192
constexpr int NPJ  = 2 * DI + 2 * DS;      // 2176 = 17*128 (in-proj GEMM cols, dt split off)
constexpr float EPSf = 1e-5f;
constexpr int TOK = Bb * Ls;              // 4096
constexpr int CH = 64, NCH = Ls / CH;     // chunked scan: 16 chunks of 64

#define DEVI __device__ __forceinline__

using bfrag = __attribute__((ext_vector_type(8))) short;  // 8 bf16 (4 VGPRs)
using f4v   = __attribute__((ext_vector_type(4))) float;  // MFMA accum

DEVI float wsum(float v) {
#pragma unroll
  for (int o = 32; o > 0; o >>= 1) v += __shfl_xor(v, o);
  return v;
}
DEVI float sigmoidf_(float x) { return 1.f / (1.f + __expf(-x)); }
DEVI unsigned short f2bf(float x) {  // RTNE fp32 -> bf16
  union { float f; unsigned u; } c{x};
  unsigned u = c.u;
  u += 0x7fffu + ((u >> 16) & 1u);
  return (unsigned short)(u >> 16);
}

DEVI void ld8(const float* __restrict__ p, int lane, float (&x)[8]) {
  float4 a = *(const float4*)(p + lane * 4);
  float4 b = *(const float4*)(p + 256 + lane * 4);
  x[0] = a.x; x[1] = a.y; x[2] = a.z; x[3] = a.w;
  x[4] = b.x; x[5] = b.y; x[6] = b.z; x[7] = b.w;
}
DEVI void st8(float* __restrict__ p, int lane, const float (&x)[8]) {
  float4 a = make_float4(x[0], x[1], x[2], x[3]);
  float4 b = make_float4(x[4], x[5], x[6], x[7]);
  *(float4*)(p + lane * 4) = a;
  *(float4*)(p + 256 + lane * 4) = b;
}
DEVI void norm8(float (&x)[8]) {
  float s = 0;
#pragma unroll
  for (int j = 0; j < 8; ++j) s += x[j];
  float mean = wsum(s) * (1.f / 512.f);
#pragma unroll
  for (int j = 0; j < 8; ++j) x[j] -= mean;
  float q = 0;
#pragma unroll
  for (int j = 0; j < 8; ++j) q += x[j] * x[j];
  float var = wsum(q) * (1.f / 512.f);
  float inv = rsqrtf(var + EPSf);
#pragma unroll
  for (int j = 0; j < 8; ++j) x[j] *= inv;
}

// ---- embedding + value-encoder stage 1 ----
__global__ __launch_bounds__(256) void k_embed(const int* __restrict__ src, const float* __restrict__ values,
    const float* __restrict__ embed, const float* __restrict__ gg, const float* __restrict__ gb,
    const float* __restrict__ vw1, const float* __restrict__ vb1,
    float* __restrict__ hbuf, float* __restrict__ v1buf) {
  int gw = (blockIdx.x * 256 + threadIdx.x) >> 6;
  int lane = threadIdx.x & 63;
  if (gw >= TOK) return;
  const float* er = embed + (size_t)src[gw] * DM;
  float x[8];
  ld8(er, lane, x);
  norm8(x);
  float g[8], bv[8];
  ld8(gg, lane, g); ld8(gb, lane, bv);
#pragma unroll
  for (int j = 0; j < 8; ++j) x[j] = x[j] * g[j] + bv[j];
  st8(hbuf + (size_t)gw * DM, lane, x);
  float val = fminf(values[gw], 512.f);
  float w1[8], b1[8];
  ld8(vw1, lane, w1); ld8(vb1, lane, b1);
  float v[8];
#pragma unroll
  for (int j = 0; j < 8; ++j) v[j] = fmaxf(val * w1[j] + b1[j], 0.f);
  st8(v1buf + (size_t)gw * DM, lane, v);
}

// h = (h + LN(t2)*g+b) * (mask?0:1)
__global__ __launch_bounds__(256) void k_haddv(const float* __restrict__ t2, const float* __restrict__ g,
    const float* __restrict__ bb, const unsigned char* __restrict__ mask, float* __restrict__ hbuf) {
  int gw = (blockIdx.x * 256 + threadIdx.x) >> 6;
  int lane = threadIdx.x & 63;
  if (gw >= TOK) return;
  float x[8];
  ld8(t2 + (size_t)gw * DM, lane, x);
  norm8(x);
  float gv[8], bv[8], h[8];
  ld8(g, lane, gv); ld8(bb, lane, bv);
  ld8(hbuf + (size_t)gw * DM, lane, h);
  float mf = mask[gw] ? 0.f : 1.f;
#pragma unroll
  for (int j = 0; j < 8; ++j) h[j] = (h[j] + x[j] * gv[j] + bv[j]) * mf;
  st8(hbuf + (size_t)gw * DM, lane, h);
}

// dst = LN(src), no affine
__global__ __launch_bounds__(256) void k_ln512(const float* __restrict__ src, float* __restrict__ dst) {
  int gw = (blockIdx.x * 256 + threadIdx.x) >> 6;
  int lane = threadIdx.x & 63;
  if (gw >= TOK) return;
  float x[8];
  ld8(src + (size_t)gw * DM, lane, x);
  norm8(x);
  st8(dst + (size_t)gw * DM, lane, x);
}

// h = LN((f+r)/2), no affine
__global__ __launch_bounds__(256) void k_comb(const float* __restrict__ f, const float* __restrict__ r,
                                              float* __restrict__ dst) {
  int gw = (blockIdx.x * 256 + threadIdx.x) >> 6;
  int lane = threadIdx.x & 63;
  if (gw >= TOK) return;
  float x[8], y[8];
  ld8(f + (size_t)gw * DM, lane, x);
  ld8(r + (size_t)gw * DM, lane, y);
#pragma unroll
  for (int j = 0; j < 8; ++j) x[j] = 0.5f * (x[j] + y[j]);
  norm8(x);
  st8(dst + (size_t)gw * DM, lane, x);
}

// ---- bf16 MFMA GEMM: C[M,N] = A[M,K] @ W[N,K]^T (+bias, act) ----
// fp32 in/out; fp32->bf16 conversion in LDS staging. Requires M%128==0, N%128==0, K%64==0.
// ACT: 0 none, 1 relu, 2 leaky(0.01)
template <int ACT>
__global__ __launch_bounds__(256) void gemm_bf16(const float* __restrict__ A, const float* __restrict__ W,
    const float* __restrict__ bias, float* __restrict__ C, int M, int N, int K) {
  constexpr int BM = 128, BN = 128, BK = 64;
  __shared__ unsigned short As[BM * BK];  // XOR-swizzled: byte ^= (row&7)<<4
  __shared__ unsigned short Bs[BN * BK];
  int tid = threadIdx.x;
  int bm = blockIdx.y * BM, bn = blockIdx.x * BN;
  int wv = tid >> 6, lane = tid & 63;
  int mb = (wv >> 1) * 64, nb = (wv & 1) * 64;
  int rr = tid >> 2;          // 0..63 (staging row)
  int cc = (tid & 3) * 16;    // staging col chunk
  const float* Ab = A + (size_t)bm * K;
  const float* Wb = W + (size_t)bn * K;

  f4v acc[4][4] = {};

  for (int k0 = 0; k0 < K; k0 += BK) {
#pragma unroll
    for (int half = 0; half < 2; ++half) {
      int r = rr + half * 64;
      {
        const float* s = Ab + (size_t)r * K + k0 + cc;
#pragma unroll
        for (int q = 0; q < 4; ++q) {
          float4 v = *(const float4*)(s + q * 4);
          ushort4 u = make_ushort4(f2bf(v.x), f2bf(v.y), f2bf(v.z), f2bf(v.w));
          int off = ((r * BK + cc + q * 4) * 2) ^ ((r & 7) << 4);
          *(ushort4*)((char*)As + off) = u;
        }
      }
      {
        const float* s = Wb + (size_t)r * K + k0 + cc;
#pragma unroll
        for (int q = 0; q < 4; ++q) {
          float4 v = *(const float4*)(s + q * 4);
          ushort4 u = make_ushort4(f2bf(v.x), f2bf(v.y), f2bf(v.z), f2bf(v.w));
          int off = ((r * BK + cc + q * 4) * 2) ^ ((r & 7) << 4);
          *(ushort4*)((char*)Bs + off) = u;
        }
      }
    }
    __syncthreads();
#pragma unroll
    for (int ks = 0; ks < BK; ks += 32) {
      int kcol = (ks + ((lane >> 4) << 3)) * 2;
      bfrag af[4], bg[4];
#pragma unroll
      for (int i = 0; i < 4; ++i) {
        int rowA = mb + i * 16 + (lane & 15);
        af[i] = *(const bfrag*)((const char*)As + ((rowA * BK * 2 + kcol) ^ ((rowA & 7) << 4)));
        int rowB = nb + i * 16 + (lane & 15);
        bg[i] = *(const bfrag*)((const char*)Bs + ((rowB * BK * 2 + kcol) ^ ((rowB & 7) << 4)));
      }
#pragma unroll
      for (int i = 0; i < 4; ++i)
#pragma unroll
        for (int j = 0; j < 4; ++j)
          acc[i][j] = __builtin_amdgcn_mfma_f32_16x16x32_bf16(af[i], bg[j], acc[i][j], 0, 0, 0);
    }
    __syncthreads();
  }

  // epilogue: D mapping col=lane&15, row=(lane>>4)*4+reg  [m89-verified]
  int cb = bn + nb + (lane & 15);
  int rb = bm + mb + ((lane >> 4) << 2);
#pragma unroll
  for (int j = 0; j < 4; ++j) {
    float bv = bias ? bias[cb + j * 16] : 0.f;
#pragma unroll
    for (int i = 0; i < 4; ++i) {
#pragma unroll
      for (int r = 0; r < 4; ++r) {
        float v = acc[i][j][r] + bv;
        if (ACT == 1) v = fmaxf(v, 0.f);
        if (ACT == 2) v = v > 0.f ? v : 0.01f * v;
        C[(size_t)(rb + i * 16 + r) * N + cb + j * 16] = v;
      }
    }
  }
}

// ---- depthwise causal conv (k=4) + silu on xBC slice of zx ----
__global__ __launch_bounds__(256) void k_conv(const float* __restrict__ zx, const float* __restrict__ cw,
                                              const float* __restrict__ cb, float* __restrict__ xbca) {
  int idx = blockIdx.x * 256 + threadIdx.x;
  if (idx >= TOK * CDIM) return;
  int c = idx % CDIM;
  int bt = idx / CDIM;
  int t = bt & (Ls - 1);
  int b = bt >> 10;
  const float* col = zx + (size_t)(b * Ls) * NPJ + DI + c;
  float4 w = *(const float4*)(cw + c * 4);
  float s = cb[c];
  if (t >= 3) {
    s += w.x * col[(size_t)(t - 3) * NPJ] + w.y * col[(size_t)(t - 2) * NPJ] +
         w.z * col[(size_t)(t - 1) * NPJ] + w.w * col[(size_t)t * NPJ];
  } else {
    float wk[4] = {w.x, w.y, w.z, w.w};
#pragma unroll
    for (int k = 0; k < 4; ++k) {
      int tt = t - 3 + k;
      if (tt >= 0) s += wk[k] * col[(size_t)tt * NPJ];
    }
  }
  xbca[idx] = s * sigmoidf_(s);
}

// ---- dt from fp32 matvec on hn (keeps decay chain in fp32):
// raw = hn[bt] . inw[2176+h] + dt_bias[h]; dt=softplus(raw); ldA=-exp(Alog)*dt
__global__ __launch_bounds__(256) void k_dtda(const float* __restrict__ hn, const float* __restrict__ inw,
    const float* __restrict__ dtbias, const float* __restrict__ Alog,
    float* __restrict__ dt, float* __restrict__ ldA) {
  int gw = (blockIdx.x * 256 + threadIdx.x) >> 6;
  int lane = threadIdx.x & 63;
  if (gw >= TOK) return;
  float x[8];
  ld8(hn + (size_t)gw * DM, lane, x);
  const float* wdt = inw + (size_t)NPJ * DM;
  float myraw = 0.f;
#pragma unroll
  for (int h = 0; h < NH; ++h) {
    float w[8];
    ld8(wdt + (size_t)h * DM, lane, w);
    float s = 0;
#pragma unroll
    for (int j = 0; j < 8; ++j) s += x[j] * w[j];
    s = wsum(s);
    if (lane == h) myraw = s;
  }
  if (lane < NH) {
    float raw = myraw + dtbias[lane];
    float d = raw > 20.f ? raw : log1pf(__expf(raw));
    dt[(size_t)gw * NH + lane] = d;
    ldA[(size_t)gw * NH + lane] = -__expf(Alog[lane]) * d;
  }
}

// ======================= chunked SSD scan =======================
__global__ __launch_bounds__(256) void k_chunk(const float* __restrict__ xbca, const float* __restrict__ dtb,
    const float* __restrict__ ldab, const float* __restrict__ Dk, float* __restrict__ y,
    float* __restrict__ gbuf, float* __restrict__ cumbuf) {
  __shared__ float xs[64][68];
  __shared__ float Bs[64][68];
  __shared__ float Cs[64][68];  // reused as W^T after matmul1
  __shared__ float ldsL[64], sdt[64];
  int blk = blockIdx.x;
  int c = blk & (NCH - 1);
  int bh = blk >> 4;
  int h = bh & (NH - 1);
  int b = bh >> 4;
  int tid = threadIdx.x;
  int t0 = (tid >> 4) * 4;
  int p0 = (tid & 15) * 4;
  int c0 = c * CH;

  {
    int r = tid >> 2;
    int col0 = (tid & 3) * 16;
    const float* rowp = xbca + ((size_t)(b * Ls + c0 + r)) * CDIM;
#pragma unroll
    for (int u = 0; u < 4; ++u) {
      *(float4*)&xs[r][col0 + u * 4] = *(const float4*)(rowp + h * 64 + col0 + u * 4);
      *(float4*)&Bs[r][col0 + u * 4] = *(const float4*)(rowp + DI + col0 + u * 4);
      *(float4*)&Cs[r][col0 + u * 4] = *(const float4*)(rowp + DI + DS + col0 + u * 4);
    }
  }
  if (tid < 64) {
    size_t off = ((size_t)(b * Ls + c0 + tid)) * NH + h;
    sdt[tid] = dtb[off];
    float v = ldab[off];
#pragma unroll
    for (int o = 1; o < 64; o <<= 1) {
      float n = __shfl_up(v, o);
      if (tid >= o) v += n;
    }
    ldsL[tid] = v;
    cumbuf[(size_t)blk * 64 + tid] = __expf(v);
  }
  __syncthreads();

  float acc[4][4] = {};
  for (int k0 = 0; k0 < 64; k0 += 4) {
    float4 a4[4], b4[4];
#pragma unroll
    for (int i = 0; i < 4; ++i) a4[i] = *(const float4*)&Cs[t0 + i][k0];
#pragma unroll
    for (int j = 0; j < 4; ++j) b4[j] = *(const float4*)&Bs[p0 + j][k0];
#pragma unroll
    for (int i = 0; i < 4; ++i)
#pragma unroll
      for (int j = 0; j < 4; ++j) {
        float v = fmaf(a4[i].x, b4[j].x, acc[i][j]);
        v = fmaf(a4[i].y, b4[j].y, v);
        v = fmaf(a4[i].z, b4[j].z, v);
        acc[i][j] = fmaf(a4[i].w, b4[j].w, v);
      }
  }
  __syncthreads();

  {
    float Lt[4], Lsv[4], dts[4];
#pragma unroll
    for (int i = 0; i < 4; ++i) Lt[i] = ldsL[t0 + i];
#pragma unroll
    for (int j = 0; j < 4; ++j) { Lsv[j] = ldsL[p0 + j]; dts[j] = sdt[p0 + j]; }
#pragma unroll
    for (int i = 0; i < 4; ++i)
#pragma unroll
      for (int j = 0; j < 4; ++j) {
        float w = (p0 + j <= t0 + i) ? acc[i][j] * dts[j] * __expf(Lt[i] - Lsv[j]) : 0.f;
        Cs[p0 + j][t0 + i] = w;  // W^T[s][t]
      }
  }
  {
    int r = tid >> 2;
    int col0 = (tid & 3) * 16;
    float f = __expf(ldsL[63] - ldsL[r]) * sdt[r];
#pragma unroll
    for (int u = 0; u < 4; ++u) {
      float4 v = *(float4*)&Bs[r][col0 + u * 4];
      v.x *= f; v.y *= f; v.z *= f; v.w *= f;
      *(float4*)&Bs[r][col0 + u * 4] = v;
    }
  }
  __syncthreads();

  float accY[4][4] = {}, accG[4][4] = {};
  for (int k = 0; k < 64; ++k) {
    float4 wv = *(const float4*)&Cs[k][t0];
    float4 xv = *(const float4*)&xs[k][p0];
    float4 bv = *(const float4*)&Bs[k][t0];
    float wa[4] = {wv.x, wv.y, wv.z, wv.w};
    float ba[4] = {bv.x, bv.y, bv.z, bv.w};
    float xa[4] = {xv.x, xv.y, xv.z, xv.w};
#pragma unroll
    for (int i = 0; i < 4; ++i)
#pragma unroll
      for (int j = 0; j < 4; ++j) {
        accY[i][j] = fmaf(wa[i], xa[j], accY[i][j]);
        accG[i][j] = fmaf(ba[i], xa[j], accG[i][j]);
      }
  }

  float Dh = Dk[h];
#pragma unroll
  for (int i = 0; i < 4; ++i) {
    float4 xr = *(const float4*)&xs[t0 + i][p0];
    float4 o;
    o.x = fmaf(Dh, xr.x, accY[i][0]);
    o.y = fmaf(Dh, xr.y, accY[i][1]);
    o.z = fmaf(Dh, xr.z, accY[i][2]);
    o.w = fmaf(Dh, xr.w, accY[i][3]);
    *(float4*)(y + ((size_t)(b * Ls + c0 + t0 + i)) * DI + h * 64 + p0) = o;
    *(float4*)(gbuf + ((size_t)blk * 64 + t0 + i) * 64 + p0) =
        make_float4(accG[i][0], accG[i][1], accG[i][2], accG[i][3]);
  }
}

__global__ __launch_bounds__(256) void k_chain(const float* __restrict__ gbuf, const float* __restrict__ cumbuf,
                                               float* __restrict__ hin) {
  int bh = blockIdx.x;
  int tid = threadIdx.x;
  float4 hv[4] = {};
  for (int c = 0; c < NCH; ++c) {
    size_t base = ((size_t)(bh * NCH + c)) * 4096;
    float Pc = cumbuf[(size_t)(bh * NCH + c) * 64 + 63];
#pragma unroll
    for (int k = 0; k < 4; ++k) {
      size_t e = base + (size_t)k * 1024 + tid * 4;
      *(float4*)(hin + e) = hv[k];
      float4 g = *(const float4*)(gbuf + e);
      hv[k].x = fmaf(Pc, hv[k].x, g.x);
      hv[k].y = fmaf(Pc, hv[k].y, g.y);
      hv[k].z = fmaf(Pc, hv[k].z, g.z);
      hv[k].w = fmaf(Pc, hv[k].w, g.w);
    }
  }
}

__global__ __launch_bounds__(256) void k_corr(const float* __restrict__ xbca, const float* __restrict__ hin,
                                              const float* __restrict__ cumbuf, float* __restrict__ y) {
  int blk = blockIdx.x;
  int c = blk & (NCH - 1);
  if (c == 0) return;
  __shared__ float Cs2[64][68];
  __shared__ float Hs[64][68];
  __shared__ float cdl[64];
  int bh = blk >> 4;
  int h = bh & (NH - 1);
  int b = bh >> 4;
  int tid = threadIdx.x;
  int t0 = (tid >> 4) * 4;
  int p0 = (tid & 15) * 4;
  int c0 = c * CH;
  {
    int r = tid >> 2;
    int col0 = (tid & 3) * 16;
    const float* rowp = xbca + ((size_t)(b * Ls + c0 + r)) * CDIM + DI + DS;
    const float* hrow = hin + ((size_t)blk) * 4096 + (size_t)r * 64;
#pragma unroll
    for (int u = 0; u < 4; ++u) {
      *(float4*)&Cs2[r][col0 + u * 4] = *(const float4*)(rowp + col0 + u * 4);
      *(float4*)&Hs[r][col0 + u * 4] = *(const float4*)(hrow + col0 + u * 4);
    }
  }
  if (tid < 64) cdl[tid] = cumbuf[(size_t)blk * 64 + tid];
  __syncthreads();

  float acc[4][4] = {};
  for (int k0 = 0; k0 < 64; k0 += 4) {
    float4 a4[4];
#pragma unroll
    for (int i = 0; i < 4; ++i) a4[i] = *(const float4*)&Cs2[t0 + i][k0];
    float a_[4][4];
#pragma unroll
    for (int i = 0; i < 4; ++i) { a_[i][0] = a4[i].x; a_[i][1] = a4[i].y; a_[i][2] = a4[i].z; a_[i][3] = a4[i].w; }
#pragma unroll
    for (int u = 0; u < 4; ++u) {
      float4 hv = *(const float4*)&Hs[k0 + u][p0];
      float ha[4] = {hv.x, hv.y, hv.z, hv.w};
#pragma unroll
      for (int i = 0; i < 4; ++i)
#pragma unroll
        for (int j = 0; j < 4; ++j) acc[i][j] = fmaf(a_[i][u], ha[j], acc[i][j]);
    }
  }
#pragma unroll
  for (int i = 0; i < 4; ++i) {
    float cd = cdl[t0 + i];
    float* yp = y + ((size_t)(b * Ls + c0 + t0 + i)) * DI + h * 64 + p0;
    float4 yv = *(float4*)yp;
    yv.x = fmaf(cd, acc[i][0], yv.x);
    yv.y = fmaf(cd, acc[i][1], yv.y);
    yv.z = fmaf(cd, acc[i][2], yv.z);
    yv.w = fmaf(cd, acc[i][3], yv.w);
    *(float4*)yp = yv;
  }
}
// ================================================================

// ---- y = y*silu(z); y = y*rsqrt(mean(y^2)+eps)*nw ---- (row width 1024)
__global__ __launch_bounds__(256) void k_gaterms(float* __restrict__ y, const float* __restrict__ zx,
                                                 const float* __restrict__ nw) {
  int gw = (blockIdx.x * 256 + threadIdx.x) >> 6;
  int lane = threadIdx.x & 63;
  if (gw >= TOK) return;
  float* yr = y + (size_t)gw * DI;
  const float* zr = zx + (size_t)gw * NPJ;
  float g[16];
  float ss = 0.f;
#pragma unroll
  for (int q = 0; q < 4; ++q) {
    float4 yv = *(const float4*)(yr + lane * 4 + q * 256);
    float4 zv = *(const float4*)(zr + lane * 4 + q * 256);
    g[4 * q + 0] = yv.x * zv.x * sigmoidf_(zv.x);
    g[4 * q + 1] = yv.y * zv.y * sigmoidf_(zv.y);
    g[4 * q + 2] = yv.z * zv.z * sigmoidf_(zv.z);
    g[4 * q + 3] = yv.w * zv.w * sigmoidf_(zv.w);
#pragma unroll
    for (int j = 0; j < 4; ++j) ss += g[4 * q + j] * g[4 * q + j];
  }
  ss = wsum(ss);
  float sc = rsqrtf(ss * (1.f / (float)DI) + EPSf);
#pragma unroll
  for (int q = 0; q < 4; ++q) {
    float4 nv = *(const float4*)(nw + lane * 4 + q * 256);
    float4 o;
    o.x = g[4 * q + 0] * sc * nv.x;
    o.y = g[4 * q + 1] * sc * nv.y;
    o.z = g[4 * q + 2] * sc * nv.z;
    o.w = g[4 * q + 3] * sc * nv.w;
    *(float4*)(yr + lane * 4 + q * 256) = o;
  }
}

// ---- lengths = sum(!mask) per batch ----
__global__ __launch_bounds__(256) void k_lengths(const unsigned char* __restrict__ mask, int* __restrict__ len) {
  int b = blockIdx.x;
  int tid = threadIdx.x;
  int cnt = 0;
  for (int t = tid; t < Ls; t += 256) cnt += mask[b * Ls + t] ? 0 : 1;
#pragma unroll
  for (int o = 32; o > 0; o >>= 1) cnt += __shfl_xor(cnt, o);
  __shared__ int red[4];
  if ((tid & 63) == 0) red[tid >> 6] = cnt;
  __syncthreads();
  if (tid == 0) len[b] = red[0] + red[1] + red[2] + red[3];
}

// ---- in-place smart flip (involution) of [B,Ls,Wd] ----
__global__ __launch_bounds__(256) void k_flip(float* __restrict__ buf, const int* __restrict__ len, int Wd) {
  int idx = blockIdx.x * 256 + threadIdx.x;
  int nc4 = Wd >> 2;
  int total = TOK * nc4;
  if (idx >= total) return;
  int c4 = idx % nc4;
  int bt = idx / nc4;
  int t = bt & (Ls - 1);
  int b = bt >> 10;
  int ln = len[b];
  int pos = (t < ln) ? (ln - 1 - t) : t;
  if (t < pos) {
    float4* p0 = (float4*)(buf + ((size_t)b * Ls + t) * Wd) + c4;
    float4* p1 = (float4*)(buf + ((size_t)b * Ls + pos) * Wd) + c4;
    float4 a = *p0, bv = *p1;
    *p0 = bv;
    *p1 = a;
  }
}

// ---- mlm head: dot(row, w3)+b3 ----
__global__ __launch_bounds__(256) void k_mlm(const float* __restrict__ e2, const float* __restrict__ w3,
                                             const float* __restrict__ b3, float* __restrict__ out) {
  int gw = (blockIdx.x * 256 + threadIdx.x) >> 6;
  int lane = threadIdx.x & 63;
  if (gw >= TOK) return;
  float x[8], w[8];
  ld8(e2 + (size_t)gw * DM, lane, x);
  ld8(w3, lane, w);
  float s = 0;
#pragma unroll
  for (int j = 0; j < 8; ++j) s += x[j] * w[j];
  s = wsum(s);
  if (lane == 0) out[gw] = s + b3[0];
}

__global__ __launch_bounds__(256) void k_cell(const float* __restrict__ h, float* __restrict__ out) {
  int i = blockIdx.x * 256 + threadIdx.x;
  if (i >= Bb * DM) return;
  int b = i >> 9, c = i & 511;
  out[i] = h[(size_t)b * Ls * DM + c];
}

// ---- classifier head ----
__global__ __launch_bounds__(256) void k_cls(const float* __restrict__ h,
    const float* __restrict__ w1, const float* __restrict__ b1, const float* __restrict__ g1, const float* __restrict__ bb1,
    const float* __restrict__ w2, const float* __restrict__ b2, const float* __restrict__ g2, const float* __restrict__ bb2,
    const float* __restrict__ wo, const float* __restrict__ bo, float* __restrict__ out) {
  __shared__ float xb[512];
  __shared__ float cc[512];
  __shared__ float red[4];
  int b = blockIdx.x, tid = threadIdx.x;
  const float* cell = h + (size_t)b * Ls * DM;
  xb[tid] = cell[tid];
  xb[tid + 256] = cell[tid + 256];
  __syncthreads();

  for (int pass = 0; pass < 2; ++pass) {
    const float* W = pass ? w2 : w1;
    const float* bias = pass ? b2 : b1;
    const float* g = pass ? g2 : g1;
    const float* bt = pass ? bb2 : bb1;
#pragma unroll 1
    for (int jj = 0; jj < 2; ++jj) {
      int j = tid + jj * 256;
      const float* wr = W + (size_t)j * DM;
      float sum = bias[j];
      for (int k = 0; k < DM; k += 4) {
        float4 wv = *(const float4*)(wr + k);
        sum += wv.x * xb[k] + wv.y * xb[k + 1] + wv.z * xb[k + 2] + wv.w * xb[k + 3];
      }
      cc[j] = fmaxf(sum, 0.f);
    }
    __syncthreads();
    float v0 = cc[tid], v1 = cc[tid + 256];
    float s = wsum(v0 + v1);
    if ((tid & 63) == 0) red[tid >> 6] = s;
    __syncthreads();
    float mean = (red[0] + red[1] + red[2] + red[3]) * (1.f / 512.f);
    __syncthreads();
    float d0 = v0 - mean, d1 = v1 - mean;
    float q = wsum(d0 * d0 + d1 * d1);
    if ((tid & 63) == 0) red[tid >> 6] = q;
    __syncthreads();
    float var = (red[0] + red[1] + red[2] + red[3]) * (1.f / 512.f);
    float inv = rsqrtf(var + EPSf);
    xb[tid] = d0 * inv * g[tid] + bt[tid];
    xb[tid + 256] = d1 * inv * g[tid + 256] + bt[tid + 256];
    __syncthreads();
  }
  if (tid < 164) {
    const float* wr = wo + (size_t)tid * DM;
    float sum = bo[tid];
    for (int k = 0; k < DM; k += 4) {
      float4 wv = *(const float4*)(wr + k);
      sum += wv.x * xb[k] + wv.y * xb[k + 1] + wv.z * xb[k + 2] + wv.w * xb[k + 3];
    }
    out[b * 164 + tid] = sum;
  }
}

// ---- workspace layout (floats) ----
constexpr size_t F_H  = 0;
constexpr size_t F_HN = F_H + (size_t)TOK * DM;
constexpr size_t F_ZX = F_HN + (size_t)TOK * DM;
constexpr size_t F_XB = F_ZX + (size_t)TOK * NPJ;
constexpr size_t F_DT = F_XB + (size_t)TOK * CDIM;
constexpr size_t F_DA = F_DT + (size_t)TOK * NH;
constexpr size_t F_Y  = F_DA + (size_t)TOK * NH;
constexpr size_t F_OF = F_Y + (size_t)TOK * DI;
constexpr size_t F_OR = F_OF + (size_t)TOK * DM;
constexpr size_t F_LEN = F_OR + (size_t)TOK * DM;
constexpr size_t F_G   = F_LEN + 16;
constexpr size_t F_HIN = F_G + (size_t)Bb * NH * NCH * HD * DS;
constexpr size_t F_CUM = F_HIN + (size_t)Bb * NH * NCH * HD * DS;

extern "C" void kernel_launch(void* const* d_in, const int* in_sizes, int n_in,
                              void* d_out, int out_size, void* d_ws, size_t ws_size,
                              hipStream_t stream) {
  const int* src = (const int*)d_in[0];
  const float* values = (const float*)d_in[1];
  const unsigned char* mask = (const unsigned char*)d_in[2];
  const float* embed = (const float*)d_in[3];
  const float* ge_g = (const float*)d_in[4];
  const float* ge_b = (const float*)d_in[5];
  const float* ve_w1 = (const float*)d_in[6];
  const float* ve_b1 = (const float*)d_in[7];
  const float* ve_w2 = (const float*)d_in[8];
  const float* ve_b2 = (const float*)d_in[9];
  const float* ve_g = (const float*)d_in[10];
  const float* ve_bb = (const float*)d_in[11];
  const float* in_w = (const float*)d_in[12];
  const float* conv_w_f = (const float*)d_in[13];
  const float* conv_b_f = (const float*)d_in[14];
  const float* A_f = (const float*)d_in[15];
  const float* dtb_f = (const float*)d_in[16];
  const float* D_f = (const float*)d_in[17];
  const float* nw_f = (const float*)d_in[18];
  const float* conv_w_r = (const float*)d_in[19];
  const float* conv_b_r = (const float*)d_in[20];
  const float* A_r = (const float*)d_in[21];
  const float* dtb_r = (const float*)d_in[22];
  const float* D_r = (const float*)d_in[23];
  const float* nw_r = (const float*)d_in[24];
  const float* out_w = (const float*)d_in[25];
  const float* expr_w1 = (const float*)d_in[26];
  const float* expr_b1 = (const float*)d_in[27];
  const float* expr_w2 = (const float*)d_in[28];
  const float* expr_b2 = (const float*)d_in[29];
  const float* expr_w3 = (const float*)d_in[30];
  const float* expr_b3 = (const float*)d_in[31];
  const float* cls_w1 = (const float*)d_in[32];
  const float* cls_b1 = (const float*)d_in[33];
  const float* cls_g1 = (const float*)d_in[34];
  const float* cls_bb1 = (const float*)d_in[35];
  const float* cls_w2 = (const float*)d_in[36];
  const float* cls_b2 = (const float*)d_in[37];
  const float* cls_g2 = (const float*)d_in[38];
  const float* cls_bb2 = (const float*)d_in[39];
  const float* cls_wo = (const float*)d_in[40];
  const float* cls_bo = (const float*)d_in[41];

  float* ws = (float*)d_ws;
  float* h = ws + F_H;
  float* hn = ws + F_HN;
  float* zx = ws + F_ZX;
  float* xbca = ws + F_XB;
  float* dtb = ws + F_DT;
  float* ldab = ws + F_DA;
  float* ybuf = ws + F_Y;
  float* obf = ws + F_OF;
  float* obr = ws + F_OR;
  int* len = (int*)(ws + F_LEN);
  float* gbuf = ws + F_G;
  float* hinb = ws + F_HIN;
  float* cumb = ws + F_CUM;
  float* v1 = obf;   // reuse before layers
  float* t2 = obr;   // reuse before layers
  float* e1 = zx;    // reuse after layers
  float* e2 = xbca;  // reuse after layers
  float* out = (float*)d_out;

  // ---- embedding + value encoder ----
  k_embed<<<TOK / 4, 256, 0, stream>>>(src, values, embed, ge_g, ge_b, ve_w1, ve_b1, h, v1);
  gemm_bf16<0><<<dim3(DM / 128, TOK / 128), 256, 0, stream>>>(v1, ve_w2, ve_b2, t2, TOK, DM, DM);
  k_haddv<<<TOK / 4, 256, 0, stream>>>(t2, ve_g, ve_bb, mask, h);
  k_lengths<<<Bb, 256, 0, stream>>>(mask, len);

  // ---- layers ----
  for (int i = 0; i < 2; ++i) {
    const float* inw = in_w + (size_t)i * DIP * DM;
    const float* outw = out_w + (size_t)i * DM * DI;
    k_ln512<<<TOK / 4, 256, 0, stream>>>(h, hn);
    for (int d = 0; d < 2; ++d) {
      const float* cw = (d ? conv_w_r : conv_w_f) + (size_t)i * CDIM * 4;
      const float* cb = (d ? conv_b_r : conv_b_f) + (size_t)i * CDIM;
      const float* Al = (d ? A_r : A_f) + (size_t)i * NH;
      const float* db = (d ? dtb_r : dtb_f) + (size_t)i * NH;
      const float* Dk = (d ? D_r : D_f) + (size_t)i * NH;
      const float* nw = (d ? nw_r : nw_f) + (size_t)i * DI;
      float* outbuf = d ? obr : obf;
      if (d == 1) k_flip<<<(TOK * (DM / 4) + 255) / 256, 256, 0, stream>>>(hn, len, DM);
      gemm_bf16<0><<<dim3(NPJ / 128, TOK / 128), 256, 0, stream>>>(hn, inw, nullptr, zx, TOK, NPJ, DM);
      k_dtda<<<TOK / 4, 256, 0, stream>>>(hn, inw, db, Al, dtb, ldab);
      k_conv<<<(TOK * CDIM + 255) / 256, 256, 0, stream>>>(zx, cw, cb, xbca);
      k_chunk<<<Bb * NH * NCH, 256, 0, stream>>>(xbca, dtb, ldab, Dk, ybuf, gbuf, cumb);
      k_chain<<<Bb * NH, 256, 0, stream>>>(gbuf, cumb, hinb);
      k_corr<<<Bb * NH * NCH, 256, 0, stream>>>(xbca, hinb, cumb, ybuf);
      k_gaterms<<<TOK / 4, 256, 0, stream>>>(ybuf, zx, nw);
      gemm_bf16<0><<<dim3(DM / 128, TOK / 128), 256, 0, stream>>>(ybuf, outw, nullptr, outbuf, TOK, DM, DI);
    }
    k_flip<<<(TOK * (DM / 4) + 255) / 256, 256, 0, stream>>>(obr, len, DM);
    k_comb<<<TOK / 4, 256, 0, stream>>>(obf, obr, h);
  }

  // ---- heads ----
  gemm_bf16<2><<<dim3(DM / 128, TOK / 128), 256, 0, stream>>>(h, expr_w1, expr_b1, e1, TOK, DM, DM);
  gemm_bf16<2><<<dim3(DM / 128, TOK / 128), 256, 0, stream>>>(e1, expr_w2, expr_b2, e2, TOK, DM, DM);
  k_mlm<<<TOK / 4, 256, 0, stream>>>(e2, expr_w3, expr_b3, out);
  k_cell<<<(Bb * DM + 255) / 256, 256, 0, stream>>>(h, out + TOK);
  k_cls<<<Bb, 256, 0, stream>>>(h, cls_w1, cls_b1, cls_g1, cls_bb1, cls_w2, cls_b2, cls_g2, cls_bb2,
                                cls_wo, cls_bo, out + TOK + Bb * DM);
}

// Round 4
// 654.390 us; speedup vs baseline: 5.7365x; 1.2722x over previous
//
#include <hip/hip_runtime.h>
#include <hip/hip_bf16.h>
#include <math.h>

// ---- model constants ----
constexpr int Bb = 4, Ls = 1024, DM = 512, DI = 1024, NH = 16, HD = 64, DS = 64;
constexpr int CDIM = DI + 2 * DS;          // 1152
constexpr int DIP  = 2 * DI + 2 * DS + NH; // 2192
constexpr int NPJ  = 2 * DI + 2 * DS;      // 2176 = 17*128
constexpr float EPSf = 1e-5f;
constexpr int TOK = Bb * Ls;               // 4096
constexpr int CH = 64, NCH = Ls / CH;

#define DEVI __device__ __forceinline__

using bfrag = __attribute__((ext_vector_type(8))) short;
using f4v   = __attribute__((ext_vector_type(4))) float;

#define GLOAD16(gp, lp)                                                              \
  __builtin_amdgcn_global_load_lds((__attribute__((address_space(1))) void*)(gp),   \
                                   (__attribute__((address_space(3))) void*)(lp),   \
                                   16, 0, 0)

DEVI float wsum(float v) {
#pragma unroll
  for (int o = 32; o > 0; o >>= 1) v += __shfl_xor(v, o);
  return v;
}
DEVI float sigmoidf_(float x) { return 1.f / (1.f + __expf(-x)); }
DEVI unsigned short f2bf(float x) {
  union { float f; unsigned u; } c{x};
  unsigned u = c.u;
  u += 0x7fffu + ((u >> 16) & 1u);
  return (unsigned short)(u >> 16);
}

DEVI void ld8(const float* __restrict__ p, int lane, float (&x)[8]) {
  float4 a = *(const float4*)(p + lane * 4);
  float4 b = *(const float4*)(p + 256 + lane * 4);
  x[0] = a.x; x[1] = a.y; x[2] = a.z; x[3] = a.w;
  x[4] = b.x; x[5] = b.y; x[6] = b.z; x[7] = b.w;
}
DEVI void st8(float* __restrict__ p, int lane, const float (&x)[8]) {
  *(float4*)(p + lane * 4) = make_float4(x[0], x[1], x[2], x[3]);
  *(float4*)(p + 256 + lane * 4) = make_float4(x[4], x[5], x[6], x[7]);
}
DEVI void st8bf(unsigned short* __restrict__ p, int lane, const float (&x)[8]) {
  *(ushort4*)(p + lane * 4) = make_ushort4(f2bf(x[0]), f2bf(x[1]), f2bf(x[2]), f2bf(x[3]));
  *(ushort4*)(p + 256 + lane * 4) = make_ushort4(f2bf(x[4]), f2bf(x[5]), f2bf(x[6]), f2bf(x[7]));
}
DEVI void norm8(float (&x)[8]) {
  float s = 0;
#pragma unroll
  for (int j = 0; j < 8; ++j) s += x[j];
  float mean = wsum(s) * (1.f / 512.f);
#pragma unroll
  for (int j = 0; j < 8; ++j) x[j] -= mean;
  float q = 0;
#pragma unroll
  for (int j = 0; j < 8; ++j) q += x[j] * x[j];
  float var = wsum(q) * (1.f / 512.f);
  float inv = rsqrtf(var + EPSf);
#pragma unroll
  for (int j = 0; j < 8; ++j) x[j] *= inv;
}

// ---- fp32 -> bf16 bulk convert (weights), 8 elems/thread ----
__global__ __launch_bounds__(256) void k_w2bf(const float* __restrict__ in,
                                              unsigned short* __restrict__ out, int n8) {
  int i = blockIdx.x * 256 + threadIdx.x;
  if (i >= n8) return;
  const float4* p = (const float4*)in + (size_t)i * 2;
  float4 a = p[0], b = p[1];
  *((ushort4*)out + (size_t)i * 2) = make_ushort4(f2bf(a.x), f2bf(a.y), f2bf(a.z), f2bf(a.w));
  *((ushort4*)out + (size_t)i * 2 + 1) = make_ushort4(f2bf(b.x), f2bf(b.y), f2bf(b.z), f2bf(b.w));
}

// ---- embedding + value-encoder stage 1 ----
__global__ __launch_bounds__(256) void k_embed(const int* __restrict__ src, const float* __restrict__ values,
    const float* __restrict__ embed, const float* __restrict__ gg, const float* __restrict__ gb,
    const float* __restrict__ vw1, const float* __restrict__ vb1,
    float* __restrict__ hbuf, unsigned short* __restrict__ v1bf) {
  int gw = (blockIdx.x * 256 + threadIdx.x) >> 6;
  int lane = threadIdx.x & 63;
  if (gw >= TOK) return;
  const float* er = embed + (size_t)src[gw] * DM;
  float x[8];
  ld8(er, lane, x);
  norm8(x);
  float g[8], bv[8];
  ld8(gg, lane, g); ld8(gb, lane, bv);
#pragma unroll
  for (int j = 0; j < 8; ++j) x[j] = x[j] * g[j] + bv[j];
  st8(hbuf + (size_t)gw * DM, lane, x);
  float val = fminf(values[gw], 512.f);
  float w1[8], b1[8];
  ld8(vw1, lane, w1); ld8(vb1, lane, b1);
  float v[8];
#pragma unroll
  for (int j = 0; j < 8; ++j) v[j] = fmaxf(val * w1[j] + b1[j], 0.f);
  st8bf(v1bf + (size_t)gw * DM, lane, v);
}

// h = (h + LN(t2)*g+b) * (mask?0:1)
__global__ __launch_bounds__(256) void k_haddv(const float* __restrict__ t2, const float* __restrict__ g,
    const float* __restrict__ bb, const unsigned char* __restrict__ mask, float* __restrict__ hbuf) {
  int gw = (blockIdx.x * 256 + threadIdx.x) >> 6;
  int lane = threadIdx.x & 63;
  if (gw >= TOK) return;
  float x[8];
  ld8(t2 + (size_t)gw * DM, lane, x);
  norm8(x);
  float gv[8], bv[8], h[8];
  ld8(g, lane, gv); ld8(bb, lane, bv);
  ld8(hbuf + (size_t)gw * DM, lane, h);
  float mf = mask[gw] ? 0.f : 1.f;
#pragma unroll
  for (int j = 0; j < 8; ++j) h[j] = (h[j] + x[j] * gv[j] + bv[j]) * mf;
  st8(hbuf + (size_t)gw * DM, lane, h);
}

// dst(bf16) = LN(src), no affine
__global__ __launch_bounds__(256) void k_ln512(const float* __restrict__ src, unsigned short* __restrict__ dst) {
  int gw = (blockIdx.x * 256 + threadIdx.x) >> 6;
  int lane = threadIdx.x & 63;
  if (gw >= TOK) return;
  float x[8];
  ld8(src + (size_t)gw * DM, lane, x);
  norm8(x);
  st8bf(dst + (size_t)gw * DM, lane, x);
}

// h = LN((f+r)/2) -> fp32 dst + bf16 dstbf
__global__ __launch_bounds__(256) void k_comb(const float* __restrict__ f, const float* __restrict__ r,
                                              float* __restrict__ dst, unsigned short* __restrict__ dstbf) {
  int gw = (blockIdx.x * 256 + threadIdx.x) >> 6;
  int lane = threadIdx.x & 63;
  if (gw >= TOK) return;
  float x[8], y[8];
  ld8(f + (size_t)gw * DM, lane, x);
  ld8(r + (size_t)gw * DM, lane, y);
#pragma unroll
  for (int j = 0; j < 8; ++j) x[j] = 0.5f * (x[j] + y[j]);
  norm8(x);
  st8(dst + (size_t)gw * DM, lane, x);
  st8bf(dstbf + (size_t)gw * DM, lane, x);
}

// ---- bf16 MFMA GEMM (m97 structure): C[M,N] = A[M,K] @ W[N,K]^T (+bias, act) ----
// A, W bf16; out fp32 (OMODE 0) or bf16 (OMODE 1). M%128==0, N%128==0, K%64==0.
// global_load_lds width-16 staging, XOR-swizzled via pre-swizzled global source.
template <int ACT, int OMODE>
__global__ __launch_bounds__(256) void gemm_bf(const unsigned short* __restrict__ A,
    const unsigned short* __restrict__ W, const float* __restrict__ bias,
    void* __restrict__ Cout, int M, int N, int K) {
  constexpr int BK = 64;
  __shared__ unsigned short As[128 * BK];
  __shared__ unsigned short Bs[128 * BK];
  int tid = threadIdx.x;
  int bm = blockIdx.y * 128, bn = blockIdx.x * 128;
  int wv = tid >> 6, lane = tid & 63;
  int mb = (wv >> 1) * 64, nb = (wv & 1) * 64;
  int rA = lane >> 3;                 // row within 8-row chunk
  int cswz = (lane & 7) ^ rA;         // pre-swizzled source col-block
  f4v acc[4][4] = {};

  for (int k0 = 0; k0 < K; k0 += BK) {
#pragma unroll
    for (int q = 0; q < 4; ++q) {
      int ch = wv * 4 + q;  // 16 chunks of 8 rows
      const unsigned short* ga = A + (size_t)(bm + ch * 8 + rA) * K + k0 + cswz * 8;
      GLOAD16(ga, &As[ch * 512]);
      const unsigned short* gb = W + (size_t)(bn + ch * 8 + rA) * K + k0 + cswz * 8;
      GLOAD16(gb, &Bs[ch * 512]);
    }
    __syncthreads();
#pragma unroll
    for (int ks = 0; ks < BK; ks += 32) {
      int kb = (ks >> 3) + (lane >> 4);
      bfrag af[4], bg[4];
#pragma unroll
      for (int i = 0; i < 4; ++i) {
        int ra_ = mb + i * 16 + (lane & 15);
        af[i] = *(const bfrag*)((const char*)As + ((ra_ * 128 + kb * 16) ^ ((ra_ & 7) << 4)));
        int rb_ = nb + i * 16 + (lane & 15);
        bg[i] = *(const bfrag*)((const char*)Bs + ((rb_ * 128 + kb * 16) ^ ((rb_ & 7) << 4)));
      }
#pragma unroll
      for (int i = 0; i < 4; ++i)
#pragma unroll
        for (int j = 0; j < 4; ++j)
          acc[i][j] = __builtin_amdgcn_mfma_f32_16x16x32_bf16(af[i], bg[j], acc[i][j], 0, 0, 0);
    }
    __syncthreads();
  }

  int cb = bn + nb + (lane & 15);
  int rb = bm + mb + ((lane >> 4) << 2);
#pragma unroll
  for (int j = 0; j < 4; ++j) {
    float bv = bias ? bias[cb + j * 16] : 0.f;
#pragma unroll
    for (int i = 0; i < 4; ++i) {
#pragma unroll
      for (int r = 0; r < 4; ++r) {
        float v = acc[i][j][r] + bv;
        if (ACT == 1) v = fmaxf(v, 0.f);
        if (ACT == 2) v = v > 0.f ? v : 0.01f * v;
        size_t idx = (size_t)(rb + i * 16 + r) * N + cb + j * 16;
        if (OMODE == 0) ((float*)Cout)[idx] = v;
        else ((unsigned short*)Cout)[idx] = f2bf(v);
      }
    }
  }
}

// ---- depthwise causal conv (k=4) + silu on xBC slice of zx ----
__global__ __launch_bounds__(256) void k_conv(const float* __restrict__ zx, const float* __restrict__ cw,
                                              const float* __restrict__ cb, float* __restrict__ xbca) {
  int idx = blockIdx.x * 256 + threadIdx.x;
  if (idx >= TOK * CDIM) return;
  int c = idx % CDIM;
  int bt = idx / CDIM;
  int t = bt & (Ls - 1);
  int b = bt >> 10;
  const float* col = zx + (size_t)(b * Ls) * NPJ + DI + c;
  float4 w = *(const float4*)(cw + c * 4);
  float s = cb[c];
  if (t >= 3) {
    s += w.x * col[(size_t)(t - 3) * NPJ] + w.y * col[(size_t)(t - 2) * NPJ] +
         w.z * col[(size_t)(t - 1) * NPJ] + w.w * col[(size_t)t * NPJ];
  } else {
    float wk[4] = {w.x, w.y, w.z, w.w};
#pragma unroll
    for (int k = 0; k < 4; ++k) {
      int tt = t - 3 + k;
      if (tt >= 0) s += wk[k] * col[(size_t)tt * NPJ];
    }
  }
  xbca[idx] = s * sigmoidf_(s);
}

// ---- dt path fully fp32: reads h, applies LN itself (flip-aware for reverse) ----
__global__ __launch_bounds__(256) void k_dtda(const float* __restrict__ h, const float* __restrict__ inw,
    const float* __restrict__ dtbias, const float* __restrict__ Alog, const int* __restrict__ len,
    int rev, float* __restrict__ dt, float* __restrict__ ldA) {
  int gw = (blockIdx.x * 256 + threadIdx.x) >> 6;
  int lane = threadIdx.x & 63;
  if (gw >= TOK) return;
  int srow = gw;
  if (rev) {
    int t = gw & (Ls - 1), b = gw >> 10;
    int ln = len[b];
    int pos = (t < ln) ? (ln - 1 - t) : t;
    srow = b * Ls + pos;
  }
  float x[8];
  ld8(h + (size_t)srow * DM, lane, x);
  norm8(x);
  const float* wdt = inw + (size_t)NPJ * DM;
  float myraw = 0.f;
#pragma unroll
  for (int hh = 0; hh < NH; ++hh) {
    float w[8];
    ld8(wdt + (size_t)hh * DM, lane, w);
    float s = 0;
#pragma unroll
    for (int j = 0; j < 8; ++j) s += x[j] * w[j];
    s = wsum(s);
    if (lane == hh) myraw = s;
  }
  if (lane < NH) {
    float raw = myraw + dtbias[lane];
    float d = raw > 20.f ? raw : log1pf(__expf(raw));
    dt[(size_t)gw * NH + lane] = d;
    ldA[(size_t)gw * NH + lane] = -__expf(Alog[lane]) * d;
  }
}

// ======================= chunked SSD scan =======================
__global__ __launch_bounds__(256) void k_chunk(const float* __restrict__ xbca, const float* __restrict__ dtb,
    const float* __restrict__ ldab, const float* __restrict__ Dk, float* __restrict__ y,
    float* __restrict__ gbuf, float* __restrict__ cumbuf) {
  __shared__ float xs[64][68];
  __shared__ float Bs[64][68];
  __shared__ float Cs[64][68];
  __shared__ float ldsL[64], sdt[64];
  int blk = blockIdx.x;
  int c = blk & (NCH - 1);
  int bh = blk >> 4;
  int h = bh & (NH - 1);
  int b = bh >> 4;
  int tid = threadIdx.x;
  int t0 = (tid >> 4) * 4;
  int p0 = (tid & 15) * 4;
  int c0 = c * CH;

  {
    int r = tid >> 2;
    int col0 = (tid & 3) * 16;
    const float* rowp = xbca + ((size_t)(b * Ls + c0 + r)) * CDIM;
#pragma unroll
    for (int u = 0; u < 4; ++u) {
      *(float4*)&xs[r][col0 + u * 4] = *(const float4*)(rowp + h * 64 + col0 + u * 4);
      *(float4*)&Bs[r][col0 + u * 4] = *(const float4*)(rowp + DI + col0 + u * 4);
      *(float4*)&Cs[r][col0 + u * 4] = *(const float4*)(rowp + DI + DS + col0 + u * 4);
    }
  }
  if (tid < 64) {
    size_t off = ((size_t)(b * Ls + c0 + tid)) * NH + h;
    sdt[tid] = dtb[off];
    float v = ldab[off];
#pragma unroll
    for (int o = 1; o < 64; o <<= 1) {
      float n = __shfl_up(v, o);
      if (tid >= o) v += n;
    }
    ldsL[tid] = v;
    cumbuf[(size_t)blk * 64 + tid] = __expf(v);
  }
  __syncthreads();

  float acc[4][4] = {};
  for (int k0 = 0; k0 < 64; k0 += 4) {
    float4 a4[4], b4[4];
#pragma unroll
    for (int i = 0; i < 4; ++i) a4[i] = *(const float4*)&Cs[t0 + i][k0];
#pragma unroll
    for (int j = 0; j < 4; ++j) b4[j] = *(const float4*)&Bs[p0 + j][k0];
#pragma unroll
    for (int i = 0; i < 4; ++i)
#pragma unroll
      for (int j = 0; j < 4; ++j) {
        float v = fmaf(a4[i].x, b4[j].x, acc[i][j]);
        v = fmaf(a4[i].y, b4[j].y, v);
        v = fmaf(a4[i].z, b4[j].z, v);
        acc[i][j] = fmaf(a4[i].w, b4[j].w, v);
      }
  }
  __syncthreads();

  {
    float Lt[4], Lsv[4], dts[4];
#pragma unroll
    for (int i = 0; i < 4; ++i) Lt[i] = ldsL[t0 + i];
#pragma unroll
    for (int j = 0; j < 4; ++j) { Lsv[j] = ldsL[p0 + j]; dts[j] = sdt[p0 + j]; }
#pragma unroll
    for (int i = 0; i < 4; ++i)
#pragma unroll
      for (int j = 0; j < 4; ++j) {
        float w = (p0 + j <= t0 + i) ? acc[i][j] * dts[j] * __expf(Lt[i] - Lsv[j]) : 0.f;
        Cs[p0 + j][t0 + i] = w;
      }
  }
  {
    int r = tid >> 2;
    int col0 = (tid & 3) * 16;
    float f = __expf(ldsL[63] - ldsL[r]) * sdt[r];
#pragma unroll
    for (int u = 0; u < 4; ++u) {
      float4 v = *(float4*)&Bs[r][col0 + u * 4];
      v.x *= f; v.y *= f; v.z *= f; v.w *= f;
      *(float4*)&Bs[r][col0 + u * 4] = v;
    }
  }
  __syncthreads();

  float accY[4][4] = {}, accG[4][4] = {};
  for (int k = 0; k < 64; ++k) {
    float4 wv = *(const float4*)&Cs[k][t0];
    float4 xv = *(const float4*)&xs[k][p0];
    float4 bv = *(const float4*)&Bs[k][t0];
    float wa[4] = {wv.x, wv.y, wv.z, wv.w};
    float ba[4] = {bv.x, bv.y, bv.z, bv.w};
    float xa[4] = {xv.x, xv.y, xv.z, xv.w};
#pragma unroll
    for (int i = 0; i < 4; ++i)
#pragma unroll
      for (int j = 0; j < 4; ++j) {
        accY[i][j] = fmaf(wa[i], xa[j], accY[i][j]);
        accG[i][j] = fmaf(ba[i], xa[j], accG[i][j]);
      }
  }

  float Dh = Dk[h];
#pragma unroll
  for (int i = 0; i < 4; ++i) {
    float4 xr = *(const float4*)&xs[t0 + i][p0];
    float4 o;
    o.x = fmaf(Dh, xr.x, accY[i][0]);
    o.y = fmaf(Dh, xr.y, accY[i][1]);
    o.z = fmaf(Dh, xr.z, accY[i][2]);
    o.w = fmaf(Dh, xr.w, accY[i][3]);
    *(float4*)(y + ((size_t)(b * Ls + c0 + t0 + i)) * DI + h * 64 + p0) = o;
    *(float4*)(gbuf + ((size_t)blk * 64 + t0 + i) * 64 + p0) =
        make_float4(accG[i][0], accG[i][1], accG[i][2], accG[i][3]);
  }
}

// in-place: gbuf[c] becomes h_in[c] (state before chunk c)
__global__ __launch_bounds__(256) void k_chain(float* __restrict__ gbuf, const float* __restrict__ cumbuf) {
  int bh = blockIdx.x;
  int tid = threadIdx.x;
  float4 hv[4] = {};
  for (int c = 0; c < NCH; ++c) {
    size_t base = ((size_t)(bh * NCH + c)) * 4096;
    float Pc = cumbuf[(size_t)(bh * NCH + c) * 64 + 63];
#pragma unroll
    for (int k = 0; k < 4; ++k) {
      size_t e = base + (size_t)k * 1024 + tid * 4;
      float4 g = *(const float4*)(gbuf + e);
      *(float4*)(gbuf + e) = hv[k];
      hv[k].x = fmaf(Pc, hv[k].x, g.x);
      hv[k].y = fmaf(Pc, hv[k].y, g.y);
      hv[k].z = fmaf(Pc, hv[k].z, g.z);
      hv[k].w = fmaf(Pc, hv[k].w, g.w);
    }
  }
}

__global__ __launch_bounds__(256) void k_corr(const float* __restrict__ xbca, const float* __restrict__ hin,
                                              const float* __restrict__ cumbuf, float* __restrict__ y) {
  int blk = blockIdx.x;
  int c = blk & (NCH - 1);
  if (c == 0) return;
  __shared__ float Cs2[64][68];
  __shared__ float Hs[64][68];
  __shared__ float cdl[64];
  int bh = blk >> 4;
  int h = bh & (NH - 1);
  int b = bh >> 4;
  int tid = threadIdx.x;
  int t0 = (tid >> 4) * 4;
  int p0 = (tid & 15) * 4;
  int c0 = c * CH;
  {
    int r = tid >> 2;
    int col0 = (tid & 3) * 16;
    const float* rowp = xbca + ((size_t)(b * Ls + c0 + r)) * CDIM + DI + DS;
    const float* hrow = hin + ((size_t)blk) * 4096 + (size_t)r * 64;
#pragma unroll
    for (int u = 0; u < 4; ++u) {
      *(float4*)&Cs2[r][col0 + u * 4] = *(const float4*)(rowp + col0 + u * 4);
      *(float4*)&Hs[r][col0 + u * 4] = *(const float4*)(hrow + col0 + u * 4);
    }
  }
  if (tid < 64) cdl[tid] = cumbuf[(size_t)blk * 64 + tid];
  __syncthreads();

  float acc[4][4] = {};
  for (int k0 = 0; k0 < 64; k0 += 4) {
    float4 a4[4];
#pragma unroll
    for (int i = 0; i < 4; ++i) a4[i] = *(const float4*)&Cs2[t0 + i][k0];
    float a_[4][4];
#pragma unroll
    for (int i = 0; i < 4; ++i) { a_[i][0] = a4[i].x; a_[i][1] = a4[i].y; a_[i][2] = a4[i].z; a_[i][3] = a4[i].w; }
#pragma unroll
    for (int u = 0; u < 4; ++u) {
      float4 hv = *(const float4*)&Hs[k0 + u][p0];
      float ha[4] = {hv.x, hv.y, hv.z, hv.w};
#pragma unroll
      for (int i = 0; i < 4; ++i)
#pragma unroll
        for (int j = 0; j < 4; ++j) acc[i][j] = fmaf(a_[i][u], ha[j], acc[i][j]);
    }
  }
#pragma unroll
  for (int i = 0; i < 4; ++i) {
    float cd = cdl[t0 + i];
    float* yp = y + ((size_t)(b * Ls + c0 + t0 + i)) * DI + h * 64 + p0;
    float4 yv = *(float4*)yp;
    yv.x = fmaf(cd, acc[i][0], yv.x);
    yv.y = fmaf(cd, acc[i][1], yv.y);
    yv.z = fmaf(cd, acc[i][2], yv.z);
    yv.w = fmaf(cd, acc[i][3], yv.w);
    *(float4*)yp = yv;
  }
}
// ================================================================

// ---- y*silu(z), RMSNorm*nw -> bf16 out ----
__global__ __launch_bounds__(256) void k_gaterms(const float* __restrict__ y, const float* __restrict__ zx,
                                                 const float* __restrict__ nw, unsigned short* __restrict__ ybf) {
  int gw = (blockIdx.x * 256 + threadIdx.x) >> 6;
  int lane = threadIdx.x & 63;
  if (gw >= TOK) return;
  const float* yr = y + (size_t)gw * DI;
  const float* zr = zx + (size_t)gw * NPJ;
  float g[16];
  float ss = 0.f;
#pragma unroll
  for (int q = 0; q < 4; ++q) {
    float4 yv = *(const float4*)(yr + lane * 4 + q * 256);
    float4 zv = *(const float4*)(zr + lane * 4 + q * 256);
    g[4 * q + 0] = yv.x * zv.x * sigmoidf_(zv.x);
    g[4 * q + 1] = yv.y * zv.y * sigmoidf_(zv.y);
    g[4 * q + 2] = yv.z * zv.z * sigmoidf_(zv.z);
    g[4 * q + 3] = yv.w * zv.w * sigmoidf_(zv.w);
#pragma unroll
    for (int j = 0; j < 4; ++j) ss += g[4 * q + j] * g[4 * q + j];
  }
  ss = wsum(ss);
  float sc = rsqrtf(ss * (1.f / (float)DI) + EPSf);
#pragma unroll
  for (int q = 0; q < 4; ++q) {
    float4 nv = *(const float4*)(nw + lane * 4 + q * 256);
    *(ushort4*)(ybf + (size_t)gw * DI + lane * 4 + q * 256) =
        make_ushort4(f2bf(g[4 * q + 0] * sc * nv.x), f2bf(g[4 * q + 1] * sc * nv.y),
                     f2bf(g[4 * q + 2] * sc * nv.z), f2bf(g[4 * q + 3] * sc * nv.w));
  }
}

// ---- lengths ----
__global__ __launch_bounds__(256) void k_lengths(const unsigned char* __restrict__ mask, int* __restrict__ len) {
  int b = blockIdx.x;
  int tid = threadIdx.x;
  int cnt = 0;
  for (int t = tid; t < Ls; t += 256) cnt += mask[b * Ls + t] ? 0 : 1;
#pragma unroll
  for (int o = 32; o > 0; o >>= 1) cnt += __shfl_xor(cnt, o);
  __shared__ int red[4];
  if ((tid & 63) == 0) red[tid >> 6] = cnt;
  __syncthreads();
  if (tid == 0) len[b] = red[0] + red[1] + red[2] + red[3];
}

// ---- in-place smart flip over 16B chunks (cpr = 16B chunks per row) ----
__global__ __launch_bounds__(256) void k_flip16(char* __restrict__ buf, const int* __restrict__ len, int cpr) {
  int idx = blockIdx.x * 256 + threadIdx.x;
  int total = TOK * cpr;
  if (idx >= total) return;
  int c4 = idx % cpr;
  int bt = idx / cpr;
  int t = bt & (Ls - 1);
  int b = bt >> 10;
  int ln = len[b];
  int pos = (t < ln) ? (ln - 1 - t) : t;
  if (t < pos) {
    uint4* p0 = (uint4*)(buf + ((size_t)(b * Ls + t) * cpr + c4) * 16);
    uint4* p1 = (uint4*)(buf + ((size_t)(b * Ls + pos) * cpr + c4) * 16);
    uint4 a = *p0, bb = *p1;
    *p0 = bb;
    *p1 = a;
  }
}

// ---- mlm head ----
__global__ __launch_bounds__(256) void k_mlm(const float* __restrict__ e2, const float* __restrict__ w3,
                                             const float* __restrict__ b3, float* __restrict__ out) {
  int gw = (blockIdx.x * 256 + threadIdx.x) >> 6;
  int lane = threadIdx.x & 63;
  if (gw >= TOK) return;
  float x[8], w[8];
  ld8(e2 + (size_t)gw * DM, lane, x);
  ld8(w3, lane, w);
  float s = 0;
#pragma unroll
  for (int j = 0; j < 8; ++j) s += x[j] * w[j];
  s = wsum(s);
  if (lane == 0) out[gw] = s + b3[0];
}

__global__ __launch_bounds__(256) void k_cell(const float* __restrict__ h, float* __restrict__ out) {
  int i = blockIdx.x * 256 + threadIdx.x;
  if (i >= Bb * DM) return;
  int b = i >> 9, c = i & 511;
  out[i] = h[(size_t)b * Ls * DM + c];
}

// ---- classifier matvec: wave-per-output; optional LN+affine on input row ----
__global__ __launch_bounds__(256) void k_clsmv(const float* __restrict__ xin, size_t xstride,
    const float* __restrict__ g, const float* __restrict__ bb, int doLN,
    const float* __restrict__ W, const float* __restrict__ bias, int doRelu,
    float* __restrict__ out, int nout) {
  int b = blockIdx.y;
  int j = blockIdx.x * 4 + (threadIdx.x >> 6);
  int lane = threadIdx.x & 63;
  if (j >= nout) return;
  float x[8];
  ld8(xin + (size_t)b * xstride, lane, x);
  if (doLN) {
    norm8(x);
    float gv[8], bv[8];
    ld8(g, lane, gv); ld8(bb, lane, bv);
#pragma unroll
    for (int k = 0; k < 8; ++k) x[k] = x[k] * gv[k] + bv[k];
  }
  float w[8];
  ld8(W + (size_t)j * DM, lane, w);
  float s = 0;
#pragma unroll
  for (int k = 0; k < 8; ++k) s += x[k] * w[k];
  s = wsum(s);
  if (lane == 0) {
    float v = s + bias[j];
    if (doRelu) v = fmaxf(v, 0.f);
    out[(size_t)b * nout + j] = v;
  }
}

// ---- workspace layout ----
constexpr size_t F_H   = 0;
constexpr size_t F_ZX  = F_H + (size_t)TOK * DM;
constexpr size_t F_XB  = F_ZX + (size_t)TOK * NPJ;
constexpr size_t F_DT  = F_XB + (size_t)TOK * CDIM;
constexpr size_t F_DA  = F_DT + (size_t)TOK * NH;
constexpr size_t F_Y   = F_DA + (size_t)TOK * NH;
constexpr size_t F_OF  = F_Y + (size_t)TOK * DI;
constexpr size_t F_OR  = F_OF + (size_t)TOK * DM;
constexpr size_t F_LEN = F_OR + (size_t)TOK * DM;
constexpr size_t F_G   = F_LEN + 16;
constexpr size_t F_CUM = F_G + (size_t)Bb * NH * NCH * HD * DS;
constexpr size_t F_CC1 = F_CUM + (size_t)Bb * NH * NCH * 64;
constexpr size_t F_CC2 = F_CC1 + Bb * DM;
constexpr size_t F_END = F_CC2 + Bb * DM;
// bf16 regions (ushort offsets from ws base*2)
constexpr size_t U0       = F_END * 2;
constexpr size_t UW_IN    = U0;                                  // 2*2192*512
constexpr size_t UW_OUT   = UW_IN + (size_t)2 * DIP * DM;        // 2*512*1024
constexpr size_t UW_VE    = UW_OUT + (size_t)2 * DM * DI;
constexpr size_t UW_E1    = UW_VE + (size_t)DM * DM;
constexpr size_t UW_E2    = UW_E1 + (size_t)DM * DM;
constexpr size_t U_BFA    = UW_E2 + (size_t)DM * DM;             // v1 / e1 (TOK*DM)
constexpr size_t U_HNBF   = U_BFA + (size_t)TOK * DM;            // hn / h_bf (TOK*DM)
constexpr size_t U_YBF    = U_HNBF + (size_t)TOK * DM;           // TOK*DI

extern "C" void kernel_launch(void* const* d_in, const int* in_sizes, int n_in,
                              void* d_out, int out_size, void* d_ws, size_t ws_size,
                              hipStream_t stream) {
  const int* src = (const int*)d_in[0];
  const float* values = (const float*)d_in[1];
  const unsigned char* mask = (const unsigned char*)d_in[2];
  const float* embed = (const float*)d_in[3];
  const float* ge_g = (const float*)d_in[4];
  const float* ge_b = (const float*)d_in[5];
  const float* ve_w1 = (const float*)d_in[6];
  const float* ve_b1 = (const float*)d_in[7];
  const float* ve_w2 = (const float*)d_in[8];
  const float* ve_b2 = (const float*)d_in[9];
  const float* ve_g = (const float*)d_in[10];
  const float* ve_bb = (const float*)d_in[11];
  const float* in_w = (const float*)d_in[12];
  const float* conv_w_f = (const float*)d_in[13];
  const float* conv_b_f = (const float*)d_in[14];
  const float* A_f = (const float*)d_in[15];
  const float* dtb_f = (const float*)d_in[16];
  const float* D_f = (const float*)d_in[17];
  const float* nw_f = (const float*)d_in[18];
  const float* conv_w_r = (const float*)d_in[19];
  const float* conv_b_r = (const float*)d_in[20];
  const float* A_r = (const float*)d_in[21];
  const float* dtb_r = (const float*)d_in[22];
  const float* D_r = (const float*)d_in[23];
  const float* nw_r = (const float*)d_in[24];
  const float* out_w = (const float*)d_in[25];
  const float* expr_w1 = (const float*)d_in[26];
  const float* expr_b1 = (const float*)d_in[27];
  const float* expr_w2 = (const float*)d_in[28];
  const float* expr_b2 = (const float*)d_in[29];
  const float* expr_w3 = (const float*)d_in[30];
  const float* expr_b3 = (const float*)d_in[31];
  const float* cls_w1 = (const float*)d_in[32];
  const float* cls_b1 = (const float*)d_in[33];
  const float* cls_g1 = (const float*)d_in[34];
  const float* cls_bb1 = (const float*)d_in[35];
  const float* cls_w2 = (const float*)d_in[36];
  const float* cls_b2 = (const float*)d_in[37];
  const float* cls_g2 = (const float*)d_in[38];
  const float* cls_bb2 = (const float*)d_in[39];
  const float* cls_wo = (const float*)d_in[40];
  const float* cls_bo = (const float*)d_in[41];

  float* ws = (float*)d_ws;
  unsigned short* wsu = (unsigned short*)d_ws;
  float* h = ws + F_H;
  float* zx = ws + F_ZX;
  float* xbca = ws + F_XB;
  float* dtb = ws + F_DT;
  float* ldab = ws + F_DA;
  float* ybuf = ws + F_Y;
  float* obf = ws + F_OF;
  float* obr = ws + F_OR;
  int* len = (int*)(ws + F_LEN);
  float* gbuf = ws + F_G;
  float* cumb = ws + F_CUM;
  float* cc1 = ws + F_CC1;
  float* cc2 = ws + F_CC2;
  unsigned short* w_in = wsu + UW_IN;
  unsigned short* w_out = wsu + UW_OUT;
  unsigned short* w_ve = wsu + UW_VE;
  unsigned short* w_e1 = wsu + UW_E1;
  unsigned short* w_e2 = wsu + UW_E2;
  unsigned short* bfa = wsu + U_BFA;    // v1 / e1
  unsigned short* hnbf = wsu + U_HNBF;  // hn / h_bf
  unsigned short* ybf = wsu + U_YBF;
  float* t2 = obr;  // reuse before layers
  float* e2 = zx;   // reuse after layers
  float* out = (float*)d_out;

  // ---- weight conversions (bf16) ----
  {
    int n;
    n = 2 * DIP * DM / 8;  k_w2bf<<<(n + 255) / 256, 256, 0, stream>>>(in_w, w_in, n);
    n = 2 * DM * DI / 8;   k_w2bf<<<(n + 255) / 256, 256, 0, stream>>>(out_w, w_out, n);
    n = DM * DM / 8;       k_w2bf<<<(n + 255) / 256, 256, 0, stream>>>(ve_w2, w_ve, n);
    n = DM * DM / 8;       k_w2bf<<<(n + 255) / 256, 256, 0, stream>>>(expr_w1, w_e1, n);
    n = DM * DM / 8;       k_w2bf<<<(n + 255) / 256, 256, 0, stream>>>(expr_w2, w_e2, n);
  }

  // ---- embedding + value encoder ----
  k_embed<<<TOK / 4, 256, 0, stream>>>(src, values, embed, ge_g, ge_b, ve_w1, ve_b1, h, bfa);
  gemm_bf<0, 0><<<dim3(DM / 128, TOK / 128), 256, 0, stream>>>(bfa, w_ve, ve_b2, t2, TOK, DM, DM);
  k_haddv<<<TOK / 4, 256, 0, stream>>>(t2, ve_g, ve_bb, mask, h);
  k_lengths<<<Bb, 256, 0, stream>>>(mask, len);

  // ---- layers ----
  for (int i = 0; i < 2; ++i) {
    const float* inw = in_w + (size_t)i * DIP * DM;
    unsigned short* inwb = w_in + (size_t)i * DIP * DM;
    unsigned short* outwb = w_out + (size_t)i * DM * DI;
    k_ln512<<<TOK / 4, 256, 0, stream>>>(h, hnbf);
    for (int d = 0; d < 2; ++d) {
      const float* cw = (d ? conv_w_r : conv_w_f) + (size_t)i * CDIM * 4;
      const float* cb = (d ? conv_b_r : conv_b_f) + (size_t)i * CDIM;
      const float* Al = (d ? A_r : A_f) + (size_t)i * NH;
      const float* db = (d ? dtb_r : dtb_f) + (size_t)i * NH;
      const float* Dk = (d ? D_r : D_f) + (size_t)i * NH;
      const float* nw = (d ? nw_r : nw_f) + (size_t)i * DI;
      float* outbuf = d ? obr : obf;
      if (d == 1) k_flip16<<<(TOK * 64 + 255) / 256, 256, 0, stream>>>((char*)hnbf, len, 64);
      gemm_bf<0, 0><<<dim3(NPJ / 128, TOK / 128), 256, 0, stream>>>(hnbf, inwb, nullptr, zx, TOK, NPJ, DM);
      k_dtda<<<TOK / 4, 256, 0, stream>>>(h, inw, db, Al, len, d, dtb, ldab);
      k_conv<<<(TOK * CDIM + 255) / 256, 256, 0, stream>>>(zx, cw, cb, xbca);
      k_chunk<<<Bb * NH * NCH, 256, 0, stream>>>(xbca, dtb, ldab, Dk, ybuf, gbuf, cumb);
      k_chain<<<Bb * NH, 256, 0, stream>>>(gbuf, cumb);
      k_corr<<<Bb * NH * NCH, 256, 0, stream>>>(xbca, gbuf, cumb, ybuf);
      k_gaterms<<<TOK / 4, 256, 0, stream>>>(ybuf, zx, nw, ybf);
      gemm_bf<0, 0><<<dim3(DM / 128, TOK / 128), 256, 0, stream>>>(ybf, outwb, nullptr, outbuf, TOK, DM, DI);
    }
    k_flip16<<<(TOK * 128 + 255) / 256, 256, 0, stream>>>((char*)obr, len, 128);
    k_comb<<<TOK / 4, 256, 0, stream>>>(obf, obr, h, hnbf);
  }

  // ---- heads ----
  gemm_bf<2, 1><<<dim3(DM / 128, TOK / 128), 256, 0, stream>>>(hnbf, w_e1, expr_b1, bfa, TOK, DM, DM);
  gemm_bf<2, 0><<<dim3(DM / 128, TOK / 128), 256, 0, stream>>>(bfa, w_e2, expr_b2, e2, TOK, DM, DM);
  k_mlm<<<TOK / 4, 256, 0, stream>>>(e2, expr_w3, expr_b3, out);
  k_cell<<<(Bb * DM + 255) / 256, 256, 0, stream>>>(h, out + TOK);
  k_clsmv<<<dim3(128, Bb), 256, 0, stream>>>(h, (size_t)Ls * DM, nullptr, nullptr, 0,
                                             cls_w1, cls_b1, 1, cc1, DM);
  k_clsmv<<<dim3(128, Bb), 256, 0, stream>>>(cc1, DM, cls_g1, cls_bb1, 1,
                                             cls_w2, cls_b2, 1, cc2, DM);
  k_clsmv<<<dim3(41, Bb), 256, 0, stream>>>(cc2, DM, cls_g2, cls_bb2, 1,
                                            cls_wo, cls_bo, 0, out + TOK + Bb * DM, 164);
}

// Round 5
// 420.497 us; speedup vs baseline: 8.9273x; 1.5562x over previous
//
#include <hip/hip_runtime.h>
#include <hip/hip_bf16.h>
#include <math.h>

// ---- model constants ----
constexpr int Bb = 4, Ls = 1024, DM = 512, DI = 1024, NH = 16, HD = 64, DS = 64;
constexpr int CDIM = DI + 2 * DS;          // 1152
constexpr int DIP  = 2 * DI + 2 * DS + NH; // 2192
constexpr int NPJ  = 2 * DI + 2 * DS;      // 2176 = 17*128
constexpr float EPSf = 1e-5f;
constexpr int TOK = Bb * Ls;               // 4096
constexpr int CH = 64, NCH = Ls / CH;      // 16 chunks of 64

#define DEVI __device__ __forceinline__

using bfrag = __attribute__((ext_vector_type(8))) short;
using f4v   = __attribute__((ext_vector_type(4))) float;
using u16x8 = __attribute__((ext_vector_type(8))) unsigned short;

#define GLOAD16(gp, lp)                                                              \
  __builtin_amdgcn_global_load_lds((__attribute__((address_space(1))) void*)(gp),   \
                                   (__attribute__((address_space(3))) void*)(lp),   \
                                   16, 0, 0)

DEVI float wsum(float v) {
#pragma unroll
  for (int o = 32; o > 0; o >>= 1) v += __shfl_xor(v, o);
  return v;
}
DEVI float sigmoidf_(float x) { return 1.f / (1.f + __expf(-x)); }
DEVI unsigned short f2bf(float x) {
  union { float f; unsigned u; } c{x};
  unsigned u = c.u;
  u += 0x7fffu + ((u >> 16) & 1u);
  return (unsigned short)(u >> 16);
}
DEVI float bf2f(unsigned short u) {
  union { unsigned u; float f; } c{(unsigned)u << 16};
  return c.f;
}

DEVI void ld8(const float* __restrict__ p, int lane, float (&x)[8]) {
  float4 a = *(const float4*)(p + lane * 4);
  float4 b = *(const float4*)(p + 256 + lane * 4);
  x[0] = a.x; x[1] = a.y; x[2] = a.z; x[3] = a.w;
  x[4] = b.x; x[5] = b.y; x[6] = b.z; x[7] = b.w;
}
DEVI void st8(float* __restrict__ p, int lane, const float (&x)[8]) {
  *(float4*)(p + lane * 4) = make_float4(x[0], x[1], x[2], x[3]);
  *(float4*)(p + 256 + lane * 4) = make_float4(x[4], x[5], x[6], x[7]);
}
DEVI void st8bf(unsigned short* __restrict__ p, int lane, const float (&x)[8]) {
  *(ushort4*)(p + lane * 4) = make_ushort4(f2bf(x[0]), f2bf(x[1]), f2bf(x[2]), f2bf(x[3]));
  *(ushort4*)(p + 256 + lane * 4) = make_ushort4(f2bf(x[4]), f2bf(x[5]), f2bf(x[6]), f2bf(x[7]));
}
DEVI void norm8(float (&x)[8]) {
  float s = 0;
#pragma unroll
  for (int j = 0; j < 8; ++j) s += x[j];
  float mean = wsum(s) * (1.f / 512.f);
#pragma unroll
  for (int j = 0; j < 8; ++j) x[j] -= mean;
  float q = 0;
#pragma unroll
  for (int j = 0; j < 8; ++j) q += x[j] * x[j];
  float var = wsum(q) * (1.f / 512.f);
  float inv = rsqrtf(var + EPSf);
#pragma unroll
  for (int j = 0; j < 8; ++j) x[j] *= inv;
}

// ---- fp32 -> bf16 bulk convert (weights) ----
__global__ __launch_bounds__(256) void k_w2bf(const float* __restrict__ in,
                                              unsigned short* __restrict__ out, int n8) {
  int i = blockIdx.x * 256 + threadIdx.x;
  if (i >= n8) return;
  const float4* p = (const float4*)in + (size_t)i * 2;
  float4 a = p[0], b = p[1];
  *((ushort4*)out + (size_t)i * 2) = make_ushort4(f2bf(a.x), f2bf(a.y), f2bf(a.z), f2bf(a.w));
  *((ushort4*)out + (size_t)i * 2 + 1) = make_ushort4(f2bf(b.x), f2bf(b.y), f2bf(b.z), f2bf(b.w));
}

// ---- embedding + value-encoder stage 1 ----
__global__ __launch_bounds__(256) void k_embed(const int* __restrict__ src, const float* __restrict__ values,
    const float* __restrict__ embed, const float* __restrict__ gg, const float* __restrict__ gb,
    const float* __restrict__ vw1, const float* __restrict__ vb1,
    float* __restrict__ hbuf, unsigned short* __restrict__ v1bf) {
  int gw = (blockIdx.x * 256 + threadIdx.x) >> 6;
  int lane = threadIdx.x & 63;
  if (gw >= TOK) return;
  const float* er = embed + (size_t)src[gw] * DM;
  float x[8];
  ld8(er, lane, x);
  norm8(x);
  float g[8], bv[8];
  ld8(gg, lane, g); ld8(gb, lane, bv);
#pragma unroll
  for (int j = 0; j < 8; ++j) x[j] = x[j] * g[j] + bv[j];
  st8(hbuf + (size_t)gw * DM, lane, x);
  float val = fminf(values[gw], 512.f);
  float w1[8], b1[8];
  ld8(vw1, lane, w1); ld8(vb1, lane, b1);
  float v[8];
#pragma unroll
  for (int j = 0; j < 8; ++j) v[j] = fmaxf(val * w1[j] + b1[j], 0.f);
  st8bf(v1bf + (size_t)gw * DM, lane, v);
}

// h = (h + LN(t2)*g+b) * (mask?0:1)
__global__ __launch_bounds__(256) void k_haddv(const float* __restrict__ t2, const float* __restrict__ g,
    const float* __restrict__ bb, const unsigned char* __restrict__ mask, float* __restrict__ hbuf) {
  int gw = (blockIdx.x * 256 + threadIdx.x) >> 6;
  int lane = threadIdx.x & 63;
  if (gw >= TOK) return;
  float x[8];
  ld8(t2 + (size_t)gw * DM, lane, x);
  norm8(x);
  float gv[8], bv[8], h[8];
  ld8(g, lane, gv); ld8(bb, lane, bv);
  ld8(hbuf + (size_t)gw * DM, lane, h);
  float mf = mask[gw] ? 0.f : 1.f;
#pragma unroll
  for (int j = 0; j < 8; ++j) h[j] = (h[j] + x[j] * gv[j] + bv[j]) * mf;
  st8(hbuf + (size_t)gw * DM, lane, h);
}

// ---- LN(h)->bf16  +  dt/ldA for BOTH directions (shared raw logits) ----
__global__ __launch_bounds__(256) void k_lndt(const float* __restrict__ h, const float* __restrict__ inw,
    const float* __restrict__ dtbF, const float* __restrict__ AlogF,
    const float* __restrict__ dtbR, const float* __restrict__ AlogR,
    const int* __restrict__ len, unsigned short* __restrict__ hnbf,
    float* __restrict__ dtf, float* __restrict__ laf,
    float* __restrict__ dtr, float* __restrict__ lar) {
  int gw = (blockIdx.x * 256 + threadIdx.x) >> 6;
  int lane = threadIdx.x & 63;
  if (gw >= TOK) return;
  float x[8];
  ld8(h + (size_t)gw * DM, lane, x);
  norm8(x);
  st8bf(hnbf + (size_t)gw * DM, lane, x);
  const float* wdt = inw + (size_t)NPJ * DM;
  float myraw = 0.f;
#pragma unroll
  for (int hh = 0; hh < NH; ++hh) {
    float w[8];
    ld8(wdt + (size_t)hh * DM, lane, w);
    float s = 0;
#pragma unroll
    for (int j = 0; j < 8; ++j) s += x[j] * w[j];
    s = wsum(s);
    if (lane == hh) myraw = s;
  }
  if (lane < NH) {
    int t = gw & (Ls - 1), b = gw >> 10;
    int ln = len[b];
    int pos = (t < ln) ? (ln - 1 - t) : t;
    size_t grev = (size_t)(b * Ls + pos);
    float rf = myraw + dtbF[lane];
    float df = rf > 20.f ? rf : log1pf(__expf(rf));
    dtf[(size_t)gw * NH + lane] = df;
    laf[(size_t)gw * NH + lane] = -__expf(AlogF[lane]) * df;
    float rr = myraw + dtbR[lane];
    float dr = rr > 20.f ? rr : log1pf(__expf(rr));
    dtr[grev * NH + lane] = dr;
    lar[grev * NH + lane] = -__expf(AlogR[lane]) * dr;
  }
}

// ---- bf16 MFMA GEMM (m97 structure): C[M,N] = A[M,K] @ W[N,K]^T (+bias, act) ----
template <int ACT, int OMODE>
__global__ __launch_bounds__(256) void gemm_bf(const unsigned short* __restrict__ A,
    const unsigned short* __restrict__ W, const float* __restrict__ bias,
    void* __restrict__ Cout, int M, int N, int K) {
  constexpr int BK = 64;
  __shared__ unsigned short As[128 * BK];
  __shared__ unsigned short Bs[128 * BK];
  int tid = threadIdx.x;
  int bm = blockIdx.y * 128, bn = blockIdx.x * 128;
  int wv = tid >> 6, lane = tid & 63;
  int mb = (wv >> 1) * 64, nb = (wv & 1) * 64;
  int rA = lane >> 3;
  int cswz = (lane & 7) ^ rA;
  f4v acc[4][4] = {};

  for (int k0 = 0; k0 < K; k0 += BK) {
#pragma unroll
    for (int q = 0; q < 4; ++q) {
      int ch = wv * 4 + q;
      const unsigned short* ga = A + (size_t)(bm + ch * 8 + rA) * K + k0 + cswz * 8;
      GLOAD16(ga, &As[ch * 512]);
      const unsigned short* gb = W + (size_t)(bn + ch * 8 + rA) * K + k0 + cswz * 8;
      GLOAD16(gb, &Bs[ch * 512]);
    }
    __syncthreads();
#pragma unroll
    for (int ks = 0; ks < BK; ks += 32) {
      int kb = (ks >> 3) + (lane >> 4);
      bfrag af[4], bg[4];
#pragma unroll
      for (int i = 0; i < 4; ++i) {
        int ra_ = mb + i * 16 + (lane & 15);
        af[i] = *(const bfrag*)((const char*)As + ((ra_ * 128 + kb * 16) ^ ((ra_ & 7) << 4)));
        int rb_ = nb + i * 16 + (lane & 15);
        bg[i] = *(const bfrag*)((const char*)Bs + ((rb_ * 128 + kb * 16) ^ ((rb_ & 7) << 4)));
      }
#pragma unroll
      for (int i = 0; i < 4; ++i)
#pragma unroll
        for (int j = 0; j < 4; ++j)
          acc[i][j] = __builtin_amdgcn_mfma_f32_16x16x32_bf16(af[i], bg[j], acc[i][j], 0, 0, 0);
    }
    __syncthreads();
  }

  int cb = bn + nb + (lane & 15);
  int rb = bm + mb + ((lane >> 4) << 2);
#pragma unroll
  for (int j = 0; j < 4; ++j) {
    float bv = bias ? bias[cb + j * 16] : 0.f;
#pragma unroll
    for (int i = 0; i < 4; ++i) {
#pragma unroll
      for (int r = 0; r < 4; ++r) {
        float v = acc[i][j][r] + bv;
        if (ACT == 1) v = fmaxf(v, 0.f);
        if (ACT == 2) v = v > 0.f ? v : 0.01f * v;
        size_t idx = (size_t)(rb + i * 16 + r) * N + cb + j * 16;
        if (OMODE == 0) ((float*)Cout)[idx] = v;
        else ((unsigned short*)Cout)[idx] = f2bf(v);
      }
    }
  }
}

// ======================= fused conv + chunked SSD (MFMA) =======================
// Per block = (b,h,chunk): depthwise conv from zx (flip-aware rows for rev),
// S=C.B^T, decay->W, Y=W@x (+D*x), G = (fB)^T@x; all matmuls bf16 MFMA.
__global__ __launch_bounds__(256) void k_chunk(const float* __restrict__ zx,
    const float* __restrict__ cw, const float* __restrict__ cbias,
    const float* __restrict__ dtp, const float* __restrict__ ldap, const float* __restrict__ Dk,
    const int* __restrict__ len, int rev,
    float* __restrict__ y, float* __restrict__ gbuf, float* __restrict__ cumbuf,
    unsigned short* __restrict__ cbuf) {
  __shared__ unsigned short Cb[4096], Bbs[4096], BbT[4096], xT[4096], Wt[4096];
  __shared__ float ldsL[64], sdt_[64], fs[64];
  int blk = blockIdx.x;
  int c = blk & 15, bh = blk >> 4, h = bh & 15, b = bh >> 4;
  int tid = threadIdx.x, wv = tid >> 6, lane = tid & 63;
  int c0 = c * CH;
  int ln = len[b];

  if (tid < 64) {
    size_t off = ((size_t)(b * Ls + c0 + tid)) * NH + h;
    float dtv = dtp[off];
    float v = ldap[off];
#pragma unroll
    for (int o = 1; o < 64; o <<= 1) {
      float n = __shfl_up(v, o);
      if (tid >= o) v += n;
    }
    ldsL[tid] = v;
    sdt_[tid] = dtv;
    cumbuf[(size_t)blk * 64 + tid] = __expf(v);
    float L63 = __shfl(v, 63);
    fs[tid] = __expf(L63 - v) * dtv;
  }
  __syncthreads();

  // conv phase: 192 channels x 4 t-groups of 16
  for (int u = tid; u < 768; u += 256) {
    int cch = u % 192, tg = (u / 192) * 16;
    int gcol = cch < 64 ? DI + h * 64 + cch : 2 * DI + (cch - 64);
    int ccd = cch < 64 ? h * 64 + cch : DI + (cch - 64);
    float4 w4 = *(const float4*)(cw + ccd * 4);
    float bias = cbias[ccd];
    float vv[19];
#pragma unroll
    for (int k = 0; k < 19; ++k) {
      int rl = c0 + tg - 3 + k;
      float val = 0.f;
      if (rl >= 0) {
        int gr = rev ? (rl < ln ? ln - 1 - rl : rl) : rl;
        val = zx[((size_t)(b * Ls + gr)) * NPJ + gcol];
      }
      vv[k] = val;
    }
    float o16[16];
#pragma unroll
    for (int t = 0; t < 16; ++t) {
      float s = bias + w4.x * vv[t] + w4.y * vv[t + 1] + w4.z * vv[t + 2] + w4.w * vv[t + 3];
      o16[t] = s * sigmoidf_(s);
    }
    if (cch < 64) {
      int p = cch;
#pragma unroll
      for (int hv = 0; hv < 2; ++hv) {
        u16x8 pk;
#pragma unroll
        for (int k = 0; k < 8; ++k) pk[k] = f2bf(o16[hv * 8 + k]);
        *(u16x8*)((char*)xT + ((p * 128 + (tg + hv * 8) * 2) ^ ((p & 7) << 4))) = pk;
      }
    } else if (cch < 128) {
      int n = cch - 64;
#pragma unroll
      for (int t = 0; t < 16; ++t) {
        int s = tg + t;
        *(unsigned short*)((char*)Bbs + ((s * 128 + n * 2) ^ ((s & 7) << 4))) = f2bf(o16[t]);
      }
#pragma unroll
      for (int hv = 0; hv < 2; ++hv) {
        u16x8 pk;
#pragma unroll
        for (int k = 0; k < 8; ++k) pk[k] = f2bf(o16[hv * 8 + k] * fs[tg + hv * 8 + k]);
        *(u16x8*)((char*)BbT + ((n * 128 + (tg + hv * 8) * 2) ^ ((n & 7) << 4))) = pk;
      }
    } else {
      int n = cch - 128;
#pragma unroll
      for (int t = 0; t < 16; ++t) {
        int s = tg + t;
        *(unsigned short*)((char*)Cb + ((s * 128 + n * 2) ^ ((s & 7) << 4))) = f2bf(o16[t]);
      }
    }
  }
  __syncthreads();

  // dump C tile for k_corr (verbatim swizzled image)
  {
    const u16x8* srcp = (const u16x8*)Cb;
    u16x8* dstp = (u16x8*)(cbuf + (size_t)blk * 4096);
    dstp[tid * 2] = srcp[tid * 2];
    dstp[tid * 2 + 1] = srcp[tid * 2 + 1];
  }

  // matmul1: S[t][s] = C . B^T
  f4v accS[4] = {};
#pragma unroll
  for (int ks = 0; ks < 64; ks += 32) {
    int kb = (ks >> 3) + (lane >> 4);
    int ra = wv * 16 + (lane & 15);
    bfrag af = *(const bfrag*)((const char*)Cb + ((ra * 128 + kb * 16) ^ ((ra & 7) << 4)));
#pragma unroll
    for (int j = 0; j < 4; ++j) {
      int rb = j * 16 + (lane & 15);
      bfrag bg = *(const bfrag*)((const char*)Bbs + ((rb * 128 + kb * 16) ^ ((rb & 7) << 4)));
      accS[j] = __builtin_amdgcn_mfma_f32_16x16x32_bf16(af, bg, accS[j], 0, 0, 0);
    }
  }
  // decay + causal mask -> Wt (bf16)
  {
    int trow = wv * 16 + ((lane >> 4) << 2);
#pragma unroll
    for (int j = 0; j < 4; ++j) {
      int s = j * 16 + (lane & 15);
      float ds = sdt_[s], Lsv = ldsL[s];
#pragma unroll
      for (int r = 0; r < 4; ++r) {
        int tt = trow + r;
        float wval = (s <= tt) ? accS[j][r] * ds * __expf(ldsL[tt] - Lsv) : 0.f;
        *(unsigned short*)((char*)Wt + ((tt * 128 + s * 2) ^ ((tt & 7) << 4))) = f2bf(wval);
      }
    }
  }
  __syncthreads();

  // matmul2: Y = W @ x ; matmul3: G = (fB)^T @ x  (shared x^T B-fragments)
  f4v accY[4] = {}, accG[4] = {};
#pragma unroll
  for (int ks = 0; ks < 64; ks += 32) {
    int kb = (ks >> 3) + (lane >> 4);
    int ra = wv * 16 + (lane & 15);
    bfrag afW = *(const bfrag*)((const char*)Wt + ((ra * 128 + kb * 16) ^ ((ra & 7) << 4)));
    bfrag afB = *(const bfrag*)((const char*)BbT + ((ra * 128 + kb * 16) ^ ((ra & 7) << 4)));
#pragma unroll
    for (int j = 0; j < 4; ++j) {
      int rb = j * 16 + (lane & 15);
      bfrag bg = *(const bfrag*)((const char*)xT + ((rb * 128 + kb * 16) ^ ((rb & 7) << 4)));
      accY[j] = __builtin_amdgcn_mfma_f32_16x16x32_bf16(afW, bg, accY[j], 0, 0, 0);
      accG[j] = __builtin_amdgcn_mfma_f32_16x16x32_bf16(afB, bg, accG[j], 0, 0, 0);
    }
  }
  float Dh = Dk[h];
  int trow = wv * 16 + ((lane >> 4) << 2);
#pragma unroll
  for (int j = 0; j < 4; ++j) {
    int p = j * 16 + (lane & 15);
#pragma unroll
    for (int r = 0; r < 4; ++r) {
      int t = trow + r;
      float xval = bf2f(*(const unsigned short*)((const char*)xT + ((p * 128 + t * 2) ^ ((p & 7) << 4))));
      y[((size_t)(b * Ls + c0 + t)) * DI + h * 64 + p] = accY[j][r] + Dh * xval;
      gbuf[((size_t)blk * 64 + t) * 64 + p] = accG[j][r];
    }
  }
}

// inter-chunk recurrence (in-place: gbuf[c] becomes h_in before chunk c)
__global__ __launch_bounds__(256) void k_chain(float* __restrict__ gbuf, const float* __restrict__ cumbuf) {
  int bh = blockIdx.x;
  int tid = threadIdx.x;
  float4 hv[4] = {};
  for (int c = 0; c < NCH; ++c) {
    size_t base = ((size_t)(bh * NCH + c)) * 4096;
    float Pc = cumbuf[(size_t)(bh * NCH + c) * 64 + 63];
#pragma unroll
    for (int k = 0; k < 4; ++k) {
      size_t e = base + (size_t)k * 1024 + tid * 4;
      float4 g = *(const float4*)(gbuf + e);
      *(float4*)(gbuf + e) = hv[k];
      hv[k].x = fmaf(Pc, hv[k].x, g.x);
      hv[k].y = fmaf(Pc, hv[k].y, g.y);
      hv[k].z = fmaf(Pc, hv[k].z, g.z);
      hv[k].w = fmaf(Pc, hv[k].w, g.w);
    }
  }
}

// correction: Y[t][p] += exp(L[t]) * sum_n C[t][n] * hin[n][p]   (MFMA)
__global__ __launch_bounds__(256) void k_corr(const unsigned short* __restrict__ cbuf,
    const float* __restrict__ hin, const float* __restrict__ cumbuf, float* __restrict__ y) {
  int blk = blockIdx.x;
  int c = blk & 15;
  if (c == 0) return;
  __shared__ unsigned short Ct[4096], HT[4096];
  __shared__ float cdl[64];
  int bh = blk >> 4, h = bh & 15, b = bh >> 4;
  int tid = threadIdx.x, wv = tid >> 6, lane = tid & 63;
  int c0 = c * CH;
  {
    const unsigned short* g = cbuf + (size_t)blk * 4096;
#pragma unroll
    for (int q = 0; q < 2; ++q)
      GLOAD16(g + wv * 1024 + q * 512 + lane * 8, &Ct[wv * 1024 + q * 512]);
  }
  {
    int n = tid >> 2, p0 = (tid & 3) * 16;
    const float* hr = hin + (size_t)blk * 4096 + (size_t)n * 64 + p0;
#pragma unroll
    for (int q = 0; q < 4; ++q) {
      float4 v = *(const float4*)(hr + q * 4);
      float va[4] = {v.x, v.y, v.z, v.w};
#pragma unroll
      for (int k = 0; k < 4; ++k) {
        int p = p0 + q * 4 + k;
        *(unsigned short*)((char*)HT + ((p * 128 + n * 2) ^ ((p & 7) << 4))) = f2bf(va[k]);
      }
    }
  }
  if (tid < 64) cdl[tid] = cumbuf[(size_t)blk * 64 + tid];
  __syncthreads();

  f4v acc[4] = {};
#pragma unroll
  for (int ks = 0; ks < 64; ks += 32) {
    int kb = (ks >> 3) + (lane >> 4);
    int ra = wv * 16 + (lane & 15);
    bfrag af = *(const bfrag*)((const char*)Ct + ((ra * 128 + kb * 16) ^ ((ra & 7) << 4)));
#pragma unroll
    for (int j = 0; j < 4; ++j) {
      int rb = j * 16 + (lane & 15);
      bfrag bg = *(const bfrag*)((const char*)HT + ((rb * 128 + kb * 16) ^ ((rb & 7) << 4)));
      acc[j] = __builtin_amdgcn_mfma_f32_16x16x32_bf16(af, bg, acc[j], 0, 0, 0);
    }
  }
  int trow = wv * 16 + ((lane >> 4) << 2);
#pragma unroll
  for (int j = 0; j < 4; ++j) {
    int p = j * 16 + (lane & 15);
#pragma unroll
    for (int r = 0; r < 4; ++r) {
      int t = trow + r;
      float* yp = &y[((size_t)(b * Ls + c0 + t)) * DI + h * 64 + p];
      *yp += cdl[t] * acc[j][r];
    }
  }
}
// ================================================================

// ---- gated RMSNorm; d=0 writes 0.5*g, d=1 adds 0.5*g at flipped rows ----
template <int REV>
__global__ __launch_bounds__(256) void k_gaterms(const float* __restrict__ y, const float* __restrict__ zx,
    const float* __restrict__ nw, const int* __restrict__ len, unsigned short* __restrict__ ybf) {
  int gw = (blockIdx.x * 256 + threadIdx.x) >> 6;
  int lane = threadIdx.x & 63;
  if (gw >= TOK) return;
  int wrow = gw;
  if (REV) {
    int t = gw & (Ls - 1), b = gw >> 10;
    int ln = len[b];
    wrow = b * Ls + ((t < ln) ? (ln - 1 - t) : t);
  }
  const float* yr = y + (size_t)gw * DI;
  const float* zr = zx + (size_t)wrow * NPJ;
  float g[16];
  float ss = 0.f;
#pragma unroll
  for (int q = 0; q < 4; ++q) {
    float4 yv = *(const float4*)(yr + lane * 4 + q * 256);
    float4 zv = *(const float4*)(zr + lane * 4 + q * 256);
    g[4 * q + 0] = yv.x * zv.x * sigmoidf_(zv.x);
    g[4 * q + 1] = yv.y * zv.y * sigmoidf_(zv.y);
    g[4 * q + 2] = yv.z * zv.z * sigmoidf_(zv.z);
    g[4 * q + 3] = yv.w * zv.w * sigmoidf_(zv.w);
#pragma unroll
    for (int j = 0; j < 4; ++j) ss += g[4 * q + j] * g[4 * q + j];
  }
  ss = wsum(ss);
  float sc = 0.5f * rsqrtf(ss * (1.f / (float)DI) + EPSf);
#pragma unroll
  for (int q = 0; q < 4; ++q) {
    float4 nv = *(const float4*)(nw + lane * 4 + q * 256);
    unsigned short* op = ybf + (size_t)wrow * DI + lane * 4 + q * 256;
    float o0 = g[4 * q + 0] * sc * nv.x;
    float o1 = g[4 * q + 1] * sc * nv.y;
    float o2 = g[4 * q + 2] * sc * nv.z;
    float o3 = g[4 * q + 3] * sc * nv.w;
    if (REV) {
      ushort4 prev = *(const ushort4*)op;
      o0 += bf2f(prev.x); o1 += bf2f(prev.y); o2 += bf2f(prev.z); o3 += bf2f(prev.w);
    }
    *(ushort4*)op = make_ushort4(f2bf(o0), f2bf(o1), f2bf(o2), f2bf(o3));
  }
}

// ---- h = LN(src) -> fp32 + bf16 ----
__global__ __launch_bounds__(256) void k_hln(const float* __restrict__ src, float* __restrict__ dst,
                                             unsigned short* __restrict__ dstbf) {
  int gw = (blockIdx.x * 256 + threadIdx.x) >> 6;
  int lane = threadIdx.x & 63;
  if (gw >= TOK) return;
  float x[8];
  ld8(src + (size_t)gw * DM, lane, x);
  norm8(x);
  st8(dst + (size_t)gw * DM, lane, x);
  st8bf(dstbf + (size_t)gw * DM, lane, x);
}

// ---- lengths ----
__global__ __launch_bounds__(256) void k_lengths(const unsigned char* __restrict__ mask, int* __restrict__ len) {
  int b = blockIdx.x;
  int tid = threadIdx.x;
  int cnt = 0;
  for (int t = tid; t < Ls; t += 256) cnt += mask[b * Ls + t] ? 0 : 1;
#pragma unroll
  for (int o = 32; o > 0; o >>= 1) cnt += __shfl_xor(cnt, o);
  __shared__ int red[4];
  if ((tid & 63) == 0) red[tid >> 6] = cnt;
  __syncthreads();
  if (tid == 0) len[b] = red[0] + red[1] + red[2] + red[3];
}

// ---- mlm head ----
__global__ __launch_bounds__(256) void k_mlm(const float* __restrict__ e2, const float* __restrict__ w3,
                                             const float* __restrict__ b3, float* __restrict__ out) {
  int gw = (blockIdx.x * 256 + threadIdx.x) >> 6;
  int lane = threadIdx.x & 63;
  if (gw >= TOK) return;
  float x[8], w[8];
  ld8(e2 + (size_t)gw * DM, lane, x);
  ld8(w3, lane, w);
  float s = 0;
#pragma unroll
  for (int j = 0; j < 8; ++j) s += x[j] * w[j];
  s = wsum(s);
  if (lane == 0) out[gw] = s + b3[0];
}

__global__ __launch_bounds__(256) void k_cell(const float* __restrict__ h, float* __restrict__ out) {
  int i = blockIdx.x * 256 + threadIdx.x;
  if (i >= Bb * DM) return;
  int b = i >> 9, c = i & 511;
  out[i] = h[(size_t)b * Ls * DM + c];
}

// ---- classifier matvec (wave-per-output; optional LN+affine on input) ----
__global__ __launch_bounds__(256) void k_clsmv(const float* __restrict__ xin, size_t xstride,
    const float* __restrict__ g, const float* __restrict__ bb, int doLN,
    const float* __restrict__ W, const float* __restrict__ bias, int doRelu,
    float* __restrict__ out, int nout) {
  int b = blockIdx.y;
  int j = blockIdx.x * 4 + (threadIdx.x >> 6);
  int lane = threadIdx.x & 63;
  if (j >= nout) return;
  float x[8];
  ld8(xin + (size_t)b * xstride, lane, x);
  if (doLN) {
    norm8(x);
    float gv[8], bv[8];
    ld8(g, lane, gv); ld8(bb, lane, bv);
#pragma unroll
    for (int k = 0; k < 8; ++k) x[k] = x[k] * gv[k] + bv[k];
  }
  float w[8];
  ld8(W + (size_t)j * DM, lane, w);
  float s = 0;
#pragma unroll
  for (int k = 0; k < 8; ++k) s += x[k] * w[k];
  s = wsum(s);
  if (lane == 0) {
    float v = s + bias[j];
    if (doRelu) v = fmaxf(v, 0.f);
    out[(size_t)b * nout + j] = v;
  }
}

// ---- workspace layout (floats) ----
constexpr size_t F_H   = 0;
constexpr size_t F_ZX  = F_H + (size_t)TOK * DM;
constexpr size_t F_DTF = F_ZX + (size_t)TOK * NPJ;
constexpr size_t F_LAF = F_DTF + (size_t)TOK * NH;
constexpr size_t F_DTR = F_LAF + (size_t)TOK * NH;
constexpr size_t F_LAR = F_DTR + (size_t)TOK * NH;
constexpr size_t F_Y   = F_LAR + (size_t)TOK * NH;
constexpr size_t F_ON  = F_Y + (size_t)TOK * DI;
constexpr size_t F_G   = F_ON + (size_t)TOK * DM;
constexpr size_t F_CUM = F_G + (size_t)Bb * NH * NCH * HD * DS;
constexpr size_t F_CC1 = F_CUM + (size_t)Bb * NH * NCH * 64;
constexpr size_t F_CC2 = F_CC1 + Bb * DM;
constexpr size_t F_LEN = F_CC2 + Bb * DM;
constexpr size_t F_END = F_LEN + 16;
// bf16 regions (ushort offsets)
constexpr size_t U0     = F_END * 2;
constexpr size_t UW_IN  = U0;
constexpr size_t UW_OUT = UW_IN + (size_t)2 * DIP * DM;
constexpr size_t UW_VE  = UW_OUT + (size_t)2 * DM * DI;
constexpr size_t UW_E1  = UW_VE + (size_t)DM * DM;
constexpr size_t UW_E2  = UW_E1 + (size_t)DM * DM;
constexpr size_t U_BFA  = UW_E2 + (size_t)DM * DM;   // v1 / e1-bf16
constexpr size_t U_HNBF = U_BFA + (size_t)TOK * DM;
constexpr size_t U_YBF  = U_HNBF + (size_t)TOK * DM;
constexpr size_t U_CBUF = U_YBF + (size_t)TOK * DI;  // 1024 * 4096

extern "C" void kernel_launch(void* const* d_in, const int* in_sizes, int n_in,
                              void* d_out, int out_size, void* d_ws, size_t ws_size,
                              hipStream_t stream) {
  const int* src = (const int*)d_in[0];
  const float* values = (const float*)d_in[1];
  const unsigned char* mask = (const unsigned char*)d_in[2];
  const float* embed = (const float*)d_in[3];
  const float* ge_g = (const float*)d_in[4];
  const float* ge_b = (const float*)d_in[5];
  const float* ve_w1 = (const float*)d_in[6];
  const float* ve_b1 = (const float*)d_in[7];
  const float* ve_w2 = (const float*)d_in[8];
  const float* ve_b2 = (const float*)d_in[9];
  const float* ve_g = (const float*)d_in[10];
  const float* ve_bb = (const float*)d_in[11];
  const float* in_w = (const float*)d_in[12];
  const float* conv_w_f = (const float*)d_in[13];
  const float* conv_b_f = (const float*)d_in[14];
  const float* A_f = (const float*)d_in[15];
  const float* dtb_f = (const float*)d_in[16];
  const float* D_f = (const float*)d_in[17];
  const float* nw_f = (const float*)d_in[18];
  const float* conv_w_r = (const float*)d_in[19];
  const float* conv_b_r = (const float*)d_in[20];
  const float* A_r = (const float*)d_in[21];
  const float* dtb_r = (const float*)d_in[22];
  const float* D_r = (const float*)d_in[23];
  const float* nw_r = (const float*)d_in[24];
  const float* out_w = (const float*)d_in[25];
  const float* expr_w1 = (const float*)d_in[26];
  const float* expr_b1 = (const float*)d_in[27];
  const float* expr_w2 = (const float*)d_in[28];
  const float* expr_b2 = (const float*)d_in[29];
  const float* expr_w3 = (const float*)d_in[30];
  const float* expr_b3 = (const float*)d_in[31];
  const float* cls_w1 = (const float*)d_in[32];
  const float* cls_b1 = (const float*)d_in[33];
  const float* cls_g1 = (const float*)d_in[34];
  const float* cls_bb1 = (const float*)d_in[35];
  const float* cls_w2 = (const float*)d_in[36];
  const float* cls_b2 = (const float*)d_in[37];
  const float* cls_g2 = (const float*)d_in[38];
  const float* cls_bb2 = (const float*)d_in[39];
  const float* cls_wo = (const float*)d_in[40];
  const float* cls_bo = (const float*)d_in[41];

  float* ws = (float*)d_ws;
  unsigned short* wsu = (unsigned short*)d_ws;
  float* h = ws + F_H;
  float* zx = ws + F_ZX;
  float* dtf = ws + F_DTF;
  float* laf = ws + F_LAF;
  float* dtr = ws + F_DTR;
  float* lar = ws + F_LAR;
  float* ybuf = ws + F_Y;
  float* onew = ws + F_ON;
  float* gbuf = ws + F_G;
  float* cumb = ws + F_CUM;
  float* cc1 = ws + F_CC1;
  float* cc2 = ws + F_CC2;
  int* len = (int*)(ws + F_LEN);
  unsigned short* w_in = wsu + UW_IN;
  unsigned short* w_out = wsu + UW_OUT;
  unsigned short* w_ve = wsu + UW_VE;
  unsigned short* w_e1 = wsu + UW_E1;
  unsigned short* w_e2 = wsu + UW_E2;
  unsigned short* bfa = wsu + U_BFA;
  unsigned short* hnbf = wsu + U_HNBF;
  unsigned short* ybf = wsu + U_YBF;
  unsigned short* cbuf = wsu + U_CBUF;
  float* t2 = onew;  // reuse before layers
  float* e2 = zx;    // reuse after layers
  float* out = (float*)d_out;

  // ---- weight conversions ----
  {
    int n;
    n = 2 * DIP * DM / 8;  k_w2bf<<<(n + 255) / 256, 256, 0, stream>>>(in_w, w_in, n);
    n = 2 * DM * DI / 8;   k_w2bf<<<(n + 255) / 256, 256, 0, stream>>>(out_w, w_out, n);
    n = DM * DM / 8;       k_w2bf<<<(n + 255) / 256, 256, 0, stream>>>(ve_w2, w_ve, n);
    n = DM * DM / 8;       k_w2bf<<<(n + 255) / 256, 256, 0, stream>>>(expr_w1, w_e1, n);
    n = DM * DM / 8;       k_w2bf<<<(n + 255) / 256, 256, 0, stream>>>(expr_w2, w_e2, n);
  }

  // ---- embedding + value encoder ----
  k_embed<<<TOK / 4, 256, 0, stream>>>(src, values, embed, ge_g, ge_b, ve_w1, ve_b1, h, bfa);
  gemm_bf<0, 0><<<dim3(DM / 128, TOK / 128), 256, 0, stream>>>(bfa, w_ve, ve_b2, t2, TOK, DM, DM);
  k_haddv<<<TOK / 4, 256, 0, stream>>>(t2, ve_g, ve_bb, mask, h);
  k_lengths<<<Bb, 256, 0, stream>>>(mask, len);

  // ---- layers ----
  for (int i = 0; i < 2; ++i) {
    const float* inw = in_w + (size_t)i * DIP * DM;
    unsigned short* inwb = w_in + (size_t)i * DIP * DM;
    unsigned short* outwb = w_out + (size_t)i * DM * DI;
    k_lndt<<<TOK / 4, 256, 0, stream>>>(h, inw, dtb_f + i * NH, A_f + i * NH,
                                        dtb_r + i * NH, A_r + i * NH, len, hnbf,
                                        dtf, laf, dtr, lar);
    gemm_bf<0, 0><<<dim3(NPJ / 128, TOK / 128), 256, 0, stream>>>(hnbf, inwb, nullptr, zx, TOK, NPJ, DM);
    for (int d = 0; d < 2; ++d) {
      const float* cw = (d ? conv_w_r : conv_w_f) + (size_t)i * CDIM * 4;
      const float* cb = (d ? conv_b_r : conv_b_f) + (size_t)i * CDIM;
      const float* Dk = (d ? D_r : D_f) + (size_t)i * NH;
      const float* nw = (d ? nw_r : nw_f) + (size_t)i * DI;
      const float* dtp = d ? dtr : dtf;
      const float* ldap = d ? lar : laf;
      k_chunk<<<Bb * NH * NCH, 256, 0, stream>>>(zx, cw, cb, dtp, ldap, Dk, len, d,
                                                 ybuf, gbuf, cumb, cbuf);
      k_chain<<<Bb * NH, 256, 0, stream>>>(gbuf, cumb);
      k_corr<<<Bb * NH * NCH, 256, 0, stream>>>(cbuf, gbuf, cumb, ybuf);
      if (d == 0)
        k_gaterms<0><<<TOK / 4, 256, 0, stream>>>(ybuf, zx, nw, len, ybf);
      else
        k_gaterms<1><<<TOK / 4, 256, 0, stream>>>(ybuf, zx, nw, len, ybf);
    }
    gemm_bf<0, 0><<<dim3(DM / 128, TOK / 128), 256, 0, stream>>>(ybf, outwb, nullptr, onew, TOK, DM, DI);
    k_hln<<<TOK / 4, 256, 0, stream>>>(onew, h, hnbf);
  }

  // ---- heads ----
  gemm_bf<2, 1><<<dim3(DM / 128, TOK / 128), 256, 0, stream>>>(hnbf, w_e1, expr_b1, bfa, TOK, DM, DM);
  gemm_bf<2, 0><<<dim3(DM / 128, TOK / 128), 256, 0, stream>>>(bfa, w_e2, expr_b2, e2, TOK, DM, DM);
  k_mlm<<<TOK / 4, 256, 0, stream>>>(e2, expr_w3, expr_b3, out);
  k_cell<<<(Bb * DM + 255) / 256, 256, 0, stream>>>(h, out + TOK);
  k_clsmv<<<dim3(128, Bb), 256, 0, stream>>>(h, (size_t)Ls * DM, nullptr, nullptr, 0,
                                             cls_w1, cls_b1, 1, cc1, DM);
  k_clsmv<<<dim3(128, Bb), 256, 0, stream>>>(cc1, DM, cls_g1, cls_bb1, 1,
                                             cls_w2, cls_b2, 1, cc2, DM);
  k_clsmv<<<dim3(41, Bb), 256, 0, stream>>>(cc2, DM, cls_g2, cls_bb2, 1,
                                            cls_wo, cls_bo, 0, out + TOK + Bb * DM, 164);
}

// Round 6
// 366.648 us; speedup vs baseline: 10.2385x; 1.1469x over previous
//
#include <hip/hip_runtime.h>
#include <hip/hip_bf16.h>
#include <math.h>

// ---- model constants ----
constexpr int Bb = 4, Ls = 1024, DM = 512, DI = 1024, NH = 16, HD = 64, DS = 64;
constexpr int CDIM = DI + 2 * DS;          // 1152
constexpr int DIP  = 2 * DI + 2 * DS + NH; // 2192
constexpr int NPJ  = 2 * DI + 2 * DS;      // 2176 = 17*128
constexpr float EPSf = 1e-5f;
constexpr int TOK = Bb * Ls;               // 4096
constexpr int CH = 64, NCH = Ls / CH;      // 16 chunks of 64

#define DEVI __device__ __forceinline__

using bfrag = __attribute__((ext_vector_type(8))) short;
using f4v   = __attribute__((ext_vector_type(4))) float;
using u16x8 = __attribute__((ext_vector_type(8))) unsigned short;

#define GLOAD16(gp, lp)                                                              \
  __builtin_amdgcn_global_load_lds((__attribute__((address_space(1))) void*)(gp),   \
                                   (__attribute__((address_space(3))) void*)(lp),   \
                                   16, 0, 0)

DEVI float wsum(float v) {
#pragma unroll
  for (int o = 32; o > 0; o >>= 1) v += __shfl_xor(v, o);
  return v;
}
DEVI float sigmoidf_(float x) { return 1.f / (1.f + __expf(-x)); }
DEVI unsigned short f2bf(float x) {
  union { float f; unsigned u; } c{x};
  unsigned u = c.u;
  u += 0x7fffu + ((u >> 16) & 1u);
  return (unsigned short)(u >> 16);
}
DEVI float bf2f(unsigned short u) {
  union { unsigned u; float f; } c{(unsigned)u << 16};
  return c.f;
}

DEVI void ld8(const float* __restrict__ p, int lane, float (&x)[8]) {
  float4 a = *(const float4*)(p + lane * 4);
  float4 b = *(const float4*)(p + 256 + lane * 4);
  x[0] = a.x; x[1] = a.y; x[2] = a.z; x[3] = a.w;
  x[4] = b.x; x[5] = b.y; x[6] = b.z; x[7] = b.w;
}
DEVI void ld8bf(const unsigned short* __restrict__ p, int lane, float (&x)[8]) {
  ushort4 a = *(const ushort4*)(p + lane * 4);
  ushort4 b = *(const ushort4*)(p + 256 + lane * 4);
  x[0] = bf2f(a.x); x[1] = bf2f(a.y); x[2] = bf2f(a.z); x[3] = bf2f(a.w);
  x[4] = bf2f(b.x); x[5] = bf2f(b.y); x[6] = bf2f(b.z); x[7] = bf2f(b.w);
}
DEVI void st8(float* __restrict__ p, int lane, const float (&x)[8]) {
  *(float4*)(p + lane * 4) = make_float4(x[0], x[1], x[2], x[3]);
  *(float4*)(p + 256 + lane * 4) = make_float4(x[4], x[5], x[6], x[7]);
}
DEVI void st8bf(unsigned short* __restrict__ p, int lane, const float (&x)[8]) {
  *(ushort4*)(p + lane * 4) = make_ushort4(f2bf(x[0]), f2bf(x[1]), f2bf(x[2]), f2bf(x[3]));
  *(ushort4*)(p + 256 + lane * 4) = make_ushort4(f2bf(x[4]), f2bf(x[5]), f2bf(x[6]), f2bf(x[7]));
}
DEVI void norm8(float (&x)[8]) {
  float s = 0;
#pragma unroll
  for (int j = 0; j < 8; ++j) s += x[j];
  float mean = wsum(s) * (1.f / 512.f);
#pragma unroll
  for (int j = 0; j < 8; ++j) x[j] -= mean;
  float q = 0;
#pragma unroll
  for (int j = 0; j < 8; ++j) q += x[j] * x[j];
  float var = wsum(q) * (1.f / 512.f);
  float inv = rsqrtf(var + EPSf);
#pragma unroll
  for (int j = 0; j < 8; ++j) x[j] *= inv;
}

// ---- fp32 -> bf16 bulk convert (weights) ----
__global__ __launch_bounds__(256) void k_w2bf(const float* __restrict__ in,
                                              unsigned short* __restrict__ out, int n8) {
  int i = blockIdx.x * 256 + threadIdx.x;
  if (i >= n8) return;
  const float4* p = (const float4*)in + (size_t)i * 2;
  float4 a = p[0], b = p[1];
  *((ushort4*)out + (size_t)i * 2) = make_ushort4(f2bf(a.x), f2bf(a.y), f2bf(a.z), f2bf(a.w));
  *((ushort4*)out + (size_t)i * 2 + 1) = make_ushort4(f2bf(b.x), f2bf(b.y), f2bf(b.z), f2bf(b.w));
}

// ---- embedding + value-encoder stage 1 ----
__global__ __launch_bounds__(256) void k_embed(const int* __restrict__ src, const float* __restrict__ values,
    const float* __restrict__ embed, const float* __restrict__ gg, const float* __restrict__ gb,
    const float* __restrict__ vw1, const float* __restrict__ vb1,
    float* __restrict__ hbuf, unsigned short* __restrict__ v1bf) {
  int gw = (blockIdx.x * 256 + threadIdx.x) >> 6;
  int lane = threadIdx.x & 63;
  if (gw >= TOK) return;
  const float* er = embed + (size_t)src[gw] * DM;
  float x[8];
  ld8(er, lane, x);
  norm8(x);
  float g[8], bv[8];
  ld8(gg, lane, g); ld8(gb, lane, bv);
#pragma unroll
  for (int j = 0; j < 8; ++j) x[j] = x[j] * g[j] + bv[j];
  st8(hbuf + (size_t)gw * DM, lane, x);
  float val = fminf(values[gw], 512.f);
  float w1[8], b1[8];
  ld8(vw1, lane, w1); ld8(vb1, lane, b1);
  float v[8];
#pragma unroll
  for (int j = 0; j < 8; ++j) v[j] = fmaxf(val * w1[j] + b1[j], 0.f);
  st8bf(v1bf + (size_t)gw * DM, lane, v);
}

// h = (h + LN(t2)*g+b) * (mask?0:1)
__global__ __launch_bounds__(256) void k_haddv(const float* __restrict__ t2, const float* __restrict__ g,
    const float* __restrict__ bb, const unsigned char* __restrict__ mask, float* __restrict__ hbuf) {
  int gw = (blockIdx.x * 256 + threadIdx.x) >> 6;
  int lane = threadIdx.x & 63;
  if (gw >= TOK) return;
  float x[8];
  ld8(t2 + (size_t)gw * DM, lane, x);
  norm8(x);
  float gv[8], bv[8], h[8];
  ld8(g, lane, gv); ld8(bb, lane, bv);
  ld8(hbuf + (size_t)gw * DM, lane, h);
  float mf = mask[gw] ? 0.f : 1.f;
#pragma unroll
  for (int j = 0; j < 8; ++j) h[j] = (h[j] + x[j] * gv[j] + bv[j]) * mf;
  st8(hbuf + (size_t)gw * DM, lane, h);
}

// ---- LN(h)->bf16  +  dt/ldA for BOTH directions (shared raw logits) ----
__global__ __launch_bounds__(256) void k_lndt(const float* __restrict__ h, const float* __restrict__ inw,
    const float* __restrict__ dtbF, const float* __restrict__ AlogF,
    const float* __restrict__ dtbR, const float* __restrict__ AlogR,
    const int* __restrict__ len, unsigned short* __restrict__ hnbf,
    float* __restrict__ dtf, float* __restrict__ laf,
    float* __restrict__ dtr, float* __restrict__ lar) {
  int gw = (blockIdx.x * 256 + threadIdx.x) >> 6;
  int lane = threadIdx.x & 63;
  if (gw >= TOK) return;
  float x[8];
  ld8(h + (size_t)gw * DM, lane, x);
  norm8(x);
  st8bf(hnbf + (size_t)gw * DM, lane, x);
  const float* wdt = inw + (size_t)NPJ * DM;
  float myraw = 0.f;
#pragma unroll
  for (int hh = 0; hh < NH; ++hh) {
    float w[8];
    ld8(wdt + (size_t)hh * DM, lane, w);
    float s = 0;
#pragma unroll
    for (int j = 0; j < 8; ++j) s += x[j] * w[j];
    s = wsum(s);
    if (lane == hh) myraw = s;
  }
  if (lane < NH) {
    int t = gw & (Ls - 1), b = gw >> 10;
    int ln = len[b];
    int pos = (t < ln) ? (ln - 1 - t) : t;
    size_t grev = (size_t)(b * Ls + pos);
    float rf = myraw + dtbF[lane];
    float df = rf > 20.f ? rf : log1pf(__expf(rf));
    dtf[(size_t)gw * NH + lane] = df;
    laf[(size_t)gw * NH + lane] = -__expf(AlogF[lane]) * df;
    float rr = myraw + dtbR[lane];
    float dr = rr > 20.f ? rr : log1pf(__expf(rr));
    dtr[grev * NH + lane] = dr;
    lar[grev * NH + lane] = -__expf(AlogR[lane]) * dr;
  }
}

// ---- bf16 MFMA GEMM: C[M,N] = A[M,K] @ W[N,K]^T (+bias, act) ----
template <int ACT, int OMODE>
__global__ __launch_bounds__(256) void gemm_bf(const unsigned short* __restrict__ A,
    const unsigned short* __restrict__ W, const float* __restrict__ bias,
    void* __restrict__ Cout, int M, int N, int K) {
  constexpr int BK = 64;
  __shared__ unsigned short As[128 * BK];
  __shared__ unsigned short Bs[128 * BK];
  int tid = threadIdx.x;
  int bm = blockIdx.y * 128, bn = blockIdx.x * 128;
  int wv = tid >> 6, lane = tid & 63;
  int mb = (wv >> 1) * 64, nb = (wv & 1) * 64;
  int rA = lane >> 3;
  int cswz = (lane & 7) ^ rA;
  f4v acc[4][4] = {};

  for (int k0 = 0; k0 < K; k0 += BK) {
#pragma unroll
    for (int q = 0; q < 4; ++q) {
      int ch = wv * 4 + q;
      const unsigned short* ga = A + (size_t)(bm + ch * 8 + rA) * K + k0 + cswz * 8;
      GLOAD16(ga, &As[ch * 512]);
      const unsigned short* gb = W + (size_t)(bn + ch * 8 + rA) * K + k0 + cswz * 8;
      GLOAD16(gb, &Bs[ch * 512]);
    }
    __syncthreads();
#pragma unroll
    for (int ks = 0; ks < BK; ks += 32) {
      int kb = (ks >> 3) + (lane >> 4);
      bfrag af[4], bg[4];
#pragma unroll
      for (int i = 0; i < 4; ++i) {
        int ra_ = mb + i * 16 + (lane & 15);
        af[i] = *(const bfrag*)((const char*)As + ((ra_ * 128 + kb * 16) ^ ((ra_ & 7) << 4)));
        int rb_ = nb + i * 16 + (lane & 15);
        bg[i] = *(const bfrag*)((const char*)Bs + ((rb_ * 128 + kb * 16) ^ ((rb_ & 7) << 4)));
      }
#pragma unroll
      for (int i = 0; i < 4; ++i)
#pragma unroll
        for (int j = 0; j < 4; ++j)
          acc[i][j] = __builtin_amdgcn_mfma_f32_16x16x32_bf16(af[i], bg[j], acc[i][j], 0, 0, 0);
    }
    __syncthreads();
  }

  int cb = bn + nb + (lane & 15);
  int rb = bm + mb + ((lane >> 4) << 2);
#pragma unroll
  for (int j = 0; j < 4; ++j) {
    float bv = bias ? bias[cb + j * 16] : 0.f;
#pragma unroll
    for (int i = 0; i < 4; ++i) {
#pragma unroll
      for (int r = 0; r < 4; ++r) {
        float v = acc[i][j][r] + bv;
        if (ACT == 1) v = fmaxf(v, 0.f);
        if (ACT == 2) v = v > 0.f ? v : 0.01f * v;
        size_t idx = (size_t)(rb + i * 16 + r) * N + cb + j * 16;
        if (OMODE == 0) ((float*)Cout)[idx] = v;
        else ((unsigned short*)Cout)[idx] = f2bf(v);
      }
    }
  }
}

// ======================= fused conv + chunked SSD, both dirs (MFMA) =======================
// grid 2048: dir = blk>>10. Depthwise conv from bf16 zx (flip-aware rows for rev),
// S=C.B^T, decay->W, Y=W@x (+D*x), G=(fB)^T@x.
__global__ __launch_bounds__(256) void k_chunk(const unsigned short* __restrict__ zx,
    const float* __restrict__ cwF, const float* __restrict__ cbF,
    const float* __restrict__ cwR, const float* __restrict__ cbR,
    const float* __restrict__ dtF, const float* __restrict__ laF,
    const float* __restrict__ dtR, const float* __restrict__ laR,
    const float* __restrict__ DkF, const float* __restrict__ DkR,
    const int* __restrict__ len,
    float* __restrict__ yF, float* __restrict__ yR,
    float* __restrict__ gbuf, float* __restrict__ cumbuf, unsigned short* __restrict__ cbuf) {
  __shared__ unsigned short Cb[4096], Bbs[4096], BbT[4096], xT[4096], Wt[4096];
  __shared__ float ldsL[64], sdt_[64], fs[64];
  int blk2 = blockIdx.x;
  int dir = blk2 >> 10;
  int blk = blk2 & 1023;
  int c = blk & 15, bh = blk >> 4, h = bh & 15, b = bh >> 4;
  int tid = threadIdx.x, wv = tid >> 6, lane = tid & 63;
  int c0 = c * CH;
  int ln = len[b];
  const float* cw = dir ? cwR : cwF;
  const float* cbias = dir ? cbR : cbF;
  const float* dtp = dir ? dtR : dtF;
  const float* ldap = dir ? laR : laF;
  float Dh = (dir ? DkR : DkF)[h];
  float* y = dir ? yR : yF;

  if (tid < 64) {
    size_t off = ((size_t)(b * Ls + c0 + tid)) * NH + h;
    float dtv = dtp[off];
    float v = ldap[off];
#pragma unroll
    for (int o = 1; o < 64; o <<= 1) {
      float n = __shfl_up(v, o);
      if (tid >= o) v += n;
    }
    ldsL[tid] = v;
    sdt_[tid] = dtv;
    cumbuf[(size_t)blk2 * 64 + tid] = __expf(v);
    float L63 = __shfl(v, 63);
    fs[tid] = __expf(L63 - v) * dtv;
  }
  __syncthreads();

  // conv phase: 192 channels x 4 t-groups of 16
  for (int u = tid; u < 768; u += 256) {
    int cch = u % 192, tg = (u / 192) * 16;
    int gcol = cch < 64 ? DI + h * 64 + cch : 2 * DI + (cch - 64);
    int ccd = cch < 64 ? h * 64 + cch : DI + (cch - 64);
    float4 w4 = *(const float4*)(cw + ccd * 4);
    float bias = cbias[ccd];
    float vv[19];
#pragma unroll
    for (int k = 0; k < 19; ++k) {
      int rl = c0 + tg - 3 + k;
      float val = 0.f;
      if (rl >= 0) {
        int gr = dir ? (rl < ln ? ln - 1 - rl : rl) : rl;
        val = bf2f(zx[((size_t)(b * Ls + gr)) * NPJ + gcol]);
      }
      vv[k] = val;
    }
    float o16[16];
#pragma unroll
    for (int t = 0; t < 16; ++t) {
      float s = bias + w4.x * vv[t] + w4.y * vv[t + 1] + w4.z * vv[t + 2] + w4.w * vv[t + 3];
      o16[t] = s * sigmoidf_(s);
    }
    if (cch < 64) {
      int p = cch;
#pragma unroll
      for (int hv = 0; hv < 2; ++hv) {
        u16x8 pk;
#pragma unroll
        for (int k = 0; k < 8; ++k) pk[k] = f2bf(o16[hv * 8 + k]);
        *(u16x8*)((char*)xT + ((p * 128 + (tg + hv * 8) * 2) ^ ((p & 7) << 4))) = pk;
      }
    } else if (cch < 128) {
      int n = cch - 64;
#pragma unroll
      for (int t = 0; t < 16; ++t) {
        int s = tg + t;
        *(unsigned short*)((char*)Bbs + ((s * 128 + n * 2) ^ ((s & 7) << 4))) = f2bf(o16[t]);
      }
#pragma unroll
      for (int hv = 0; hv < 2; ++hv) {
        u16x8 pk;
#pragma unroll
        for (int k = 0; k < 8; ++k) pk[k] = f2bf(o16[hv * 8 + k] * fs[tg + hv * 8 + k]);
        *(u16x8*)((char*)BbT + ((n * 128 + (tg + hv * 8) * 2) ^ ((n & 7) << 4))) = pk;
      }
    } else {
      int n = cch - 128;
#pragma unroll
      for (int t = 0; t < 16; ++t) {
        int s = tg + t;
        *(unsigned short*)((char*)Cb + ((s * 128 + n * 2) ^ ((s & 7) << 4))) = f2bf(o16[t]);
      }
    }
  }
  __syncthreads();

  // dump C tile for k_corr (verbatim swizzled image)
  {
    const u16x8* srcp = (const u16x8*)Cb;
    u16x8* dstp = (u16x8*)(cbuf + (size_t)blk2 * 4096);
    dstp[tid * 2] = srcp[tid * 2];
    dstp[tid * 2 + 1] = srcp[tid * 2 + 1];
  }

  // matmul1: S[t][s] = C . B^T
  f4v accS[4] = {};
#pragma unroll
  for (int ks = 0; ks < 64; ks += 32) {
    int kb = (ks >> 3) + (lane >> 4);
    int ra = wv * 16 + (lane & 15);
    bfrag af = *(const bfrag*)((const char*)Cb + ((ra * 128 + kb * 16) ^ ((ra & 7) << 4)));
#pragma unroll
    for (int j = 0; j < 4; ++j) {
      int rb = j * 16 + (lane & 15);
      bfrag bg = *(const bfrag*)((const char*)Bbs + ((rb * 128 + kb * 16) ^ ((rb & 7) << 4)));
      accS[j] = __builtin_amdgcn_mfma_f32_16x16x32_bf16(af, bg, accS[j], 0, 0, 0);
    }
  }
  // decay + causal mask -> Wt (bf16)
  {
    int trow = wv * 16 + ((lane >> 4) << 2);
#pragma unroll
    for (int j = 0; j < 4; ++j) {
      int s = j * 16 + (lane & 15);
      float ds = sdt_[s], Lsv = ldsL[s];
#pragma unroll
      for (int r = 0; r < 4; ++r) {
        int tt = trow + r;
        float wval = (s <= tt) ? accS[j][r] * ds * __expf(ldsL[tt] - Lsv) : 0.f;
        *(unsigned short*)((char*)Wt + ((tt * 128 + s * 2) ^ ((tt & 7) << 4))) = f2bf(wval);
      }
    }
  }
  __syncthreads();

  // matmul2: Y = W @ x ; matmul3: G = (fB)^T @ x
  f4v accY[4] = {}, accG[4] = {};
#pragma unroll
  for (int ks = 0; ks < 64; ks += 32) {
    int kb = (ks >> 3) + (lane >> 4);
    int ra = wv * 16 + (lane & 15);
    bfrag afW = *(const bfrag*)((const char*)Wt + ((ra * 128 + kb * 16) ^ ((ra & 7) << 4)));
    bfrag afB = *(const bfrag*)((const char*)BbT + ((ra * 128 + kb * 16) ^ ((ra & 7) << 4)));
#pragma unroll
    for (int j = 0; j < 4; ++j) {
      int rb = j * 16 + (lane & 15);
      bfrag bg = *(const bfrag*)((const char*)xT + ((rb * 128 + kb * 16) ^ ((rb & 7) << 4)));
      accY[j] = __builtin_amdgcn_mfma_f32_16x16x32_bf16(afW, bg, accY[j], 0, 0, 0);
      accG[j] = __builtin_amdgcn_mfma_f32_16x16x32_bf16(afB, bg, accG[j], 0, 0, 0);
    }
  }
  int trow = wv * 16 + ((lane >> 4) << 2);
#pragma unroll
  for (int j = 0; j < 4; ++j) {
    int p = j * 16 + (lane & 15);
#pragma unroll
    for (int r = 0; r < 4; ++r) {
      int t = trow + r;
      float xval = bf2f(*(const unsigned short*)((const char*)xT + ((p * 128 + t * 2) ^ ((p & 7) << 4))));
      y[((size_t)(b * Ls + c0 + t)) * DI + h * 64 + p] = accY[j][r] + Dh * xval;
      gbuf[((size_t)blk2 * 64 + t) * 64 + p] = accG[j][r];
    }
  }
}

// inter-chunk recurrence with prefetch (in-place: gbuf[c] -> h_in before chunk c); grid 128
__global__ __launch_bounds__(256) void k_chain(float* __restrict__ gbuf, const float* __restrict__ cumbuf) {
  int bh = blockIdx.x;
  int tid = threadIdx.x;
  size_t base = (size_t)bh * NCH * 4096;
  float4 hv[4] = {};
  float4 g[4], gn[4];
#pragma unroll
  for (int k = 0; k < 4; ++k) g[k] = *(const float4*)(gbuf + base + (size_t)k * 1024 + tid * 4);
  float Pc = cumbuf[(size_t)bh * NCH * 64 + 63];
  for (int c = 0; c < NCH; ++c) {
    float Pn = 0.f;
    if (c + 1 < NCH) {
      Pn = cumbuf[((size_t)bh * NCH + c + 1) * 64 + 63];
#pragma unroll
      for (int k = 0; k < 4; ++k)
        gn[k] = *(const float4*)(gbuf + base + (size_t)(c + 1) * 4096 + (size_t)k * 1024 + tid * 4);
    }
#pragma unroll
    for (int k = 0; k < 4; ++k) {
      *(float4*)(gbuf + base + (size_t)c * 4096 + (size_t)k * 1024 + tid * 4) = hv[k];
      hv[k].x = fmaf(Pc, hv[k].x, g[k].x);
      hv[k].y = fmaf(Pc, hv[k].y, g[k].y);
      hv[k].z = fmaf(Pc, hv[k].z, g[k].z);
      hv[k].w = fmaf(Pc, hv[k].w, g[k].w);
      g[k] = gn[k];
    }
    Pc = Pn;
  }
}

// correction: Y[t][p] += exp(L[t]) * sum_n C[t][n] * hin[n][p]; grid 2048
__global__ __launch_bounds__(256) void k_corr(const unsigned short* __restrict__ cbuf,
    const float* __restrict__ hin, const float* __restrict__ cumbuf,
    float* __restrict__ yF, float* __restrict__ yR) {
  int blk2 = blockIdx.x;
  int c = blk2 & 15;
  if (c == 0) return;
  __shared__ unsigned short Ct[4096], HT[4096];
  __shared__ float cdl[64];
  int dir = blk2 >> 10;
  int bh = (blk2 & 1023) >> 4, h = bh & 15, b = bh >> 4;
  int tid = threadIdx.x, wv = tid >> 6, lane = tid & 63;
  int c0 = c * CH;
  float* y = dir ? yR : yF;
  {
    const unsigned short* g = cbuf + (size_t)blk2 * 4096;
#pragma unroll
    for (int q = 0; q < 2; ++q)
      GLOAD16(g + wv * 1024 + q * 512 + lane * 8, &Ct[wv * 1024 + q * 512]);
  }
  {
    int n = tid >> 2, p0 = (tid & 3) * 16;
    const float* hr = hin + (size_t)blk2 * 4096 + (size_t)n * 64 + p0;
#pragma unroll
    for (int q = 0; q < 4; ++q) {
      float4 v = *(const float4*)(hr + q * 4);
      float va[4] = {v.x, v.y, v.z, v.w};
#pragma unroll
      for (int k = 0; k < 4; ++k) {
        int p = p0 + q * 4 + k;
        *(unsigned short*)((char*)HT + ((p * 128 + n * 2) ^ ((p & 7) << 4))) = f2bf(va[k]);
      }
    }
  }
  if (tid < 64) cdl[tid] = cumbuf[(size_t)blk2 * 64 + tid];
  __syncthreads();

  f4v acc[4] = {};
#pragma unroll
  for (int ks = 0; ks < 64; ks += 32) {
    int kb = (ks >> 3) + (lane >> 4);
    int ra = wv * 16 + (lane & 15);
    bfrag af = *(const bfrag*)((const char*)Ct + ((ra * 128 + kb * 16) ^ ((ra & 7) << 4)));
#pragma unroll
    for (int j = 0; j < 4; ++j) {
      int rb = j * 16 + (lane & 15);
      bfrag bg = *(const bfrag*)((const char*)HT + ((rb * 128 + kb * 16) ^ ((rb & 7) << 4)));
      acc[j] = __builtin_amdgcn_mfma_f32_16x16x32_bf16(af, bg, acc[j], 0, 0, 0);
    }
  }
  int trow = wv * 16 + ((lane >> 4) << 2);
#pragma unroll
  for (int j = 0; j < 4; ++j) {
    int p = j * 16 + (lane & 15);
#pragma unroll
    for (int r = 0; r < 4; ++r) {
      int t = trow + r;
      float* yp = &y[((size_t)(b * Ls + c0 + t)) * DI + h * 64 + p];
      *yp += cdl[t] * acc[j][r];
    }
  }
}
// ================================================================

// ---- both-direction gated RMSNorm: ybf[w] = 0.5*(gate_f(w) + gate_r(flip(w))) ----
__global__ __launch_bounds__(256) void k_gab(const float* __restrict__ yF, const float* __restrict__ yR,
    const unsigned short* __restrict__ zxb, const float* __restrict__ nwF, const float* __restrict__ nwR,
    const int* __restrict__ len, unsigned short* __restrict__ ybf) {
  int w = (blockIdx.x * 256 + threadIdx.x) >> 6;
  int lane = threadIdx.x & 63;
  if (w >= TOK) return;
  int t = w & (Ls - 1), b = w >> 10;
  int ln = len[b];
  int r = b * Ls + ((t < ln) ? (ln - 1 - t) : t);  // involution
  const float* yf = yF + (size_t)w * DI;
  const float* yr = yR + (size_t)r * DI;
  const unsigned short* zr = zxb + (size_t)w * NPJ;
  float gf[16], gr[16];
  float ssf = 0.f, ssr = 0.f;
#pragma unroll
  for (int q = 0; q < 4; ++q) {
    float4 yv = *(const float4*)(yf + lane * 4 + q * 256);
    float4 rv = *(const float4*)(yr + lane * 4 + q * 256);
    ushort4 zu = *(const ushort4*)(zr + lane * 4 + q * 256);
    float z0 = bf2f(zu.x), z1 = bf2f(zu.y), z2 = bf2f(zu.z), z3 = bf2f(zu.w);
    float s0 = z0 * sigmoidf_(z0), s1 = z1 * sigmoidf_(z1), s2 = z2 * sigmoidf_(z2), s3 = z3 * sigmoidf_(z3);
    gf[4 * q + 0] = yv.x * s0; gf[4 * q + 1] = yv.y * s1; gf[4 * q + 2] = yv.z * s2; gf[4 * q + 3] = yv.w * s3;
    gr[4 * q + 0] = rv.x * s0; gr[4 * q + 1] = rv.y * s1; gr[4 * q + 2] = rv.z * s2; gr[4 * q + 3] = rv.w * s3;
#pragma unroll
    for (int j = 0; j < 4; ++j) {
      ssf += gf[4 * q + j] * gf[4 * q + j];
      ssr += gr[4 * q + j] * gr[4 * q + j];
    }
  }
  ssf = wsum(ssf);
  ssr = wsum(ssr);
  float scf = 0.5f * rsqrtf(ssf * (1.f / (float)DI) + EPSf);
  float scr = 0.5f * rsqrtf(ssr * (1.f / (float)DI) + EPSf);
#pragma unroll
  for (int q = 0; q < 4; ++q) {
    float4 nf = *(const float4*)(nwF + lane * 4 + q * 256);
    float4 nr = *(const float4*)(nwR + lane * 4 + q * 256);
    float o0 = gf[4 * q + 0] * scf * nf.x + gr[4 * q + 0] * scr * nr.x;
    float o1 = gf[4 * q + 1] * scf * nf.y + gr[4 * q + 1] * scr * nr.y;
    float o2 = gf[4 * q + 2] * scf * nf.z + gr[4 * q + 2] * scr * nr.z;
    float o3 = gf[4 * q + 3] * scf * nf.w + gr[4 * q + 3] * scr * nr.w;
    *(ushort4*)(ybf + (size_t)w * DI + lane * 4 + q * 256) =
        make_ushort4(f2bf(o0), f2bf(o1), f2bf(o2), f2bf(o3));
  }
}

// ---- h = LN(src) -> fp32 + bf16 ----
__global__ __launch_bounds__(256) void k_hln(const float* __restrict__ src, float* __restrict__ dst,
                                             unsigned short* __restrict__ dstbf) {
  int gw = (blockIdx.x * 256 + threadIdx.x) >> 6;
  int lane = threadIdx.x & 63;
  if (gw >= TOK) return;
  float x[8];
  ld8(src + (size_t)gw * DM, lane, x);
  norm8(x);
  st8(dst + (size_t)gw * DM, lane, x);
  st8bf(dstbf + (size_t)gw * DM, lane, x);
}

// ---- lengths ----
__global__ __launch_bounds__(256) void k_lengths(const unsigned char* __restrict__ mask, int* __restrict__ len) {
  int b = blockIdx.x;
  int tid = threadIdx.x;
  int cnt = 0;
  for (int t = tid; t < Ls; t += 256) cnt += mask[b * Ls + t] ? 0 : 1;
#pragma unroll
  for (int o = 32; o > 0; o >>= 1) cnt += __shfl_xor(cnt, o);
  __shared__ int red[4];
  if ((tid & 63) == 0) red[tid >> 6] = cnt;
  __syncthreads();
  if (tid == 0) len[b] = red[0] + red[1] + red[2] + red[3];
}

// ---- mlm head (bf16 input) ----
__global__ __launch_bounds__(256) void k_mlm(const unsigned short* __restrict__ e2,
                                             const float* __restrict__ w3,
                                             const float* __restrict__ b3, float* __restrict__ out) {
  int gw = (blockIdx.x * 256 + threadIdx.x) >> 6;
  int lane = threadIdx.x & 63;
  if (gw >= TOK) return;
  float x[8], w[8];
  ld8bf(e2 + (size_t)gw * DM, lane, x);
  ld8(w3, lane, w);
  float s = 0;
#pragma unroll
  for (int j = 0; j < 8; ++j) s += x[j] * w[j];
  s = wsum(s);
  if (lane == 0) out[gw] = s + b3[0];
}

__global__ __launch_bounds__(256) void k_cell(const float* __restrict__ h, float* __restrict__ out) {
  int i = blockIdx.x * 256 + threadIdx.x;
  if (i >= Bb * DM) return;
  int b = i >> 9, c = i & 511;
  out[i] = h[(size_t)b * Ls * DM + c];
}

// ---- classifier matvec (wave-per-output; optional LN+affine on input) ----
__global__ __launch_bounds__(256) void k_clsmv(const float* __restrict__ xin, size_t xstride,
    const float* __restrict__ g, const float* __restrict__ bb, int doLN,
    const float* __restrict__ W, const float* __restrict__ bias, int doRelu,
    float* __restrict__ out, int nout) {
  int b = blockIdx.y;
  int j = blockIdx.x * 4 + (threadIdx.x >> 6);
  int lane = threadIdx.x & 63;
  if (j >= nout) return;
  float x[8];
  ld8(xin + (size_t)b * xstride, lane, x);
  if (doLN) {
    norm8(x);
    float gv[8], bv[8];
    ld8(g, lane, gv); ld8(bb, lane, bv);
#pragma unroll
    for (int k = 0; k < 8; ++k) x[k] = x[k] * gv[k] + bv[k];
  }
  float w[8];
  ld8(W + (size_t)j * DM, lane, w);
  float s = 0;
#pragma unroll
  for (int k = 0; k < 8; ++k) s += x[k] * w[k];
  s = wsum(s);
  if (lane == 0) {
    float v = s + bias[j];
    if (doRelu) v = fmaxf(v, 0.f);
    out[(size_t)b * nout + j] = v;
  }
}

// ---- workspace layout (floats) ----
constexpr size_t F_H   = 0;
constexpr size_t F_DTF = F_H + (size_t)TOK * DM;
constexpr size_t F_LAF = F_DTF + (size_t)TOK * NH;
constexpr size_t F_DTR = F_LAF + (size_t)TOK * NH;
constexpr size_t F_LAR = F_DTR + (size_t)TOK * NH;
constexpr size_t F_YF  = F_LAR + (size_t)TOK * NH;
constexpr size_t F_YR  = F_YF + (size_t)TOK * DI;
constexpr size_t F_ON  = F_YR + (size_t)TOK * DI;
constexpr size_t F_G   = F_ON + (size_t)TOK * DM;                 // 2 dirs
constexpr size_t F_CUM = F_G + (size_t)2 * Bb * NH * NCH * HD * DS;
constexpr size_t F_CC1 = F_CUM + (size_t)2 * Bb * NH * NCH * 64;
constexpr size_t F_CC2 = F_CC1 + Bb * DM;
constexpr size_t F_LEN = F_CC2 + Bb * DM;
constexpr size_t F_END = F_LEN + 16;
// bf16 regions (ushort offsets)
constexpr size_t U0     = F_END * 2;
constexpr size_t UW_IN  = U0;
constexpr size_t UW_OUT = UW_IN + (size_t)2 * DIP * DM;
constexpr size_t UW_VE  = UW_OUT + (size_t)2 * DM * DI;
constexpr size_t UW_E1  = UW_VE + (size_t)DM * DM;
constexpr size_t UW_E2  = UW_E1 + (size_t)DM * DM;
constexpr size_t U_BFA  = UW_E2 + (size_t)DM * DM;   // v1 / e1-bf16
constexpr size_t U_HNBF = U_BFA + (size_t)TOK * DM;
constexpr size_t U_YBF  = U_HNBF + (size_t)TOK * DM;
constexpr size_t U_ZX   = U_YBF + (size_t)TOK * DI;  // bf16 zx (TOK*NPJ)
constexpr size_t U_CBUF = U_ZX + (size_t)TOK * NPJ;  // 2 dirs * 1024 * 4096

extern "C" void kernel_launch(void* const* d_in, const int* in_sizes, int n_in,
                              void* d_out, int out_size, void* d_ws, size_t ws_size,
                              hipStream_t stream) {
  const int* src = (const int*)d_in[0];
  const float* values = (const float*)d_in[1];
  const unsigned char* mask = (const unsigned char*)d_in[2];
  const float* embed = (const float*)d_in[3];
  const float* ge_g = (const float*)d_in[4];
  const float* ge_b = (const float*)d_in[5];
  const float* ve_w1 = (const float*)d_in[6];
  const float* ve_b1 = (const float*)d_in[7];
  const float* ve_w2 = (const float*)d_in[8];
  const float* ve_b2 = (const float*)d_in[9];
  const float* ve_g = (const float*)d_in[10];
  const float* ve_bb = (const float*)d_in[11];
  const float* in_w = (const float*)d_in[12];
  const float* conv_w_f = (const float*)d_in[13];
  const float* conv_b_f = (const float*)d_in[14];
  const float* A_f = (const float*)d_in[15];
  const float* dtb_f = (const float*)d_in[16];
  const float* D_f = (const float*)d_in[17];
  const float* nw_f = (const float*)d_in[18];
  const float* conv_w_r = (const float*)d_in[19];
  const float* conv_b_r = (const float*)d_in[20];
  const float* A_r = (const float*)d_in[21];
  const float* dtb_r = (const float*)d_in[22];
  const float* D_r = (const float*)d_in[23];
  const float* nw_r = (const float*)d_in[24];
  const float* out_w = (const float*)d_in[25];
  const float* expr_w1 = (const float*)d_in[26];
  const float* expr_b1 = (const float*)d_in[27];
  const float* expr_w2 = (const float*)d_in[28];
  const float* expr_b2 = (const float*)d_in[29];
  const float* expr_w3 = (const float*)d_in[30];
  const float* expr_b3 = (const float*)d_in[31];
  const float* cls_w1 = (const float*)d_in[32];
  const float* cls_b1 = (const float*)d_in[33];
  const float* cls_g1 = (const float*)d_in[34];
  const float* cls_bb1 = (const float*)d_in[35];
  const float* cls_w2 = (const float*)d_in[36];
  const float* cls_b2 = (const float*)d_in[37];
  const float* cls_g2 = (const float*)d_in[38];
  const float* cls_bb2 = (const float*)d_in[39];
  const float* cls_wo = (const float*)d_in[40];
  const float* cls_bo = (const float*)d_in[41];

  float* ws = (float*)d_ws;
  unsigned short* wsu = (unsigned short*)d_ws;
  float* h = ws + F_H;
  float* dtf = ws + F_DTF;
  float* laf = ws + F_LAF;
  float* dtr = ws + F_DTR;
  float* lar = ws + F_LAR;
  float* yF = ws + F_YF;
  float* yR = ws + F_YR;
  float* onew = ws + F_ON;
  float* gbuf = ws + F_G;
  float* cumb = ws + F_CUM;
  float* cc1 = ws + F_CC1;
  float* cc2 = ws + F_CC2;
  int* len = (int*)(ws + F_LEN);
  unsigned short* w_in = wsu + UW_IN;
  unsigned short* w_out = wsu + UW_OUT;
  unsigned short* w_ve = wsu + UW_VE;
  unsigned short* w_e1 = wsu + UW_E1;
  unsigned short* w_e2 = wsu + UW_E2;
  unsigned short* bfa = wsu + U_BFA;
  unsigned short* hnbf = wsu + U_HNBF;
  unsigned short* ybf = wsu + U_YBF;
  unsigned short* zxb = wsu + U_ZX;
  unsigned short* cbuf = wsu + U_CBUF;
  float* t2 = onew;                 // reuse before layers
  unsigned short* e2b = zxb;        // reuse after layers
  float* out = (float*)d_out;

  // ---- weight conversions ----
  {
    int n;
    n = 2 * DIP * DM / 8;  k_w2bf<<<(n + 255) / 256, 256, 0, stream>>>(in_w, w_in, n);
    n = 2 * DM * DI / 8;   k_w2bf<<<(n + 255) / 256, 256, 0, stream>>>(out_w, w_out, n);
    n = DM * DM / 8;       k_w2bf<<<(n + 255) / 256, 256, 0, stream>>>(ve_w2, w_ve, n);
    n = DM * DM / 8;       k_w2bf<<<(n + 255) / 256, 256, 0, stream>>>(expr_w1, w_e1, n);
    n = DM * DM / 8;       k_w2bf<<<(n + 255) / 256, 256, 0, stream>>>(expr_w2, w_e2, n);
  }

  // ---- embedding + value encoder ----
  k_embed<<<TOK / 4, 256, 0, stream>>>(src, values, embed, ge_g, ge_b, ve_w1, ve_b1, h, bfa);
  gemm_bf<0, 0><<<dim3(DM / 128, TOK / 128), 256, 0, stream>>>(bfa, w_ve, ve_b2, t2, TOK, DM, DM);
  k_haddv<<<TOK / 4, 256, 0, stream>>>(t2, ve_g, ve_bb, mask, h);
  k_lengths<<<Bb, 256, 0, stream>>>(mask, len);

  // ---- layers ----
  for (int i = 0; i < 2; ++i) {
    const float* inw = in_w + (size_t)i * DIP * DM;
    unsigned short* inwb = w_in + (size_t)i * DIP * DM;
    unsigned short* outwb = w_out + (size_t)i * DM * DI;
    k_lndt<<<TOK / 4, 256, 0, stream>>>(h, inw, dtb_f + i * NH, A_f + i * NH,
                                        dtb_r + i * NH, A_r + i * NH, len, hnbf,
                                        dtf, laf, dtr, lar);
    gemm_bf<0, 1><<<dim3(NPJ / 128, TOK / 128), 256, 0, stream>>>(hnbf, inwb, nullptr, zxb, TOK, NPJ, DM);
    k_chunk<<<2 * Bb * NH * NCH, 256, 0, stream>>>(zxb,
        conv_w_f + (size_t)i * CDIM * 4, conv_b_f + (size_t)i * CDIM,
        conv_w_r + (size_t)i * CDIM * 4, conv_b_r + (size_t)i * CDIM,
        dtf, laf, dtr, lar, D_f + i * NH, D_r + i * NH, len,
        yF, yR, gbuf, cumb, cbuf);
    k_chain<<<2 * Bb * NH, 256, 0, stream>>>(gbuf, cumb);
    k_corr<<<2 * Bb * NH * NCH, 256, 0, stream>>>(cbuf, gbuf, cumb, yF, yR);
    k_gab<<<TOK / 4, 256, 0, stream>>>(yF, yR, zxb, nw_f + (size_t)i * DI, nw_r + (size_t)i * DI,
                                       len, ybf);
    gemm_bf<0, 0><<<dim3(DM / 128, TOK / 128), 256, 0, stream>>>(ybf, outwb, nullptr, onew, TOK, DM, DI);
    k_hln<<<TOK / 4, 256, 0, stream>>>(onew, h, hnbf);
  }

  // ---- heads ----
  gemm_bf<2, 1><<<dim3(DM / 128, TOK / 128), 256, 0, stream>>>(hnbf, w_e1, expr_b1, bfa, TOK, DM, DM);
  gemm_bf<2, 1><<<dim3(DM / 128, TOK / 128), 256, 0, stream>>>(bfa, w_e2, expr_b2, e2b, TOK, DM, DM);
  k_mlm<<<TOK / 4, 256, 0, stream>>>(e2b, expr_w3, expr_b3, out);
  k_cell<<<(Bb * DM + 255) / 256, 256, 0, stream>>>(h, out + TOK);
  k_clsmv<<<dim3(128, Bb), 256, 0, stream>>>(h, (size_t)Ls * DM, nullptr, nullptr, 0,
                                             cls_w1, cls_b1, 1, cc1, DM);
  k_clsmv<<<dim3(128, Bb), 256, 0, stream>>>(cc1, DM, cls_g1, cls_bb1, 1,
                                             cls_w2, cls_b2, 1, cc2, DM);
  k_clsmv<<<dim3(41, Bb), 256, 0, stream>>>(cc2, DM, cls_g2, cls_bb2, 1,
                                            cls_wo, cls_bo, 0, out + TOK + Bb * DM, 164);
}

// Round 7
// 347.909 us; speedup vs baseline: 10.7899x; 1.0539x over previous
//
#include <hip/hip_runtime.h>
#include <hip/hip_bf16.h>
#include <math.h>

// ---- model constants ----
constexpr int Bb = 4, Ls = 1024, DM = 512, DI = 1024, NH = 16, HD = 64, DS = 64;
constexpr int CDIM = DI + 2 * DS;          // 1152
constexpr int DIP  = 2 * DI + 2 * DS + NH; // 2192
constexpr int NPJ  = 2 * DI + 2 * DS;      // 2176 = 17*128
constexpr float EPSf = 1e-5f;
constexpr int TOK = Bb * Ls;               // 4096
constexpr int CH = 64, NCH = Ls / CH;      // 16 chunks of 64

#define DEVI __device__ __forceinline__

using bfrag = __attribute__((ext_vector_type(8))) short;
using f4v   = __attribute__((ext_vector_type(4))) float;
using u16x8 = __attribute__((ext_vector_type(8))) unsigned short;

#define GLOAD16(gp, lp)                                                              \
  __builtin_amdgcn_global_load_lds((__attribute__((address_space(1))) void*)(gp),   \
                                   (__attribute__((address_space(3))) void*)(lp),   \
                                   16, 0, 0)

DEVI float wsum(float v) {
#pragma unroll
  for (int o = 32; o > 0; o >>= 1) v += __shfl_xor(v, o);
  return v;
}
DEVI float sigmoidf_(float x) { return 1.f / (1.f + __expf(-x)); }
DEVI unsigned short f2bf(float x) {
  union { float f; unsigned u; } c{x};
  unsigned u = c.u;
  u += 0x7fffu + ((u >> 16) & 1u);
  return (unsigned short)(u >> 16);
}
DEVI float bf2f(unsigned short u) {
  union { unsigned u; float f; } c{(unsigned)u << 16};
  return c.f;
}

DEVI void ld8(const float* __restrict__ p, int lane, float (&x)[8]) {
  float4 a = *(const float4*)(p + lane * 4);
  float4 b = *(const float4*)(p + 256 + lane * 4);
  x[0] = a.x; x[1] = a.y; x[2] = a.z; x[3] = a.w;
  x[4] = b.x; x[5] = b.y; x[6] = b.z; x[7] = b.w;
}
DEVI void ld8bf(const unsigned short* __restrict__ p, int lane, float (&x)[8]) {
  ushort4 a = *(const ushort4*)(p + lane * 4);
  ushort4 b = *(const ushort4*)(p + 256 + lane * 4);
  x[0] = bf2f(a.x); x[1] = bf2f(a.y); x[2] = bf2f(a.z); x[3] = bf2f(a.w);
  x[4] = bf2f(b.x); x[5] = bf2f(b.y); x[6] = bf2f(b.z); x[7] = bf2f(b.w);
}
DEVI void st8(float* __restrict__ p, int lane, const float (&x)[8]) {
  *(float4*)(p + lane * 4) = make_float4(x[0], x[1], x[2], x[3]);
  *(float4*)(p + 256 + lane * 4) = make_float4(x[4], x[5], x[6], x[7]);
}
DEVI void st8bf(unsigned short* __restrict__ p, int lane, const float (&x)[8]) {
  *(ushort4*)(p + lane * 4) = make_ushort4(f2bf(x[0]), f2bf(x[1]), f2bf(x[2]), f2bf(x[3]));
  *(ushort4*)(p + 256 + lane * 4) = make_ushort4(f2bf(x[4]), f2bf(x[5]), f2bf(x[6]), f2bf(x[7]));
}
DEVI void norm8(float (&x)[8]) {
  float s = 0;
#pragma unroll
  for (int j = 0; j < 8; ++j) s += x[j];
  float mean = wsum(s) * (1.f / 512.f);
#pragma unroll
  for (int j = 0; j < 8; ++j) x[j] -= mean;
  float q = 0;
#pragma unroll
  for (int j = 0; j < 8; ++j) q += x[j] * x[j];
  float var = wsum(q) * (1.f / 512.f);
  float inv = rsqrtf(var + EPSf);
#pragma unroll
  for (int j = 0; j < 8; ++j) x[j] *= inv;
}

// ---- fp32 -> bf16 bulk convert (weights) ----
__global__ __launch_bounds__(256) void k_w2bf(const float* __restrict__ in,
                                              unsigned short* __restrict__ out, int n8) {
  int i = blockIdx.x * 256 + threadIdx.x;
  if (i >= n8) return;
  const float4* p = (const float4*)in + (size_t)i * 2;
  float4 a = p[0], b = p[1];
  *((ushort4*)out + (size_t)i * 2) = make_ushort4(f2bf(a.x), f2bf(a.y), f2bf(a.z), f2bf(a.w));
  *((ushort4*)out + (size_t)i * 2 + 1) = make_ushort4(f2bf(b.x), f2bf(b.y), f2bf(b.z), f2bf(b.w));
}

// ---- embedding + value-encoder stage 1 ----
__global__ __launch_bounds__(256) void k_embed(const int* __restrict__ src, const float* __restrict__ values,
    const float* __restrict__ embed, const float* __restrict__ gg, const float* __restrict__ gb,
    const float* __restrict__ vw1, const float* __restrict__ vb1,
    float* __restrict__ hbuf, unsigned short* __restrict__ v1bf) {
  int gw = (blockIdx.x * 256 + threadIdx.x) >> 6;
  int lane = threadIdx.x & 63;
  if (gw >= TOK) return;
  const float* er = embed + (size_t)src[gw] * DM;
  float x[8];
  ld8(er, lane, x);
  norm8(x);
  float g[8], bv[8];
  ld8(gg, lane, g); ld8(gb, lane, bv);
#pragma unroll
  for (int j = 0; j < 8; ++j) x[j] = x[j] * g[j] + bv[j];
  st8(hbuf + (size_t)gw * DM, lane, x);
  float val = fminf(values[gw], 512.f);
  float w1[8], b1[8];
  ld8(vw1, lane, w1); ld8(vb1, lane, b1);
  float v[8];
#pragma unroll
  for (int j = 0; j < 8; ++j) v[j] = fmaxf(val * w1[j] + b1[j], 0.f);
  st8bf(v1bf + (size_t)gw * DM, lane, v);
}

// h = (h + LN(t2)*g+b) * (mask?0:1)
__global__ __launch_bounds__(256) void k_haddv(const float* __restrict__ t2, const float* __restrict__ g,
    const float* __restrict__ bb, const unsigned char* __restrict__ mask, float* __restrict__ hbuf) {
  int gw = (blockIdx.x * 256 + threadIdx.x) >> 6;
  int lane = threadIdx.x & 63;
  if (gw >= TOK) return;
  float x[8];
  ld8(t2 + (size_t)gw * DM, lane, x);
  norm8(x);
  float gv[8], bv[8], h[8];
  ld8(g, lane, gv); ld8(bb, lane, bv);
  ld8(hbuf + (size_t)gw * DM, lane, h);
  float mf = mask[gw] ? 0.f : 1.f;
#pragma unroll
  for (int j = 0; j < 8; ++j) h[j] = (h[j] + x[j] * gv[j] + bv[j]) * mf;
  st8(hbuf + (size_t)gw * DM, lane, h);
}

// ---- LN(h)->bf16  +  dt/ldA for BOTH directions (shared raw logits) ----
__global__ __launch_bounds__(256) void k_lndt(const float* __restrict__ h, const float* __restrict__ inw,
    const float* __restrict__ dtbF, const float* __restrict__ AlogF,
    const float* __restrict__ dtbR, const float* __restrict__ AlogR,
    const int* __restrict__ len, unsigned short* __restrict__ hnbf,
    float* __restrict__ dtf, float* __restrict__ laf,
    float* __restrict__ dtr, float* __restrict__ lar) {
  int gw = (blockIdx.x * 256 + threadIdx.x) >> 6;
  int lane = threadIdx.x & 63;
  if (gw >= TOK) return;
  float x[8];
  ld8(h + (size_t)gw * DM, lane, x);
  norm8(x);
  st8bf(hnbf + (size_t)gw * DM, lane, x);
  const float* wdt = inw + (size_t)NPJ * DM;
  float myraw = 0.f;
#pragma unroll
  for (int hh = 0; hh < NH; ++hh) {
    float w[8];
    ld8(wdt + (size_t)hh * DM, lane, w);
    float s = 0;
#pragma unroll
    for (int j = 0; j < 8; ++j) s += x[j] * w[j];
    s = wsum(s);
    if (lane == hh) myraw = s;
  }
  if (lane < NH) {
    int t = gw & (Ls - 1), b = gw >> 10;
    int ln = len[b];
    int pos = (t < ln) ? (ln - 1 - t) : t;
    size_t grev = (size_t)(b * Ls + pos);
    float rf = myraw + dtbF[lane];
    float df = rf > 20.f ? rf : log1pf(__expf(rf));
    dtf[(size_t)gw * NH + lane] = df;
    laf[(size_t)gw * NH + lane] = -__expf(AlogF[lane]) * df;
    float rr = myraw + dtbR[lane];
    float dr = rr > 20.f ? rr : log1pf(__expf(rr));
    dtr[grev * NH + lane] = dr;
    lar[grev * NH + lane] = -__expf(AlogR[lane]) * dr;
  }
}

// ---- bf16 MFMA GEMM: C[M,N] = A[M,K] @ W[N,K]^T (+bias, act) ----
template <int ACT, int OMODE>
__global__ __launch_bounds__(256) void gemm_bf(const unsigned short* __restrict__ A,
    const unsigned short* __restrict__ W, const float* __restrict__ bias,
    void* __restrict__ Cout, int M, int N, int K) {
  constexpr int BK = 64;
  __shared__ unsigned short As[128 * BK];
  __shared__ unsigned short Bs[128 * BK];
  int tid = threadIdx.x;
  int bm = blockIdx.y * 128, bn = blockIdx.x * 128;
  int wv = tid >> 6, lane = tid & 63;
  int mb = (wv >> 1) * 64, nb = (wv & 1) * 64;
  int rA = lane >> 3;
  int cswz = (lane & 7) ^ rA;
  f4v acc[4][4] = {};

  for (int k0 = 0; k0 < K; k0 += BK) {
#pragma unroll
    for (int q = 0; q < 4; ++q) {
      int ch = wv * 4 + q;
      const unsigned short* ga = A + (size_t)(bm + ch * 8 + rA) * K + k0 + cswz * 8;
      GLOAD16(ga, &As[ch * 512]);
      const unsigned short* gb = W + (size_t)(bn + ch * 8 + rA) * K + k0 + cswz * 8;
      GLOAD16(gb, &Bs[ch * 512]);
    }
    __syncthreads();
#pragma unroll
    for (int ks = 0; ks < BK; ks += 32) {
      int kb = (ks >> 3) + (lane >> 4);
      bfrag af[4], bg[4];
#pragma unroll
      for (int i = 0; i < 4; ++i) {
        int ra_ = mb + i * 16 + (lane & 15);
        af[i] = *(const bfrag*)((const char*)As + ((ra_ * 128 + kb * 16) ^ ((ra_ & 7) << 4)));
        int rb_ = nb + i * 16 + (lane & 15);
        bg[i] = *(const bfrag*)((const char*)Bs + ((rb_ * 128 + kb * 16) ^ ((rb_ & 7) << 4)));
      }
#pragma unroll
      for (int i = 0; i < 4; ++i)
#pragma unroll
        for (int j = 0; j < 4; ++j)
          acc[i][j] = __builtin_amdgcn_mfma_f32_16x16x32_bf16(af[i], bg[j], acc[i][j], 0, 0, 0);
    }
    __syncthreads();
  }

  int cb = bn + nb + (lane & 15);
  int rb = bm + mb + ((lane >> 4) << 2);
#pragma unroll
  for (int j = 0; j < 4; ++j) {
    float bv = bias ? bias[cb + j * 16] : 0.f;
#pragma unroll
    for (int i = 0; i < 4; ++i) {
#pragma unroll
      for (int r = 0; r < 4; ++r) {
        float v = acc[i][j][r] + bv;
        if (ACT == 1) v = fmaxf(v, 0.f);
        if (ACT == 2) v = v > 0.f ? v : 0.01f * v;
        size_t idx = (size_t)(rb + i * 16 + r) * N + cb + j * 16;
        if (OMODE == 0) ((float*)Cout)[idx] = v;
        else ((unsigned short*)Cout)[idx] = f2bf(v);
      }
    }
  }
}

// ---- shared B/C conv+silu, both dirs: bcbuf[dir][bt][128] (B=0..63, C=64..127) ----
__global__ __launch_bounds__(256) void k_convbc(const unsigned short* __restrict__ zx,
    const float* __restrict__ cwF, const float* __restrict__ cbF,
    const float* __restrict__ cwR, const float* __restrict__ cbR,
    const int* __restrict__ len, unsigned short* __restrict__ bcbuf) {
  int idx = blockIdx.x * 256 + threadIdx.x;
  if (idx >= 2 * TOK * 128) return;
  int col = idx & 127;
  int bt = (idx >> 7) & (TOK - 1);
  int dir = idx >> 19;
  int b = bt >> 10, t = bt & (Ls - 1);
  int ln = len[b];
  const float* cw = dir ? cwR : cwF;
  const float* cb = dir ? cbR : cbF;
  int ccd = DI + col;
  float4 w4 = *(const float4*)(cw + ccd * 4);
  float s = cb[ccd];
  float wk[4] = {w4.x, w4.y, w4.z, w4.w};
#pragma unroll
  for (int k = 0; k < 4; ++k) {
    int rl = t - 3 + k;
    if (rl >= 0) {
      int gr = dir ? (rl < ln ? ln - 1 - rl : rl) : rl;
      s += wk[k] * bf2f(zx[((size_t)(b * Ls + gr)) * NPJ + 2 * DI + col]);
    }
  }
  s = s * sigmoidf_(s);
  bcbuf[idx] = f2bf(s);
}

// ======================= fused x-conv + chunked SSD, both dirs (MFMA) =======================
__global__ __launch_bounds__(256) void k_chunk(const unsigned short* __restrict__ zx,
    const unsigned short* __restrict__ bcbuf,
    const float* __restrict__ cwF, const float* __restrict__ cbF,
    const float* __restrict__ cwR, const float* __restrict__ cbR,
    const float* __restrict__ dtF, const float* __restrict__ laF,
    const float* __restrict__ dtR, const float* __restrict__ laR,
    const float* __restrict__ DkF, const float* __restrict__ DkR,
    const int* __restrict__ len,
    float* __restrict__ yF, float* __restrict__ yR,
    float* __restrict__ gbuf, float* __restrict__ cumbuf) {
  __shared__ unsigned short Cb[4096], Bbs[4096], BbT[4096], xT[4096], Wt[4096];
  __shared__ float ldsL[64], sdt_[64], fs[64];
  int blk2 = blockIdx.x;
  int dir = blk2 >> 10;
  int blk = blk2 & 1023;
  int c = blk & 15, bh = blk >> 4, h = bh & 15, b = bh >> 4;
  int tid = threadIdx.x, wv = tid >> 6, lane = tid & 63;
  int c0 = c * CH;
  int ln = len[b];
  const float* cw = dir ? cwR : cwF;
  const float* cbias = dir ? cbR : cbF;
  const float* dtp = dir ? dtR : dtF;
  const float* ldap = dir ? laR : laF;
  float Dh = (dir ? DkR : DkF)[h];
  float* y = dir ? yR : yF;

  if (tid < 64) {
    size_t off = ((size_t)(b * Ls + c0 + tid)) * NH + h;
    float dtv = dtp[off];
    float v = ldap[off];
#pragma unroll
    for (int o = 1; o < 64; o <<= 1) {
      float n = __shfl_up(v, o);
      if (tid >= o) v += n;
    }
    ldsL[tid] = v;
    sdt_[tid] = dtv;
    cumbuf[(size_t)blk2 * 64 + tid] = __expf(v);
    float L63 = __shfl(v, 63);
    fs[tid] = __expf(L63 - v) * dtv;
  }
  __syncthreads();

  // stage B (rows) + C tiles from bcbuf (vectorized)
  {
    const unsigned short* bc = bcbuf + ((size_t)(dir * TOK + b * Ls + c0)) * 128;
    int r = tid >> 2;
    int colq = (tid & 3) * 32;
#pragma unroll
    for (int g = 0; g < 2; ++g) {
      int col = colq + g * 16;
      u16x8 v0 = *(const u16x8*)(bc + (size_t)r * 128 + col);
      u16x8 v1 = *(const u16x8*)(bc + (size_t)r * 128 + col + 8);
      if (col < 64) {
        *(u16x8*)((char*)Bbs + ((r * 128 + col * 2) ^ ((r & 7) << 4))) = v0;
        *(u16x8*)((char*)Bbs + ((r * 128 + col * 2 + 16) ^ ((r & 7) << 4))) = v1;
      } else {
        int n = col - 64;
        *(u16x8*)((char*)Cb + ((r * 128 + n * 2) ^ ((r & 7) << 4))) = v0;
        *(u16x8*)((char*)Cb + ((r * 128 + n * 2 + 16) ^ ((r & 7) << 4))) = v1;
      }
    }
  }
  // stage BbT (transposed, fs-scaled)
  {
    int n = tid & 63;
    int tg = (tid >> 6) * 16;
    const unsigned short* bc = bcbuf + ((size_t)(dir * TOK + b * Ls + c0 + tg)) * 128 + n;
    float vals[16];
#pragma unroll
    for (int t = 0; t < 16; ++t) vals[t] = bf2f(bc[(size_t)t * 128]) * fs[tg + t];
#pragma unroll
    for (int hv = 0; hv < 2; ++hv) {
      u16x8 pk;
#pragma unroll
      for (int k = 0; k < 8; ++k) pk[k] = f2bf(vals[hv * 8 + k]);
      *(u16x8*)((char*)BbT + ((n * 128 + (tg + hv * 8) * 2) ^ ((n & 7) << 4))) = pk;
    }
  }
  // x-conv (per-head 64 channels), pack transposed xT[p][t]
  {
    int cch = tid & 63;
    int tg = (tid >> 6) * 16;
    int gcol = DI + h * 64 + cch;
    int ccd = h * 64 + cch;
    float4 w4 = *(const float4*)(cw + ccd * 4);
    float bias = cbias[ccd];
    float vv[19];
#pragma unroll
    for (int k = 0; k < 19; ++k) {
      int rl = c0 + tg - 3 + k;
      float val = 0.f;
      if (rl >= 0) {
        int gr = dir ? (rl < ln ? ln - 1 - rl : rl) : rl;
        val = bf2f(zx[((size_t)(b * Ls + gr)) * NPJ + gcol]);
      }
      vv[k] = val;
    }
    int p = cch;
#pragma unroll
    for (int hv = 0; hv < 2; ++hv) {
      u16x8 pk;
#pragma unroll
      for (int k = 0; k < 8; ++k) {
        int t = hv * 8 + k;
        float s = bias + w4.x * vv[t] + w4.y * vv[t + 1] + w4.z * vv[t + 2] + w4.w * vv[t + 3];
        pk[k] = f2bf(s * sigmoidf_(s));
      }
      *(u16x8*)((char*)xT + ((p * 128 + (tg + hv * 8) * 2) ^ ((p & 7) << 4))) = pk;
    }
  }
  __syncthreads();

  // matmul1: S[t][s] = C . B^T
  f4v accS[4] = {};
#pragma unroll
  for (int ks = 0; ks < 64; ks += 32) {
    int kb = (ks >> 3) + (lane >> 4);
    int ra = wv * 16 + (lane & 15);
    bfrag af = *(const bfrag*)((const char*)Cb + ((ra * 128 + kb * 16) ^ ((ra & 7) << 4)));
#pragma unroll
    for (int j = 0; j < 4; ++j) {
      int rb = j * 16 + (lane & 15);
      bfrag bg = *(const bfrag*)((const char*)Bbs + ((rb * 128 + kb * 16) ^ ((rb & 7) << 4)));
      accS[j] = __builtin_amdgcn_mfma_f32_16x16x32_bf16(af, bg, accS[j], 0, 0, 0);
    }
  }
  // decay + causal mask -> Wt (bf16)
  {
    int trow = wv * 16 + ((lane >> 4) << 2);
#pragma unroll
    for (int j = 0; j < 4; ++j) {
      int s = j * 16 + (lane & 15);
      float ds = sdt_[s], Lsv = ldsL[s];
#pragma unroll
      for (int r = 0; r < 4; ++r) {
        int tt = trow + r;
        float wval = (s <= tt) ? accS[j][r] * ds * __expf(ldsL[tt] - Lsv) : 0.f;
        *(unsigned short*)((char*)Wt + ((tt * 128 + s * 2) ^ ((tt & 7) << 4))) = f2bf(wval);
      }
    }
  }
  __syncthreads();

  // matmul2: Y = W @ x ; matmul3: G = (fB)^T @ x
  f4v accY[4] = {}, accG[4] = {};
#pragma unroll
  for (int ks = 0; ks < 64; ks += 32) {
    int kb = (ks >> 3) + (lane >> 4);
    int ra = wv * 16 + (lane & 15);
    bfrag afW = *(const bfrag*)((const char*)Wt + ((ra * 128 + kb * 16) ^ ((ra & 7) << 4)));
    bfrag afB = *(const bfrag*)((const char*)BbT + ((ra * 128 + kb * 16) ^ ((ra & 7) << 4)));
#pragma unroll
    for (int j = 0; j < 4; ++j) {
      int rb = j * 16 + (lane & 15);
      bfrag bg = *(const bfrag*)((const char*)xT + ((rb * 128 + kb * 16) ^ ((rb & 7) << 4)));
      accY[j] = __builtin_amdgcn_mfma_f32_16x16x32_bf16(afW, bg, accY[j], 0, 0, 0);
      accG[j] = __builtin_amdgcn_mfma_f32_16x16x32_bf16(afB, bg, accG[j], 0, 0, 0);
    }
  }
  int trow = wv * 16 + ((lane >> 4) << 2);
#pragma unroll
  for (int j = 0; j < 4; ++j) {
    int p = j * 16 + (lane & 15);
#pragma unroll
    for (int r = 0; r < 4; ++r) {
      int t = trow + r;
      float xval = bf2f(*(const unsigned short*)((const char*)xT + ((p * 128 + t * 2) ^ ((p & 7) << 4))));
      y[((size_t)(b * Ls + c0 + t)) * DI + h * 64 + p] = accY[j][r] + Dh * xval;
      gbuf[((size_t)blk2 * 64 + t) * 64 + p] = accG[j][r];
    }
  }
}

// inter-chunk recurrence with prefetch (in-place: gbuf[c] -> h_in before chunk c); grid 128
__global__ __launch_bounds__(256) void k_chain(float* __restrict__ gbuf, const float* __restrict__ cumbuf) {
  int bh = blockIdx.x;
  int tid = threadIdx.x;
  size_t base = (size_t)bh * NCH * 4096;
  float4 hv[4] = {};
  float4 g[4], gn[4];
#pragma unroll
  for (int k = 0; k < 4; ++k) g[k] = *(const float4*)(gbuf + base + (size_t)k * 1024 + tid * 4);
  float Pc = cumbuf[(size_t)bh * NCH * 64 + 63];
  for (int c = 0; c < NCH; ++c) {
    float Pn = 0.f;
    if (c + 1 < NCH) {
      Pn = cumbuf[((size_t)bh * NCH + c + 1) * 64 + 63];
#pragma unroll
      for (int k = 0; k < 4; ++k)
        gn[k] = *(const float4*)(gbuf + base + (size_t)(c + 1) * 4096 + (size_t)k * 1024 + tid * 4);
    }
#pragma unroll
    for (int k = 0; k < 4; ++k) {
      *(float4*)(gbuf + base + (size_t)c * 4096 + (size_t)k * 1024 + tid * 4) = hv[k];
      hv[k].x = fmaf(Pc, hv[k].x, g[k].x);
      hv[k].y = fmaf(Pc, hv[k].y, g[k].y);
      hv[k].z = fmaf(Pc, hv[k].z, g[k].z);
      hv[k].w = fmaf(Pc, hv[k].w, g[k].w);
      g[k] = gn[k];
    }
    Pc = Pn;
  }
}

// correction: Y[t][p] += exp(L[t]) * sum_n C[t][n] * hin[n][p]; grid 2048
__global__ __launch_bounds__(256) void k_corr(const unsigned short* __restrict__ bcbuf,
    const float* __restrict__ hin, const float* __restrict__ cumbuf,
    float* __restrict__ yF, float* __restrict__ yR) {
  int blk2 = blockIdx.x;
  int c = blk2 & 15;
  if (c == 0) return;
  __shared__ unsigned short Ct[4096], HT[4096];
  __shared__ float cdl[64];
  int dir = blk2 >> 10;
  int bh = (blk2 & 1023) >> 4, h = bh & 15, b = bh >> 4;
  int tid = threadIdx.x, wv = tid >> 6, lane = tid & 63;
  int c0 = c * CH;
  float* y = dir ? yR : yF;
  {
    int r = tid >> 2;
    int colq = (tid & 3) * 16;
    const unsigned short* bc = bcbuf + ((size_t)(dir * TOK + b * Ls + c0 + r)) * 128 + 64 + colq;
    u16x8 v0 = *(const u16x8*)bc;
    u16x8 v1 = *(const u16x8*)(bc + 8);
    *(u16x8*)((char*)Ct + ((r * 128 + colq * 2) ^ ((r & 7) << 4))) = v0;
    *(u16x8*)((char*)Ct + ((r * 128 + colq * 2 + 16) ^ ((r & 7) << 4))) = v1;
  }
  {
    int n = tid >> 2, p0 = (tid & 3) * 16;
    const float* hr = hin + (size_t)blk2 * 4096 + (size_t)n * 64 + p0;
#pragma unroll
    for (int q = 0; q < 4; ++q) {
      float4 v = *(const float4*)(hr + q * 4);
      float va[4] = {v.x, v.y, v.z, v.w};
#pragma unroll
      for (int k = 0; k < 4; ++k) {
        int p = p0 + q * 4 + k;
        *(unsigned short*)((char*)HT + ((p * 128 + n * 2) ^ ((p & 7) << 4))) = f2bf(va[k]);
      }
    }
  }
  if (tid < 64) cdl[tid] = cumbuf[(size_t)blk2 * 64 + tid];
  __syncthreads();

  f4v acc[4] = {};
#pragma unroll
  for (int ks = 0; ks < 64; ks += 32) {
    int kb = (ks >> 3) + (lane >> 4);
    int ra = wv * 16 + (lane & 15);
    bfrag af = *(const bfrag*)((const char*)Ct + ((ra * 128 + kb * 16) ^ ((ra & 7) << 4)));
#pragma unroll
    for (int j = 0; j < 4; ++j) {
      int rb = j * 16 + (lane & 15);
      bfrag bg = *(const bfrag*)((const char*)HT + ((rb * 128 + kb * 16) ^ ((rb & 7) << 4)));
      acc[j] = __builtin_amdgcn_mfma_f32_16x16x32_bf16(af, bg, acc[j], 0, 0, 0);
    }
  }
  int trow = wv * 16 + ((lane >> 4) << 2);
#pragma unroll
  for (int j = 0; j < 4; ++j) {
    int p = j * 16 + (lane & 15);
#pragma unroll
    for (int r = 0; r < 4; ++r) {
      int t = trow + r;
      float* yp = &y[((size_t)(b * Ls + c0 + t)) * DI + h * 64 + p];
      *yp += cdl[t] * acc[j][r];
    }
  }
}
// ================================================================

// ---- both-direction gated RMSNorm: ybf[w] = 0.5*(gate_f(w) + gate_r(flip(w))) ----
__global__ __launch_bounds__(256) void k_gab(const float* __restrict__ yF, const float* __restrict__ yR,
    const unsigned short* __restrict__ zxb, const float* __restrict__ nwF, const float* __restrict__ nwR,
    const int* __restrict__ len, unsigned short* __restrict__ ybf) {
  int w = (blockIdx.x * 256 + threadIdx.x) >> 6;
  int lane = threadIdx.x & 63;
  if (w >= TOK) return;
  int t = w & (Ls - 1), b = w >> 10;
  int ln = len[b];
  int r = b * Ls + ((t < ln) ? (ln - 1 - t) : t);
  const float* yf = yF + (size_t)w * DI;
  const float* yr = yR + (size_t)r * DI;
  const unsigned short* zr = zxb + (size_t)w * NPJ;
  float gf[16], gr[16];
  float ssf = 0.f, ssr = 0.f;
#pragma unroll
  for (int q = 0; q < 4; ++q) {
    float4 yv = *(const float4*)(yf + lane * 4 + q * 256);
    float4 rv = *(const float4*)(yr + lane * 4 + q * 256);
    ushort4 zu = *(const ushort4*)(zr + lane * 4 + q * 256);
    float z0 = bf2f(zu.x), z1 = bf2f(zu.y), z2 = bf2f(zu.z), z3 = bf2f(zu.w);
    float s0 = z0 * sigmoidf_(z0), s1 = z1 * sigmoidf_(z1), s2 = z2 * sigmoidf_(z2), s3 = z3 * sigmoidf_(z3);
    gf[4 * q + 0] = yv.x * s0; gf[4 * q + 1] = yv.y * s1; gf[4 * q + 2] = yv.z * s2; gf[4 * q + 3] = yv.w * s3;
    gr[4 * q + 0] = rv.x * s0; gr[4 * q + 1] = rv.y * s1; gr[4 * q + 2] = rv.z * s2; gr[4 * q + 3] = rv.w * s3;
#pragma unroll
    for (int j = 0; j < 4; ++j) {
      ssf += gf[4 * q + j] * gf[4 * q + j];
      ssr += gr[4 * q + j] * gr[4 * q + j];
    }
  }
  ssf = wsum(ssf);
  ssr = wsum(ssr);
  float scf = 0.5f * rsqrtf(ssf * (1.f / (float)DI) + EPSf);
  float scr = 0.5f * rsqrtf(ssr * (1.f / (float)DI) + EPSf);
#pragma unroll
  for (int q = 0; q < 4; ++q) {
    float4 nf = *(const float4*)(nwF + lane * 4 + q * 256);
    float4 nr = *(const float4*)(nwR + lane * 4 + q * 256);
    float o0 = gf[4 * q + 0] * scf * nf.x + gr[4 * q + 0] * scr * nr.x;
    float o1 = gf[4 * q + 1] * scf * nf.y + gr[4 * q + 1] * scr * nr.y;
    float o2 = gf[4 * q + 2] * scf * nf.z + gr[4 * q + 2] * scr * nr.z;
    float o3 = gf[4 * q + 3] * scf * nf.w + gr[4 * q + 3] * scr * nr.w;
    *(ushort4*)(ybf + (size_t)w * DI + lane * 4 + q * 256) =
        make_ushort4(f2bf(o0), f2bf(o1), f2bf(o2), f2bf(o3));
  }
}

// ---- h = LN(src) -> fp32 + bf16 ----
__global__ __launch_bounds__(256) void k_hln(const float* __restrict__ src, float* __restrict__ dst,
                                             unsigned short* __restrict__ dstbf) {
  int gw = (blockIdx.x * 256 + threadIdx.x) >> 6;
  int lane = threadIdx.x & 63;
  if (gw >= TOK) return;
  float x[8];
  ld8(src + (size_t)gw * DM, lane, x);
  norm8(x);
  st8(dst + (size_t)gw * DM, lane, x);
  st8bf(dstbf + (size_t)gw * DM, lane, x);
}

// ---- lengths ----
__global__ __launch_bounds__(256) void k_lengths(const unsigned char* __restrict__ mask, int* __restrict__ len) {
  int b = blockIdx.x;
  int tid = threadIdx.x;
  int cnt = 0;
  for (int t = tid; t < Ls; t += 256) cnt += mask[b * Ls + t] ? 0 : 1;
#pragma unroll
  for (int o = 32; o > 0; o >>= 1) cnt += __shfl_xor(cnt, o);
  __shared__ int red[4];
  if ((tid & 63) == 0) red[tid >> 6] = cnt;
  __syncthreads();
  if (tid == 0) len[b] = red[0] + red[1] + red[2] + red[3];
}

// ---- mlm head (bf16 input) ----
__global__ __launch_bounds__(256) void k_mlm(const unsigned short* __restrict__ e2,
                                             const float* __restrict__ w3,
                                             const float* __restrict__ b3, float* __restrict__ out) {
  int gw = (blockIdx.x * 256 + threadIdx.x) >> 6;
  int lane = threadIdx.x & 63;
  if (gw >= TOK) return;
  float x[8], w[8];
  ld8bf(e2 + (size_t)gw * DM, lane, x);
  ld8(w3, lane, w);
  float s = 0;
#pragma unroll
  for (int j = 0; j < 8; ++j) s += x[j] * w[j];
  s = wsum(s);
  if (lane == 0) out[gw] = s + b3[0];
}

__global__ __launch_bounds__(256) void k_cell(const float* __restrict__ h, float* __restrict__ out) {
  int i = blockIdx.x * 256 + threadIdx.x;
  if (i >= Bb * DM) return;
  int b = i >> 9, c = i & 511;
  out[i] = h[(size_t)b * Ls * DM + c];
}

// ---- classifier matvec (wave-per-output; optional LN+affine on input) ----
__global__ __launch_bounds__(256) void k_clsmv(const float* __restrict__ xin, size_t xstride,
    const float* __restrict__ g, const float* __restrict__ bb, int doLN,
    const float* __restrict__ W, const float* __restrict__ bias, int doRelu,
    float* __restrict__ out, int nout) {
  int b = blockIdx.y;
  int j = blockIdx.x * 4 + (threadIdx.x >> 6);
  int lane = threadIdx.x & 63;
  if (j >= nout) return;
  float x[8];
  ld8(xin + (size_t)b * xstride, lane, x);
  if (doLN) {
    norm8(x);
    float gv[8], bv[8];
    ld8(g, lane, gv); ld8(bb, lane, bv);
#pragma unroll
    for (int k = 0; k < 8; ++k) x[k] = x[k] * gv[k] + bv[k];
  }
  float w[8];
  ld8(W + (size_t)j * DM, lane, w);
  float s = 0;
#pragma unroll
  for (int k = 0; k < 8; ++k) s += x[k] * w[k];
  s = wsum(s);
  if (lane == 0) {
    float v = s + bias[j];
    if (doRelu) v = fmaxf(v, 0.f);
    out[(size_t)b * nout + j] = v;
  }
}

// ---- workspace layout (floats) ----
constexpr size_t F_H   = 0;
constexpr size_t F_DTF = F_H + (size_t)TOK * DM;
constexpr size_t F_LAF = F_DTF + (size_t)TOK * NH;
constexpr size_t F_DTR = F_LAF + (size_t)TOK * NH;
constexpr size_t F_LAR = F_DTR + (size_t)TOK * NH;
constexpr size_t F_YF  = F_LAR + (size_t)TOK * NH;
constexpr size_t F_YR  = F_YF + (size_t)TOK * DI;
constexpr size_t F_ON  = F_YR + (size_t)TOK * DI;
constexpr size_t F_G   = F_ON + (size_t)TOK * DM;                 // 2 dirs
constexpr size_t F_CUM = F_G + (size_t)2 * Bb * NH * NCH * HD * DS;
constexpr size_t F_CC1 = F_CUM + (size_t)2 * Bb * NH * NCH * 64;
constexpr size_t F_CC2 = F_CC1 + Bb * DM;
constexpr size_t F_LEN = F_CC2 + Bb * DM;
constexpr size_t F_END = F_LEN + 16;
// bf16 regions (ushort offsets)
constexpr size_t U0     = F_END * 2;
constexpr size_t UW_IN  = U0;
constexpr size_t UW_OUT = UW_IN + (size_t)2 * DIP * DM;
constexpr size_t UW_VE  = UW_OUT + (size_t)2 * DM * DI;
constexpr size_t UW_E1  = UW_VE + (size_t)DM * DM;
constexpr size_t UW_E2  = UW_E1 + (size_t)DM * DM;
constexpr size_t U_BFA  = UW_E2 + (size_t)DM * DM;   // v1 / e1-bf16
constexpr size_t U_HNBF = U_BFA + (size_t)TOK * DM;
constexpr size_t U_YBF  = U_HNBF + (size_t)TOK * DM;
constexpr size_t U_ZX   = U_YBF + (size_t)TOK * DI;  // bf16 zx (TOK*NPJ)
constexpr size_t U_BC   = U_ZX + (size_t)TOK * NPJ;  // 2 * TOK * 128

extern "C" void kernel_launch(void* const* d_in, const int* in_sizes, int n_in,
                              void* d_out, int out_size, void* d_ws, size_t ws_size,
                              hipStream_t stream) {
  const int* src = (const int*)d_in[0];
  const float* values = (const float*)d_in[1];
  const unsigned char* mask = (const unsigned char*)d_in[2];
  const float* embed = (const float*)d_in[3];
  const float* ge_g = (const float*)d_in[4];
  const float* ge_b = (const float*)d_in[5];
  const float* ve_w1 = (const float*)d_in[6];
  const float* ve_b1 = (const float*)d_in[7];
  const float* ve_w2 = (const float*)d_in[8];
  const float* ve_b2 = (const float*)d_in[9];
  const float* ve_g = (const float*)d_in[10];
  const float* ve_bb = (const float*)d_in[11];
  const float* in_w = (const float*)d_in[12];
  const float* conv_w_f = (const float*)d_in[13];
  const float* conv_b_f = (const float*)d_in[14];
  const float* A_f = (const float*)d_in[15];
  const float* dtb_f = (const float*)d_in[16];
  const float* D_f = (const float*)d_in[17];
  const float* nw_f = (const float*)d_in[18];
  const float* conv_w_r = (const float*)d_in[19];
  const float* conv_b_r = (const float*)d_in[20];
  const float* A_r = (const float*)d_in[21];
  const float* dtb_r = (const float*)d_in[22];
  const float* D_r = (const float*)d_in[23];
  const float* nw_r = (const float*)d_in[24];
  const float* out_w = (const float*)d_in[25];
  const float* expr_w1 = (const float*)d_in[26];
  const float* expr_b1 = (const float*)d_in[27];
  const float* expr_w2 = (const float*)d_in[28];
  const float* expr_b2 = (const float*)d_in[29];
  const float* expr_w3 = (const float*)d_in[30];
  const float* expr_b3 = (const float*)d_in[31];
  const float* cls_w1 = (const float*)d_in[32];
  const float* cls_b1 = (const float*)d_in[33];
  const float* cls_g1 = (const float*)d_in[34];
  const float* cls_bb1 = (const float*)d_in[35];
  const float* cls_w2 = (const float*)d_in[36];
  const float* cls_b2 = (const float*)d_in[37];
  const float* cls_g2 = (const float*)d_in[38];
  const float* cls_bb2 = (const float*)d_in[39];
  const float* cls_wo = (const float*)d_in[40];
  const float* cls_bo = (const float*)d_in[41];

  float* ws = (float*)d_ws;
  unsigned short* wsu = (unsigned short*)d_ws;
  float* h = ws + F_H;
  float* dtf = ws + F_DTF;
  float* laf = ws + F_LAF;
  float* dtr = ws + F_DTR;
  float* lar = ws + F_LAR;
  float* yF = ws + F_YF;
  float* yR = ws + F_YR;
  float* onew = ws + F_ON;
  float* gbuf = ws + F_G;
  float* cumb = ws + F_CUM;
  float* cc1 = ws + F_CC1;
  float* cc2 = ws + F_CC2;
  int* len = (int*)(ws + F_LEN);
  unsigned short* w_in = wsu + UW_IN;
  unsigned short* w_out = wsu + UW_OUT;
  unsigned short* w_ve = wsu + UW_VE;
  unsigned short* w_e1 = wsu + UW_E1;
  unsigned short* w_e2 = wsu + UW_E2;
  unsigned short* bfa = wsu + U_BFA;
  unsigned short* hnbf = wsu + U_HNBF;
  unsigned short* ybf = wsu + U_YBF;
  unsigned short* zxb = wsu + U_ZX;
  unsigned short* bcbuf = wsu + U_BC;
  float* t2 = onew;                 // reuse before layers
  unsigned short* e2b = zxb;        // reuse after layers
  float* out = (float*)d_out;

  // ---- weight conversions ----
  {
    int n;
    n = 2 * DIP * DM / 8;  k_w2bf<<<(n + 255) / 256, 256, 0, stream>>>(in_w, w_in, n);
    n = 2 * DM * DI / 8;   k_w2bf<<<(n + 255) / 256, 256, 0, stream>>>(out_w, w_out, n);
    n = DM * DM / 8;       k_w2bf<<<(n + 255) / 256, 256, 0, stream>>>(ve_w2, w_ve, n);
    n = DM * DM / 8;       k_w2bf<<<(n + 255) / 256, 256, 0, stream>>>(expr_w1, w_e1, n);
    n = DM * DM / 8;       k_w2bf<<<(n + 255) / 256, 256, 0, stream>>>(expr_w2, w_e2, n);
  }

  // ---- embedding + value encoder ----
  k_embed<<<TOK / 4, 256, 0, stream>>>(src, values, embed, ge_g, ge_b, ve_w1, ve_b1, h, bfa);
  gemm_bf<0, 0><<<dim3(DM / 128, TOK / 128), 256, 0, stream>>>(bfa, w_ve, ve_b2, t2, TOK, DM, DM);
  k_haddv<<<TOK / 4, 256, 0, stream>>>(t2, ve_g, ve_bb, mask, h);
  k_lengths<<<Bb, 256, 0, stream>>>(mask, len);

  // ---- layers ----
  for (int i = 0; i < 2; ++i) {
    const float* inw = in_w + (size_t)i * DIP * DM;
    unsigned short* inwb = w_in + (size_t)i * DIP * DM;
    unsigned short* outwb = w_out + (size_t)i * DM * DI;
    const float* cwF = conv_w_f + (size_t)i * CDIM * 4;
    const float* cbF = conv_b_f + (size_t)i * CDIM;
    const float* cwR = conv_w_r + (size_t)i * CDIM * 4;
    const float* cbR = conv_b_r + (size_t)i * CDIM;
    k_lndt<<<TOK / 4, 256, 0, stream>>>(h, inw, dtb_f + i * NH, A_f + i * NH,
                                        dtb_r + i * NH, A_r + i * NH, len, hnbf,
                                        dtf, laf, dtr, lar);
    gemm_bf<0, 1><<<dim3(NPJ / 128, TOK / 128), 256, 0, stream>>>(hnbf, inwb, nullptr, zxb, TOK, NPJ, DM);
    k_convbc<<<(2 * TOK * 128) / 256, 256, 0, stream>>>(zxb, cwF, cbF, cwR, cbR, len, bcbuf);
    k_chunk<<<2 * Bb * NH * NCH, 256, 0, stream>>>(zxb, bcbuf, cwF, cbF, cwR, cbR,
        dtf, laf, dtr, lar, D_f + i * NH, D_r + i * NH, len, yF, yR, gbuf, cumb);
    k_chain<<<2 * Bb * NH, 256, 0, stream>>>(gbuf, cumb);
    k_corr<<<2 * Bb * NH * NCH, 256, 0, stream>>>(bcbuf, gbuf, cumb, yF, yR);
    k_gab<<<TOK / 4, 256, 0, stream>>>(yF, yR, zxb, nw_f + (size_t)i * DI, nw_r + (size_t)i * DI,
                                       len, ybf);
    gemm_bf<0, 0><<<dim3(DM / 128, TOK / 128), 256, 0, stream>>>(ybf, outwb, nullptr, onew, TOK, DM, DI);
    k_hln<<<TOK / 4, 256, 0, stream>>>(onew, h, hnbf);
  }

  // ---- heads ----
  gemm_bf<2, 1><<<dim3(DM / 128, TOK / 128), 256, 0, stream>>>(hnbf, w_e1, expr_b1, bfa, TOK, DM, DM);
  gemm_bf<2, 1><<<dim3(DM / 128, TOK / 128), 256, 0, stream>>>(bfa, w_e2, expr_b2, e2b, TOK, DM, DM);
  k_mlm<<<TOK / 4, 256, 0, stream>>>(e2b, expr_w3, expr_b3, out);
  k_cell<<<(Bb * DM + 255) / 256, 256, 0, stream>>>(h, out + TOK);
  k_clsmv<<<dim3(128, Bb), 256, 0, stream>>>(h, (size_t)Ls * DM, nullptr, nullptr, 0,
                                             cls_w1, cls_b1, 1, cc1, DM);
  k_clsmv<<<dim3(128, Bb), 256, 0, stream>>>(cc1, DM, cls_g1, cls_bb1, 1,
                                             cls_w2, cls_b2, 1, cc2, DM);
  k_clsmv<<<dim3(41, Bb), 256, 0, stream>>>(cc2, DM, cls_g2, cls_bb2, 1,
                                            cls_wo, cls_bo, 0, out + TOK + Bb * DM, 164);
}

// Round 8
// 322.199 us; speedup vs baseline: 11.6509x; 1.0798x over previous
//
#include <hip/hip_runtime.h>
#include <hip/hip_bf16.h>
#include <math.h>

// ---- model constants ----
constexpr int Bb = 4, Ls = 1024, DM = 512, DI = 1024, NH = 16, HD = 64, DS = 64;
constexpr int CDIM = DI + 2 * DS;          // 1152
constexpr int DIP  = 2 * DI + 2 * DS + NH; // 2192
constexpr int NPJ  = 2 * DI + 2 * DS;      // 2176 = 17*128
constexpr float EPSf = 1e-5f;
constexpr int TOK = Bb * Ls;               // 4096
constexpr int CH = 64, NCH = Ls / CH;      // 16 chunks of 64

#define DEVI __device__ __forceinline__

using bfrag = __attribute__((ext_vector_type(8))) short;
using f4v   = __attribute__((ext_vector_type(4))) float;
using u16x8 = __attribute__((ext_vector_type(8))) unsigned short;

#define GLOAD16(gp, lp)                                                              \
  __builtin_amdgcn_global_load_lds((__attribute__((address_space(1))) void*)(gp),   \
                                   (__attribute__((address_space(3))) void*)(lp),   \
                                   16, 0, 0)

DEVI float wsum(float v) {
#pragma unroll
  for (int o = 32; o > 0; o >>= 1) v += __shfl_xor(v, o);
  return v;
}
DEVI float sigmoidf_(float x) { return 1.f / (1.f + __expf(-x)); }
DEVI unsigned short f2bf(float x) {
  union { float f; unsigned u; } c{x};
  unsigned u = c.u;
  u += 0x7fffu + ((u >> 16) & 1u);
  return (unsigned short)(u >> 16);
}
DEVI float bf2f(unsigned short u) {
  union { unsigned u; float f; } c{(unsigned)u << 16};
  return c.f;
}

DEVI void ld8(const float* __restrict__ p, int lane, float (&x)[8]) {
  float4 a = *(const float4*)(p + lane * 4);
  float4 b = *(const float4*)(p + 256 + lane * 4);
  x[0] = a.x; x[1] = a.y; x[2] = a.z; x[3] = a.w;
  x[4] = b.x; x[5] = b.y; x[6] = b.z; x[7] = b.w;
}
DEVI void ld8bf(const unsigned short* __restrict__ p, int lane, float (&x)[8]) {
  ushort4 a = *(const ushort4*)(p + lane * 4);
  ushort4 b = *(const ushort4*)(p + 256 + lane * 4);
  x[0] = bf2f(a.x); x[1] = bf2f(a.y); x[2] = bf2f(a.z); x[3] = bf2f(a.w);
  x[4] = bf2f(b.x); x[5] = bf2f(b.y); x[6] = bf2f(b.z); x[7] = bf2f(b.w);
}
DEVI void st8(float* __restrict__ p, int lane, const float (&x)[8]) {
  *(float4*)(p + lane * 4) = make_float4(x[0], x[1], x[2], x[3]);
  *(float4*)(p + 256 + lane * 4) = make_float4(x[4], x[5], x[6], x[7]);
}
DEVI void st8bf(unsigned short* __restrict__ p, int lane, const float (&x)[8]) {
  *(ushort4*)(p + lane * 4) = make_ushort4(f2bf(x[0]), f2bf(x[1]), f2bf(x[2]), f2bf(x[3]));
  *(ushort4*)(p + 256 + lane * 4) = make_ushort4(f2bf(x[4]), f2bf(x[5]), f2bf(x[6]), f2bf(x[7]));
}
DEVI void norm8(float (&x)[8]) {
  float s = 0;
#pragma unroll
  for (int j = 0; j < 8; ++j) s += x[j];
  float mean = wsum(s) * (1.f / 512.f);
#pragma unroll
  for (int j = 0; j < 8; ++j) x[j] -= mean;
  float q = 0;
#pragma unroll
  for (int j = 0; j < 8; ++j) q += x[j] * x[j];
  float var = wsum(q) * (1.f / 512.f);
  float inv = rsqrtf(var + EPSf);
#pragma unroll
  for (int j = 0; j < 8; ++j) x[j] *= inv;
}

// ---- fp32 -> bf16 bulk convert (weights) ----
__global__ __launch_bounds__(256) void k_w2bf(const float* __restrict__ in,
                                              unsigned short* __restrict__ out, int n8) {
  int i = blockIdx.x * 256 + threadIdx.x;
  if (i >= n8) return;
  const float4* p = (const float4*)in + (size_t)i * 2;
  float4 a = p[0], b = p[1];
  *((ushort4*)out + (size_t)i * 2) = make_ushort4(f2bf(a.x), f2bf(a.y), f2bf(a.z), f2bf(a.w));
  *((ushort4*)out + (size_t)i * 2 + 1) = make_ushort4(f2bf(b.x), f2bf(b.y), f2bf(b.z), f2bf(b.w));
}

// ---- embedding + value-encoder stage 1 ----
__global__ __launch_bounds__(256) void k_embed(const int* __restrict__ src, const float* __restrict__ values,
    const float* __restrict__ embed, const float* __restrict__ gg, const float* __restrict__ gb,
    const float* __restrict__ vw1, const float* __restrict__ vb1,
    float* __restrict__ hbuf, unsigned short* __restrict__ v1bf) {
  int gw = (blockIdx.x * 256 + threadIdx.x) >> 6;
  int lane = threadIdx.x & 63;
  if (gw >= TOK) return;
  const float* er = embed + (size_t)src[gw] * DM;
  float x[8];
  ld8(er, lane, x);
  norm8(x);
  float g[8], bv[8];
  ld8(gg, lane, g); ld8(gb, lane, bv);
#pragma unroll
  for (int j = 0; j < 8; ++j) x[j] = x[j] * g[j] + bv[j];
  st8(hbuf + (size_t)gw * DM, lane, x);
  float val = fminf(values[gw], 512.f);
  float w1[8], b1[8];
  ld8(vw1, lane, w1); ld8(vb1, lane, b1);
  float v[8];
#pragma unroll
  for (int j = 0; j < 8; ++j) v[j] = fmaxf(val * w1[j] + b1[j], 0.f);
  st8bf(v1bf + (size_t)gw * DM, lane, v);
}

// h = (h + LN(t2)*g+b) * (mask?0:1)
__global__ __launch_bounds__(256) void k_haddv(const float* __restrict__ t2, const float* __restrict__ g,
    const float* __restrict__ bb, const unsigned char* __restrict__ mask, float* __restrict__ hbuf) {
  int gw = (blockIdx.x * 256 + threadIdx.x) >> 6;
  int lane = threadIdx.x & 63;
  if (gw >= TOK) return;
  float x[8];
  ld8(t2 + (size_t)gw * DM, lane, x);
  norm8(x);
  float gv[8], bv[8], h[8];
  ld8(g, lane, gv); ld8(bb, lane, bv);
  ld8(hbuf + (size_t)gw * DM, lane, h);
  float mf = mask[gw] ? 0.f : 1.f;
#pragma unroll
  for (int j = 0; j < 8; ++j) h[j] = (h[j] + x[j] * gv[j] + bv[j]) * mf;
  st8(hbuf + (size_t)gw * DM, lane, h);
}

// ---- LN(pre)->bf16  +  dt/ldA for BOTH directions (shared raw logits) ----
__global__ __launch_bounds__(256) void k_lndt(const float* __restrict__ pre, const float* __restrict__ inw,
    const float* __restrict__ dtbF, const float* __restrict__ AlogF,
    const float* __restrict__ dtbR, const float* __restrict__ AlogR,
    const int* __restrict__ len, unsigned short* __restrict__ hnbf,
    float* __restrict__ dtf, float* __restrict__ laf,
    float* __restrict__ dtr, float* __restrict__ lar) {
  int gw = (blockIdx.x * 256 + threadIdx.x) >> 6;
  int lane = threadIdx.x & 63;
  if (gw >= TOK) return;
  float x[8];
  ld8(pre + (size_t)gw * DM, lane, x);
  norm8(x);
  st8bf(hnbf + (size_t)gw * DM, lane, x);
  const float* wdt = inw + (size_t)NPJ * DM;
  float myraw = 0.f;
#pragma unroll
  for (int hh = 0; hh < NH; ++hh) {
    float w[8];
    ld8(wdt + (size_t)hh * DM, lane, w);
    float s = 0;
#pragma unroll
    for (int j = 0; j < 8; ++j) s += x[j] * w[j];
    s = wsum(s);
    if (lane == hh) myraw = s;
  }
  if (lane < NH) {
    int t = gw & (Ls - 1), b = gw >> 10;
    int ln = len[b];
    int pos = (t < ln) ? (ln - 1 - t) : t;
    size_t grev = (size_t)(b * Ls + pos);
    float rf = myraw + dtbF[lane];
    float df = rf > 20.f ? rf : log1pf(__expf(rf));
    dtf[(size_t)gw * NH + lane] = df;
    laf[(size_t)gw * NH + lane] = -__expf(AlogF[lane]) * df;
    float rr = myraw + dtbR[lane];
    float dr = rr > 20.f ? rr : log1pf(__expf(rr));
    dtr[grev * NH + lane] = dr;
    lar[grev * NH + lane] = -__expf(AlogR[lane]) * dr;
  }
}

// ---- bf16 MFMA GEMM: C[M,N] = A[M,K] @ W[N,K]^T (+bias, act) ----
template <int ACT, int OMODE>
__global__ __launch_bounds__(256) void gemm_bf(const unsigned short* __restrict__ A,
    const unsigned short* __restrict__ W, const float* __restrict__ bias,
    void* __restrict__ Cout, int M, int N, int K) {
  constexpr int BK = 64;
  __shared__ unsigned short As[128 * BK];
  __shared__ unsigned short Bs[128 * BK];
  int tid = threadIdx.x;
  int bm = blockIdx.y * 128, bn = blockIdx.x * 128;
  int wv = tid >> 6, lane = tid & 63;
  int mb = (wv >> 1) * 64, nb = (wv & 1) * 64;
  int rA = lane >> 3;
  int cswz = (lane & 7) ^ rA;
  f4v acc[4][4] = {};

  for (int k0 = 0; k0 < K; k0 += BK) {
#pragma unroll
    for (int q = 0; q < 4; ++q) {
      int ch = wv * 4 + q;
      const unsigned short* ga = A + (size_t)(bm + ch * 8 + rA) * K + k0 + cswz * 8;
      GLOAD16(ga, &As[ch * 512]);
      const unsigned short* gb = W + (size_t)(bn + ch * 8 + rA) * K + k0 + cswz * 8;
      GLOAD16(gb, &Bs[ch * 512]);
    }
    __syncthreads();
#pragma unroll
    for (int ks = 0; ks < BK; ks += 32) {
      int kb = (ks >> 3) + (lane >> 4);
      bfrag af[4], bg[4];
#pragma unroll
      for (int i = 0; i < 4; ++i) {
        int ra_ = mb + i * 16 + (lane & 15);
        af[i] = *(const bfrag*)((const char*)As + ((ra_ * 128 + kb * 16) ^ ((ra_ & 7) << 4)));
        int rb_ = nb + i * 16 + (lane & 15);
        bg[i] = *(const bfrag*)((const char*)Bs + ((rb_ * 128 + kb * 16) ^ ((rb_ & 7) << 4)));
      }
#pragma unroll
      for (int i = 0; i < 4; ++i)
#pragma unroll
        for (int j = 0; j < 4; ++j)
          acc[i][j] = __builtin_amdgcn_mfma_f32_16x16x32_bf16(af[i], bg[j], acc[i][j], 0, 0, 0);
    }
    __syncthreads();
  }

  int cb = bn + nb + (lane & 15);
  int rb = bm + mb + ((lane >> 4) << 2);
#pragma unroll
  for (int j = 0; j < 4; ++j) {
    float bv = bias ? bias[cb + j * 16] : 0.f;
#pragma unroll
    for (int i = 0; i < 4; ++i) {
#pragma unroll
      for (int r = 0; r < 4; ++r) {
        float v = acc[i][j][r] + bv;
        if (ACT == 1) v = fmaxf(v, 0.f);
        if (ACT == 2) v = v > 0.f ? v : 0.01f * v;
        size_t idx = (size_t)(rb + i * 16 + r) * N + cb + j * 16;
        if (OMODE == 0) ((float*)Cout)[idx] = v;
        else ((unsigned short*)Cout)[idx] = f2bf(v);
      }
    }
  }
}

// ---- shared B/C conv+silu, both dirs: bcbuf[dir][bt][128] (B=0..63, C=64..127) ----
__global__ __launch_bounds__(256) void k_convbc(const unsigned short* __restrict__ zx,
    const float* __restrict__ cwF, const float* __restrict__ cbF,
    const float* __restrict__ cwR, const float* __restrict__ cbR,
    const int* __restrict__ len, unsigned short* __restrict__ bcbuf) {
  int idx = blockIdx.x * 256 + threadIdx.x;
  if (idx >= 2 * TOK * 128) return;
  int col = idx & 127;
  int bt = (idx >> 7) & (TOK - 1);
  int dir = idx >> 19;
  int b = bt >> 10, t = bt & (Ls - 1);
  int ln = len[b];
  const float* cw = dir ? cwR : cwF;
  const float* cb = dir ? cbR : cbF;
  int ccd = DI + col;
  float4 w4 = *(const float4*)(cw + ccd * 4);
  float s = cb[ccd];
  float wk[4] = {w4.x, w4.y, w4.z, w4.w};
#pragma unroll
  for (int k = 0; k < 4; ++k) {
    int rl = t - 3 + k;
    if (rl >= 0) {
      int gr = dir ? (rl < ln ? ln - 1 - rl : rl) : rl;
      s += wk[k] * bf2f(zx[((size_t)(b * Ls + gr)) * NPJ + 2 * DI + col]);
    }
  }
  s = s * sigmoidf_(s);
  bcbuf[idx] = f2bf(s);
}

// ======================= fused x-conv + chunked SSD, both dirs (MFMA) =======================
__global__ __launch_bounds__(256) void k_chunk(const unsigned short* __restrict__ zx,
    const unsigned short* __restrict__ bcbuf,
    const float* __restrict__ cwF, const float* __restrict__ cbF,
    const float* __restrict__ cwR, const float* __restrict__ cbR,
    const float* __restrict__ dtF, const float* __restrict__ laF,
    const float* __restrict__ dtR, const float* __restrict__ laR,
    const float* __restrict__ DkF, const float* __restrict__ DkR,
    const int* __restrict__ len,
    unsigned short* __restrict__ yF, unsigned short* __restrict__ yR,
    unsigned short* __restrict__ gbuf, float* __restrict__ cumbuf) {
  __shared__ unsigned short Cb[4096], Bbs[4096], BbT[4096], xT[4096], Wt[4096];
  __shared__ float ldsL[64], sdt_[64], fs[64];
  int blk2 = blockIdx.x;
  int dir = blk2 >> 10;
  int blk = blk2 & 1023;
  int c = blk & 15, bh = blk >> 4, h = bh & 15, b = bh >> 4;
  int tid = threadIdx.x, wv = tid >> 6, lane = tid & 63;
  int c0 = c * CH;
  int ln = len[b];
  const float* cw = dir ? cwR : cwF;
  const float* cbias = dir ? cbR : cbF;
  const float* dtp = dir ? dtR : dtF;
  const float* ldap = dir ? laR : laF;
  float Dh = (dir ? DkR : DkF)[h];
  unsigned short* y = dir ? yR : yF;

  if (tid < 64) {
    size_t off = ((size_t)(b * Ls + c0 + tid)) * NH + h;
    float dtv = dtp[off];
    float v = ldap[off];
#pragma unroll
    for (int o = 1; o < 64; o <<= 1) {
      float n = __shfl_up(v, o);
      if (tid >= o) v += n;
    }
    ldsL[tid] = v;
    sdt_[tid] = dtv;
    cumbuf[(size_t)blk2 * 64 + tid] = __expf(v);
    float L63 = __shfl(v, 63);
    fs[tid] = __expf(L63 - v) * dtv;
  }
  __syncthreads();

  // stage B (rows) + C tiles from bcbuf (vectorized)
  {
    const unsigned short* bc = bcbuf + ((size_t)(dir * TOK + b * Ls + c0)) * 128;
    int r = tid >> 2;
    int colq = (tid & 3) * 32;
#pragma unroll
    for (int g = 0; g < 2; ++g) {
      int col = colq + g * 16;
      u16x8 v0 = *(const u16x8*)(bc + (size_t)r * 128 + col);
      u16x8 v1 = *(const u16x8*)(bc + (size_t)r * 128 + col + 8);
      if (col < 64) {
        *(u16x8*)((char*)Bbs + ((r * 128 + col * 2) ^ ((r & 7) << 4))) = v0;
        *(u16x8*)((char*)Bbs + ((r * 128 + col * 2 + 16) ^ ((r & 7) << 4))) = v1;
      } else {
        int n = col - 64;
        *(u16x8*)((char*)Cb + ((r * 128 + n * 2) ^ ((r & 7) << 4))) = v0;
        *(u16x8*)((char*)Cb + ((r * 128 + n * 2 + 16) ^ ((r & 7) << 4))) = v1;
      }
    }
  }
  // stage BbT (transposed, fs-scaled)
  {
    int n = tid & 63;
    int tg = (tid >> 6) * 16;
    const unsigned short* bc = bcbuf + ((size_t)(dir * TOK + b * Ls + c0 + tg)) * 128 + n;
    float vals[16];
#pragma unroll
    for (int t = 0; t < 16; ++t) vals[t] = bf2f(bc[(size_t)t * 128]) * fs[tg + t];
#pragma unroll
    for (int hv = 0; hv < 2; ++hv) {
      u16x8 pk;
#pragma unroll
      for (int k = 0; k < 8; ++k) pk[k] = f2bf(vals[hv * 8 + k]);
      *(u16x8*)((char*)BbT + ((n * 128 + (tg + hv * 8) * 2) ^ ((n & 7) << 4))) = pk;
    }
  }
  // x-conv (per-head 64 channels), pack transposed xT[p][t]
  {
    int cch = tid & 63;
    int tg = (tid >> 6) * 16;
    int gcol = DI + h * 64 + cch;
    int ccd = h * 64 + cch;
    float4 w4 = *(const float4*)(cw + ccd * 4);
    float bias = cbias[ccd];
    float vv[19];
#pragma unroll
    for (int k = 0; k < 19; ++k) {
      int rl = c0 + tg - 3 + k;
      float val = 0.f;
      if (rl >= 0) {
        int gr = dir ? (rl < ln ? ln - 1 - rl : rl) : rl;
        val = bf2f(zx[((size_t)(b * Ls + gr)) * NPJ + gcol]);
      }
      vv[k] = val;
    }
    int p = cch;
#pragma unroll
    for (int hv = 0; hv < 2; ++hv) {
      u16x8 pk;
#pragma unroll
      for (int k = 0; k < 8; ++k) {
        int t = hv * 8 + k;
        float s = bias + w4.x * vv[t] + w4.y * vv[t + 1] + w4.z * vv[t + 2] + w4.w * vv[t + 3];
        pk[k] = f2bf(s * sigmoidf_(s));
      }
      *(u16x8*)((char*)xT + ((p * 128 + (tg + hv * 8) * 2) ^ ((p & 7) << 4))) = pk;
    }
  }
  __syncthreads();

  // matmul1: S[t][s] = C . B^T
  f4v accS[4] = {};
#pragma unroll
  for (int ks = 0; ks < 64; ks += 32) {
    int kb = (ks >> 3) + (lane >> 4);
    int ra = wv * 16 + (lane & 15);
    bfrag af = *(const bfrag*)((const char*)Cb + ((ra * 128 + kb * 16) ^ ((ra & 7) << 4)));
#pragma unroll
    for (int j = 0; j < 4; ++j) {
      int rb = j * 16 + (lane & 15);
      bfrag bg = *(const bfrag*)((const char*)Bbs + ((rb * 128 + kb * 16) ^ ((rb & 7) << 4)));
      accS[j] = __builtin_amdgcn_mfma_f32_16x16x32_bf16(af, bg, accS[j], 0, 0, 0);
    }
  }
  // decay + causal mask -> Wt (bf16)
  {
    int trow = wv * 16 + ((lane >> 4) << 2);
#pragma unroll
    for (int j = 0; j < 4; ++j) {
      int s = j * 16 + (lane & 15);
      float ds = sdt_[s], Lsv = ldsL[s];
#pragma unroll
      for (int r = 0; r < 4; ++r) {
        int tt = trow + r;
        float wval = (s <= tt) ? accS[j][r] * ds * __expf(ldsL[tt] - Lsv) : 0.f;
        *(unsigned short*)((char*)Wt + ((tt * 128 + s * 2) ^ ((tt & 7) << 4))) = f2bf(wval);
      }
    }
  }
  __syncthreads();

  // matmul2: Y = W @ x ; matmul3: G = (fB)^T @ x
  f4v accY[4] = {}, accG[4] = {};
#pragma unroll
  for (int ks = 0; ks < 64; ks += 32) {
    int kb = (ks >> 3) + (lane >> 4);
    int ra = wv * 16 + (lane & 15);
    bfrag afW = *(const bfrag*)((const char*)Wt + ((ra * 128 + kb * 16) ^ ((ra & 7) << 4)));
    bfrag afB = *(const bfrag*)((const char*)BbT + ((ra * 128 + kb * 16) ^ ((ra & 7) << 4)));
#pragma unroll
    for (int j = 0; j < 4; ++j) {
      int rb = j * 16 + (lane & 15);
      bfrag bg = *(const bfrag*)((const char*)xT + ((rb * 128 + kb * 16) ^ ((rb & 7) << 4)));
      accY[j] = __builtin_amdgcn_mfma_f32_16x16x32_bf16(afW, bg, accY[j], 0, 0, 0);
      accG[j] = __builtin_amdgcn_mfma_f32_16x16x32_bf16(afB, bg, accG[j], 0, 0, 0);
    }
  }
  int trow = wv * 16 + ((lane >> 4) << 2);
#pragma unroll
  for (int j = 0; j < 4; ++j) {
    int p = j * 16 + (lane & 15);
#pragma unroll
    for (int r = 0; r < 4; ++r) {
      int t = trow + r;
      float xval = bf2f(*(const unsigned short*)((const char*)xT + ((p * 128 + t * 2) ^ ((p & 7) << 4))));
      y[((size_t)(b * Ls + c0 + t)) * DI + h * 64 + p] = f2bf(accY[j][r] + Dh * xval);
      gbuf[((size_t)blk2 * 64 + t) * 64 + p] = f2bf(accG[j][r]);
    }
  }
}

// inter-chunk recurrence, bf16 storage, fp32 accumulator; grid 128
__global__ __launch_bounds__(256) void k_chain(unsigned short* __restrict__ gbuf,
                                               const float* __restrict__ cumbuf) {
  int bh = blockIdx.x;
  int tid = threadIdx.x;
  size_t base = (size_t)bh * NCH * 4096 + (size_t)tid * 16;
  float hv[16] = {};
  u16x8 ga = *(const u16x8*)(gbuf + base);
  u16x8 gb_ = *(const u16x8*)(gbuf + base + 8);
  float Pc = cumbuf[(size_t)bh * NCH * 64 + 63];
  for (int c = 0; c < NCH; ++c) {
    u16x8 na = {}, nb = {};
    float Pn = 0.f;
    if (c + 1 < NCH) {
      Pn = cumbuf[((size_t)bh * NCH + c + 1) * 64 + 63];
      na = *(const u16x8*)(gbuf + base + (size_t)(c + 1) * 4096);
      nb = *(const u16x8*)(gbuf + base + (size_t)(c + 1) * 4096 + 8);
    }
    u16x8 oa, ob;
#pragma unroll
    for (int k = 0; k < 8; ++k) { oa[k] = f2bf(hv[k]); ob[k] = f2bf(hv[8 + k]); }
    *(u16x8*)(gbuf + base + (size_t)c * 4096) = oa;
    *(u16x8*)(gbuf + base + (size_t)c * 4096 + 8) = ob;
#pragma unroll
    for (int k = 0; k < 8; ++k) {
      hv[k] = fmaf(Pc, hv[k], bf2f(ga[k]));
      hv[8 + k] = fmaf(Pc, hv[8 + k], bf2f(gb_[k]));
    }
    ga = na; gb_ = nb;
    Pc = Pn;
  }
}

// correction: Y[t][p] += exp(L[t]) * sum_n C[t][n] * hin[n][p]; grid 2048
__global__ __launch_bounds__(256) void k_corr(const unsigned short* __restrict__ bcbuf,
    const unsigned short* __restrict__ gbuf, const float* __restrict__ cumbuf,
    unsigned short* __restrict__ yF, unsigned short* __restrict__ yR) {
  int blk2 = blockIdx.x;
  int c = blk2 & 15;
  if (c == 0) return;
  __shared__ unsigned short Ct[4096], HT[4096];
  __shared__ float cdl[64];
  int dir = blk2 >> 10;
  int bh = (blk2 & 1023) >> 4, h = bh & 15, b = bh >> 4;
  int tid = threadIdx.x, wv = tid >> 6, lane = tid & 63;
  int c0 = c * CH;
  unsigned short* y = dir ? yR : yF;
  {
    int r = tid >> 2;
    int colq = (tid & 3) * 16;
    const unsigned short* bc = bcbuf + ((size_t)(dir * TOK + b * Ls + c0 + r)) * 128 + 64 + colq;
    u16x8 v0 = *(const u16x8*)bc;
    u16x8 v1 = *(const u16x8*)(bc + 8);
    *(u16x8*)((char*)Ct + ((r * 128 + colq * 2) ^ ((r & 7) << 4))) = v0;
    *(u16x8*)((char*)Ct + ((r * 128 + colq * 2 + 16) ^ ((r & 7) << 4))) = v1;
  }
  {
    int n = tid >> 2, p0 = (tid & 3) * 16;
    const unsigned short* hr = gbuf + (size_t)blk2 * 4096 + (size_t)n * 64 + p0;
    u16x8 v0 = *(const u16x8*)hr;
    u16x8 v1 = *(const u16x8*)(hr + 8);
#pragma unroll
    for (int k = 0; k < 8; ++k) {
      int p = p0 + k;
      *(unsigned short*)((char*)HT + ((p * 128 + n * 2) ^ ((p & 7) << 4))) = v0[k];
      int p2 = p0 + 8 + k;
      *(unsigned short*)((char*)HT + ((p2 * 128 + n * 2) ^ ((p2 & 7) << 4))) = v1[k];
    }
  }
  if (tid < 64) cdl[tid] = cumbuf[(size_t)blk2 * 64 + tid];
  __syncthreads();

  f4v acc[4] = {};
#pragma unroll
  for (int ks = 0; ks < 64; ks += 32) {
    int kb = (ks >> 3) + (lane >> 4);
    int ra = wv * 16 + (lane & 15);
    bfrag af = *(const bfrag*)((const char*)Ct + ((ra * 128 + kb * 16) ^ ((ra & 7) << 4)));
#pragma unroll
    for (int j = 0; j < 4; ++j) {
      int rb = j * 16 + (lane & 15);
      bfrag bg = *(const bfrag*)((const char*)HT + ((rb * 128 + kb * 16) ^ ((rb & 7) << 4)));
      acc[j] = __builtin_amdgcn_mfma_f32_16x16x32_bf16(af, bg, acc[j], 0, 0, 0);
    }
  }
  int trow = wv * 16 + ((lane >> 4) << 2);
#pragma unroll
  for (int j = 0; j < 4; ++j) {
    int p = j * 16 + (lane & 15);
#pragma unroll
    for (int r = 0; r < 4; ++r) {
      int t = trow + r;
      unsigned short* yp = &y[((size_t)(b * Ls + c0 + t)) * DI + h * 64 + p];
      *yp = f2bf(bf2f(*yp) + cdl[t] * acc[j][r]);
    }
  }
}
// ================================================================

// ---- both-direction gated RMSNorm: ybf[w] = 0.5*(gate_f(w) + gate_r(flip(w))) ----
__global__ __launch_bounds__(256) void k_gab(const unsigned short* __restrict__ yF,
    const unsigned short* __restrict__ yR, const unsigned short* __restrict__ zxb,
    const float* __restrict__ nwF, const float* __restrict__ nwR,
    const int* __restrict__ len, unsigned short* __restrict__ ybf) {
  int w = (blockIdx.x * 256 + threadIdx.x) >> 6;
  int lane = threadIdx.x & 63;
  if (w >= TOK) return;
  int t = w & (Ls - 1), b = w >> 10;
  int ln = len[b];
  int r = b * Ls + ((t < ln) ? (ln - 1 - t) : t);
  const unsigned short* yf = yF + (size_t)w * DI;
  const unsigned short* yr = yR + (size_t)r * DI;
  const unsigned short* zr = zxb + (size_t)w * NPJ;
  float gf[16], gr[16];
  float ssf = 0.f, ssr = 0.f;
#pragma unroll
  for (int q = 0; q < 4; ++q) {
    ushort4 yv = *(const ushort4*)(yf + lane * 4 + q * 256);
    ushort4 rv = *(const ushort4*)(yr + lane * 4 + q * 256);
    ushort4 zu = *(const ushort4*)(zr + lane * 4 + q * 256);
    float z0 = bf2f(zu.x), z1 = bf2f(zu.y), z2 = bf2f(zu.z), z3 = bf2f(zu.w);
    float s0 = z0 * sigmoidf_(z0), s1 = z1 * sigmoidf_(z1), s2 = z2 * sigmoidf_(z2), s3 = z3 * sigmoidf_(z3);
    gf[4 * q + 0] = bf2f(yv.x) * s0; gf[4 * q + 1] = bf2f(yv.y) * s1;
    gf[4 * q + 2] = bf2f(yv.z) * s2; gf[4 * q + 3] = bf2f(yv.w) * s3;
    gr[4 * q + 0] = bf2f(rv.x) * s0; gr[4 * q + 1] = bf2f(rv.y) * s1;
    gr[4 * q + 2] = bf2f(rv.z) * s2; gr[4 * q + 3] = bf2f(rv.w) * s3;
#pragma unroll
    for (int j = 0; j < 4; ++j) {
      ssf += gf[4 * q + j] * gf[4 * q + j];
      ssr += gr[4 * q + j] * gr[4 * q + j];
    }
  }
  ssf = wsum(ssf);
  ssr = wsum(ssr);
  float scf = 0.5f * rsqrtf(ssf * (1.f / (float)DI) + EPSf);
  float scr = 0.5f * rsqrtf(ssr * (1.f / (float)DI) + EPSf);
#pragma unroll
  for (int q = 0; q < 4; ++q) {
    float4 nf = *(const float4*)(nwF + lane * 4 + q * 256);
    float4 nr = *(const float4*)(nwR + lane * 4 + q * 256);
    float o0 = gf[4 * q + 0] * scf * nf.x + gr[4 * q + 0] * scr * nr.x;
    float o1 = gf[4 * q + 1] * scf * nf.y + gr[4 * q + 1] * scr * nr.y;
    float o2 = gf[4 * q + 2] * scf * nf.z + gr[4 * q + 2] * scr * nr.z;
    float o3 = gf[4 * q + 3] * scf * nf.w + gr[4 * q + 3] * scr * nr.w;
    *(ushort4*)(ybf + (size_t)w * DI + lane * 4 + q * 256) =
        make_ushort4(f2bf(o0), f2bf(o1), f2bf(o2), f2bf(o3));
  }
}

// ---- hnbf = LN(src) bf16 only (final heads input) ----
__global__ __launch_bounds__(256) void k_hl2(const float* __restrict__ src,
                                             unsigned short* __restrict__ dstbf) {
  int gw = (blockIdx.x * 256 + threadIdx.x) >> 6;
  int lane = threadIdx.x & 63;
  if (gw >= TOK) return;
  float x[8];
  ld8(src + (size_t)gw * DM, lane, x);
  norm8(x);
  st8bf(dstbf + (size_t)gw * DM, lane, x);
}

// ---- lengths ----
__global__ __launch_bounds__(256) void k_lengths(const unsigned char* __restrict__ mask, int* __restrict__ len) {
  int b = blockIdx.x;
  int tid = threadIdx.x;
  int cnt = 0;
  for (int t = tid; t < Ls; t += 256) cnt += mask[b * Ls + t] ? 0 : 1;
#pragma unroll
  for (int o = 32; o > 0; o >>= 1) cnt += __shfl_xor(cnt, o);
  __shared__ int red[4];
  if ((tid & 63) == 0) red[tid >> 6] = cnt;
  __syncthreads();
  if (tid == 0) len[b] = red[0] + red[1] + red[2] + red[3];
}

// ---- mlm head (bf16 input) ----
__global__ __launch_bounds__(256) void k_mlm(const unsigned short* __restrict__ e2,
                                             const float* __restrict__ w3,
                                             const float* __restrict__ b3, float* __restrict__ out) {
  int gw = (blockIdx.x * 256 + threadIdx.x) >> 6;
  int lane = threadIdx.x & 63;
  if (gw >= TOK) return;
  float x[8], w[8];
  ld8bf(e2 + (size_t)gw * DM, lane, x);
  ld8(w3, lane, w);
  float s = 0;
#pragma unroll
  for (int j = 0; j < 8; ++j) s += x[j] * w[j];
  s = wsum(s);
  if (lane == 0) out[gw] = s + b3[0];
}

// ---- cell = LN(onew)[:,0,:] -> out + cc0 (for cls head); 1 block, 4 waves ----
__global__ __launch_bounds__(256) void k_cell(const float* __restrict__ onew, float* __restrict__ out,
                                              float* __restrict__ cc0) {
  int b = threadIdx.x >> 6;
  int lane = threadIdx.x & 63;
  float x[8];
  ld8(onew + (size_t)b * Ls * DM, lane, x);
  norm8(x);
  st8(out + (size_t)b * DM, lane, x);
  st8(cc0 + (size_t)b * DM, lane, x);
}

// ---- classifier matvec (wave-per-output; optional LN+affine on input) ----
__global__ __launch_bounds__(256) void k_clsmv(const float* __restrict__ xin, size_t xstride,
    const float* __restrict__ g, const float* __restrict__ bb, int doLN,
    const float* __restrict__ W, const float* __restrict__ bias, int doRelu,
    float* __restrict__ out, int nout) {
  int b = blockIdx.y;
  int j = blockIdx.x * 4 + (threadIdx.x >> 6);
  int lane = threadIdx.x & 63;
  if (j >= nout) return;
  float x[8];
  ld8(xin + (size_t)b * xstride, lane, x);
  if (doLN) {
    norm8(x);
    float gv[8], bv[8];
    ld8(g, lane, gv); ld8(bb, lane, bv);
#pragma unroll
    for (int k = 0; k < 8; ++k) x[k] = x[k] * gv[k] + bv[k];
  }
  float w[8];
  ld8(W + (size_t)j * DM, lane, w);
  float s = 0;
#pragma unroll
  for (int k = 0; k < 8; ++k) s += x[k] * w[k];
  s = wsum(s);
  if (lane == 0) {
    float v = s + bias[j];
    if (doRelu) v = fmaxf(v, 0.f);
    out[(size_t)b * nout + j] = v;
  }
}

// ---- workspace layout (floats) ----
constexpr size_t F_H   = 0;
constexpr size_t F_DTF = F_H + (size_t)TOK * DM;
constexpr size_t F_LAF = F_DTF + (size_t)TOK * NH;
constexpr size_t F_DTR = F_LAF + (size_t)TOK * NH;
constexpr size_t F_LAR = F_DTR + (size_t)TOK * NH;
constexpr size_t F_ON  = F_LAR + (size_t)TOK * NH;
constexpr size_t F_CUM = F_ON + (size_t)TOK * DM;
constexpr size_t F_CC0 = F_CUM + (size_t)2 * Bb * NH * NCH * 64;
constexpr size_t F_CC1 = F_CC0 + Bb * DM;
constexpr size_t F_CC2 = F_CC1 + Bb * DM;
constexpr size_t F_LEN = F_CC2 + Bb * DM;
constexpr size_t F_END = F_LEN + 16;
// bf16 regions (ushort offsets)
constexpr size_t U0     = F_END * 2;
constexpr size_t UW_IN  = U0;
constexpr size_t UW_OUT = UW_IN + (size_t)2 * DIP * DM;
constexpr size_t UW_VE  = UW_OUT + (size_t)2 * DM * DI;
constexpr size_t UW_E1  = UW_VE + (size_t)DM * DM;
constexpr size_t UW_E2  = UW_E1 + (size_t)DM * DM;
constexpr size_t U_BFA  = UW_E2 + (size_t)DM * DM;   // v1 / e1-bf16
constexpr size_t U_HNBF = U_BFA + (size_t)TOK * DM;
constexpr size_t U_YBF  = U_HNBF + (size_t)TOK * DM;
constexpr size_t U_ZX   = U_YBF + (size_t)TOK * DI;   // bf16 zx (TOK*NPJ)
constexpr size_t U_YF   = U_ZX + (size_t)TOK * NPJ;   // bf16 y fwd
constexpr size_t U_YR   = U_YF + (size_t)TOK * DI;    // bf16 y rev
constexpr size_t U_G    = U_YR + (size_t)TOK * DI;    // bf16 G/hin (2*1024*4096)

extern "C" void kernel_launch(void* const* d_in, const int* in_sizes, int n_in,
                              void* d_out, int out_size, void* d_ws, size_t ws_size,
                              hipStream_t stream) {
  const int* src = (const int*)d_in[0];
  const float* values = (const float*)d_in[1];
  const unsigned char* mask = (const unsigned char*)d_in[2];
  const float* embed = (const float*)d_in[3];
  const float* ge_g = (const float*)d_in[4];
  const float* ge_b = (const float*)d_in[5];
  const float* ve_w1 = (const float*)d_in[6];
  const float* ve_b1 = (const float*)d_in[7];
  const float* ve_w2 = (const float*)d_in[8];
  const float* ve_b2 = (const float*)d_in[9];
  const float* ve_g = (const float*)d_in[10];
  const float* ve_bb = (const float*)d_in[11];
  const float* in_w = (const float*)d_in[12];
  const float* conv_w_f = (const float*)d_in[13];
  const float* conv_b_f = (const float*)d_in[14];
  const float* A_f = (const float*)d_in[15];
  const float* dtb_f = (const float*)d_in[16];
  const float* D_f = (const float*)d_in[17];
  const float* nw_f = (const float*)d_in[18];
  const float* conv_w_r = (const float*)d_in[19];
  const float* conv_b_r = (const float*)d_in[20];
  const float* A_r = (const float*)d_in[21];
  const float* dtb_r = (const float*)d_in[22];
  const float* D_r = (const float*)d_in[23];
  const float* nw_r = (const float*)d_in[24];
  const float* out_w = (const float*)d_in[25];
  const float* expr_w1 = (const float*)d_in[26];
  const float* expr_b1 = (const float*)d_in[27];
  const float* expr_w2 = (const float*)d_in[28];
  const float* expr_b2 = (const float*)d_in[29];
  const float* expr_w3 = (const float*)d_in[30];
  const float* expr_b3 = (const float*)d_in[31];
  const float* cls_w1 = (const float*)d_in[32];
  const float* cls_b1 = (const float*)d_in[33];
  const float* cls_g1 = (const float*)d_in[34];
  const float* cls_bb1 = (const float*)d_in[35];
  const float* cls_w2 = (const float*)d_in[36];
  const float* cls_b2 = (const float*)d_in[37];
  const float* cls_g2 = (const float*)d_in[38];
  const float* cls_bb2 = (const float*)d_in[39];
  const float* cls_wo = (const float*)d_in[40];
  const float* cls_bo = (const float*)d_in[41];

  float* ws = (float*)d_ws;
  unsigned short* wsu = (unsigned short*)d_ws;
  float* h = ws + F_H;
  float* dtf = ws + F_DTF;
  float* laf = ws + F_LAF;
  float* dtr = ws + F_DTR;
  float* lar = ws + F_LAR;
  float* onew = ws + F_ON;
  float* cumb = ws + F_CUM;
  float* cc0 = ws + F_CC0;
  float* cc1 = ws + F_CC1;
  float* cc2 = ws + F_CC2;
  int* len = (int*)(ws + F_LEN);
  unsigned short* w_in = wsu + UW_IN;
  unsigned short* w_out = wsu + UW_OUT;
  unsigned short* w_ve = wsu + UW_VE;
  unsigned short* w_e1 = wsu + UW_E1;
  unsigned short* w_e2 = wsu + UW_E2;
  unsigned short* bfa = wsu + U_BFA;
  unsigned short* hnbf = wsu + U_HNBF;
  unsigned short* ybf = wsu + U_YBF;
  unsigned short* zxb = wsu + U_ZX;
  unsigned short* yFb = wsu + U_YF;
  unsigned short* yRb = wsu + U_YR;
  unsigned short* gbuf = wsu + U_G;
  unsigned short* bcbuf = ybf;      // reuse: bcbuf (2*TOK*128) fits in ybf before gab writes it
  float* t2 = onew;                 // reuse before layers
  unsigned short* e2b = zxb;        // reuse after layers
  float* out = (float*)d_out;

  // ---- weight conversions ----
  {
    int n;
    n = 2 * DIP * DM / 8;  k_w2bf<<<(n + 255) / 256, 256, 0, stream>>>(in_w, w_in, n);
    n = 2 * DM * DI / 8;   k_w2bf<<<(n + 255) / 256, 256, 0, stream>>>(out_w, w_out, n);
    n = DM * DM / 8;       k_w2bf<<<(n + 255) / 256, 256, 0, stream>>>(ve_w2, w_ve, n);
    n = DM * DM / 8;       k_w2bf<<<(n + 255) / 256, 256, 0, stream>>>(expr_w1, w_e1, n);
    n = DM * DM / 8;       k_w2bf<<<(n + 255) / 256, 256, 0, stream>>>(expr_w2, w_e2, n);
  }

  // ---- embedding + value encoder ----
  k_embed<<<TOK / 4, 256, 0, stream>>>(src, values, embed, ge_g, ge_b, ve_w1, ve_b1, h, bfa);
  gemm_bf<0, 0><<<dim3(DM / 128, TOK / 128), 256, 0, stream>>>(bfa, w_ve, ve_b2, t2, TOK, DM, DM);
  k_haddv<<<TOK / 4, 256, 0, stream>>>(t2, ve_g, ve_bb, mask, h);
  k_lengths<<<Bb, 256, 0, stream>>>(mask, len);

  // ---- layers ----
  for (int i = 0; i < 2; ++i) {
    const float* inw = in_w + (size_t)i * DIP * DM;
    unsigned short* inwb = w_in + (size_t)i * DIP * DM;
    unsigned short* outwb = w_out + (size_t)i * DM * DI;
    const float* cwF = conv_w_f + (size_t)i * CDIM * 4;
    const float* cbF = conv_b_f + (size_t)i * CDIM;
    const float* cwR = conv_w_r + (size_t)i * CDIM * 4;
    const float* cbR = conv_b_r + (size_t)i * CDIM;
    const float* pre = (i == 0) ? h : onew;
    k_lndt<<<TOK / 4, 256, 0, stream>>>(pre, inw, dtb_f + i * NH, A_f + i * NH,
                                        dtb_r + i * NH, A_r + i * NH, len, hnbf,
                                        dtf, laf, dtr, lar);
    gemm_bf<0, 1><<<dim3(NPJ / 128, TOK / 128), 256, 0, stream>>>(hnbf, inwb, nullptr, zxb, TOK, NPJ, DM);
    k_convbc<<<(2 * TOK * 128) / 256, 256, 0, stream>>>(zxb, cwF, cbF, cwR, cbR, len, bcbuf);
    k_chunk<<<2 * Bb * NH * NCH, 256, 0, stream>>>(zxb, bcbuf, cwF, cbF, cwR, cbR,
        dtf, laf, dtr, lar, D_f + i * NH, D_r + i * NH, len, yFb, yRb, gbuf, cumb);
    k_chain<<<2 * Bb * NH, 256, 0, stream>>>(gbuf, cumb);
    k_corr<<<2 * Bb * NH * NCH, 256, 0, stream>>>(bcbuf, gbuf, cumb, yFb, yRb);
    k_gab<<<TOK / 4, 256, 0, stream>>>(yFb, yRb, zxb, nw_f + (size_t)i * DI, nw_r + (size_t)i * DI,
                                       len, ybf);
    gemm_bf<0, 0><<<dim3(DM / 128, TOK / 128), 256, 0, stream>>>(ybf, outwb, nullptr, onew, TOK, DM, DI);
  }

  // ---- heads ----
  k_hl2<<<TOK / 4, 256, 0, stream>>>(onew, hnbf);
  gemm_bf<2, 1><<<dim3(DM / 128, TOK / 128), 256, 0, stream>>>(hnbf, w_e1, expr_b1, bfa, TOK, DM, DM);
  gemm_bf<2, 1><<<dim3(DM / 128, TOK / 128), 256, 0, stream>>>(bfa, w_e2, expr_b2, e2b, TOK, DM, DM);
  k_mlm<<<TOK / 4, 256, 0, stream>>>(e2b, expr_w3, expr_b3, out);
  k_cell<<<1, 256, 0, stream>>>(onew, out + TOK, cc0);
  k_clsmv<<<dim3(128, Bb), 256, 0, stream>>>(cc0, DM, nullptr, nullptr, 0,
                                             cls_w1, cls_b1, 1, cc1, DM);
  k_clsmv<<<dim3(128, Bb), 256, 0, stream>>>(cc1, DM, cls_g1, cls_bb1, 1,
                                             cls_w2, cls_b2, 1, cc2, DM);
  k_clsmv<<<dim3(41, Bb), 256, 0, stream>>>(cc2, DM, cls_g2, cls_bb2, 1,
                                            cls_wo, cls_bo, 0, out + TOK + Bb * DM, 164);
}

// Round 9
// 313.025 us; speedup vs baseline: 11.9924x; 1.0293x over previous
//
#include <hip/hip_runtime.h>
#include <hip/hip_bf16.h>
#include <math.h>

// ---- model constants ----
constexpr int Bb = 4, Ls = 1024, DM = 512, DI = 1024, NH = 16, HD = 64, DS = 64;
constexpr int CDIM = DI + 2 * DS;          // 1152
constexpr int DIP  = 2 * DI + 2 * DS + NH; // 2192
constexpr int NPJ  = 2 * DI + 2 * DS;      // 2176 = 17*128
constexpr float EPSf = 1e-5f;
constexpr int TOK = Bb * Ls;               // 4096
constexpr int CH = 64, NCH = Ls / CH;      // 16 chunks of 64

#define DEVI __device__ __forceinline__

using bfrag = __attribute__((ext_vector_type(8))) short;
using f4v   = __attribute__((ext_vector_type(4))) float;
using u16x8 = __attribute__((ext_vector_type(8))) unsigned short;

#define GLOAD16(gp, lp)                                                              \
  __builtin_amdgcn_global_load_lds((__attribute__((address_space(1))) void*)(gp),   \
                                   (__attribute__((address_space(3))) void*)(lp),   \
                                   16, 0, 0)

DEVI float wsum(float v) {
#pragma unroll
  for (int o = 32; o > 0; o >>= 1) v += __shfl_xor(v, o);
  return v;
}
DEVI float sigmoidf_(float x) { return 1.f / (1.f + __expf(-x)); }
DEVI unsigned short f2bf(float x) {
  union { float f; unsigned u; } c{x};
  unsigned u = c.u;
  u += 0x7fffu + ((u >> 16) & 1u);
  return (unsigned short)(u >> 16);
}
DEVI float bf2f(unsigned short u) {
  union { unsigned u; float f; } c{(unsigned)u << 16};
  return c.f;
}

DEVI void ld8(const float* __restrict__ p, int lane, float (&x)[8]) {
  float4 a = *(const float4*)(p + lane * 4);
  float4 b = *(const float4*)(p + 256 + lane * 4);
  x[0] = a.x; x[1] = a.y; x[2] = a.z; x[3] = a.w;
  x[4] = b.x; x[5] = b.y; x[6] = b.z; x[7] = b.w;
}
DEVI void ld8bf(const unsigned short* __restrict__ p, int lane, float (&x)[8]) {
  ushort4 a = *(const ushort4*)(p + lane * 4);
  ushort4 b = *(const ushort4*)(p + 256 + lane * 4);
  x[0] = bf2f(a.x); x[1] = bf2f(a.y); x[2] = bf2f(a.z); x[3] = bf2f(a.w);
  x[4] = bf2f(b.x); x[5] = bf2f(b.y); x[6] = bf2f(b.z); x[7] = bf2f(b.w);
}
DEVI void st8(float* __restrict__ p, int lane, const float (&x)[8]) {
  *(float4*)(p + lane * 4) = make_float4(x[0], x[1], x[2], x[3]);
  *(float4*)(p + 256 + lane * 4) = make_float4(x[4], x[5], x[6], x[7]);
}
DEVI void st8bf(unsigned short* __restrict__ p, int lane, const float (&x)[8]) {
  *(ushort4*)(p + lane * 4) = make_ushort4(f2bf(x[0]), f2bf(x[1]), f2bf(x[2]), f2bf(x[3]));
  *(ushort4*)(p + 256 + lane * 4) = make_ushort4(f2bf(x[4]), f2bf(x[5]), f2bf(x[6]), f2bf(x[7]));
}
DEVI void norm8(float (&x)[8]) {
  float s = 0;
#pragma unroll
  for (int j = 0; j < 8; ++j) s += x[j];
  float mean = wsum(s) * (1.f / 512.f);
#pragma unroll
  for (int j = 0; j < 8; ++j) x[j] -= mean;
  float q = 0;
#pragma unroll
  for (int j = 0; j < 8; ++j) q += x[j] * x[j];
  float var = wsum(q) * (1.f / 512.f);
  float inv = rsqrtf(var + EPSf);
#pragma unroll
  for (int j = 0; j < 8; ++j) x[j] *= inv;
}

// ---- all weight conversions in ONE launch ----
DEVI void cvt8(const float* __restrict__ in, unsigned short* __restrict__ out, int i) {
  const float4* p = (const float4*)in + (size_t)i * 2;
  float4 a = p[0], b = p[1];
  *((ushort4*)out + (size_t)i * 2) = make_ushort4(f2bf(a.x), f2bf(a.y), f2bf(a.z), f2bf(a.w));
  *((ushort4*)out + (size_t)i * 2 + 1) = make_ushort4(f2bf(b.x), f2bf(b.y), f2bf(b.z), f2bf(b.w));
}
__global__ __launch_bounds__(256) void k_w2bf5(
    const float* __restrict__ s0, unsigned short* __restrict__ d0, int n0,
    const float* __restrict__ s1, unsigned short* __restrict__ d1, int n1,
    const float* __restrict__ s2, unsigned short* __restrict__ d2, int n2,
    const float* __restrict__ s3, unsigned short* __restrict__ d3, int n3,
    const float* __restrict__ s4, unsigned short* __restrict__ d4, int n4) {
  int i = blockIdx.x * 256 + threadIdx.x;
  if (i < n0) { cvt8(s0, d0, i); return; }
  i -= n0;
  if (i < n1) { cvt8(s1, d1, i); return; }
  i -= n1;
  if (i < n2) { cvt8(s2, d2, i); return; }
  i -= n2;
  if (i < n3) { cvt8(s3, d3, i); return; }
  i -= n3;
  if (i < n4) { cvt8(s4, d4, i); return; }
}

// ---- embedding + value-encoder stage 1 ----
__global__ __launch_bounds__(256) void k_embed(const int* __restrict__ src, const float* __restrict__ values,
    const float* __restrict__ embed, const float* __restrict__ gg, const float* __restrict__ gb,
    const float* __restrict__ vw1, const float* __restrict__ vb1,
    float* __restrict__ hbuf, unsigned short* __restrict__ v1bf) {
  int gw = (blockIdx.x * 256 + threadIdx.x) >> 6;
  int lane = threadIdx.x & 63;
  if (gw >= TOK) return;
  const float* er = embed + (size_t)src[gw] * DM;
  float x[8];
  ld8(er, lane, x);
  norm8(x);
  float g[8], bv[8];
  ld8(gg, lane, g); ld8(gb, lane, bv);
#pragma unroll
  for (int j = 0; j < 8; ++j) x[j] = x[j] * g[j] + bv[j];
  st8(hbuf + (size_t)gw * DM, lane, x);
  float val = fminf(values[gw], 512.f);
  float w1[8], b1[8];
  ld8(vw1, lane, w1); ld8(vb1, lane, b1);
  float v[8];
#pragma unroll
  for (int j = 0; j < 8; ++j) v[j] = fmaxf(val * w1[j] + b1[j], 0.f);
  st8bf(v1bf + (size_t)gw * DM, lane, v);
}

// h = (h + LN(t2)*g+b) * (mask?0:1)
__global__ __launch_bounds__(256) void k_haddv(const float* __restrict__ t2, const float* __restrict__ g,
    const float* __restrict__ bb, const unsigned char* __restrict__ mask, float* __restrict__ hbuf) {
  int gw = (blockIdx.x * 256 + threadIdx.x) >> 6;
  int lane = threadIdx.x & 63;
  if (gw >= TOK) return;
  float x[8];
  ld8(t2 + (size_t)gw * DM, lane, x);
  norm8(x);
  float gv[8], bv[8], h[8];
  ld8(g, lane, gv); ld8(bb, lane, bv);
  ld8(hbuf + (size_t)gw * DM, lane, h);
  float mf = mask[gw] ? 0.f : 1.f;
#pragma unroll
  for (int j = 0; j < 8; ++j) h[j] = (h[j] + x[j] * gv[j] + bv[j]) * mf;
  st8(hbuf + (size_t)gw * DM, lane, h);
}

// ---- LN(pre)->bf16  +  dt/ldA for BOTH directions; wdt staged in LDS ----
__global__ __launch_bounds__(256) void k_lndt(const float* __restrict__ pre, const float* __restrict__ inw,
    const float* __restrict__ dtbF, const float* __restrict__ AlogF,
    const float* __restrict__ dtbR, const float* __restrict__ AlogR,
    const int* __restrict__ len, unsigned short* __restrict__ hnbf,
    float* __restrict__ dtf, float* __restrict__ laf,
    float* __restrict__ dtr, float* __restrict__ lar) {
  __shared__ float wdts[NH * DM];
  {
    const float4* src4 = (const float4*)(inw + (size_t)NPJ * DM);
    for (int i = threadIdx.x; i < NH * DM / 4; i += 256) ((float4*)wdts)[i] = src4[i];
  }
  __syncthreads();
  int gw = (blockIdx.x * 256 + threadIdx.x) >> 6;
  int lane = threadIdx.x & 63;
  if (gw >= TOK) return;
  float x[8];
  ld8(pre + (size_t)gw * DM, lane, x);
  norm8(x);
  st8bf(hnbf + (size_t)gw * DM, lane, x);
  float myraw = 0.f;
#pragma unroll
  for (int hh = 0; hh < NH; ++hh) {
    float w[8];
    ld8(wdts + hh * DM, lane, w);
    float s = 0;
#pragma unroll
    for (int j = 0; j < 8; ++j) s += x[j] * w[j];
    s = wsum(s);
    if (lane == hh) myraw = s;
  }
  if (lane < NH) {
    int t = gw & (Ls - 1), b = gw >> 10;
    int ln = len[b];
    int pos = (t < ln) ? (ln - 1 - t) : t;
    size_t grev = (size_t)(b * Ls + pos);
    float rf = myraw + dtbF[lane];
    float df = rf > 20.f ? rf : log1pf(__expf(rf));
    dtf[(size_t)gw * NH + lane] = df;
    laf[(size_t)gw * NH + lane] = -__expf(AlogF[lane]) * df;
    float rr = myraw + dtbR[lane];
    float dr = rr > 20.f ? rr : log1pf(__expf(rr));
    dtr[grev * NH + lane] = dr;
    lar[grev * NH + lane] = -__expf(AlogR[lane]) * dr;
  }
}

// ---- bf16 MFMA GEMM: C[M,N] = A[M,K] @ W[N,K]^T (+bias, act) ----
template <int ACT, int OMODE>
__global__ __launch_bounds__(256) void gemm_bf(const unsigned short* __restrict__ A,
    const unsigned short* __restrict__ W, const float* __restrict__ bias,
    void* __restrict__ Cout, int M, int N, int K) {
  constexpr int BK = 64;
  __shared__ unsigned short As[128 * BK];
  __shared__ unsigned short Bs[128 * BK];
  int tid = threadIdx.x;
  int bm = blockIdx.y * 128, bn = blockIdx.x * 128;
  int wv = tid >> 6, lane = tid & 63;
  int mb = (wv >> 1) * 64, nb = (wv & 1) * 64;
  int rA = lane >> 3;
  int cswz = (lane & 7) ^ rA;
  f4v acc[4][4] = {};

  for (int k0 = 0; k0 < K; k0 += BK) {
#pragma unroll
    for (int q = 0; q < 4; ++q) {
      int ch = wv * 4 + q;
      const unsigned short* ga = A + (size_t)(bm + ch * 8 + rA) * K + k0 + cswz * 8;
      GLOAD16(ga, &As[ch * 512]);
      const unsigned short* gb = W + (size_t)(bn + ch * 8 + rA) * K + k0 + cswz * 8;
      GLOAD16(gb, &Bs[ch * 512]);
    }
    __syncthreads();
#pragma unroll
    for (int ks = 0; ks < BK; ks += 32) {
      int kb = (ks >> 3) + (lane >> 4);
      bfrag af[4], bg[4];
#pragma unroll
      for (int i = 0; i < 4; ++i) {
        int ra_ = mb + i * 16 + (lane & 15);
        af[i] = *(const bfrag*)((const char*)As + ((ra_ * 128 + kb * 16) ^ ((ra_ & 7) << 4)));
        int rb_ = nb + i * 16 + (lane & 15);
        bg[i] = *(const bfrag*)((const char*)Bs + ((rb_ * 128 + kb * 16) ^ ((rb_ & 7) << 4)));
      }
#pragma unroll
      for (int i = 0; i < 4; ++i)
#pragma unroll
        for (int j = 0; j < 4; ++j)
          acc[i][j] = __builtin_amdgcn_mfma_f32_16x16x32_bf16(af[i], bg[j], acc[i][j], 0, 0, 0);
    }
    __syncthreads();
  }

  int cb = bn + nb + (lane & 15);
  int rb = bm + mb + ((lane >> 4) << 2);
#pragma unroll
  for (int j = 0; j < 4; ++j) {
    float bv = bias ? bias[cb + j * 16] : 0.f;
#pragma unroll
    for (int i = 0; i < 4; ++i) {
#pragma unroll
      for (int r = 0; r < 4; ++r) {
        float v = acc[i][j][r] + bv;
        if (ACT == 1) v = fmaxf(v, 0.f);
        if (ACT == 2) v = v > 0.f ? v : 0.01f * v;
        size_t idx = (size_t)(rb + i * 16 + r) * N + cb + j * 16;
        if (OMODE == 0) ((float*)Cout)[idx] = v;
        else ((unsigned short*)Cout)[idx] = f2bf(v);
      }
    }
  }
}

// ---- shared B/C conv+silu, both dirs: bcbuf[dir][bt][128] (B=0..63, C=64..127) ----
__global__ __launch_bounds__(256) void k_convbc(const unsigned short* __restrict__ zx,
    const float* __restrict__ cwF, const float* __restrict__ cbF,
    const float* __restrict__ cwR, const float* __restrict__ cbR,
    const int* __restrict__ len, unsigned short* __restrict__ bcbuf) {
  int idx = blockIdx.x * 256 + threadIdx.x;
  if (idx >= 2 * TOK * 128) return;
  int col = idx & 127;
  int bt = (idx >> 7) & (TOK - 1);
  int dir = idx >> 19;
  int b = bt >> 10, t = bt & (Ls - 1);
  int ln = len[b];
  const float* cw = dir ? cwR : cwF;
  const float* cb = dir ? cbR : cbF;
  int ccd = DI + col;
  float4 w4 = *(const float4*)(cw + ccd * 4);
  float s = cb[ccd];
  float wk[4] = {w4.x, w4.y, w4.z, w4.w};
#pragma unroll
  for (int k = 0; k < 4; ++k) {
    int rl = t - 3 + k;
    if (rl >= 0) {
      int gr = dir ? (rl < ln ? ln - 1 - rl : rl) : rl;
      s += wk[k] * bf2f(zx[((size_t)(b * Ls + gr)) * NPJ + 2 * DI + col]);
    }
  }
  s = s * sigmoidf_(s);
  bcbuf[idx] = f2bf(s);
}

// ======================= fused x-conv + chunked SSD, both dirs (MFMA) =======================
__global__ __launch_bounds__(256) void k_chunk(const unsigned short* __restrict__ zx,
    const unsigned short* __restrict__ bcbuf,
    const float* __restrict__ cwF, const float* __restrict__ cbF,
    const float* __restrict__ cwR, const float* __restrict__ cbR,
    const float* __restrict__ dtF, const float* __restrict__ laF,
    const float* __restrict__ dtR, const float* __restrict__ laR,
    const float* __restrict__ DkF, const float* __restrict__ DkR,
    const int* __restrict__ len,
    unsigned short* __restrict__ yF, unsigned short* __restrict__ yR,
    unsigned short* __restrict__ gbuf, float* __restrict__ cumbuf) {
  __shared__ unsigned short Cb[4096], Bbs[4096], BbT[4096], xT[4096], Wt[4096];
  __shared__ float ldsL[64], sdt_[64], fs[64];
  int blk2 = blockIdx.x;
  int dir = blk2 >> 10;
  int blk = blk2 & 1023;
  int c = blk & 15, bh = blk >> 4, h = bh & 15, b = bh >> 4;
  int tid = threadIdx.x, wv = tid >> 6, lane = tid & 63;
  int c0 = c * CH;
  int ln = len[b];
  const float* cw = dir ? cwR : cwF;
  const float* cbias = dir ? cbR : cbF;
  const float* dtp = dir ? dtR : dtF;
  const float* ldap = dir ? laR : laF;
  float Dh = (dir ? DkR : DkF)[h];
  unsigned short* y = dir ? yR : yF;

  if (tid < 64) {
    size_t off = ((size_t)(b * Ls + c0 + tid)) * NH + h;
    float dtv = dtp[off];
    float v = ldap[off];
#pragma unroll
    for (int o = 1; o < 64; o <<= 1) {
      float n = __shfl_up(v, o);
      if (tid >= o) v += n;
    }
    ldsL[tid] = v;
    sdt_[tid] = dtv;
    cumbuf[(size_t)blk2 * 64 + tid] = __expf(v);
    float L63 = __shfl(v, 63);
    fs[tid] = __expf(L63 - v) * dtv;
  }
  __syncthreads();

  // stage B (rows) + C tiles from bcbuf (vectorized)
  {
    const unsigned short* bc = bcbuf + ((size_t)(dir * TOK + b * Ls + c0)) * 128;
    int r = tid >> 2;
    int colq = (tid & 3) * 32;
#pragma unroll
    for (int g = 0; g < 2; ++g) {
      int col = colq + g * 16;
      u16x8 v0 = *(const u16x8*)(bc + (size_t)r * 128 + col);
      u16x8 v1 = *(const u16x8*)(bc + (size_t)r * 128 + col + 8);
      if (col < 64) {
        *(u16x8*)((char*)Bbs + ((r * 128 + col * 2) ^ ((r & 7) << 4))) = v0;
        *(u16x8*)((char*)Bbs + ((r * 128 + col * 2 + 16) ^ ((r & 7) << 4))) = v1;
      } else {
        int n = col - 64;
        *(u16x8*)((char*)Cb + ((r * 128 + n * 2) ^ ((r & 7) << 4))) = v0;
        *(u16x8*)((char*)Cb + ((r * 128 + n * 2 + 16) ^ ((r & 7) << 4))) = v1;
      }
    }
  }
  // x-conv (per-head 64 channels), pack transposed xT[p][t]
  {
    int cch = tid & 63;
    int tg = (tid >> 6) * 16;
    int gcol = DI + h * 64 + cch;
    int ccd = h * 64 + cch;
    float4 w4 = *(const float4*)(cw + ccd * 4);
    float bias = cbias[ccd];
    float vv[19];
#pragma unroll
    for (int k = 0; k < 19; ++k) {
      int rl = c0 + tg - 3 + k;
      float val = 0.f;
      if (rl >= 0) {
        int gr = dir ? (rl < ln ? ln - 1 - rl : rl) : rl;
        val = bf2f(zx[((size_t)(b * Ls + gr)) * NPJ + gcol]);
      }
      vv[k] = val;
    }
    int p = cch;
#pragma unroll
    for (int hv = 0; hv < 2; ++hv) {
      u16x8 pk;
#pragma unroll
      for (int k = 0; k < 8; ++k) {
        int t = hv * 8 + k;
        float s = bias + w4.x * vv[t] + w4.y * vv[t + 1] + w4.z * vv[t + 2] + w4.w * vv[t + 3];
        pk[k] = f2bf(s * sigmoidf_(s));
      }
      *(u16x8*)((char*)xT + ((p * 128 + (tg + hv * 8) * 2) ^ ((p & 7) << 4))) = pk;
    }
  }
  __syncthreads();

  // matmul1: S[t][s] = C . B^T
  f4v accS[4] = {};
#pragma unroll
  for (int ks = 0; ks < 64; ks += 32) {
    int kb = (ks >> 3) + (lane >> 4);
    int ra = wv * 16 + (lane & 15);
    bfrag af = *(const bfrag*)((const char*)Cb + ((ra * 128 + kb * 16) ^ ((ra & 7) << 4)));
#pragma unroll
    for (int j = 0; j < 4; ++j) {
      int rb = j * 16 + (lane & 15);
      bfrag bg = *(const bfrag*)((const char*)Bbs + ((rb * 128 + kb * 16) ^ ((rb & 7) << 4)));
      accS[j] = __builtin_amdgcn_mfma_f32_16x16x32_bf16(af, bg, accS[j], 0, 0, 0);
    }
  }
  // build BbT (transposed, fs-scaled) from LDS Bbs
  {
    int n = tid & 63;
    int tg = (tid >> 6) * 16;
    float vals[16];
#pragma unroll
    for (int t = 0; t < 16; ++t) {
      int s = tg + t;
      unsigned short raw = *(const unsigned short*)((const char*)Bbs + ((s * 128 + n * 2) ^ ((s & 7) << 4)));
      vals[t] = bf2f(raw) * fs[s];
    }
#pragma unroll
    for (int hv = 0; hv < 2; ++hv) {
      u16x8 pk;
#pragma unroll
      for (int k = 0; k < 8; ++k) pk[k] = f2bf(vals[hv * 8 + k]);
      *(u16x8*)((char*)BbT + ((n * 128 + (tg + hv * 8) * 2) ^ ((n & 7) << 4))) = pk;
    }
  }
  // decay + causal mask -> Wt (bf16)
  {
    int trow = wv * 16 + ((lane >> 4) << 2);
#pragma unroll
    for (int j = 0; j < 4; ++j) {
      int s = j * 16 + (lane & 15);
      float ds = sdt_[s], Lsv = ldsL[s];
#pragma unroll
      for (int r = 0; r < 4; ++r) {
        int tt = trow + r;
        float wval = (s <= tt) ? accS[j][r] * ds * __expf(ldsL[tt] - Lsv) : 0.f;
        *(unsigned short*)((char*)Wt + ((tt * 128 + s * 2) ^ ((tt & 7) << 4))) = f2bf(wval);
      }
    }
  }
  __syncthreads();

  // matmul2: Y = W @ x ; matmul3: G = (fB)^T @ x
  f4v accY[4] = {}, accG[4] = {};
#pragma unroll
  for (int ks = 0; ks < 64; ks += 32) {
    int kb = (ks >> 3) + (lane >> 4);
    int ra = wv * 16 + (lane & 15);
    bfrag afW = *(const bfrag*)((const char*)Wt + ((ra * 128 + kb * 16) ^ ((ra & 7) << 4)));
    bfrag afB = *(const bfrag*)((const char*)BbT + ((ra * 128 + kb * 16) ^ ((ra & 7) << 4)));
#pragma unroll
    for (int j = 0; j < 4; ++j) {
      int rb = j * 16 + (lane & 15);
      bfrag bg = *(const bfrag*)((const char*)xT + ((rb * 128 + kb * 16) ^ ((rb & 7) << 4)));
      accY[j] = __builtin_amdgcn_mfma_f32_16x16x32_bf16(afW, bg, accY[j], 0, 0, 0);
      accG[j] = __builtin_amdgcn_mfma_f32_16x16x32_bf16(afB, bg, accG[j], 0, 0, 0);
    }
  }
  int trow = wv * 16 + ((lane >> 4) << 2);
#pragma unroll
  for (int j = 0; j < 4; ++j) {
    int p = j * 16 + (lane & 15);
#pragma unroll
    for (int r = 0; r < 4; ++r) {
      int t = trow + r;
      float xval = bf2f(*(const unsigned short*)((const char*)xT + ((p * 128 + t * 2) ^ ((p & 7) << 4))));
      y[((size_t)(b * Ls + c0 + t)) * DI + h * 64 + p] = f2bf(accY[j][r] + Dh * xval);
      gbuf[((size_t)blk2 * 64 + t) * 64 + p] = f2bf(accG[j][r]);
    }
  }
}

// inter-chunk recurrence, bf16 storage, fp32 accumulator, 2-deep prefetch; grid 256
__global__ __launch_bounds__(256) void k_chain(unsigned short* __restrict__ gbuf,
                                               const float* __restrict__ cumbuf) {
  int blk = blockIdx.x;          // 128 groups x 2 splits
  int grp = blk >> 1, sp = blk & 1;
  size_t base = (size_t)grp * NCH * 4096 + sp * 2048 + (size_t)threadIdx.x * 8;
  const float* cum = cumbuf + (size_t)grp * NCH * 64 + 63;
  float hv[8] = {};
  u16x8 g0 = *(const u16x8*)(gbuf + base);
  u16x8 g1 = *(const u16x8*)(gbuf + base + 4096);
  float P0 = cum[0], P1 = cum[64];
  for (int c = 0; c < NCH; ++c) {
    u16x8 g2 = {};
    float P2 = 0.f;
    if (c + 2 < NCH) {
      g2 = *(const u16x8*)(gbuf + base + (size_t)(c + 2) * 4096);
      P2 = cum[(size_t)(c + 2) * 64];
    }
    u16x8 o;
#pragma unroll
    for (int k = 0; k < 8; ++k) o[k] = f2bf(hv[k]);
    *(u16x8*)(gbuf + base + (size_t)c * 4096) = o;
#pragma unroll
    for (int k = 0; k < 8; ++k) hv[k] = fmaf(P0, hv[k], bf2f(g0[k]));
    g0 = g1; g1 = g2; P0 = P1; P1 = P2;
  }
}

// correction: Y[t][p] += exp(L[t]) * sum_n C[t][n] * hin[n][p]; grid 2048
__global__ __launch_bounds__(256) void k_corr(const unsigned short* __restrict__ bcbuf,
    const unsigned short* __restrict__ gbuf, const float* __restrict__ cumbuf,
    unsigned short* __restrict__ yF, unsigned short* __restrict__ yR) {
  int blk2 = blockIdx.x;
  int c = blk2 & 15;
  if (c == 0) return;
  __shared__ unsigned short Ct[4096], HT[4096];
  __shared__ float cdl[64];
  int dir = blk2 >> 10;
  int bh = (blk2 & 1023) >> 4, h = bh & 15, b = bh >> 4;
  int tid = threadIdx.x, wv = tid >> 6, lane = tid & 63;
  int c0 = c * CH;
  unsigned short* y = dir ? yR : yF;
  {
    int r = tid >> 2;
    int colq = (tid & 3) * 16;
    const unsigned short* bc = bcbuf + ((size_t)(dir * TOK + b * Ls + c0 + r)) * 128 + 64 + colq;
    u16x8 v0 = *(const u16x8*)bc;
    u16x8 v1 = *(const u16x8*)(bc + 8);
    *(u16x8*)((char*)Ct + ((r * 128 + colq * 2) ^ ((r & 7) << 4))) = v0;
    *(u16x8*)((char*)Ct + ((r * 128 + colq * 2 + 16) ^ ((r & 7) << 4))) = v1;
  }
  {
    int n = tid >> 2, p0 = (tid & 3) * 16;
    const unsigned short* hr = gbuf + (size_t)blk2 * 4096 + (size_t)n * 64 + p0;
    u16x8 v0 = *(const u16x8*)hr;
    u16x8 v1 = *(const u16x8*)(hr + 8);
#pragma unroll
    for (int k = 0; k < 8; ++k) {
      int p = p0 + k;
      *(unsigned short*)((char*)HT + ((p * 128 + n * 2) ^ ((p & 7) << 4))) = v0[k];
      int p2 = p0 + 8 + k;
      *(unsigned short*)((char*)HT + ((p2 * 128 + n * 2) ^ ((p2 & 7) << 4))) = v1[k];
    }
  }
  if (tid < 64) cdl[tid] = cumbuf[(size_t)blk2 * 64 + tid];
  __syncthreads();

  f4v acc[4] = {};
#pragma unroll
  for (int ks = 0; ks < 64; ks += 32) {
    int kb = (ks >> 3) + (lane >> 4);
    int ra = wv * 16 + (lane & 15);
    bfrag af = *(const bfrag*)((const char*)Ct + ((ra * 128 + kb * 16) ^ ((ra & 7) << 4)));
#pragma unroll
    for (int j = 0; j < 4; ++j) {
      int rb = j * 16 + (lane & 15);
      bfrag bg = *(const bfrag*)((const char*)HT + ((rb * 128 + kb * 16) ^ ((rb & 7) << 4)));
      acc[j] = __builtin_amdgcn_mfma_f32_16x16x32_bf16(af, bg, acc[j], 0, 0, 0);
    }
  }
  int trow = wv * 16 + ((lane >> 4) << 2);
#pragma unroll
  for (int j = 0; j < 4; ++j) {
    int p = j * 16 + (lane & 15);
#pragma unroll
    for (int r = 0; r < 4; ++r) {
      int t = trow + r;
      unsigned short* yp = &y[((size_t)(b * Ls + c0 + t)) * DI + h * 64 + p];
      *yp = f2bf(bf2f(*yp) + cdl[t] * acc[j][r]);
    }
  }
}
// ================================================================

// ---- both-direction gated RMSNorm: ybf[w] = 0.5*(gate_f(w) + gate_r(flip(w))) ----
__global__ __launch_bounds__(256) void k_gab(const unsigned short* __restrict__ yF,
    const unsigned short* __restrict__ yR, const unsigned short* __restrict__ zxb,
    const float* __restrict__ nwF, const float* __restrict__ nwR,
    const int* __restrict__ len, unsigned short* __restrict__ ybf) {
  int w = (blockIdx.x * 256 + threadIdx.x) >> 6;
  int lane = threadIdx.x & 63;
  if (w >= TOK) return;
  int t = w & (Ls - 1), b = w >> 10;
  int ln = len[b];
  int r = b * Ls + ((t < ln) ? (ln - 1 - t) : t);
  const unsigned short* yf = yF + (size_t)w * DI;
  const unsigned short* yr = yR + (size_t)r * DI;
  const unsigned short* zr = zxb + (size_t)w * NPJ;
  float gf[16], gr[16];
  float ssf = 0.f, ssr = 0.f;
#pragma unroll
  for (int q = 0; q < 4; ++q) {
    ushort4 yv = *(const ushort4*)(yf + lane * 4 + q * 256);
    ushort4 rv = *(const ushort4*)(yr + lane * 4 + q * 256);
    ushort4 zu = *(const ushort4*)(zr + lane * 4 + q * 256);
    float z0 = bf2f(zu.x), z1 = bf2f(zu.y), z2 = bf2f(zu.z), z3 = bf2f(zu.w);
    float s0 = z0 * sigmoidf_(z0), s1 = z1 * sigmoidf_(z1), s2 = z2 * sigmoidf_(z2), s3 = z3 * sigmoidf_(z3);
    gf[4 * q + 0] = bf2f(yv.x) * s0; gf[4 * q + 1] = bf2f(yv.y) * s1;
    gf[4 * q + 2] = bf2f(yv.z) * s2; gf[4 * q + 3] = bf2f(yv.w) * s3;
    gr[4 * q + 0] = bf2f(rv.x) * s0; gr[4 * q + 1] = bf2f(rv.y) * s1;
    gr[4 * q + 2] = bf2f(rv.z) * s2; gr[4 * q + 3] = bf2f(rv.w) * s3;
#pragma unroll
    for (int j = 0; j < 4; ++j) {
      ssf += gf[4 * q + j] * gf[4 * q + j];
      ssr += gr[4 * q + j] * gr[4 * q + j];
    }
  }
  ssf = wsum(ssf);
  ssr = wsum(ssr);
  float scf = 0.5f * rsqrtf(ssf * (1.f / (float)DI) + EPSf);
  float scr = 0.5f * rsqrtf(ssr * (1.f / (float)DI) + EPSf);
#pragma unroll
  for (int q = 0; q < 4; ++q) {
    float4 nf = *(const float4*)(nwF + lane * 4 + q * 256);
    float4 nr = *(const float4*)(nwR + lane * 4 + q * 256);
    float o0 = gf[4 * q + 0] * scf * nf.x + gr[4 * q + 0] * scr * nr.x;
    float o1 = gf[4 * q + 1] * scf * nf.y + gr[4 * q + 1] * scr * nr.y;
    float o2 = gf[4 * q + 2] * scf * nf.z + gr[4 * q + 2] * scr * nr.z;
    float o3 = gf[4 * q + 3] * scf * nf.w + gr[4 * q + 3] * scr * nr.w;
    *(ushort4*)(ybf + (size_t)w * DI + lane * 4 + q * 256) =
        make_ushort4(f2bf(o0), f2bf(o1), f2bf(o2), f2bf(o3));
  }
}

// ---- hnbf = LN(src) bf16 (heads input); rows t==0 also -> cell out (fp32) + cc0 ----
__global__ __launch_bounds__(256) void k_hl2(const float* __restrict__ src,
    unsigned short* __restrict__ dstbf, float* __restrict__ cellout, float* __restrict__ cc0) {
  int gw = (blockIdx.x * 256 + threadIdx.x) >> 6;
  int lane = threadIdx.x & 63;
  if (gw >= TOK) return;
  float x[8];
  ld8(src + (size_t)gw * DM, lane, x);
  norm8(x);
  st8bf(dstbf + (size_t)gw * DM, lane, x);
  if ((gw & (Ls - 1)) == 0) {
    int b = gw >> 10;
    st8(cellout + (size_t)b * DM, lane, x);
    st8(cc0 + (size_t)b * DM, lane, x);
  }
}

// ---- lengths ----
__global__ __launch_bounds__(256) void k_lengths(const unsigned char* __restrict__ mask, int* __restrict__ len) {
  int b = blockIdx.x;
  int tid = threadIdx.x;
  int cnt = 0;
  for (int t = tid; t < Ls; t += 256) cnt += mask[b * Ls + t] ? 0 : 1;
#pragma unroll
  for (int o = 32; o > 0; o >>= 1) cnt += __shfl_xor(cnt, o);
  __shared__ int red[4];
  if ((tid & 63) == 0) red[tid >> 6] = cnt;
  __syncthreads();
  if (tid == 0) len[b] = red[0] + red[1] + red[2] + red[3];
}

// ---- mlm head (bf16 input) ----
__global__ __launch_bounds__(256) void k_mlm(const unsigned short* __restrict__ e2,
                                             const float* __restrict__ w3,
                                             const float* __restrict__ b3, float* __restrict__ out) {
  int gw = (blockIdx.x * 256 + threadIdx.x) >> 6;
  int lane = threadIdx.x & 63;
  if (gw >= TOK) return;
  float x[8], w[8];
  ld8bf(e2 + (size_t)gw * DM, lane, x);
  ld8(w3, lane, w);
  float s = 0;
#pragma unroll
  for (int j = 0; j < 8; ++j) s += x[j] * w[j];
  s = wsum(s);
  if (lane == 0) out[gw] = s + b3[0];
}

// ---- classifier matvec (wave-per-output; optional LN+affine on input) ----
__global__ __launch_bounds__(256) void k_clsmv(const float* __restrict__ xin, size_t xstride,
    const float* __restrict__ g, const float* __restrict__ bb, int doLN,
    const float* __restrict__ W, const float* __restrict__ bias, int doRelu,
    float* __restrict__ out, int nout) {
  int b = blockIdx.y;
  int j = blockIdx.x * 4 + (threadIdx.x >> 6);
  int lane = threadIdx.x & 63;
  if (j >= nout) return;
  float x[8];
  ld8(xin + (size_t)b * xstride, lane, x);
  if (doLN) {
    norm8(x);
    float gv[8], bv[8];
    ld8(g, lane, gv); ld8(bb, lane, bv);
#pragma unroll
    for (int k = 0; k < 8; ++k) x[k] = x[k] * gv[k] + bv[k];
  }
  float w[8];
  ld8(W + (size_t)j * DM, lane, w);
  float s = 0;
#pragma unroll
  for (int k = 0; k < 8; ++k) s += x[k] * w[k];
  s = wsum(s);
  if (lane == 0) {
    float v = s + bias[j];
    if (doRelu) v = fmaxf(v, 0.f);
    out[(size_t)b * nout + j] = v;
  }
}

// ---- workspace layout (floats) ----
constexpr size_t F_H   = 0;
constexpr size_t F_DTF = F_H + (size_t)TOK * DM;
constexpr size_t F_LAF = F_DTF + (size_t)TOK * NH;
constexpr size_t F_DTR = F_LAF + (size_t)TOK * NH;
constexpr size_t F_LAR = F_DTR + (size_t)TOK * NH;
constexpr size_t F_ON  = F_LAR + (size_t)TOK * NH;
constexpr size_t F_CUM = F_ON + (size_t)TOK * DM;
constexpr size_t F_CC0 = F_CUM + (size_t)2 * Bb * NH * NCH * 64;
constexpr size_t F_CC1 = F_CC0 + Bb * DM;
constexpr size_t F_CC2 = F_CC1 + Bb * DM;
constexpr size_t F_LEN = F_CC2 + Bb * DM;
constexpr size_t F_END = F_LEN + 16;
// bf16 regions (ushort offsets)
constexpr size_t U0     = F_END * 2;
constexpr size_t UW_IN  = U0;
constexpr size_t UW_OUT = UW_IN + (size_t)2 * DIP * DM;
constexpr size_t UW_VE  = UW_OUT + (size_t)2 * DM * DI;
constexpr size_t UW_E1  = UW_VE + (size_t)DM * DM;
constexpr size_t UW_E2  = UW_E1 + (size_t)DM * DM;
constexpr size_t U_BFA  = UW_E2 + (size_t)DM * DM;   // v1 / e1-bf16
constexpr size_t U_HNBF = U_BFA + (size_t)TOK * DM;
constexpr size_t U_YBF  = U_HNBF + (size_t)TOK * DM;
constexpr size_t U_ZX   = U_YBF + (size_t)TOK * DI;   // bf16 zx (TOK*NPJ)
constexpr size_t U_YF   = U_ZX + (size_t)TOK * NPJ;   // bf16 y fwd
constexpr size_t U_YR   = U_YF + (size_t)TOK * DI;    // bf16 y rev
constexpr size_t U_G    = U_YR + (size_t)TOK * DI;    // bf16 G/hin (2*1024*4096)

extern "C" void kernel_launch(void* const* d_in, const int* in_sizes, int n_in,
                              void* d_out, int out_size, void* d_ws, size_t ws_size,
                              hipStream_t stream) {
  const int* src = (const int*)d_in[0];
  const float* values = (const float*)d_in[1];
  const unsigned char* mask = (const unsigned char*)d_in[2];
  const float* embed = (const float*)d_in[3];
  const float* ge_g = (const float*)d_in[4];
  const float* ge_b = (const float*)d_in[5];
  const float* ve_w1 = (const float*)d_in[6];
  const float* ve_b1 = (const float*)d_in[7];
  const float* ve_w2 = (const float*)d_in[8];
  const float* ve_b2 = (const float*)d_in[9];
  const float* ve_g = (const float*)d_in[10];
  const float* ve_bb = (const float*)d_in[11];
  const float* in_w = (const float*)d_in[12];
  const float* conv_w_f = (const float*)d_in[13];
  const float* conv_b_f = (const float*)d_in[14];
  const float* A_f = (const float*)d_in[15];
  const float* dtb_f = (const float*)d_in[16];
  const float* D_f = (const float*)d_in[17];
  const float* nw_f = (const float*)d_in[18];
  const float* conv_w_r = (const float*)d_in[19];
  const float* conv_b_r = (const float*)d_in[20];
  const float* A_r = (const float*)d_in[21];
  const float* dtb_r = (const float*)d_in[22];
  const float* D_r = (const float*)d_in[23];
  const float* nw_r = (const float*)d_in[24];
  const float* out_w = (const float*)d_in[25];
  const float* expr_w1 = (const float*)d_in[26];
  const float* expr_b1 = (const float*)d_in[27];
  const float* expr_w2 = (const float*)d_in[28];
  const float* expr_b2 = (const float*)d_in[29];
  const float* expr_w3 = (const float*)d_in[30];
  const float* expr_b3 = (const float*)d_in[31];
  const float* cls_w1 = (const float*)d_in[32];
  const float* cls_b1 = (const float*)d_in[33];
  const float* cls_g1 = (const float*)d_in[34];
  const float* cls_bb1 = (const float*)d_in[35];
  const float* cls_w2 = (const float*)d_in[36];
  const float* cls_b2 = (const float*)d_in[37];
  const float* cls_g2 = (const float*)d_in[38];
  const float* cls_bb2 = (const float*)d_in[39];
  const float* cls_wo = (const float*)d_in[40];
  const float* cls_bo = (const float*)d_in[41];

  float* ws = (float*)d_ws;
  unsigned short* wsu = (unsigned short*)d_ws;
  float* h = ws + F_H;
  float* dtf = ws + F_DTF;
  float* laf = ws + F_LAF;
  float* dtr = ws + F_DTR;
  float* lar = ws + F_LAR;
  float* onew = ws + F_ON;
  float* cumb = ws + F_CUM;
  float* cc0 = ws + F_CC0;
  float* cc1 = ws + F_CC1;
  float* cc2 = ws + F_CC2;
  int* len = (int*)(ws + F_LEN);
  unsigned short* w_in = wsu + UW_IN;
  unsigned short* w_out = wsu + UW_OUT;
  unsigned short* w_ve = wsu + UW_VE;
  unsigned short* w_e1 = wsu + UW_E1;
  unsigned short* w_e2 = wsu + UW_E2;
  unsigned short* bfa = wsu + U_BFA;
  unsigned short* hnbf = wsu + U_HNBF;
  unsigned short* ybf = wsu + U_YBF;
  unsigned short* zxb = wsu + U_ZX;
  unsigned short* yFb = wsu + U_YF;
  unsigned short* yRb = wsu + U_YR;
  unsigned short* gbuf = wsu + U_G;
  unsigned short* bcbuf = ybf;      // reuse: bcbuf (2*TOK*128) lives in ybf until gab writes it
  float* t2 = onew;                 // reuse before layers
  unsigned short* e2b = zxb;        // reuse after layers
  float* out = (float*)d_out;

  // ---- weight conversions (single launch) ----
  {
    int n0 = 2 * DIP * DM / 8, n1 = 2 * DM * DI / 8, n2 = DM * DM / 8, n3 = n2, n4 = n2;
    int tot = n0 + n1 + n2 + n3 + n4;
    k_w2bf5<<<(tot + 255) / 256, 256, 0, stream>>>(in_w, w_in, n0, out_w, w_out, n1,
                                                   ve_w2, w_ve, n2, expr_w1, w_e1, n3,
                                                   expr_w2, w_e2, n4);
  }

  // ---- embedding + value encoder ----
  k_embed<<<TOK / 4, 256, 0, stream>>>(src, values, embed, ge_g, ge_b, ve_w1, ve_b1, h, bfa);
  gemm_bf<0, 0><<<dim3(DM / 128, TOK / 128), 256, 0, stream>>>(bfa, w_ve, ve_b2, t2, TOK, DM, DM);
  k_haddv<<<TOK / 4, 256, 0, stream>>>(t2, ve_g, ve_bb, mask, h);
  k_lengths<<<Bb, 256, 0, stream>>>(mask, len);

  // ---- layers ----
  for (int i = 0; i < 2; ++i) {
    const float* inw = in_w + (size_t)i * DIP * DM;
    unsigned short* inwb = w_in + (size_t)i * DIP * DM;
    unsigned short* outwb = w_out + (size_t)i * DM * DI;
    const float* cwF = conv_w_f + (size_t)i * CDIM * 4;
    const float* cbF = conv_b_f + (size_t)i * CDIM;
    const float* cwR = conv_w_r + (size_t)i * CDIM * 4;
    const float* cbR = conv_b_r + (size_t)i * CDIM;
    const float* pre = (i == 0) ? h : onew;
    k_lndt<<<TOK / 4, 256, 0, stream>>>(pre, inw, dtb_f + i * NH, A_f + i * NH,
                                        dtb_r + i * NH, A_r + i * NH, len, hnbf,
                                        dtf, laf, dtr, lar);
    gemm_bf<0, 1><<<dim3(NPJ / 128, TOK / 128), 256, 0, stream>>>(hnbf, inwb, nullptr, zxb, TOK, NPJ, DM);
    k_convbc<<<(2 * TOK * 128) / 256, 256, 0, stream>>>(zxb, cwF, cbF, cwR, cbR, len, bcbuf);
    k_chunk<<<2 * Bb * NH * NCH, 256, 0, stream>>>(zxb, bcbuf, cwF, cbF, cwR, cbR,
        dtf, laf, dtr, lar, D_f + i * NH, D_r + i * NH, len, yFb, yRb, gbuf, cumb);
    k_chain<<<2 * 2 * Bb * NH, 256, 0, stream>>>(gbuf, cumb);
    k_corr<<<2 * Bb * NH * NCH, 256, 0, stream>>>(bcbuf, gbuf, cumb, yFb, yRb);
    k_gab<<<TOK / 4, 256, 0, stream>>>(yFb, yRb, zxb, nw_f + (size_t)i * DI, nw_r + (size_t)i * DI,
                                       len, ybf);
    gemm_bf<0, 0><<<dim3(DM / 128, TOK / 128), 256, 0, stream>>>(ybf, outwb, nullptr, onew, TOK, DM, DI);
  }

  // ---- heads ----
  k_hl2<<<TOK / 4, 256, 0, stream>>>(onew, hnbf, out + TOK, cc0);
  gemm_bf<2, 1><<<dim3(DM / 128, TOK / 128), 256, 0, stream>>>(hnbf, w_e1, expr_b1, bfa, TOK, DM, DM);
  gemm_bf<2, 1><<<dim3(DM / 128, TOK / 128), 256, 0, stream>>>(bfa, w_e2, expr_b2, e2b, TOK, DM, DM);
  k_mlm<<<TOK / 4, 256, 0, stream>>>(e2b, expr_w3, expr_b3, out);
  k_clsmv<<<dim3(128, Bb), 256, 0, stream>>>(cc0, DM, nullptr, nullptr, 0,
                                             cls_w1, cls_b1, 1, cc1, DM);
  k_clsmv<<<dim3(128, Bb), 256, 0, stream>>>(cc1, DM, cls_g1, cls_bb1, 1,
                                             cls_w2, cls_b2, 1, cc2, DM);
  k_clsmv<<<dim3(41, Bb), 256, 0, stream>>>(cc2, DM, cls_g2, cls_bb2, 1,
                                            cls_wo, cls_bo, 0, out + TOK + Bb * DM, 164);
}

// Round 10
// 305.067 us; speedup vs baseline: 12.3052x; 1.0261x over previous
//
#include <hip/hip_runtime.h>
#include <hip/hip_bf16.h>
#include <math.h>

// ---- model constants ----
constexpr int Bb = 4, Ls = 1024, DM = 512, DI = 1024, NH = 16, HD = 64, DS = 64;
constexpr int CDIM = DI + 2 * DS;          // 1152
constexpr int DIP  = 2 * DI + 2 * DS + NH; // 2192
constexpr int NPJ  = 2 * DI + 2 * DS;      // 2176 = 17*128
constexpr float EPSf = 1e-5f;
constexpr int TOK = Bb * Ls;               // 4096
constexpr int CH = 64, NCH = Ls / CH;      // 16 chunks of 64

#define DEVI __device__ __forceinline__

using bfrag = __attribute__((ext_vector_type(8))) short;
using f4v   = __attribute__((ext_vector_type(4))) float;
using u16x8 = __attribute__((ext_vector_type(8))) unsigned short;

#define GLOAD16(gp, lp)                                                              \
  __builtin_amdgcn_global_load_lds((__attribute__((address_space(1))) void*)(gp),   \
                                   (__attribute__((address_space(3))) void*)(lp),   \
                                   16, 0, 0)

DEVI float wsum(float v) {
#pragma unroll
  for (int o = 32; o > 0; o >>= 1) v += __shfl_xor(v, o);
  return v;
}
DEVI float sigmoidf_(float x) { return 1.f / (1.f + __expf(-x)); }
DEVI unsigned short f2bf(float x) {
  union { float f; unsigned u; } c{x};
  unsigned u = c.u;
  u += 0x7fffu + ((u >> 16) & 1u);
  return (unsigned short)(u >> 16);
}
DEVI float bf2f(unsigned short u) {
  union { unsigned u; float f; } c{(unsigned)u << 16};
  return c.f;
}

DEVI void ld8(const float* __restrict__ p, int lane, float (&x)[8]) {
  float4 a = *(const float4*)(p + lane * 4);
  float4 b = *(const float4*)(p + 256 + lane * 4);
  x[0] = a.x; x[1] = a.y; x[2] = a.z; x[3] = a.w;
  x[4] = b.x; x[5] = b.y; x[6] = b.z; x[7] = b.w;
}
DEVI void ld8bf(const unsigned short* __restrict__ p, int lane, float (&x)[8]) {
  ushort4 a = *(const ushort4*)(p + lane * 4);
  ushort4 b = *(const ushort4*)(p + 256 + lane * 4);
  x[0] = bf2f(a.x); x[1] = bf2f(a.y); x[2] = bf2f(a.z); x[3] = bf2f(a.w);
  x[4] = bf2f(b.x); x[5] = bf2f(b.y); x[6] = bf2f(b.z); x[7] = bf2f(b.w);
}
DEVI void st8(float* __restrict__ p, int lane, const float (&x)[8]) {
  *(float4*)(p + lane * 4) = make_float4(x[0], x[1], x[2], x[3]);
  *(float4*)(p + 256 + lane * 4) = make_float4(x[4], x[5], x[6], x[7]);
}
DEVI void st8bf(unsigned short* __restrict__ p, int lane, const float (&x)[8]) {
  *(ushort4*)(p + lane * 4) = make_ushort4(f2bf(x[0]), f2bf(x[1]), f2bf(x[2]), f2bf(x[3]));
  *(ushort4*)(p + 256 + lane * 4) = make_ushort4(f2bf(x[4]), f2bf(x[5]), f2bf(x[6]), f2bf(x[7]));
}
DEVI void norm8(float (&x)[8]) {
  float s = 0;
#pragma unroll
  for (int j = 0; j < 8; ++j) s += x[j];
  float mean = wsum(s) * (1.f / 512.f);
#pragma unroll
  for (int j = 0; j < 8; ++j) x[j] -= mean;
  float q = 0;
#pragma unroll
  for (int j = 0; j < 8; ++j) q += x[j] * x[j];
  float var = wsum(q) * (1.f / 512.f);
  float inv = rsqrtf(var + EPSf);
#pragma unroll
  for (int j = 0; j < 8; ++j) x[j] *= inv;
}

// ---- all weight conversions in ONE launch ----
DEVI void cvt8(const float* __restrict__ in, unsigned short* __restrict__ out, int i) {
  const float4* p = (const float4*)in + (size_t)i * 2;
  float4 a = p[0], b = p[1];
  *((ushort4*)out + (size_t)i * 2) = make_ushort4(f2bf(a.x), f2bf(a.y), f2bf(a.z), f2bf(a.w));
  *((ushort4*)out + (size_t)i * 2 + 1) = make_ushort4(f2bf(b.x), f2bf(b.y), f2bf(b.z), f2bf(b.w));
}
__global__ __launch_bounds__(256) void k_w2bf5(
    const float* __restrict__ s0, unsigned short* __restrict__ d0, int n0,
    const float* __restrict__ s1, unsigned short* __restrict__ d1, int n1,
    const float* __restrict__ s2, unsigned short* __restrict__ d2, int n2,
    const float* __restrict__ s3, unsigned short* __restrict__ d3, int n3,
    const float* __restrict__ s4, unsigned short* __restrict__ d4, int n4) {
  int i = blockIdx.x * 256 + threadIdx.x;
  if (i < n0) { cvt8(s0, d0, i); return; }
  i -= n0;
  if (i < n1) { cvt8(s1, d1, i); return; }
  i -= n1;
  if (i < n2) { cvt8(s2, d2, i); return; }
  i -= n2;
  if (i < n3) { cvt8(s3, d3, i); return; }
  i -= n3;
  if (i < n4) { cvt8(s4, d4, i); return; }
}

// ---- embedding + value-encoder stage 1 ----
__global__ __launch_bounds__(256) void k_embed(const int* __restrict__ src, const float* __restrict__ values,
    const float* __restrict__ embed, const float* __restrict__ gg, const float* __restrict__ gb,
    const float* __restrict__ vw1, const float* __restrict__ vb1,
    float* __restrict__ hbuf, unsigned short* __restrict__ v1bf) {
  int gw = (blockIdx.x * 256 + threadIdx.x) >> 6;
  int lane = threadIdx.x & 63;
  if (gw >= TOK) return;
  const float* er = embed + (size_t)src[gw] * DM;
  float x[8];
  ld8(er, lane, x);
  norm8(x);
  float g[8], bv[8];
  ld8(gg, lane, g); ld8(gb, lane, bv);
#pragma unroll
  for (int j = 0; j < 8; ++j) x[j] = x[j] * g[j] + bv[j];
  st8(hbuf + (size_t)gw * DM, lane, x);
  float val = fminf(values[gw], 512.f);
  float w1[8], b1[8];
  ld8(vw1, lane, w1); ld8(vb1, lane, b1);
  float v[8];
#pragma unroll
  for (int j = 0; j < 8; ++j) v[j] = fmaxf(val * w1[j] + b1[j], 0.f);
  st8bf(v1bf + (size_t)gw * DM, lane, v);
}

// h = (h + LN(t2)*g+b) * (mask?0:1)
__global__ __launch_bounds__(256) void k_haddv(const float* __restrict__ t2, const float* __restrict__ g,
    const float* __restrict__ bb, const unsigned char* __restrict__ mask, float* __restrict__ hbuf) {
  int gw = (blockIdx.x * 256 + threadIdx.x) >> 6;
  int lane = threadIdx.x & 63;
  if (gw >= TOK) return;
  float x[8];
  ld8(t2 + (size_t)gw * DM, lane, x);
  norm8(x);
  float gv[8], bv[8], h[8];
  ld8(g, lane, gv); ld8(bb, lane, bv);
  ld8(hbuf + (size_t)gw * DM, lane, h);
  float mf = mask[gw] ? 0.f : 1.f;
#pragma unroll
  for (int j = 0; j < 8; ++j) h[j] = (h[j] + x[j] * gv[j] + bv[j]) * mf;
  st8(hbuf + (size_t)gw * DM, lane, h);
}

// ---- LN(pre)->bf16  +  dt/ldA for BOTH directions; wdt staged in LDS ----
__global__ __launch_bounds__(256) void k_lndt(const float* __restrict__ pre, const float* __restrict__ inw,
    const float* __restrict__ dtbF, const float* __restrict__ AlogF,
    const float* __restrict__ dtbR, const float* __restrict__ AlogR,
    const int* __restrict__ len, unsigned short* __restrict__ hnbf,
    float* __restrict__ dtf, float* __restrict__ laf,
    float* __restrict__ dtr, float* __restrict__ lar) {
  __shared__ float wdts[NH * DM];
  {
    const float4* src4 = (const float4*)(inw + (size_t)NPJ * DM);
    for (int i = threadIdx.x; i < NH * DM / 4; i += 256) ((float4*)wdts)[i] = src4[i];
  }
  __syncthreads();
  int gw = (blockIdx.x * 256 + threadIdx.x) >> 6;
  int lane = threadIdx.x & 63;
  if (gw >= TOK) return;
  float x[8];
  ld8(pre + (size_t)gw * DM, lane, x);
  norm8(x);
  st8bf(hnbf + (size_t)gw * DM, lane, x);
  float myraw = 0.f;
#pragma unroll
  for (int hh = 0; hh < NH; ++hh) {
    float w[8];
    ld8(wdts + hh * DM, lane, w);
    float s = 0;
#pragma unroll
    for (int j = 0; j < 8; ++j) s += x[j] * w[j];
    s = wsum(s);
    if (lane == hh) myraw = s;
  }
  if (lane < NH) {
    int t = gw & (Ls - 1), b = gw >> 10;
    int ln = len[b];
    int pos = (t < ln) ? (ln - 1 - t) : t;
    size_t grev = (size_t)(b * Ls + pos);
    float rf = myraw + dtbF[lane];
    float df = rf > 20.f ? rf : log1pf(__expf(rf));
    dtf[(size_t)gw * NH + lane] = df;
    laf[(size_t)gw * NH + lane] = -__expf(AlogF[lane]) * df;
    float rr = myraw + dtbR[lane];
    float dr = rr > 20.f ? rr : log1pf(__expf(rr));
    dtr[grev * NH + lane] = dr;
    lar[grev * NH + lane] = -__expf(AlogR[lane]) * dr;
  }
}

// ---- bf16 MFMA GEMM: C[M,N] = A[M,K] @ W[N,K]^T (+bias, act) ----
template <int ACT, int OMODE>
__global__ __launch_bounds__(256) void gemm_bf(const unsigned short* __restrict__ A,
    const unsigned short* __restrict__ W, const float* __restrict__ bias,
    void* __restrict__ Cout, int M, int N, int K) {
  constexpr int BK = 64;
  __shared__ unsigned short As[128 * BK];
  __shared__ unsigned short Bs[128 * BK];
  int tid = threadIdx.x;
  int bm = blockIdx.y * 128, bn = blockIdx.x * 128;
  int wv = tid >> 6, lane = tid & 63;
  int mb = (wv >> 1) * 64, nb = (wv & 1) * 64;
  int rA = lane >> 3;
  int cswz = (lane & 7) ^ rA;
  f4v acc[4][4] = {};

  for (int k0 = 0; k0 < K; k0 += BK) {
#pragma unroll
    for (int q = 0; q < 4; ++q) {
      int ch = wv * 4 + q;
      const unsigned short* ga = A + (size_t)(bm + ch * 8 + rA) * K + k0 + cswz * 8;
      GLOAD16(ga, &As[ch * 512]);
      const unsigned short* gb = W + (size_t)(bn + ch * 8 + rA) * K + k0 + cswz * 8;
      GLOAD16(gb, &Bs[ch * 512]);
    }
    __syncthreads();
#pragma unroll
    for (int ks = 0; ks < BK; ks += 32) {
      int kb = (ks >> 3) + (lane >> 4);
      bfrag af[4], bg[4];
#pragma unroll
      for (int i = 0; i < 4; ++i) {
        int ra_ = mb + i * 16 + (lane & 15);
        af[i] = *(const bfrag*)((const char*)As + ((ra_ * 128 + kb * 16) ^ ((ra_ & 7) << 4)));
        int rb_ = nb + i * 16 + (lane & 15);
        bg[i] = *(const bfrag*)((const char*)Bs + ((rb_ * 128 + kb * 16) ^ ((rb_ & 7) << 4)));
      }
#pragma unroll
      for (int i = 0; i < 4; ++i)
#pragma unroll
        for (int j = 0; j < 4; ++j)
          acc[i][j] = __builtin_amdgcn_mfma_f32_16x16x32_bf16(af[i], bg[j], acc[i][j], 0, 0, 0);
    }
    __syncthreads();
  }

  int cb = bn + nb + (lane & 15);
  int rb = bm + mb + ((lane >> 4) << 2);
#pragma unroll
  for (int j = 0; j < 4; ++j) {
    float bv = bias ? bias[cb + j * 16] : 0.f;
#pragma unroll
    for (int i = 0; i < 4; ++i) {
#pragma unroll
      for (int r = 0; r < 4; ++r) {
        float v = acc[i][j][r] + bv;
        if (ACT == 1) v = fmaxf(v, 0.f);
        if (ACT == 2) v = v > 0.f ? v : 0.01f * v;
        size_t idx = (size_t)(rb + i * 16 + r) * N + cb + j * 16;
        if (OMODE == 0) ((float*)Cout)[idx] = v;
        else ((unsigned short*)Cout)[idx] = f2bf(v);
      }
    }
  }
}

// ---- shared B/C conv+silu, both dirs: bcbuf[dir][bt][128] (B=0..63, C=64..127) ----
__global__ __launch_bounds__(256) void k_convbc(const unsigned short* __restrict__ zx,
    const float* __restrict__ cwF, const float* __restrict__ cbF,
    const float* __restrict__ cwR, const float* __restrict__ cbR,
    const int* __restrict__ len, unsigned short* __restrict__ bcbuf) {
  int idx = blockIdx.x * 256 + threadIdx.x;
  if (idx >= 2 * TOK * 128) return;
  int col = idx & 127;
  int bt = (idx >> 7) & (TOK - 1);
  int dir = idx >> 19;
  int b = bt >> 10, t = bt & (Ls - 1);
  int ln = len[b];
  const float* cw = dir ? cwR : cwF;
  const float* cb = dir ? cbR : cbF;
  int ccd = DI + col;
  float4 w4 = *(const float4*)(cw + ccd * 4);
  float s = cb[ccd];
  float wk[4] = {w4.x, w4.y, w4.z, w4.w};
#pragma unroll
  for (int k = 0; k < 4; ++k) {
    int rl = t - 3 + k;
    if (rl >= 0) {
      int gr = dir ? (rl < ln ? ln - 1 - rl : rl) : rl;
      s += wk[k] * bf2f(zx[((size_t)(b * Ls + gr)) * NPJ + 2 * DI + col]);
    }
  }
  s = s * sigmoidf_(s);
  bcbuf[idx] = f2bf(s);
}

// ======================= fused x-conv + chunked SSD, both dirs (MFMA) =======================
// LDS tile reuse: Cb = {C -> W -> Y}, Bbs = {B -> fB^T -> G}, xT = x^T. 25 KB total.
__global__ __launch_bounds__(256) void k_chunk(const unsigned short* __restrict__ zx,
    const unsigned short* __restrict__ bcbuf,
    const float* __restrict__ cwF, const float* __restrict__ cbF,
    const float* __restrict__ cwR, const float* __restrict__ cbR,
    const float* __restrict__ dtF, const float* __restrict__ laF,
    const float* __restrict__ dtR, const float* __restrict__ laR,
    const float* __restrict__ DkF, const float* __restrict__ DkR,
    const int* __restrict__ len,
    unsigned short* __restrict__ yF, unsigned short* __restrict__ yR,
    unsigned short* __restrict__ gbuf, float* __restrict__ cumbuf) {
  __shared__ unsigned short Cb[4096], Bbs[4096], xT[4096];
  __shared__ float ldsL[64], sdt_[64], fs[64];
  int blk2 = blockIdx.x;
  int dir = blk2 >> 10;
  int blk = blk2 & 1023;
  int c = blk & 15, bh = blk >> 4, h = bh & 15, b = bh >> 4;
  int tid = threadIdx.x, wv = tid >> 6, lane = tid & 63;
  int c0 = c * CH;
  int ln = len[b];
  const float* cw = dir ? cwR : cwF;
  const float* cbias = dir ? cbR : cbF;
  const float* dtp = dir ? dtR : dtF;
  const float* ldap = dir ? laR : laF;
  float Dh = (dir ? DkR : DkF)[h];
  unsigned short* y = dir ? yR : yF;

  if (tid < 64) {
    size_t off = ((size_t)(b * Ls + c0 + tid)) * NH + h;
    float dtv = dtp[off];
    float v = ldap[off];
#pragma unroll
    for (int o = 1; o < 64; o <<= 1) {
      float n = __shfl_up(v, o);
      if (tid >= o) v += n;
    }
    ldsL[tid] = v;
    sdt_[tid] = dtv;
    cumbuf[(size_t)blk2 * 64 + tid] = __expf(v);
    float L63 = __shfl(v, 63);
    fs[tid] = __expf(L63 - v) * dtv;
  }
  __syncthreads();

  // stage B (rows) + C tiles from bcbuf (vectorized)
  {
    const unsigned short* bc = bcbuf + ((size_t)(dir * TOK + b * Ls + c0)) * 128;
    int r = tid >> 2;
    int colq = (tid & 3) * 32;
#pragma unroll
    for (int g = 0; g < 2; ++g) {
      int col = colq + g * 16;
      u16x8 v0 = *(const u16x8*)(bc + (size_t)r * 128 + col);
      u16x8 v1 = *(const u16x8*)(bc + (size_t)r * 128 + col + 8);
      if (col < 64) {
        *(u16x8*)((char*)Bbs + ((r * 128 + col * 2) ^ ((r & 7) << 4))) = v0;
        *(u16x8*)((char*)Bbs + ((r * 128 + col * 2 + 16) ^ ((r & 7) << 4))) = v1;
      } else {
        int n = col - 64;
        *(u16x8*)((char*)Cb + ((r * 128 + n * 2) ^ ((r & 7) << 4))) = v0;
        *(u16x8*)((char*)Cb + ((r * 128 + n * 2 + 16) ^ ((r & 7) << 4))) = v1;
      }
    }
  }
  // x-conv (per-head 64 channels), pack transposed xT[p][t]
  {
    int cch = tid & 63;
    int tg = (tid >> 6) * 16;
    int gcol = DI + h * 64 + cch;
    int ccd = h * 64 + cch;
    float4 w4 = *(const float4*)(cw + ccd * 4);
    float bias = cbias[ccd];
    float vv[19];
#pragma unroll
    for (int k = 0; k < 19; ++k) {
      int rl = c0 + tg - 3 + k;
      float val = 0.f;
      if (rl >= 0) {
        int gr = dir ? (rl < ln ? ln - 1 - rl : rl) : rl;
        val = bf2f(zx[((size_t)(b * Ls + gr)) * NPJ + gcol]);
      }
      vv[k] = val;
    }
    int p = cch;
#pragma unroll
    for (int hv = 0; hv < 2; ++hv) {
      u16x8 pk;
#pragma unroll
      for (int k = 0; k < 8; ++k) {
        int t = hv * 8 + k;
        float s = bias + w4.x * vv[t] + w4.y * vv[t + 1] + w4.z * vv[t + 2] + w4.w * vv[t + 3];
        pk[k] = f2bf(s * sigmoidf_(s));
      }
      *(u16x8*)((char*)xT + ((p * 128 + (tg + hv * 8) * 2) ^ ((p & 7) << 4))) = pk;
    }
  }
  __syncthreads();

  // matmul1: S[t][s] = C . B^T  (reads Cb, Bbs)
  f4v accS[4] = {};
#pragma unroll
  for (int ks = 0; ks < 64; ks += 32) {
    int kb = (ks >> 3) + (lane >> 4);
    int ra = wv * 16 + (lane & 15);
    bfrag af = *(const bfrag*)((const char*)Cb + ((ra * 128 + kb * 16) ^ ((ra & 7) << 4)));
#pragma unroll
    for (int j = 0; j < 4; ++j) {
      int rb = j * 16 + (lane & 15);
      bfrag bg = *(const bfrag*)((const char*)Bbs + ((rb * 128 + kb * 16) ^ ((rb & 7) << 4)));
      accS[j] = __builtin_amdgcn_mfma_f32_16x16x32_bf16(af, bg, accS[j], 0, 0, 0);
    }
  }
  // read BbT source values (fs-scaled) from Bbs into regs
  float vals[16];
  int nB = tid & 63, tgB = (tid >> 6) * 16;
#pragma unroll
  for (int t = 0; t < 16; ++t) {
    int s = tgB + t;
    unsigned short raw = *(const unsigned short*)((const char*)Bbs + ((s * 128 + nB * 2) ^ ((s & 7) << 4)));
    vals[t] = bf2f(raw) * fs[s];
  }
  __syncthreads();  // all reads of Cb/Bbs complete

  // overwrite: Wt -> Cb space, BbT -> Bbs space
  {
    int trow = wv * 16 + ((lane >> 4) << 2);
#pragma unroll
    for (int j = 0; j < 4; ++j) {
      int s = j * 16 + (lane & 15);
      float ds = sdt_[s], Lsv = ldsL[s];
#pragma unroll
      for (int r = 0; r < 4; ++r) {
        int tt = trow + r;
        float wval = (s <= tt) ? accS[j][r] * ds * __expf(ldsL[tt] - Lsv) : 0.f;
        *(unsigned short*)((char*)Cb + ((tt * 128 + s * 2) ^ ((tt & 7) << 4))) = f2bf(wval);
      }
    }
  }
#pragma unroll
  for (int hv = 0; hv < 2; ++hv) {
    u16x8 pk;
#pragma unroll
    for (int k = 0; k < 8; ++k) pk[k] = f2bf(vals[hv * 8 + k]);
    *(u16x8*)((char*)Bbs + ((nB * 128 + (tgB + hv * 8) * 2) ^ ((nB & 7) << 4))) = pk;
  }
  __syncthreads();

  // matmul2: Y = W @ x ; matmul3: G = (fB)^T @ x   (W in Cb, fB^T in Bbs)
  f4v accY[4] = {}, accG[4] = {};
#pragma unroll
  for (int ks = 0; ks < 64; ks += 32) {
    int kb = (ks >> 3) + (lane >> 4);
    int ra = wv * 16 + (lane & 15);
    bfrag afW = *(const bfrag*)((const char*)Cb + ((ra * 128 + kb * 16) ^ ((ra & 7) << 4)));
    bfrag afB = *(const bfrag*)((const char*)Bbs + ((ra * 128 + kb * 16) ^ ((ra & 7) << 4)));
#pragma unroll
    for (int j = 0; j < 4; ++j) {
      int rb = j * 16 + (lane & 15);
      bfrag bg = *(const bfrag*)((const char*)xT + ((rb * 128 + kb * 16) ^ ((rb & 7) << 4)));
      accY[j] = __builtin_amdgcn_mfma_f32_16x16x32_bf16(afW, bg, accY[j], 0, 0, 0);
      accG[j] = __builtin_amdgcn_mfma_f32_16x16x32_bf16(afB, bg, accG[j], 0, 0, 0);
    }
  }
  // fold D*x into Y (reads xT)
  float yout[4][4];
  int trow = wv * 16 + ((lane >> 4) << 2);
#pragma unroll
  for (int j = 0; j < 4; ++j) {
    int p = j * 16 + (lane & 15);
#pragma unroll
    for (int r = 0; r < 4; ++r) {
      int t = trow + r;
      float xval = bf2f(*(const unsigned short*)((const char*)xT + ((p * 128 + t * 2) ^ ((p & 7) << 4))));
      yout[j][r] = accY[j][r] + Dh * xval;
    }
  }
  __syncthreads();  // all LDS reads done

  // stage Y -> Cb space, G -> Bbs space (bf16, row-swizzled [t][p])
#pragma unroll
  for (int j = 0; j < 4; ++j) {
    int p = j * 16 + (lane & 15);
#pragma unroll
    for (int r = 0; r < 4; ++r) {
      int t = trow + r;
      int off = (t * 128 + p * 2) ^ ((t & 7) << 4);
      *(unsigned short*)((char*)Cb + off) = f2bf(yout[j][r]);
      *(unsigned short*)((char*)Bbs + off) = f2bf(accG[j][r]);
    }
  }
  __syncthreads();

  // coalesced global stores
  {
    int r = tid >> 2, colq = (tid & 3) * 16;
    int o0 = (r * 128 + colq * 2) ^ ((r & 7) << 4);
    int o1 = (r * 128 + colq * 2 + 16) ^ ((r & 7) << 4);
    u16x8 yv0 = *(const u16x8*)((const char*)Cb + o0);
    u16x8 yv1 = *(const u16x8*)((const char*)Cb + o1);
    unsigned short* yp = y + ((size_t)(b * Ls + c0 + r)) * DI + h * 64 + colq;
    *(u16x8*)yp = yv0;
    *(u16x8*)(yp + 8) = yv1;
    u16x8 gv0 = *(const u16x8*)((const char*)Bbs + o0);
    u16x8 gv1 = *(const u16x8*)((const char*)Bbs + o1);
    unsigned short* gp = gbuf + ((size_t)blk2 * 64 + r) * 64 + colq;
    *(u16x8*)gp = gv0;
    *(u16x8*)(gp + 8) = gv1;
  }
}

// inter-chunk recurrence, bf16 storage, fp32 accumulator, 2-deep prefetch; grid 256
__global__ __launch_bounds__(256) void k_chain(unsigned short* __restrict__ gbuf,
                                               const float* __restrict__ cumbuf) {
  int blk = blockIdx.x;          // 128 groups x 2 splits
  int grp = blk >> 1, sp = blk & 1;
  size_t base = (size_t)grp * NCH * 4096 + sp * 2048 + (size_t)threadIdx.x * 8;
  const float* cum = cumbuf + (size_t)grp * NCH * 64 + 63;
  float hv[8] = {};
  u16x8 g0 = *(const u16x8*)(gbuf + base);
  u16x8 g1 = *(const u16x8*)(gbuf + base + 4096);
  float P0 = cum[0], P1 = cum[64];
  for (int c = 0; c < NCH; ++c) {
    u16x8 g2 = {};
    float P2 = 0.f;
    if (c + 2 < NCH) {
      g2 = *(const u16x8*)(gbuf + base + (size_t)(c + 2) * 4096);
      P2 = cum[(size_t)(c + 2) * 64];
    }
    u16x8 o;
#pragma unroll
    for (int k = 0; k < 8; ++k) o[k] = f2bf(hv[k]);
    *(u16x8*)(gbuf + base + (size_t)c * 4096) = o;
#pragma unroll
    for (int k = 0; k < 8; ++k) hv[k] = fmaf(P0, hv[k], bf2f(g0[k]));
    g0 = g1; g1 = g2; P0 = P1; P1 = P2;
  }
}

// correction: Y[t][p] += exp(L[t]) * sum_n C[t][n] * hin[n][p]; grid 2048
__global__ __launch_bounds__(256) void k_corr(const unsigned short* __restrict__ bcbuf,
    const unsigned short* __restrict__ gbuf, const float* __restrict__ cumbuf,
    unsigned short* __restrict__ yF, unsigned short* __restrict__ yR) {
  int blk2 = blockIdx.x;
  int c = blk2 & 15;
  if (c == 0) return;
  __shared__ unsigned short Ct[4096], HT[4096];
  __shared__ float cdl[64];
  int dir = blk2 >> 10;
  int bh = (blk2 & 1023) >> 4, h = bh & 15, b = bh >> 4;
  int tid = threadIdx.x, wv = tid >> 6, lane = tid & 63;
  int c0 = c * CH;
  unsigned short* y = dir ? yR : yF;
  {
    int r = tid >> 2;
    int colq = (tid & 3) * 16;
    const unsigned short* bc = bcbuf + ((size_t)(dir * TOK + b * Ls + c0 + r)) * 128 + 64 + colq;
    u16x8 v0 = *(const u16x8*)bc;
    u16x8 v1 = *(const u16x8*)(bc + 8);
    *(u16x8*)((char*)Ct + ((r * 128 + colq * 2) ^ ((r & 7) << 4))) = v0;
    *(u16x8*)((char*)Ct + ((r * 128 + colq * 2 + 16) ^ ((r & 7) << 4))) = v1;
  }
  {
    int n = tid >> 2, p0 = (tid & 3) * 16;
    const unsigned short* hr = gbuf + (size_t)blk2 * 4096 + (size_t)n * 64 + p0;
    u16x8 v0 = *(const u16x8*)hr;
    u16x8 v1 = *(const u16x8*)(hr + 8);
#pragma unroll
    for (int k = 0; k < 8; ++k) {
      int p = p0 + k;
      *(unsigned short*)((char*)HT + ((p * 128 + n * 2) ^ ((p & 7) << 4))) = v0[k];
      int p2 = p0 + 8 + k;
      *(unsigned short*)((char*)HT + ((p2 * 128 + n * 2) ^ ((p2 & 7) << 4))) = v1[k];
    }
  }
  if (tid < 64) cdl[tid] = cumbuf[(size_t)blk2 * 64 + tid];
  __syncthreads();

  f4v acc[4] = {};
#pragma unroll
  for (int ks = 0; ks < 64; ks += 32) {
    int kb = (ks >> 3) + (lane >> 4);
    int ra = wv * 16 + (lane & 15);
    bfrag af = *(const bfrag*)((const char*)Ct + ((ra * 128 + kb * 16) ^ ((ra & 7) << 4)));
#pragma unroll
    for (int j = 0; j < 4; ++j) {
      int rb = j * 16 + (lane & 15);
      bfrag bg = *(const bfrag*)((const char*)HT + ((rb * 128 + kb * 16) ^ ((rb & 7) << 4)));
      acc[j] = __builtin_amdgcn_mfma_f32_16x16x32_bf16(af, bg, acc[j], 0, 0, 0);
    }
  }
  __syncthreads();  // done reading Ct/HT

  // stage cdl-scaled correction into Ct space (bf16, row-swizzled [t][p])
  int trow = wv * 16 + ((lane >> 4) << 2);
#pragma unroll
  for (int j = 0; j < 4; ++j) {
    int p = j * 16 + (lane & 15);
#pragma unroll
    for (int r = 0; r < 4; ++r) {
      int t = trow + r;
      *(unsigned short*)((char*)Ct + ((t * 128 + p * 2) ^ ((t & 7) << 4))) = f2bf(cdl[t] * acc[j][r]);
    }
  }
  __syncthreads();

  // coalesced RMW
  {
    int r = tid >> 2, colq = (tid & 3) * 16;
    u16x8 c0v = *(const u16x8*)((const char*)Ct + ((r * 128 + colq * 2) ^ ((r & 7) << 4)));
    u16x8 c1v = *(const u16x8*)((const char*)Ct + ((r * 128 + colq * 2 + 16) ^ ((r & 7) << 4)));
    unsigned short* yp = y + ((size_t)(b * Ls + c0 + r)) * DI + h * 64 + colq;
    u16x8 y0 = *(const u16x8*)yp;
    u16x8 y1 = *(const u16x8*)(yp + 8);
#pragma unroll
    for (int k = 0; k < 8; ++k) {
      y0[k] = f2bf(bf2f(y0[k]) + bf2f(c0v[k]));
      y1[k] = f2bf(bf2f(y1[k]) + bf2f(c1v[k]));
    }
    *(u16x8*)yp = y0;
    *(u16x8*)(yp + 8) = y1;
  }
}
// ================================================================

// ---- both-direction gated RMSNorm: ybf[w] = 0.5*(gate_f(w) + gate_r(flip(w))) ----
__global__ __launch_bounds__(256) void k_gab(const unsigned short* __restrict__ yF,
    const unsigned short* __restrict__ yR, const unsigned short* __restrict__ zxb,
    const float* __restrict__ nwF, const float* __restrict__ nwR,
    const int* __restrict__ len, unsigned short* __restrict__ ybf) {
  int w = (blockIdx.x * 256 + threadIdx.x) >> 6;
  int lane = threadIdx.x & 63;
  if (w >= TOK) return;
  int t = w & (Ls - 1), b = w >> 10;
  int ln = len[b];
  int r = b * Ls + ((t < ln) ? (ln - 1 - t) : t);
  const unsigned short* yf = yF + (size_t)w * DI;
  const unsigned short* yr = yR + (size_t)r * DI;
  const unsigned short* zr = zxb + (size_t)w * NPJ;
  float gf[16], gr[16];
  float ssf = 0.f, ssr = 0.f;
#pragma unroll
  for (int q = 0; q < 4; ++q) {
    ushort4 yv = *(const ushort4*)(yf + lane * 4 + q * 256);
    ushort4 rv = *(const ushort4*)(yr + lane * 4 + q * 256);
    ushort4 zu = *(const ushort4*)(zr + lane * 4 + q * 256);
    float z0 = bf2f(zu.x), z1 = bf2f(zu.y), z2 = bf2f(zu.z), z3 = bf2f(zu.w);
    float s0 = z0 * sigmoidf_(z0), s1 = z1 * sigmoidf_(z1), s2 = z2 * sigmoidf_(z2), s3 = z3 * sigmoidf_(z3);
    gf[4 * q + 0] = bf2f(yv.x) * s0; gf[4 * q + 1] = bf2f(yv.y) * s1;
    gf[4 * q + 2] = bf2f(yv.z) * s2; gf[4 * q + 3] = bf2f(yv.w) * s3;
    gr[4 * q + 0] = bf2f(rv.x) * s0; gr[4 * q + 1] = bf2f(rv.y) * s1;
    gr[4 * q + 2] = bf2f(rv.z) * s2; gr[4 * q + 3] = bf2f(rv.w) * s3;
#pragma unroll
    for (int j = 0; j < 4; ++j) {
      ssf += gf[4 * q + j] * gf[4 * q + j];
      ssr += gr[4 * q + j] * gr[4 * q + j];
    }
  }
  ssf = wsum(ssf);
  ssr = wsum(ssr);
  float scf = 0.5f * rsqrtf(ssf * (1.f / (float)DI) + EPSf);
  float scr = 0.5f * rsqrtf(ssr * (1.f / (float)DI) + EPSf);
#pragma unroll
  for (int q = 0; q < 4; ++q) {
    float4 nf = *(const float4*)(nwF + lane * 4 + q * 256);
    float4 nr = *(const float4*)(nwR + lane * 4 + q * 256);
    float o0 = gf[4 * q + 0] * scf * nf.x + gr[4 * q + 0] * scr * nr.x;
    float o1 = gf[4 * q + 1] * scf * nf.y + gr[4 * q + 1] * scr * nr.y;
    float o2 = gf[4 * q + 2] * scf * nf.z + gr[4 * q + 2] * scr * nr.z;
    float o3 = gf[4 * q + 3] * scf * nf.w + gr[4 * q + 3] * scr * nr.w;
    *(ushort4*)(ybf + (size_t)w * DI + lane * 4 + q * 256) =
        make_ushort4(f2bf(o0), f2bf(o1), f2bf(o2), f2bf(o3));
  }
}

// ---- hnbf = LN(src) bf16 (heads input); rows t==0 also -> cell out (fp32) + cc0 ----
__global__ __launch_bounds__(256) void k_hl2(const float* __restrict__ src,
    unsigned short* __restrict__ dstbf, float* __restrict__ cellout, float* __restrict__ cc0) {
  int gw = (blockIdx.x * 256 + threadIdx.x) >> 6;
  int lane = threadIdx.x & 63;
  if (gw >= TOK) return;
  float x[8];
  ld8(src + (size_t)gw * DM, lane, x);
  norm8(x);
  st8bf(dstbf + (size_t)gw * DM, lane, x);
  if ((gw & (Ls - 1)) == 0) {
    int b = gw >> 10;
    st8(cellout + (size_t)b * DM, lane, x);
    st8(cc0 + (size_t)b * DM, lane, x);
  }
}

// ---- lengths ----
__global__ __launch_bounds__(256) void k_lengths(const unsigned char* __restrict__ mask, int* __restrict__ len) {
  int b = blockIdx.x;
  int tid = threadIdx.x;
  int cnt = 0;
  for (int t = tid; t < Ls; t += 256) cnt += mask[b * Ls + t] ? 0 : 1;
#pragma unroll
  for (int o = 32; o > 0; o >>= 1) cnt += __shfl_xor(cnt, o);
  __shared__ int red[4];
  if ((tid & 63) == 0) red[tid >> 6] = cnt;
  __syncthreads();
  if (tid == 0) len[b] = red[0] + red[1] + red[2] + red[3];
}

// ---- mlm head (bf16 input) ----
__global__ __launch_bounds__(256) void k_mlm(const unsigned short* __restrict__ e2,
                                             const float* __restrict__ w3,
                                             const float* __restrict__ b3, float* __restrict__ out) {
  int gw = (blockIdx.x * 256 + threadIdx.x) >> 6;
  int lane = threadIdx.x & 63;
  if (gw >= TOK) return;
  float x[8], w[8];
  ld8bf(e2 + (size_t)gw * DM, lane, x);
  ld8(w3, lane, w);
  float s = 0;
#pragma unroll
  for (int j = 0; j < 8; ++j) s += x[j] * w[j];
  s = wsum(s);
  if (lane == 0) out[gw] = s + b3[0];
}

// ---- classifier matvec (wave-per-output; optional LN+affine on input) ----
__global__ __launch_bounds__(256) void k_clsmv(const float* __restrict__ xin, size_t xstride,
    const float* __restrict__ g, const float* __restrict__ bb, int doLN,
    const float* __restrict__ W, const float* __restrict__ bias, int doRelu,
    float* __restrict__ out, int nout) {
  int b = blockIdx.y;
  int j = blockIdx.x * 4 + (threadIdx.x >> 6);
  int lane = threadIdx.x & 63;
  if (j >= nout) return;
  float x[8];
  ld8(xin + (size_t)b * xstride, lane, x);
  if (doLN) {
    norm8(x);
    float gv[8], bv[8];
    ld8(g, lane, gv); ld8(bb, lane, bv);
#pragma unroll
    for (int k = 0; k < 8; ++k) x[k] = x[k] * gv[k] + bv[k];
  }
  float w[8];
  ld8(W + (size_t)j * DM, lane, w);
  float s = 0;
#pragma unroll
  for (int k = 0; k < 8; ++k) s += x[k] * w[k];
  s = wsum(s);
  if (lane == 0) {
    float v = s + bias[j];
    if (doRelu) v = fmaxf(v, 0.f);
    out[(size_t)b * nout + j] = v;
  }
}

// ---- workspace layout (floats) ----
constexpr size_t F_H   = 0;
constexpr size_t F_DTF = F_H + (size_t)TOK * DM;
constexpr size_t F_LAF = F_DTF + (size_t)TOK * NH;
constexpr size_t F_DTR = F_LAF + (size_t)TOK * NH;
constexpr size_t F_LAR = F_DTR + (size_t)TOK * NH;
constexpr size_t F_ON  = F_LAR + (size_t)TOK * NH;
constexpr size_t F_CUM = F_ON + (size_t)TOK * DM;
constexpr size_t F_CC0 = F_CUM + (size_t)2 * Bb * NH * NCH * 64;
constexpr size_t F_CC1 = F_CC0 + Bb * DM;
constexpr size_t F_CC2 = F_CC1 + Bb * DM;
constexpr size_t F_LEN = F_CC2 + Bb * DM;
constexpr size_t F_END = F_LEN + 16;
// bf16 regions (ushort offsets)
constexpr size_t U0     = F_END * 2;
constexpr size_t UW_IN  = U0;
constexpr size_t UW_OUT = UW_IN + (size_t)2 * DIP * DM;
constexpr size_t UW_VE  = UW_OUT + (size_t)2 * DM * DI;
constexpr size_t UW_E1  = UW_VE + (size_t)DM * DM;
constexpr size_t UW_E2  = UW_E1 + (size_t)DM * DM;
constexpr size_t U_BFA  = UW_E2 + (size_t)DM * DM;   // v1 / e1-bf16
constexpr size_t U_HNBF = U_BFA + (size_t)TOK * DM;
constexpr size_t U_YBF  = U_HNBF + (size_t)TOK * DM;
constexpr size_t U_ZX   = U_YBF + (size_t)TOK * DI;   // bf16 zx (TOK*NPJ)
constexpr size_t U_YF   = U_ZX + (size_t)TOK * NPJ;   // bf16 y fwd
constexpr size_t U_YR   = U_YF + (size_t)TOK * DI;    // bf16 y rev
constexpr size_t U_G    = U_YR + (size_t)TOK * DI;    // bf16 G/hin (2*1024*4096)

extern "C" void kernel_launch(void* const* d_in, const int* in_sizes, int n_in,
                              void* d_out, int out_size, void* d_ws, size_t ws_size,
                              hipStream_t stream) {
  const int* src = (const int*)d_in[0];
  const float* values = (const float*)d_in[1];
  const unsigned char* mask = (const unsigned char*)d_in[2];
  const float* embed = (const float*)d_in[3];
  const float* ge_g = (const float*)d_in[4];
  const float* ge_b = (const float*)d_in[5];
  const float* ve_w1 = (const float*)d_in[6];
  const float* ve_b1 = (const float*)d_in[7];
  const float* ve_w2 = (const float*)d_in[8];
  const float* ve_b2 = (const float*)d_in[9];
  const float* ve_g = (const float*)d_in[10];
  const float* ve_bb = (const float*)d_in[11];
  const float* in_w = (const float*)d_in[12];
  const float* conv_w_f = (const float*)d_in[13];
  const float* conv_b_f = (const float*)d_in[14];
  const float* A_f = (const float*)d_in[15];
  const float* dtb_f = (const float*)d_in[16];
  const float* D_f = (const float*)d_in[17];
  const float* nw_f = (const float*)d_in[18];
  const float* conv_w_r = (const float*)d_in[19];
  const float* conv_b_r = (const float*)d_in[20];
  const float* A_r = (const float*)d_in[21];
  const float* dtb_r = (const float*)d_in[22];
  const float* D_r = (const float*)d_in[23];
  const float* nw_r = (const float*)d_in[24];
  const float* out_w = (const float*)d_in[25];
  const float* expr_w1 = (const float*)d_in[26];
  const float* expr_b1 = (const float*)d_in[27];
  const float* expr_w2 = (const float*)d_in[28];
  const float* expr_b2 = (const float*)d_in[29];
  const float* expr_w3 = (const float*)d_in[30];
  const float* expr_b3 = (const float*)d_in[31];
  const float* cls_w1 = (const float*)d_in[32];
  const float* cls_b1 = (const float*)d_in[33];
  const float* cls_g1 = (const float*)d_in[34];
  const float* cls_bb1 = (const float*)d_in[35];
  const float* cls_w2 = (const float*)d_in[36];
  const float* cls_b2 = (const float*)d_in[37];
  const float* cls_g2 = (const float*)d_in[38];
  const float* cls_bb2 = (const float*)d_in[39];
  const float* cls_wo = (const float*)d_in[40];
  const float* cls_bo = (const float*)d_in[41];

  float* ws = (float*)d_ws;
  unsigned short* wsu = (unsigned short*)d_ws;
  float* h = ws + F_H;
  float* dtf = ws + F_DTF;
  float* laf = ws + F_LAF;
  float* dtr = ws + F_DTR;
  float* lar = ws + F_LAR;
  float* onew = ws + F_ON;
  float* cumb = ws + F_CUM;
  float* cc0 = ws + F_CC0;
  float* cc1 = ws + F_CC1;
  float* cc2 = ws + F_CC2;
  int* len = (int*)(ws + F_LEN);
  unsigned short* w_in = wsu + UW_IN;
  unsigned short* w_out = wsu + UW_OUT;
  unsigned short* w_ve = wsu + UW_VE;
  unsigned short* w_e1 = wsu + UW_E1;
  unsigned short* w_e2 = wsu + UW_E2;
  unsigned short* bfa = wsu + U_BFA;
  unsigned short* hnbf = wsu + U_HNBF;
  unsigned short* ybf = wsu + U_YBF;
  unsigned short* zxb = wsu + U_ZX;
  unsigned short* yFb = wsu + U_YF;
  unsigned short* yRb = wsu + U_YR;
  unsigned short* gbuf = wsu + U_G;
  unsigned short* bcbuf = ybf;      // reuse: bcbuf (2*TOK*128) lives in ybf until gab writes it
  float* t2 = onew;                 // reuse before layers
  unsigned short* e2b = zxb;        // reuse after layers
  float* out = (float*)d_out;

  // ---- weight conversions (single launch) ----
  {
    int n0 = 2 * DIP * DM / 8, n1 = 2 * DM * DI / 8, n2 = DM * DM / 8, n3 = n2, n4 = n2;
    int tot = n0 + n1 + n2 + n3 + n4;
    k_w2bf5<<<(tot + 255) / 256, 256, 0, stream>>>(in_w, w_in, n0, out_w, w_out, n1,
                                                   ve_w2, w_ve, n2, expr_w1, w_e1, n3,
                                                   expr_w2, w_e2, n4);
  }

  // ---- embedding + value encoder ----
  k_embed<<<TOK / 4, 256, 0, stream>>>(src, values, embed, ge_g, ge_b, ve_w1, ve_b1, h, bfa);
  gemm_bf<0, 0><<<dim3(DM / 128, TOK / 128), 256, 0, stream>>>(bfa, w_ve, ve_b2, t2, TOK, DM, DM);
  k_haddv<<<TOK / 4, 256, 0, stream>>>(t2, ve_g, ve_bb, mask, h);
  k_lengths<<<Bb, 256, 0, stream>>>(mask, len);

  // ---- layers ----
  for (int i = 0; i < 2; ++i) {
    const float* inw = in_w + (size_t)i * DIP * DM;
    unsigned short* inwb = w_in + (size_t)i * DIP * DM;
    unsigned short* outwb = w_out + (size_t)i * DM * DI;
    const float* cwF = conv_w_f + (size_t)i * CDIM * 4;
    const float* cbF = conv_b_f + (size_t)i * CDIM;
    const float* cwR = conv_w_r + (size_t)i * CDIM * 4;
    const float* cbR = conv_b_r + (size_t)i * CDIM;
    const float* pre = (i == 0) ? h : onew;
    k_lndt<<<TOK / 4, 256, 0, stream>>>(pre, inw, dtb_f + i * NH, A_f + i * NH,
                                        dtb_r + i * NH, A_r + i * NH, len, hnbf,
                                        dtf, laf, dtr, lar);
    gemm_bf<0, 1><<<dim3(NPJ / 128, TOK / 128), 256, 0, stream>>>(hnbf, inwb, nullptr, zxb, TOK, NPJ, DM);
    k_convbc<<<(2 * TOK * 128) / 256, 256, 0, stream>>>(zxb, cwF, cbF, cwR, cbR, len, bcbuf);
    k_chunk<<<2 * Bb * NH * NCH, 256, 0, stream>>>(zxb, bcbuf, cwF, cbF, cwR, cbR,
        dtf, laf, dtr, lar, D_f + i * NH, D_r + i * NH, len, yFb, yRb, gbuf, cumb);
    k_chain<<<2 * 2 * Bb * NH, 256, 0, stream>>>(gbuf, cumb);
    k_corr<<<2 * Bb * NH * NCH, 256, 0, stream>>>(bcbuf, gbuf, cumb, yFb, yRb);
    k_gab<<<TOK / 4, 256, 0, stream>>>(yFb, yRb, zxb, nw_f + (size_t)i * DI, nw_r + (size_t)i * DI,
                                       len, ybf);
    gemm_bf<0, 0><<<dim3(DM / 128, TOK / 128), 256, 0, stream>>>(ybf, outwb, nullptr, onew, TOK, DM, DI);
  }

  // ---- heads ----
  k_hl2<<<TOK / 4, 256, 0, stream>>>(onew, hnbf, out + TOK, cc0);
  gemm_bf<2, 1><<<dim3(DM / 128, TOK / 128), 256, 0, stream>>>(hnbf, w_e1, expr_b1, bfa, TOK, DM, DM);
  gemm_bf<2, 1><<<dim3(DM / 128, TOK / 128), 256, 0, stream>>>(bfa, w_e2, expr_b2, e2b, TOK, DM, DM);
  k_mlm<<<TOK / 4, 256, 0, stream>>>(e2b, expr_w3, expr_b3, out);
  k_clsmv<<<dim3(128, Bb), 256, 0, stream>>>(cc0, DM, nullptr, nullptr, 0,
                                             cls_w1, cls_b1, 1, cc1, DM);
  k_clsmv<<<dim3(128, Bb), 256, 0, stream>>>(cc1, DM, cls_g1, cls_bb1, 1,
                                             cls_w2, cls_b2, 1, cc2, DM);
  k_clsmv<<<dim3(41, Bb), 256, 0, stream>>>(cc2, DM, cls_g2, cls_bb2, 1,
                                            cls_wo, cls_bo, 0, out + TOK + Bb * DM, 164);
}